// Round 2
// baseline (3490.644 us; speedup 1.0000x reference)
//
#include <hip/hip_runtime.h>
#include <math.h>

#define BB 2
#define SEQ 4096
#define DMODEL 768
#define DSTATE 128
#define NHH 24
#define HDIM 64
#define DSSM 1536
#define CDIM 1792
#define CHK 256
#define NC 16
#define DPROJ 3352
#define MR (BB*SEQ)

__device__ __forceinline__ float siluf(float x) { return x / (1.0f + expf(-x)); }

// ---------------- generic f32 GEMM: C(MxN) = A(MxK) @ B(NxK)^T + bias(N), act: 0=none 1=silu
__global__ __launch_bounds__(256) void gemm_nt(const float* __restrict__ A,
    const float* __restrict__ Bw, const float* __restrict__ bias,
    float* __restrict__ C, int M, int N, int K, int act)
{
    __shared__ float As[16][68];
    __shared__ float Bs[16][68];
    const int tx = threadIdx.x & 15, ty = threadIdx.x >> 4;
    const int m0 = blockIdx.y * 64, n0 = blockIdx.x * 64;
    float acc[4][4] = {{0.f}};
    for (int k0 = 0; k0 < K; k0 += 16) {
        for (int idx = threadIdx.x; idx < 1024; idx += 256) {
            int r = idx >> 4, kk = idx & 15;
            int m = m0 + r, n = n0 + r;
            As[kk][r] = (m < M) ? A[(size_t)m * K + k0 + kk] : 0.0f;
            Bs[kk][r] = (n < N) ? Bw[(size_t)n * K + k0 + kk] : 0.0f;
        }
        __syncthreads();
#pragma unroll
        for (int kk = 0; kk < 16; ++kk) {
            float4 a4 = *(const float4*)&As[kk][ty * 4];
            float4 b4 = *(const float4*)&Bs[kk][tx * 4];
            float av[4] = {a4.x, a4.y, a4.z, a4.w};
            float bv[4] = {b4.x, b4.y, b4.z, b4.w};
#pragma unroll
            for (int i = 0; i < 4; ++i)
#pragma unroll
                for (int j = 0; j < 4; ++j)
                    acc[i][j] = fmaf(av[i], bv[j], acc[i][j]);
        }
        __syncthreads();
    }
#pragma unroll
    for (int i = 0; i < 4; ++i) {
        int m = m0 + ty * 4 + i;
        if (m >= M) continue;
#pragma unroll
        for (int j = 0; j < 4; ++j) {
            int n = n0 + tx * 4 + j;
            if (n >= N) continue;
            float v = acc[i][j] + bias[n];
            if (act == 1) v = siluf(v);
            C[(size_t)m * N + n] = v;
        }
    }
}

// ---------------- depthwise causal conv (window 4) + silu over contiguous xBC buffer
__global__ __launch_bounds__(256) void conv_xbc_k(const float* __restrict__ xbc,
    const float* __restrict__ cw, const float* __restrict__ cb, float* __restrict__ out)
{
    int idx = blockIdx.x * 256 + threadIdx.x;
    if (idx >= MR * CDIM) return;
    int c = idx % CDIM;
    int row = idx / CDIM;          // b*SEQ + t
    int t = row % SEQ;
    float acc = cb[c];
#pragma unroll
    for (int k = 0; k < 4; ++k) {
        int tt = t + k - 3;
        if (tt >= 0) acc = fmaf(xbc[(size_t)(row + k - 3) * CDIM + c], cw[c * 4 + k], acc);
    }
    out[idx] = siluf(acc);
}

// ---------------- per-(b,h) row: tdt0 = ts*td; conv1+silu; conv2+silu
__global__ __launch_bounds__(256) void time_conv_k(const float* __restrict__ ts,
    const float* __restrict__ td, const float* __restrict__ w1, const float* __restrict__ b1,
    const float* __restrict__ w2, const float* __restrict__ b2, float* __restrict__ tdt)
{
    __shared__ float u0[SEQ];
    __shared__ float u1[SEQ];
    int row = blockIdx.x, h = row % NHH;
    const float* tsr = ts + (size_t)row * SEQ;
    const float* tdr = td + (size_t)row * SEQ;
    for (int i = threadIdx.x; i < SEQ; i += 256) u0[i] = tsr[i] * tdr[i];
    __syncthreads();
    float wa[4], wb[4];
#pragma unroll
    for (int k = 0; k < 4; ++k) { wa[k] = w1[h * 4 + k]; wb[k] = w2[h * 4 + k]; }
    float ba = b1[h], bbv = b2[h];
    for (int i = threadIdx.x; i < SEQ; i += 256) {
        float acc = ba;
#pragma unroll
        for (int k = 0; k < 4; ++k) { int tt = i + k - 3; if (tt >= 0) acc = fmaf(u0[tt], wa[k], acc); }
        u1[i] = siluf(acc);
    }
    __syncthreads();
    for (int i = threadIdx.x; i < SEQ; i += 256) {
        float acc = bbv;
#pragma unroll
        for (int k = 0; k < 4; ++k) { int tt = i + k - 3; if (tt >= 0) acc = fmaf(u1[tt], wb[k], acc); }
        tdt[(size_t)row * SEQ + i] = siluf(acc);
    }
}

// ---------------- dt_sp = softplus(dt * tdt^T + dt_bias)   (B,SEQ,NH)
__global__ __launch_bounds__(256) void dtsp_k(const float* __restrict__ dtraw,
    const float* __restrict__ tdt, const float* __restrict__ dt_bias, float* __restrict__ dtp)
{
    int idx = blockIdx.x * 256 + threadIdx.x;
    if (idx >= MR * NHH) return;
    int h = idx % NHH;
    int row = idx / NHH;           // b*SEQ + s
    int b = row / SEQ, s = row % SEQ;
    float x = dtraw[(size_t)row * NHH + h] * tdt[((size_t)(b * NHH + h)) * SEQ + s] + dt_bias[h];
    dtp[idx] = (x > 20.0f) ? x : log1pf(expf(x));
}

// ---------------- SSD: per-(b,c,h) chunk states (64 x 128) + alast
__global__ __launch_bounds__(256) void ssd_states_k(const float* __restrict__ xc,
    const float* __restrict__ dtp, const float* __restrict__ A_log,
    float* __restrict__ st, float* __restrict__ al)
{
    __shared__ float s_acs[256];
    __shared__ float s_coef[256];
    __shared__ float xs[64][64];
    __shared__ float bs[64][128];
    int blk = blockIdx.x;
    int h = blk % NHH, c = (blk / NHH) % NC, b = blk / (NHH * NC);
    int tid = threadIdx.x;
    size_t rowbase = (size_t)b * SEQ + c * CHK;
    float Ah = -expf(A_log[h]);
    float dtv = dtp[(rowbase + tid) * NHH + h];
    s_acs[tid] = Ah * dtv;
    __syncthreads();
    for (int off = 1; off < 256; off <<= 1) {
        float pv_ = (tid >= off) ? s_acs[tid - off] : 0.f;
        __syncthreads();
        s_acs[tid] += pv_;
        __syncthreads();
    }
    float alv = s_acs[255];
    s_coef[tid] = expf(alv - s_acs[tid]) * dtv;
    if (tid == 255) al[blk] = alv;
    __syncthreads();
    int p = tid >> 2, t4 = tid & 3;
    float acc[32];
#pragma unroll
    for (int j = 0; j < 32; ++j) acc[j] = 0.f;
    for (int z0 = 0; z0 < CHK; z0 += 64) {
        for (int idx = tid; idx < 64 * 64; idx += 256) {
            int zz = idx >> 6, pp = idx & 63;
            xs[zz][pp] = xc[(rowbase + z0 + zz) * CDIM + h * HDIM + pp];
        }
        for (int idx = tid; idx < 64 * 128; idx += 256) {
            int zz = idx >> 7, nn = idx & 127;
            bs[zz][nn] = xc[(rowbase + z0 + zz) * CDIM + DSSM + nn] * s_coef[z0 + zz];
        }
        __syncthreads();
        for (int zz = 0; zz < 64; ++zz) {
            float xv = xs[zz][p];
#pragma unroll
            for (int j = 0; j < 32; ++j)
                acc[j] = fmaf(xv, bs[zz][t4 + j * 4], acc[j]);
        }
        __syncthreads();
    }
    size_t base = (size_t)blk * (HDIM * DSTATE);
#pragma unroll
    for (int j = 0; j < 32; ++j)
        st[base + p * DSTATE + t4 + j * 4] = acc[j];
}

// ---------------- inter-chunk scan: prev[c] = running state before chunk c
__global__ __launch_bounds__(256) void ssd_scan_k(const float* __restrict__ st,
    const float* __restrict__ al, float* __restrict__ pv)
{
    int b = blockIdx.x / NHH, h = blockIdx.x % NHH;
    int tid = threadIdx.x;
    float carry[32];
#pragma unroll
    for (int j = 0; j < 32; ++j) carry[j] = 0.f;
    for (int c = 0; c < NC; ++c) {
        int bch = (b * NC + c) * NHH + h;
        size_t base = (size_t)bch * (HDIM * DSTATE);
        float dcy = expf(al[bch]);
#pragma unroll
        for (int j = 0; j < 32; ++j) {
            pv[base + tid + j * 256] = carry[j];
            carry[j] = fmaf(dcy, carry[j], st[base + tid + j * 256]);
        }
    }
}

// ---------------- per-(b,c,h,s-tile) Y: diag + off-chunk + D*x
__global__ __launch_bounds__(256) void ssd_y_k(const float* __restrict__ xc,
    const float* __restrict__ dtp, const float* __restrict__ A_log,
    const float* __restrict__ pv, const float* __restrict__ Dp,
    float* __restrict__ Y)
{
    __shared__ float s_acs[256];
    __shared__ float s_dt[256];
    __shared__ float Ct[64][132];
    __shared__ float Bt[64][132];
    __shared__ float Xt[64][68];
    __shared__ float Sm[64][68];
    int blk = blockIdx.x;
    int st_ = blk & 3;
    int h = (blk >> 2) % NHH;
    int c = (blk / (4 * NHH)) % NC;
    int b = blk / (4 * NHH * NC);
    int tid = threadIdx.x;
    int tx = tid & 15, ty = tid >> 4;
    size_t rowbase = (size_t)b * SEQ + c * CHK;
    float Ah = -expf(A_log[h]);
    float dtv = dtp[(rowbase + tid) * NHH + h];
    s_dt[tid] = dtv;
    s_acs[tid] = Ah * dtv;
    __syncthreads();
    for (int off = 1; off < 256; off <<= 1) {
        float t = (tid >= off) ? s_acs[tid - off] : 0.f;
        __syncthreads();
        s_acs[tid] += t;
        __syncthreads();
    }
    int s0 = st_ * 64;
    for (int idx = tid; idx < 64 * 128; idx += 256) {
        int r = idx >> 7, nn = idx & 127;
        Ct[r][nn] = xc[(rowbase + s0 + r) * CDIM + DSSM + DSTATE + nn];
    }
    float acc[4][4] = {{0.f}};
    for (int z0 = 0; z0 <= s0; z0 += 64) {
        for (int idx = tid; idx < 64 * 128; idx += 256) {
            int r = idx >> 7, nn = idx & 127;
            Bt[r][nn] = xc[(rowbase + z0 + r) * CDIM + DSSM + nn];
        }
        for (int idx = tid; idx < 64 * 64; idx += 256) {
            int r = idx >> 6, pp = idx & 63;
            Xt[r][pp] = xc[(rowbase + z0 + r) * CDIM + h * HDIM + pp];
        }
        __syncthreads();
        float sacc[4][4] = {{0.f}};
        for (int n4 = 0; n4 < 128; n4 += 4) {
            float4 cv[4], bv[4];
#pragma unroll
            for (int i = 0; i < 4; ++i) cv[i] = *(const float4*)&Ct[ty * 4 + i][n4];
#pragma unroll
            for (int j = 0; j < 4; ++j) bv[j] = *(const float4*)&Bt[tx * 4 + j][n4];
#pragma unroll
            for (int i = 0; i < 4; ++i)
#pragma unroll
                for (int j = 0; j < 4; ++j)
                    sacc[i][j] += cv[i].x * bv[j].x + cv[i].y * bv[j].y + cv[i].z * bv[j].z + cv[i].w * bv[j].w;
        }
#pragma unroll
        for (int i = 0; i < 4; ++i) {
            int s = s0 + ty * 4 + i;
#pragma unroll
            for (int j = 0; j < 4; ++j) {
                int z = z0 + tx * 4 + j;
                float v = 0.f;
                if (z <= s) v = sacc[i][j] * expf(s_acs[s] - s_acs[z]) * s_dt[z];
                Sm[ty * 4 + i][tx * 4 + j] = v;
            }
        }
        __syncthreads();
        for (int zz = 0; zz < 64; ++zz) {
            float4 xv = *(const float4*)&Xt[zz][tx * 4];
            float xa[4] = {xv.x, xv.y, xv.z, xv.w};
            float sv[4];
#pragma unroll
            for (int i = 0; i < 4; ++i) sv[i] = Sm[ty * 4 + i][zz];
#pragma unroll
            for (int i = 0; i < 4; ++i)
#pragma unroll
                for (int j = 0; j < 4; ++j)
                    acc[i][j] = fmaf(sv[i], xa[j], acc[i][j]);
        }
        __syncthreads();
    }
    // off-chunk: load prev(64p x 128n) into Bt
    size_t pbase = (size_t)(blk >> 2) * (HDIM * DSTATE);
    for (int idx = tid; idx < 64 * 128; idx += 256) {
        int r = idx >> 7, nn = idx & 127;
        Bt[r][nn] = pv[pbase + idx];
    }
    __syncthreads();
    {
        float gacc[4][4] = {{0.f}};
        for (int n4 = 0; n4 < 128; n4 += 4) {
            float4 cv[4], bv[4];
#pragma unroll
            for (int i = 0; i < 4; ++i) cv[i] = *(const float4*)&Ct[ty * 4 + i][n4];
#pragma unroll
            for (int j = 0; j < 4; ++j) bv[j] = *(const float4*)&Bt[tx * 4 + j][n4];
#pragma unroll
            for (int i = 0; i < 4; ++i)
#pragma unroll
                for (int j = 0; j < 4; ++j)
                    gacc[i][j] += cv[i].x * bv[j].x + cv[i].y * bv[j].y + cv[i].z * bv[j].z + cv[i].w * bv[j].w;
        }
#pragma unroll
        for (int i = 0; i < 4; ++i) {
            float e = expf(s_acs[s0 + ty * 4 + i]);
#pragma unroll
            for (int j = 0; j < 4; ++j)
                acc[i][j] = fmaf(e, gacc[i][j], acc[i][j]);
        }
    }
    float dph = Dp[h];
#pragma unroll
    for (int i = 0; i < 4; ++i) {
        int s = s0 + ty * 4 + i;
#pragma unroll
        for (int j = 0; j < 4; ++j) {
            int p = tx * 4 + j;
            float xv = xc[(rowbase + s) * CDIM + h * HDIM + p];
            Y[(rowbase + s) * DSSM + h * HDIM + p] = acc[i][j] + dph * xv;
        }
    }
}

// ---------------- gated RMS norm in place: y = (Y*silu(z)) * rsqrt(mean^2) * nw
__global__ __launch_bounds__(256) void rmsnorm_k(float* __restrict__ Y,
    const float* __restrict__ zbuf, const float* __restrict__ nw)
{
    __shared__ float red[8];
    int row = blockIdx.x;
    float* y = Y + (size_t)row * DSSM;
    const float* z = zbuf + (size_t)row * DSSM;
    float v[6];
    float ss = 0.f;
#pragma unroll
    for (int k = 0; k < 6; ++k) {
        int i = threadIdx.x + k * 256;
        float g = y[i] * siluf(z[i]);
        v[k] = g;
        ss = fmaf(g, g, ss);
    }
#pragma unroll
    for (int o = 32; o > 0; o >>= 1) ss += __shfl_down(ss, o, 64);
    int wv = threadIdx.x >> 6, ln = threadIdx.x & 63;
    if (ln == 0) red[wv] = ss;
    __syncthreads();
    float tot = red[0] + red[1] + red[2] + red[3];
    float sc = rsqrtf(tot / (float)DSSM + 1e-12f);
#pragma unroll
    for (int k = 0; k < 6; ++k) {
        int i = threadIdx.x + k * 256;
        y[i] = v[k] * sc * nw[i];
    }
}

// ---------------- time_out: gate + mix + LayerNorm over SEQ
__global__ __launch_bounds__(256) void timeout_k(const float* __restrict__ td,
    const float* __restrict__ tdt, const float* __restrict__ gw, const float* __restrict__ gb,
    const float* __restrict__ lnw, const float* __restrict__ lnb, float* __restrict__ out2)
{
    __shared__ float tm[SEQ];
    __shared__ float red[8];
    int row = blockIdx.x;
    const float* tdr = td + (size_t)row * SEQ;
    const float* tdtr = tdt + (size_t)row * SEQ;
    int wv = threadIdx.x >> 6, ln = threadIdx.x & 63;
    float part = 0.f;
    for (int i = threadIdx.x; i < SEQ; i += 256) part = fmaf(tdr[i], gw[i], part);
#pragma unroll
    for (int o = 32; o > 0; o >>= 1) part += __shfl_down(part, o, 64);
    if (ln == 0) red[wv] = part;
    __syncthreads();
    float dot = red[0] + red[1] + red[2] + red[3];
    float tg = 1.f / (1.f + expf(-(dot + gb[0])));
    __syncthreads();
    float sum = 0.f;
    for (int i = threadIdx.x; i < SEQ; i += 256) {
        float x = tg * tdr[i] + (1.f - tg) * tdtr[i];
        tm[i] = x;
        sum += x;
    }
#pragma unroll
    for (int o = 32; o > 0; o >>= 1) sum += __shfl_down(sum, o, 64);
    if (ln == 0) red[wv] = sum;
    __syncthreads();
    float mu = (red[0] + red[1] + red[2] + red[3]) / (float)SEQ;
    __syncthreads();
    float s2 = 0.f;
    for (int i = threadIdx.x; i < SEQ; i += 256) { float d = tm[i] - mu; s2 = fmaf(d, d, s2); }
#pragma unroll
    for (int o = 32; o > 0; o >>= 1) s2 += __shfl_down(s2, o, 64);
    if (ln == 0) red[wv] = s2;
    __syncthreads();
    float var = (red[0] + red[1] + red[2] + red[3]) / (float)SEQ;
    float inv = rsqrtf(var + 1e-12f);
    for (int i = threadIdx.x; i < SEQ; i += 256)
        out2[(size_t)row * SEQ + i] = (tm[i] - mu) * inv * lnw[i] + lnb[i];
}

extern "C" void kernel_launch(void* const* d_in, const int* in_sizes, int n_in,
                              void* d_out, int out_size, void* d_ws, size_t ws_size,
                              hipStream_t stream)
{
    const float* u      = (const float*)d_in[0];
    const float* td     = (const float*)d_in[1];
    const float* W_in   = (const float*)d_in[2];
    const float* b_in   = (const float*)d_in[3];
    const float* conv_w = (const float*)d_in[4];
    const float* conv_b = (const float*)d_in[5];
    const float* t1w    = (const float*)d_in[6];
    const float* t1b    = (const float*)d_in[7];
    const float* t2w    = (const float*)d_in[8];
    const float* t2b    = (const float*)d_in[9];
    const float* m1w    = (const float*)d_in[10];
    const float* m1b    = (const float*)d_in[11];
    const float* m2w    = (const float*)d_in[12];
    const float* m2b    = (const float*)d_in[13];
    const float* gw     = (const float*)d_in[14];
    const float* gb     = (const float*)d_in[15];
    const float* lnw    = (const float*)d_in[16];
    const float* lnb    = (const float*)d_in[17];
    const float* A_log  = (const float*)d_in[18];
    const float* dt_bias= (const float*)d_in[19];
    const float* Dpv    = (const float*)d_in[20];
    const float* nw     = (const float*)d_in[21];
    const float* W_out  = (const float*)d_in[22];
    const float* b_out  = (const float*)d_in[23];
    float* out  = (float*)d_out;
    float* out2 = out + (size_t)MR * DMODEL;

    // ---- workspace layout (49,218,304 floats = 187.8 MiB) ----
    float* ws = (float*)d_ws;
    size_t o = 0;
    float* zbuf  = ws + o; o += (size_t)MR * DSSM;          // 12,582,912  z slice (live till rmsnorm)
    float* r1    = ws + o; o += (size_t)MR * CDIM;          // 14,680,064  xBC_raw -> stb -> Yb
    float* xcv   = ws + o; o += (size_t)MR * CDIM;          // 14,680,064  conv output
    float* dtraw = ws + o; o += (size_t)MR * NHH;           //    196,608
    float* hid   = ws + o; o += (size_t)BB * NHH * SEQ;     //    196,608
    float* tss   = ws + o; o += (size_t)BB * NHH * SEQ;
    float* tdt   = ws + o; o += (size_t)BB * NHH * SEQ;
    float* dtp   = ws + o; o += (size_t)MR * NHH;
    float* pvb   = ws + o; o += (size_t)BB * NC * NHH * HDIM * DSTATE;  // 6,291,456
    float* alb   = ws + o; o += (size_t)BB * NC * NHH;      //        768
    // aliases into r1 (xBC_raw dead after conv; stb dead after scan):
    float* stb = r1;   // 6,291,456 used between ssd_states_k and ssd_scan_k
    float* Yb  = r1;   // 12,582,912 written by ssd_y_k

    dim3 blk(256);
    // 1: in-proj slices: xBC -> r1, z -> zbuf, dt -> dtraw
    gemm_nt<<<dim3((CDIM + 63) / 64, MR / 64), blk, 0, stream>>>(
        u, W_in + (size_t)DSSM * DMODEL, b_in + DSSM, r1, MR, CDIM, DMODEL, 0);
    // 2: causal depthwise conv + silu on xBC (r1 -> xcv); r1 dead after this
    conv_xbc_k<<<dim3((MR * CDIM + 255) / 256), blk, 0, stream>>>(r1, conv_w, conv_b, xcv);
    gemm_nt<<<dim3(DSSM / 64, MR / 64), blk, 0, stream>>>(
        u, W_in, b_in, zbuf, MR, DSSM, DMODEL, 0);
    gemm_nt<<<dim3(1, MR / 64), blk, 0, stream>>>(
        u, W_in + (size_t)(DSSM + CDIM) * DMODEL, b_in + DSSM + CDIM, dtraw, MR, NHH, DMODEL, 0);
    // 3: time MLP + elementwise + two causal convs
    gemm_nt<<<dim3(SEQ / 64, 1), blk, 0, stream>>>(td, m1w, m1b, hid, BB * NHH, SEQ, SEQ, 1);
    gemm_nt<<<dim3(SEQ / 64, 1), blk, 0, stream>>>(hid, m2w, m2b, tss, BB * NHH, SEQ, SEQ, 0);
    time_conv_k<<<dim3(BB * NHH), blk, 0, stream>>>(tss, td, t1w, t1b, t2w, t2b, tdt);
    // 4: dt softplus
    dtsp_k<<<dim3((MR * NHH + 255) / 256), blk, 0, stream>>>(dtraw, tdt, dt_bias, dtp);
    // 5: SSD
    ssd_states_k<<<dim3(BB * NC * NHH), blk, 0, stream>>>(xcv, dtp, A_log, stb, alb);
    ssd_scan_k<<<dim3(BB * NHH), blk, 0, stream>>>(stb, alb, pvb);
    ssd_y_k<<<dim3(BB * NC * NHH * 4), blk, 0, stream>>>(xcv, dtp, A_log, pvb, Dpv, Yb);
    // 6: gated RMS norm (in-place on Yb)
    rmsnorm_k<<<dim3(MR), blk, 0, stream>>>(Yb, zbuf, nw);
    // 7: out projection -> d_out
    gemm_nt<<<dim3((DMODEL + 63) / 64, MR / 64), blk, 0, stream>>>(Yb, W_out, b_out, out, MR, DMODEL, DSSM, 0);
    // 8: time_out -> d_out tail
    timeout_k<<<dim3(BB * NHH), blk, 0, stream>>>(td, tdt, gw, gb, lnw, lnb, out2);
}

// Round 3
// 2463.682 us; speedup vs baseline: 1.4168x; 1.4168x over previous
//
#include <hip/hip_runtime.h>
#include <math.h>

#define BB 2
#define SEQ 4096
#define DMODEL 768
#define DSTATE 128
#define NHH 24
#define HDIM 64
#define DSSM 1536
#define CDIM 1792
#define CHK 256
#define NC 16
#define DPROJ 3352
#define MR (BB*SEQ)

typedef __attribute__((ext_vector_type(8))) short bf16x8;
typedef __attribute__((ext_vector_type(4))) float f32x4;

__device__ __forceinline__ float siluf(float x) { return x / (1.0f + expf(-x)); }

__device__ __forceinline__ unsigned short f2bf(float f) {
    unsigned u = __float_as_uint(f);
    unsigned r = (u + 0x7fffu + ((u >> 16) & 1u)) >> 16;
    return (unsigned short)r;
}

__device__ __forceinline__ void gload_lds16(const void* g, void* l) {
    __builtin_amdgcn_global_load_lds((const __attribute__((address_space(1))) unsigned int*)g,
                                     (__attribute__((address_space(3))) unsigned int*)l, 16, 0, 0);
}

// ---------------- f32 -> bf16 conversion (vectorized)
__global__ __launch_bounds__(256) void cvt_bf16_k(const float* __restrict__ in,
    unsigned short* __restrict__ out, int n)
{
    int i = (blockIdx.x * 256 + threadIdx.x) * 4;
    if (i >= n) return;
    float4 v = *(const float4*)&in[i];
    ushort4 o;
    o.x = f2bf(v.x); o.y = f2bf(v.y); o.z = f2bf(v.z); o.w = f2bf(v.w);
    *(ushort4*)&out[i] = o;
}

// ---------------- bf16 MFMA GEMM: C(MxN) = A(MxK) @ B(NxK)^T + bias(N)
// 128x128 tile, 4 waves (2x2 of 64x64), 16x16x32 bf16 MFMA, K-step 32,
// global_load_lds(16B) staging, double-buffered LDS, 1 barrier/K-step.
// Requires: M%128==0, N%128==0, K%32==0.
__global__ __launch_bounds__(256) void gemm_mfma_nt(
    const unsigned short* __restrict__ A, const unsigned short* __restrict__ B,
    const float* __restrict__ bias, float* __restrict__ C, int N, int K, int KT)
{
    __shared__ unsigned short SA[2][128 * 32];
    __shared__ unsigned short SB[2][128 * 32];
    const int tid = threadIdx.x;
    const int w = tid >> 6, l = tid & 63;
    const int wr = w >> 1, wc = w & 1;
    const int lr = l & 15, lk = l >> 4;
    const int m0 = blockIdx.y * 128, n0 = blockIdx.x * 128;
    f32x4 acc[4][4] = {};
    const int i16 = w * 64 + l;                 // 0..255 (16B unit within half-tile)
    const int row0 = i16 >> 2, sl = i16 & 3;
    const size_t ga0 = (size_t)(m0 + row0) * K + sl * 8;
    const size_t ga1 = (size_t)(m0 + row0 + 64) * K + sl * 8;
    const size_t gb0 = (size_t)(n0 + row0) * K + sl * 8;
    const size_t gb1 = (size_t)(n0 + row0 + 64) * K + sl * 8;
    const int lo0 = (w * 64) * 8;               // wave-base LDS ushort offset, half 0
    const int lo1 = (256 + w * 64) * 8;         // half 1

#define STAGE(bb, kt) { int ko = (kt) * 32;                      \
      gload_lds16(A + ga0 + ko, &SA[bb][lo0]);                   \
      gload_lds16(A + ga1 + ko, &SA[bb][lo1]);                   \
      gload_lds16(B + gb0 + ko, &SB[bb][lo0]);                   \
      gload_lds16(B + gb1 + ko, &SB[bb][lo1]); }

    STAGE(0, 0);
    for (int kt = 0; kt < KT; ++kt) {
        int cur = kt & 1;
        asm volatile("s_waitcnt vmcnt(0)" ::: "memory");
        __syncthreads();
        if (kt + 1 < KT) STAGE(cur ^ 1, kt + 1);
        bf16x8 af[4], bg[4];
#pragma unroll
        for (int mi = 0; mi < 4; ++mi)
            af[mi] = *(const bf16x8*)&SA[cur][(wr * 64 + mi * 16 + lr) * 32 + lk * 8];
#pragma unroll
        for (int nj = 0; nj < 4; ++nj)
            bg[nj] = *(const bf16x8*)&SB[cur][(wc * 64 + nj * 16 + lr) * 32 + lk * 8];
#pragma unroll
        for (int mi = 0; mi < 4; ++mi)
#pragma unroll
            for (int nj = 0; nj < 4; ++nj)
                acc[mi][nj] = __builtin_amdgcn_mfma_f32_16x16x32_bf16(af[mi], bg[nj], acc[mi][nj], 0, 0, 0);
    }
#undef STAGE
#pragma unroll
    for (int nj = 0; nj < 4; ++nj) {
        int col = n0 + wc * 64 + nj * 16 + lr;
        float bz = bias[col];
#pragma unroll
        for (int mi = 0; mi < 4; ++mi) {
#pragma unroll
            for (int r = 0; r < 4; ++r) {
                int m = m0 + wr * 64 + mi * 16 + lk * 4 + r;
                C[(size_t)m * N + col] = acc[mi][nj][r] + bz;
            }
        }
    }
}

// ---------------- generic f32 GEMM (small shapes): C = A @ B^T + bias, act 1 = silu
__global__ __launch_bounds__(256) void gemm_nt(const float* __restrict__ A,
    const float* __restrict__ Bw, const float* __restrict__ bias,
    float* __restrict__ C, int M, int N, int K, int act)
{
    __shared__ float As[16][68];
    __shared__ float Bs[16][68];
    const int tx = threadIdx.x & 15, ty = threadIdx.x >> 4;
    const int m0 = blockIdx.y * 64, n0 = blockIdx.x * 64;
    float acc[4][4] = {{0.f}};
    for (int k0 = 0; k0 < K; k0 += 16) {
        for (int idx = threadIdx.x; idx < 1024; idx += 256) {
            int r = idx >> 4, kk = idx & 15;
            int m = m0 + r, n = n0 + r;
            As[kk][r] = (m < M) ? A[(size_t)m * K + k0 + kk] : 0.0f;
            Bs[kk][r] = (n < N) ? Bw[(size_t)n * K + k0 + kk] : 0.0f;
        }
        __syncthreads();
#pragma unroll
        for (int kk = 0; kk < 16; ++kk) {
            float4 a4 = *(const float4*)&As[kk][ty * 4];
            float4 b4 = *(const float4*)&Bs[kk][tx * 4];
            float av[4] = {a4.x, a4.y, a4.z, a4.w};
            float bv[4] = {b4.x, b4.y, b4.z, b4.w};
#pragma unroll
            for (int i = 0; i < 4; ++i)
#pragma unroll
                for (int j = 0; j < 4; ++j)
                    acc[i][j] = fmaf(av[i], bv[j], acc[i][j]);
        }
        __syncthreads();
    }
#pragma unroll
    for (int i = 0; i < 4; ++i) {
        int m = m0 + ty * 4 + i;
        if (m >= M) continue;
#pragma unroll
        for (int j = 0; j < 4; ++j) {
            int n = n0 + tx * 4 + j;
            if (n >= N) continue;
            float v = acc[i][j] + bias[n];
            if (act == 1) v = siluf(v);
            C[(size_t)m * N + n] = v;
        }
    }
}

// ---------------- depthwise causal conv (window 4) + silu over contiguous xBC buffer
__global__ __launch_bounds__(256) void conv_xbc_k(const float* __restrict__ xbc,
    const float* __restrict__ cw, const float* __restrict__ cb, float* __restrict__ out)
{
    int idx = blockIdx.x * 256 + threadIdx.x;
    if (idx >= MR * CDIM) return;
    int c = idx % CDIM;
    int row = idx / CDIM;
    int t = row % SEQ;
    float acc = cb[c];
#pragma unroll
    for (int k = 0; k < 4; ++k) {
        int tt = t + k - 3;
        if (tt >= 0) acc = fmaf(xbc[(size_t)(row + k - 3) * CDIM + c], cw[c * 4 + k], acc);
    }
    out[idx] = siluf(acc);
}

// ---------------- per-(b,h) row: tdt0 = ts*td; conv1+silu; conv2+silu
__global__ __launch_bounds__(256) void time_conv_k(const float* __restrict__ ts,
    const float* __restrict__ td, const float* __restrict__ w1, const float* __restrict__ b1,
    const float* __restrict__ w2, const float* __restrict__ b2, float* __restrict__ tdt)
{
    __shared__ float u0[SEQ];
    __shared__ float u1[SEQ];
    int row = blockIdx.x, h = row % NHH;
    const float* tsr = ts + (size_t)row * SEQ;
    const float* tdr = td + (size_t)row * SEQ;
    for (int i = threadIdx.x; i < SEQ; i += 256) u0[i] = tsr[i] * tdr[i];
    __syncthreads();
    float wa[4], wb[4];
#pragma unroll
    for (int k = 0; k < 4; ++k) { wa[k] = w1[h * 4 + k]; wb[k] = w2[h * 4 + k]; }
    float ba = b1[h], bbv = b2[h];
    for (int i = threadIdx.x; i < SEQ; i += 256) {
        float acc = ba;
#pragma unroll
        for (int k = 0; k < 4; ++k) { int tt = i + k - 3; if (tt >= 0) acc = fmaf(u0[tt], wa[k], acc); }
        u1[i] = siluf(acc);
    }
    __syncthreads();
    for (int i = threadIdx.x; i < SEQ; i += 256) {
        float acc = bbv;
#pragma unroll
        for (int k = 0; k < 4; ++k) { int tt = i + k - 3; if (tt >= 0) acc = fmaf(u1[tt], wb[k], acc); }
        tdt[(size_t)row * SEQ + i] = siluf(acc);
    }
}

// ---------------- dt_sp = softplus(dt * tdt^T + dt_bias)
__global__ __launch_bounds__(256) void dtsp_k(const float* __restrict__ dtraw,
    const float* __restrict__ tdt, const float* __restrict__ dt_bias, float* __restrict__ dtp)
{
    int idx = blockIdx.x * 256 + threadIdx.x;
    if (idx >= MR * NHH) return;
    int h = idx % NHH;
    int row = idx / NHH;
    int b = row / SEQ, s = row % SEQ;
    float x = dtraw[(size_t)row * NHH + h] * tdt[((size_t)(b * NHH + h)) * SEQ + s] + dt_bias[h];
    dtp[idx] = (x > 20.0f) ? x : log1pf(expf(x));
}

// ---------------- SSD: per-(b,c,h) chunk states (64 x 128) + alast
__global__ __launch_bounds__(256) void ssd_states_k(const float* __restrict__ xc,
    const float* __restrict__ dtp, const float* __restrict__ A_log,
    float* __restrict__ st, float* __restrict__ al)
{
    __shared__ float s_acs[256];
    __shared__ float s_coef[256];
    __shared__ float xs[64][64];
    __shared__ float bs[64][128];
    int blk = blockIdx.x;
    int h = blk % NHH, c = (blk / NHH) % NC, b = blk / (NHH * NC);
    int tid = threadIdx.x;
    size_t rowbase = (size_t)b * SEQ + c * CHK;
    float Ah = -expf(A_log[h]);
    float dtv = dtp[(rowbase + tid) * NHH + h];
    s_acs[tid] = Ah * dtv;
    __syncthreads();
    for (int off = 1; off < 256; off <<= 1) {
        float pv_ = (tid >= off) ? s_acs[tid - off] : 0.f;
        __syncthreads();
        s_acs[tid] += pv_;
        __syncthreads();
    }
    float alv = s_acs[255];
    s_coef[tid] = expf(alv - s_acs[tid]) * dtv;
    if (tid == 255) al[blk] = alv;
    __syncthreads();
    int p = tid >> 2, t4 = tid & 3;
    float acc[32];
#pragma unroll
    for (int j = 0; j < 32; ++j) acc[j] = 0.f;
    for (int z0 = 0; z0 < CHK; z0 += 64) {
        for (int idx = tid; idx < 64 * 64; idx += 256) {
            int zz = idx >> 6, pp = idx & 63;
            xs[zz][pp] = xc[(rowbase + z0 + zz) * CDIM + h * HDIM + pp];
        }
        for (int idx = tid; idx < 64 * 128; idx += 256) {
            int zz = idx >> 7, nn = idx & 127;
            bs[zz][nn] = xc[(rowbase + z0 + zz) * CDIM + DSSM + nn] * s_coef[z0 + zz];
        }
        __syncthreads();
        for (int zz = 0; zz < 64; ++zz) {
            float xv = xs[zz][p];
#pragma unroll
            for (int j = 0; j < 32; ++j)
                acc[j] = fmaf(xv, bs[zz][t4 + j * 4], acc[j]);
        }
        __syncthreads();
    }
    size_t base = (size_t)blk * (HDIM * DSTATE);
#pragma unroll
    for (int j = 0; j < 32; ++j)
        st[base + p * DSTATE + t4 + j * 4] = acc[j];
}

// ---------------- inter-chunk scan
__global__ __launch_bounds__(256) void ssd_scan_k(const float* __restrict__ st,
    const float* __restrict__ al, float* __restrict__ pv)
{
    int b = blockIdx.x / NHH, h = blockIdx.x % NHH;
    int tid = threadIdx.x;
    float carry[32];
#pragma unroll
    for (int j = 0; j < 32; ++j) carry[j] = 0.f;
    for (int c = 0; c < NC; ++c) {
        int bch = (b * NC + c) * NHH + h;
        size_t base = (size_t)bch * (HDIM * DSTATE);
        float dcy = expf(al[bch]);
#pragma unroll
        for (int j = 0; j < 32; ++j) {
            pv[base + tid + j * 256] = carry[j];
            carry[j] = fmaf(dcy, carry[j], st[base + tid + j * 256]);
        }
    }
}

// ---------------- per-(b,c,h,s-tile) Y: diag + off-chunk + D*x
__global__ __launch_bounds__(256) void ssd_y_k(const float* __restrict__ xc,
    const float* __restrict__ dtp, const float* __restrict__ A_log,
    const float* __restrict__ pv, const float* __restrict__ Dp,
    float* __restrict__ Y)
{
    __shared__ float s_acs[256];
    __shared__ float s_dt[256];
    __shared__ float Ct[64][132];
    __shared__ float Bt[64][132];
    __shared__ float Xt[64][68];
    __shared__ float Sm[64][68];
    int blk = blockIdx.x;
    int st_ = blk & 3;
    int h = (blk >> 2) % NHH;
    int c = (blk / (4 * NHH)) % NC;
    int b = blk / (4 * NHH * NC);
    int tid = threadIdx.x;
    int tx = tid & 15, ty = tid >> 4;
    size_t rowbase = (size_t)b * SEQ + c * CHK;
    float Ah = -expf(A_log[h]);
    float dtv = dtp[(rowbase + tid) * NHH + h];
    s_dt[tid] = dtv;
    s_acs[tid] = Ah * dtv;
    __syncthreads();
    for (int off = 1; off < 256; off <<= 1) {
        float t = (tid >= off) ? s_acs[tid - off] : 0.f;
        __syncthreads();
        s_acs[tid] += t;
        __syncthreads();
    }
    int s0 = st_ * 64;
    for (int idx = tid; idx < 64 * 128; idx += 256) {
        int r = idx >> 7, nn = idx & 127;
        Ct[r][nn] = xc[(rowbase + s0 + r) * CDIM + DSSM + DSTATE + nn];
    }
    float acc[4][4] = {{0.f}};
    for (int z0 = 0; z0 <= s0; z0 += 64) {
        for (int idx = tid; idx < 64 * 128; idx += 256) {
            int r = idx >> 7, nn = idx & 127;
            Bt[r][nn] = xc[(rowbase + z0 + r) * CDIM + DSSM + nn];
        }
        for (int idx = tid; idx < 64 * 64; idx += 256) {
            int r = idx >> 6, pp = idx & 63;
            Xt[r][pp] = xc[(rowbase + z0 + r) * CDIM + h * HDIM + pp];
        }
        __syncthreads();
        float sacc[4][4] = {{0.f}};
        for (int n4 = 0; n4 < 128; n4 += 4) {
            float4 cv[4], bv[4];
#pragma unroll
            for (int i = 0; i < 4; ++i) cv[i] = *(const float4*)&Ct[ty * 4 + i][n4];
#pragma unroll
            for (int j = 0; j < 4; ++j) bv[j] = *(const float4*)&Bt[tx * 4 + j][n4];
#pragma unroll
            for (int i = 0; i < 4; ++i)
#pragma unroll
                for (int j = 0; j < 4; ++j)
                    sacc[i][j] += cv[i].x * bv[j].x + cv[i].y * bv[j].y + cv[i].z * bv[j].z + cv[i].w * bv[j].w;
        }
#pragma unroll
        for (int i = 0; i < 4; ++i) {
            int s = s0 + ty * 4 + i;
#pragma unroll
            for (int j = 0; j < 4; ++j) {
                int z = z0 + tx * 4 + j;
                float v = 0.f;
                if (z <= s) v = sacc[i][j] * expf(s_acs[s] - s_acs[z]) * s_dt[z];
                Sm[ty * 4 + i][tx * 4 + j] = v;
            }
        }
        __syncthreads();
        for (int zz = 0; zz < 64; ++zz) {
            float4 xv = *(const float4*)&Xt[zz][tx * 4];
            float xa[4] = {xv.x, xv.y, xv.z, xv.w};
            float sv[4];
#pragma unroll
            for (int i = 0; i < 4; ++i) sv[i] = Sm[ty * 4 + i][zz];
#pragma unroll
            for (int i = 0; i < 4; ++i)
#pragma unroll
                for (int j = 0; j < 4; ++j)
                    acc[i][j] = fmaf(sv[i], xa[j], acc[i][j]);
        }
        __syncthreads();
    }
    size_t pbase = (size_t)(blk >> 2) * (HDIM * DSTATE);
    for (int idx = tid; idx < 64 * 128; idx += 256) {
        int r = idx >> 7, nn = idx & 127;
        Bt[r][nn] = pv[pbase + idx];
    }
    __syncthreads();
    {
        float gacc[4][4] = {{0.f}};
        for (int n4 = 0; n4 < 128; n4 += 4) {
            float4 cv[4], bv[4];
#pragma unroll
            for (int i = 0; i < 4; ++i) cv[i] = *(const float4*)&Ct[ty * 4 + i][n4];
#pragma unroll
            for (int j = 0; j < 4; ++j) bv[j] = *(const float4*)&Bt[tx * 4 + j][n4];
#pragma unroll
            for (int i = 0; i < 4; ++i)
#pragma unroll
                for (int j = 0; j < 4; ++j)
                    gacc[i][j] += cv[i].x * bv[j].x + cv[i].y * bv[j].y + cv[i].z * bv[j].z + cv[i].w * bv[j].w;
        }
#pragma unroll
        for (int i = 0; i < 4; ++i) {
            float e = expf(s_acs[s0 + ty * 4 + i]);
#pragma unroll
            for (int j = 0; j < 4; ++j)
                acc[i][j] = fmaf(e, gacc[i][j], acc[i][j]);
        }
    }
    float dph = Dp[h];
#pragma unroll
    for (int i = 0; i < 4; ++i) {
        int s = s0 + ty * 4 + i;
#pragma unroll
        for (int j = 0; j < 4; ++j) {
            int p = tx * 4 + j;
            float xv = xc[(rowbase + s) * CDIM + h * HDIM + p];
            Y[(rowbase + s) * DSSM + h * HDIM + p] = acc[i][j] + dph * xv;
        }
    }
}

// ---------------- gated RMS norm in place
__global__ __launch_bounds__(256) void rmsnorm_k(float* __restrict__ Y,
    const float* __restrict__ zbuf, const float* __restrict__ nw)
{
    __shared__ float red[8];
    int row = blockIdx.x;
    float* y = Y + (size_t)row * DSSM;
    const float* z = zbuf + (size_t)row * DSSM;
    float v[6];
    float ss = 0.f;
#pragma unroll
    for (int k = 0; k < 6; ++k) {
        int i = threadIdx.x + k * 256;
        float g = y[i] * siluf(z[i]);
        v[k] = g;
        ss = fmaf(g, g, ss);
    }
#pragma unroll
    for (int o = 32; o > 0; o >>= 1) ss += __shfl_down(ss, o, 64);
    int wv = threadIdx.x >> 6, ln = threadIdx.x & 63;
    if (ln == 0) red[wv] = ss;
    __syncthreads();
    float tot = red[0] + red[1] + red[2] + red[3];
    float sc = rsqrtf(tot / (float)DSSM + 1e-12f);
#pragma unroll
    for (int k = 0; k < 6; ++k) {
        int i = threadIdx.x + k * 256;
        y[i] = v[k] * sc * nw[i];
    }
}

// ---------------- time_out: gate + mix + LayerNorm over SEQ
__global__ __launch_bounds__(256) void timeout_k(const float* __restrict__ td,
    const float* __restrict__ tdt, const float* __restrict__ gw, const float* __restrict__ gb,
    const float* __restrict__ lnw, const float* __restrict__ lnb, float* __restrict__ out2)
{
    __shared__ float tm[SEQ];
    __shared__ float red[8];
    int row = blockIdx.x;
    const float* tdr = td + (size_t)row * SEQ;
    const float* tdtr = tdt + (size_t)row * SEQ;
    int wv = threadIdx.x >> 6, ln = threadIdx.x & 63;
    float part = 0.f;
    for (int i = threadIdx.x; i < SEQ; i += 256) part = fmaf(tdr[i], gw[i], part);
#pragma unroll
    for (int o = 32; o > 0; o >>= 1) part += __shfl_down(part, o, 64);
    if (ln == 0) red[wv] = part;
    __syncthreads();
    float dot = red[0] + red[1] + red[2] + red[3];
    float tg = 1.f / (1.f + expf(-(dot + gb[0])));
    __syncthreads();
    float sum = 0.f;
    for (int i = threadIdx.x; i < SEQ; i += 256) {
        float x = tg * tdr[i] + (1.f - tg) * tdtr[i];
        tm[i] = x;
        sum += x;
    }
#pragma unroll
    for (int o = 32; o > 0; o >>= 1) sum += __shfl_down(sum, o, 64);
    if (ln == 0) red[wv] = sum;
    __syncthreads();
    float mu = (red[0] + red[1] + red[2] + red[3]) / (float)SEQ;
    __syncthreads();
    float s2 = 0.f;
    for (int i = threadIdx.x; i < SEQ; i += 256) { float d = tm[i] - mu; s2 = fmaf(d, d, s2); }
#pragma unroll
    for (int o = 32; o > 0; o >>= 1) s2 += __shfl_down(s2, o, 64);
    if (ln == 0) red[wv] = s2;
    __syncthreads();
    float var = (red[0] + red[1] + red[2] + red[3]) / (float)SEQ;
    float inv = rsqrtf(var + 1e-12f);
    for (int i = threadIdx.x; i < SEQ; i += 256)
        out2[(size_t)row * SEQ + i] = (tm[i] - mu) * inv * lnw[i] + lnb[i];
}

extern "C" void kernel_launch(void* const* d_in, const int* in_sizes, int n_in,
                              void* d_out, int out_size, void* d_ws, size_t ws_size,
                              hipStream_t stream)
{
    const float* u      = (const float*)d_in[0];
    const float* td     = (const float*)d_in[1];
    const float* W_in   = (const float*)d_in[2];
    const float* b_in   = (const float*)d_in[3];
    const float* conv_w = (const float*)d_in[4];
    const float* conv_b = (const float*)d_in[5];
    const float* t1w    = (const float*)d_in[6];
    const float* t1b    = (const float*)d_in[7];
    const float* t2w    = (const float*)d_in[8];
    const float* t2b    = (const float*)d_in[9];
    const float* m1w    = (const float*)d_in[10];
    const float* m1b    = (const float*)d_in[11];
    const float* m2w    = (const float*)d_in[12];
    const float* m2b    = (const float*)d_in[13];
    const float* gw     = (const float*)d_in[14];
    const float* gb     = (const float*)d_in[15];
    const float* lnw    = (const float*)d_in[16];
    const float* lnb    = (const float*)d_in[17];
    const float* A_log  = (const float*)d_in[18];
    const float* dt_bias= (const float*)d_in[19];
    const float* Dpv    = (const float*)d_in[20];
    const float* nw     = (const float*)d_in[21];
    const float* W_out  = (const float*)d_in[22];
    const float* b_out  = (const float*)d_in[23];
    float* out  = (float*)d_out;
    float* out2 = out + (size_t)MR * DMODEL;

    // ---- workspace layout (49,218,304 floats = 187.8 MiB), same as round 2 ----
    float* ws = (float*)d_ws;
    size_t o = 0;
    float* zbuf  = ws + o; o += (size_t)MR * DSSM;          // z slice (live till rmsnorm); then Y_bf/Wo_bf
    float* r1    = ws + o; o += (size_t)MR * CDIM;          // xBC_raw -> stb -> Yb
    float* xcv   = ws + o; o += (size_t)MR * CDIM;          // conv output
    float* dtraw = ws + o; o += (size_t)MR * NHH;
    float* hid   = ws + o; o += (size_t)BB * NHH * SEQ;
    float* tss   = ws + o; o += (size_t)BB * NHH * SEQ;
    float* tdt   = ws + o; o += (size_t)BB * NHH * SEQ;
    float* dtp   = ws + o; o += (size_t)MR * NHH;
    float* pvb   = ws + o; o += (size_t)BB * NC * NHH * HDIM * DSTATE;  // prev states; early: u_bf/Wi_bf
    float* alb   = ws + o; o += (size_t)BB * NC * NHH;
    // aliases into r1:
    float* stb = r1;
    float* Yb  = r1;
    // bf16 aliases (dead-region reuse):
    unsigned short* u_bf  = (unsigned short*)pvb;                         // 6,291,456 sh
    unsigned short* Wi_bf = (unsigned short*)(pvb + 3145728);             // 3328*768 sh
    unsigned short* Y_bf  = (unsigned short*)zbuf;                        // 12,582,912 sh (after rmsnorm)
    unsigned short* Wo_bf = (unsigned short*)(zbuf + 6291456);            // 768*1536 sh

    dim3 blk(256);
    // 0: bf16 conversions for in-proj
    cvt_bf16_k<<<dim3((MR * DMODEL / 4 + 255) / 256), blk, 0, stream>>>(u, u_bf, MR * DMODEL);
    cvt_bf16_k<<<dim3((3328 * DMODEL / 4 + 255) / 256), blk, 0, stream>>>(W_in, Wi_bf, 3328 * DMODEL);
    // 1: in-proj slices via MFMA: xBC -> r1, z -> zbuf; dt via f32 gemm
    gemm_mfma_nt<<<dim3(CDIM / 128, MR / 128), blk, 0, stream>>>(
        u_bf, Wi_bf + (size_t)DSSM * DMODEL, b_in + DSSM, r1, CDIM, DMODEL, DMODEL / 32);
    conv_xbc_k<<<dim3((MR * CDIM + 255) / 256), blk, 0, stream>>>(r1, conv_w, conv_b, xcv);
    gemm_mfma_nt<<<dim3(DSSM / 128, MR / 128), blk, 0, stream>>>(
        u_bf, Wi_bf, b_in, zbuf, DSSM, DMODEL, DMODEL / 32);
    gemm_nt<<<dim3(1, MR / 64), blk, 0, stream>>>(
        u, W_in + (size_t)(DSSM + CDIM) * DMODEL, b_in + DSSM + CDIM, dtraw, MR, NHH, DMODEL, 0);
    // 3: time MLP + two causal convs
    gemm_nt<<<dim3(SEQ / 64, 1), blk, 0, stream>>>(td, m1w, m1b, hid, BB * NHH, SEQ, SEQ, 1);
    gemm_nt<<<dim3(SEQ / 64, 1), blk, 0, stream>>>(hid, m2w, m2b, tss, BB * NHH, SEQ, SEQ, 0);
    time_conv_k<<<dim3(BB * NHH), blk, 0, stream>>>(tss, td, t1w, t1b, t2w, t2b, tdt);
    // 4: dt softplus
    dtsp_k<<<dim3((MR * NHH + 255) / 256), blk, 0, stream>>>(dtraw, tdt, dt_bias, dtp);
    // 5: SSD
    ssd_states_k<<<dim3(BB * NC * NHH), blk, 0, stream>>>(xcv, dtp, A_log, stb, alb);
    ssd_scan_k<<<dim3(BB * NHH), blk, 0, stream>>>(stb, alb, pvb);
    ssd_y_k<<<dim3(BB * NC * NHH * 4), blk, 0, stream>>>(xcv, dtp, A_log, pvb, Dpv, Yb);
    // 6: gated RMS norm (in-place on Yb); zbuf dead after
    rmsnorm_k<<<dim3(MR), blk, 0, stream>>>(Yb, zbuf, nw);
    // 7: out projection via MFMA
    cvt_bf16_k<<<dim3((MR * DSSM / 4 + 255) / 256), blk, 0, stream>>>(Yb, Y_bf, MR * DSSM);
    cvt_bf16_k<<<dim3((DMODEL * DSSM / 4 + 255) / 256), blk, 0, stream>>>(W_out, Wo_bf, DMODEL * DSSM);
    gemm_mfma_nt<<<dim3(DMODEL / 128, MR / 128), blk, 0, stream>>>(
        Y_bf, Wo_bf, b_out, out, DMODEL, DSSM, DSSM / 32);
    // 8: time_out
    timeout_k<<<dim3(BB * NHH), blk, 0, stream>>>(td, tdt, gw, gb, lnw, lnb, out2);
}

// Round 4
// 1802.576 us; speedup vs baseline: 1.9365x; 1.3668x over previous
//
#include <hip/hip_runtime.h>
#include <math.h>

#define BB 2
#define SEQ 4096
#define DMODEL 768
#define DSTATE 128
#define NHH 24
#define HDIM 64
#define DSSM 1536
#define CDIM 1792
#define CHK 256
#define NC 16
#define DPROJ 3352
#define MR (BB*SEQ)

typedef __attribute__((ext_vector_type(8))) short bf16x8;
typedef __attribute__((ext_vector_type(4))) float f32x4;

__device__ __forceinline__ float siluf(float x) { return x / (1.0f + expf(-x)); }

__device__ __forceinline__ unsigned short f2bf(float f) {
    unsigned u = __float_as_uint(f);
    unsigned r = (u + 0x7fffu + ((u >> 16) & 1u)) >> 16;
    return (unsigned short)r;
}

__device__ __forceinline__ void gload_lds16(const void* g, void* l) {
    __builtin_amdgcn_global_load_lds((const __attribute__((address_space(1))) unsigned int*)g,
                                     (__attribute__((address_space(3))) unsigned int*)l, 16, 0, 0);
}

// ---------------- f32 -> bf16 conversion (vectorized)
__global__ __launch_bounds__(256) void cvt_bf16_k(const float* __restrict__ in,
    unsigned short* __restrict__ out, int n)
{
    int i = (blockIdx.x * 256 + threadIdx.x) * 4;
    if (i >= n) return;
    float4 v = *(const float4*)&in[i];
    ushort4 o;
    o.x = f2bf(v.x); o.y = f2bf(v.y); o.z = f2bf(v.z); o.w = f2bf(v.w);
    *(ushort4*)&out[i] = o;
}

// ---------------- bf16 MFMA GEMM: C(MxN) = A(MxK) @ B(NxK)^T + bias(N)
__global__ __launch_bounds__(256) void gemm_mfma_nt(
    const unsigned short* __restrict__ A, const unsigned short* __restrict__ B,
    const float* __restrict__ bias, float* __restrict__ C, int N, int K, int KT)
{
    __shared__ unsigned short SA[2][128 * 32];
    __shared__ unsigned short SB[2][128 * 32];
    const int tid = threadIdx.x;
    const int w = tid >> 6, l = tid & 63;
    const int wr = w >> 1, wc = w & 1;
    const int lr = l & 15, lk = l >> 4;
    const int m0 = blockIdx.y * 128, n0 = blockIdx.x * 128;
    f32x4 acc[4][4] = {};
    const int i16 = w * 64 + l;
    const int row0 = i16 >> 2, sl = i16 & 3;
    const size_t ga0 = (size_t)(m0 + row0) * K + sl * 8;
    const size_t ga1 = (size_t)(m0 + row0 + 64) * K + sl * 8;
    const size_t gb0 = (size_t)(n0 + row0) * K + sl * 8;
    const size_t gb1 = (size_t)(n0 + row0 + 64) * K + sl * 8;
    const int lo0 = (w * 64) * 8;
    const int lo1 = (256 + w * 64) * 8;

#define STAGE(bb, kt) { int ko = (kt) * 32;                      \
      gload_lds16(A + ga0 + ko, &SA[bb][lo0]);                   \
      gload_lds16(A + ga1 + ko, &SA[bb][lo1]);                   \
      gload_lds16(B + gb0 + ko, &SB[bb][lo0]);                   \
      gload_lds16(B + gb1 + ko, &SB[bb][lo1]); }

    STAGE(0, 0);
    for (int kt = 0; kt < KT; ++kt) {
        int cur = kt & 1;
        asm volatile("s_waitcnt vmcnt(0)" ::: "memory");
        __syncthreads();
        if (kt + 1 < KT) STAGE(cur ^ 1, kt + 1);
        bf16x8 af[4], bg[4];
#pragma unroll
        for (int mi = 0; mi < 4; ++mi)
            af[mi] = *(const bf16x8*)&SA[cur][(wr * 64 + mi * 16 + lr) * 32 + lk * 8];
#pragma unroll
        for (int nj = 0; nj < 4; ++nj)
            bg[nj] = *(const bf16x8*)&SB[cur][(wc * 64 + nj * 16 + lr) * 32 + lk * 8];
#pragma unroll
        for (int mi = 0; mi < 4; ++mi)
#pragma unroll
            for (int nj = 0; nj < 4; ++nj)
                acc[mi][nj] = __builtin_amdgcn_mfma_f32_16x16x32_bf16(af[mi], bg[nj], acc[mi][nj], 0, 0, 0);
    }
#undef STAGE
#pragma unroll
    for (int nj = 0; nj < 4; ++nj) {
        int col = n0 + wc * 64 + nj * 16 + lr;
        float bz = bias[col];
#pragma unroll
        for (int mi = 0; mi < 4; ++mi) {
#pragma unroll
            for (int r = 0; r < 4; ++r) {
                int m = m0 + wr * 64 + mi * 16 + lk * 4 + r;
                C[(size_t)m * N + col] = acc[mi][nj][r] + bz;
            }
        }
    }
}

// ---------------- generic f32 GEMM (small shapes)
__global__ __launch_bounds__(256) void gemm_nt(const float* __restrict__ A,
    const float* __restrict__ Bw, const float* __restrict__ bias,
    float* __restrict__ C, int M, int N, int K, int act)
{
    __shared__ float As[16][68];
    __shared__ float Bs[16][68];
    const int tx = threadIdx.x & 15, ty = threadIdx.x >> 4;
    const int m0 = blockIdx.y * 64, n0 = blockIdx.x * 64;
    float acc[4][4] = {{0.f}};
    for (int k0 = 0; k0 < K; k0 += 16) {
        for (int idx = threadIdx.x; idx < 1024; idx += 256) {
            int r = idx >> 4, kk = idx & 15;
            int m = m0 + r, n = n0 + r;
            As[kk][r] = (m < M) ? A[(size_t)m * K + k0 + kk] : 0.0f;
            Bs[kk][r] = (n < N) ? Bw[(size_t)n * K + k0 + kk] : 0.0f;
        }
        __syncthreads();
#pragma unroll
        for (int kk = 0; kk < 16; ++kk) {
            float4 a4 = *(const float4*)&As[kk][ty * 4];
            float4 b4 = *(const float4*)&Bs[kk][tx * 4];
            float av[4] = {a4.x, a4.y, a4.z, a4.w};
            float bv[4] = {b4.x, b4.y, b4.z, b4.w};
#pragma unroll
            for (int i = 0; i < 4; ++i)
#pragma unroll
                for (int j = 0; j < 4; ++j)
                    acc[i][j] = fmaf(av[i], bv[j], acc[i][j]);
        }
        __syncthreads();
    }
#pragma unroll
    for (int i = 0; i < 4; ++i) {
        int m = m0 + ty * 4 + i;
        if (m >= M) continue;
#pragma unroll
        for (int j = 0; j < 4; ++j) {
            int n = n0 + tx * 4 + j;
            if (n >= N) continue;
            float v = acc[i][j] + bias[n];
            if (act == 1) v = siluf(v);
            C[(size_t)m * N + n] = v;
        }
    }
}

// ---------------- depthwise causal conv (window 4) + silu
__global__ __launch_bounds__(256) void conv_xbc_k(const float* __restrict__ xbc,
    const float* __restrict__ cw, const float* __restrict__ cb, float* __restrict__ out)
{
    int idx = blockIdx.x * 256 + threadIdx.x;
    if (idx >= MR * CDIM) return;
    int c = idx % CDIM;
    int row = idx / CDIM;
    int t = row % SEQ;
    float acc = cb[c];
#pragma unroll
    for (int k = 0; k < 4; ++k) {
        int tt = t + k - 3;
        if (tt >= 0) acc = fmaf(xbc[(size_t)(row + k - 3) * CDIM + c], cw[c * 4 + k], acc);
    }
    out[idx] = siluf(acc);
}

// ---------------- per-(b,h) row: tdt0 = ts*td; conv1+silu; conv2+silu
__global__ __launch_bounds__(256) void time_conv_k(const float* __restrict__ ts,
    const float* __restrict__ td, const float* __restrict__ w1, const float* __restrict__ b1,
    const float* __restrict__ w2, const float* __restrict__ b2, float* __restrict__ tdt)
{
    __shared__ float u0[SEQ];
    __shared__ float u1[SEQ];
    int row = blockIdx.x, h = row % NHH;
    const float* tsr = ts + (size_t)row * SEQ;
    const float* tdr = td + (size_t)row * SEQ;
    for (int i = threadIdx.x; i < SEQ; i += 256) u0[i] = tsr[i] * tdr[i];
    __syncthreads();
    float wa[4], wb[4];
#pragma unroll
    for (int k = 0; k < 4; ++k) { wa[k] = w1[h * 4 + k]; wb[k] = w2[h * 4 + k]; }
    float ba = b1[h], bbv = b2[h];
    for (int i = threadIdx.x; i < SEQ; i += 256) {
        float acc = ba;
#pragma unroll
        for (int k = 0; k < 4; ++k) { int tt = i + k - 3; if (tt >= 0) acc = fmaf(u0[tt], wa[k], acc); }
        u1[i] = siluf(acc);
    }
    __syncthreads();
    for (int i = threadIdx.x; i < SEQ; i += 256) {
        float acc = bbv;
#pragma unroll
        for (int k = 0; k < 4; ++k) { int tt = i + k - 3; if (tt >= 0) acc = fmaf(u1[tt], wb[k], acc); }
        tdt[(size_t)row * SEQ + i] = siluf(acc);
    }
}

// ---------------- dt_sp = softplus(dt * tdt^T + dt_bias)
__global__ __launch_bounds__(256) void dtsp_k(const float* __restrict__ dtraw,
    const float* __restrict__ tdt, const float* __restrict__ dt_bias, float* __restrict__ dtp)
{
    int idx = blockIdx.x * 256 + threadIdx.x;
    if (idx >= MR * NHH) return;
    int h = idx % NHH;
    int row = idx / NHH;
    int b = row / SEQ, s = row % SEQ;
    float x = dtraw[(size_t)row * NHH + h] * tdt[((size_t)(b * NHH + h)) * SEQ + s] + dt_bias[h];
    dtp[idx] = (x > 20.0f) ? x : log1pf(expf(x));
}

// ---------------- SSD: per-(b,c,h) chunk states (64 x 128) + alast
__global__ __launch_bounds__(256) void ssd_states_k(const float* __restrict__ xc,
    const float* __restrict__ dtp, const float* __restrict__ A_log,
    float* __restrict__ st, float* __restrict__ al)
{
    __shared__ float s_acs[256];
    __shared__ float s_coef[256];
    __shared__ float xs[64][64];
    __shared__ float bs[64][128];
    int blk = blockIdx.x;
    int h = blk % NHH, c = (blk / NHH) % NC, b = blk / (NHH * NC);
    int tid = threadIdx.x;
    size_t rowbase = (size_t)b * SEQ + c * CHK;
    float Ah = -expf(A_log[h]);
    float dtv = dtp[(rowbase + tid) * NHH + h];
    s_acs[tid] = Ah * dtv;
    __syncthreads();
    for (int off = 1; off < 256; off <<= 1) {
        float pv_ = (tid >= off) ? s_acs[tid - off] : 0.f;
        __syncthreads();
        s_acs[tid] += pv_;
        __syncthreads();
    }
    float alv = s_acs[255];
    s_coef[tid] = expf(alv - s_acs[tid]) * dtv;
    if (tid == 255) al[blk] = alv;
    __syncthreads();
    int p = tid >> 2, t4 = tid & 3;
    float acc[32];
#pragma unroll
    for (int j = 0; j < 32; ++j) acc[j] = 0.f;
    for (int z0 = 0; z0 < CHK; z0 += 64) {
        for (int idx = tid; idx < 64 * 64; idx += 256) {
            int zz = idx >> 6, pp = idx & 63;
            xs[zz][pp] = xc[(rowbase + z0 + zz) * CDIM + h * HDIM + pp];
        }
        for (int idx = tid; idx < 64 * 128; idx += 256) {
            int zz = idx >> 7, nn = idx & 127;
            bs[zz][nn] = xc[(rowbase + z0 + zz) * CDIM + DSSM + nn] * s_coef[z0 + zz];
        }
        __syncthreads();
        for (int zz = 0; zz < 64; ++zz) {
            float xv = xs[zz][p];
#pragma unroll
            for (int j = 0; j < 32; ++j)
                acc[j] = fmaf(xv, bs[zz][t4 + j * 4], acc[j]);
        }
        __syncthreads();
    }
    size_t base = (size_t)blk * (HDIM * DSTATE);
#pragma unroll
    for (int j = 0; j < 32; ++j)
        st[base + p * DSTATE + t4 + j * 4] = acc[j];
}

// ---------------- inter-chunk scan
__global__ __launch_bounds__(256) void ssd_scan_k(const float* __restrict__ st,
    const float* __restrict__ al, float* __restrict__ pv)
{
    int b = blockIdx.x / NHH, h = blockIdx.x % NHH;
    int tid = threadIdx.x;
    float carry[32];
#pragma unroll
    for (int j = 0; j < 32; ++j) carry[j] = 0.f;
    for (int c = 0; c < NC; ++c) {
        int bch = (b * NC + c) * NHH + h;
        size_t base = (size_t)bch * (HDIM * DSTATE);
        float dcy = expf(al[bch]);
#pragma unroll
        for (int j = 0; j < 32; ++j) {
            pv[base + tid + j * 256] = carry[j];
            carry[j] = fmaf(dcy, carry[j], st[base + tid + j * 256]);
        }
    }
}

// ---------------- MFMA SSD-Y: per (b,c,h) block, 4 waves = 4 s-tiles of 64
// S = C.B^T (bf16 MFMA, K=128) -> mask*exp(acs[s]-acs[z])*dt[z] -> P (bf16, LDS)
// Y = P.X^T (K=64) + C.prev^T (K=128) * exp(acs[s]) + Dp*x
#define PCS 136   // padded row stride (ushorts) for 128-wide tiles
#define PXS 72    // padded row stride for 64-wide tiles
__global__ __launch_bounds__(256) void ssd_y_mfma_k(const float* __restrict__ xc,
    const float* __restrict__ dtp, const float* __restrict__ A_log,
    const float* __restrict__ pv, const float* __restrict__ Dp,
    float* __restrict__ Y)
{
    __shared__ float s_acs[256];
    __shared__ float s_dt[256];
    __shared__ unsigned short SC[256 * PCS];   // C tile 256x128
    __shared__ unsigned short SBz[64 * PCS];   // B z-tile / prev 64x128
    __shared__ unsigned short SXT[64 * PXS];   // X^T 64(p) x 64(z)
    __shared__ unsigned short SP[4][64 * PXS]; // per-wave masked P 64x64
    int blk = blockIdx.x;
    int h = blk % NHH;
    int tid = threadIdx.x;
    int w = tid >> 6, l = tid & 63;
    int lr = l & 15, lk = l >> 4;
    int b = blk / (NHH * NC);
    int c = (blk / NHH) % NC;
    size_t rowbase = (size_t)b * SEQ + c * CHK;
    float Ah = -expf(A_log[h]);
    float dtv = dtp[(rowbase + tid) * NHH + h];
    s_dt[tid] = dtv;
    s_acs[tid] = Ah * dtv;
    __syncthreads();
    for (int off = 1; off < 256; off <<= 1) {
        float t = (tid >= off) ? s_acs[tid - off] : 0.f;
        __syncthreads();
        s_acs[tid] += t;
        __syncthreads();
    }
    // stage C (256x128) -> bf16
    for (int i = tid; i < 256 * 32; i += 256) {
        int r = i >> 5, c4 = (i & 31) * 4;
        float4 v = *(const float4*)&xc[(rowbase + r) * CDIM + DSSM + DSTATE + c4];
        ushort4 o; o.x = f2bf(v.x); o.y = f2bf(v.y); o.z = f2bf(v.z); o.w = f2bf(v.w);
        *(ushort4*)&SC[r * PCS + c4] = o;
    }

    f32x4 acc[4][4] = {};
    for (int zt = 0; zt < 4; ++zt) {
        __syncthreads();   // protect SBz/SXT from previous iteration's readers
        // stage B z-tile (64x128)
        for (int i = tid; i < 64 * 32; i += 256) {
            int r = i >> 5, c4 = (i & 31) * 4;
            float4 v = *(const float4*)&xc[(rowbase + zt * 64 + r) * CDIM + DSSM + c4];
            ushort4 o; o.x = f2bf(v.x); o.y = f2bf(v.y); o.z = f2bf(v.z); o.w = f2bf(v.w);
            *(ushort4*)&SBz[r * PCS + c4] = o;
        }
        // stage X^T (p-major 64x64)
        for (int i = tid; i < 64 * 16; i += 256) {
            int z = i >> 4, p4 = (i & 15) * 4;
            float4 v = *(const float4*)&xc[(rowbase + zt * 64 + z) * CDIM + h * HDIM + p4];
            SXT[(p4 + 0) * PXS + z] = f2bf(v.x);
            SXT[(p4 + 1) * PXS + z] = f2bf(v.y);
            SXT[(p4 + 2) * PXS + z] = f2bf(v.z);
            SXT[(p4 + 3) * PXS + z] = f2bf(v.w);
        }
        __syncthreads();
        if (w >= zt) {
            // S = C_w . Bz^T   (64x64, K=128)
            f32x4 sfr[4][4] = {};
#pragma unroll
            for (int kk = 0; kk < 4; ++kk) {
                bf16x8 av[4], bv[4];
#pragma unroll
                for (int mi = 0; mi < 4; ++mi)
                    av[mi] = *(const bf16x8*)&SC[(w * 64 + mi * 16 + lr) * PCS + kk * 32 + lk * 8];
#pragma unroll
                for (int nj = 0; nj < 4; ++nj)
                    bv[nj] = *(const bf16x8*)&SBz[(nj * 16 + lr) * PCS + kk * 32 + lk * 8];
#pragma unroll
                for (int mi = 0; mi < 4; ++mi)
#pragma unroll
                    for (int nj = 0; nj < 4; ++nj)
                        sfr[mi][nj] = __builtin_amdgcn_mfma_f32_16x16x32_bf16(av[mi], bv[nj], sfr[mi][nj], 0, 0, 0);
            }
            // mask * exp(acs[s]-acs[z]) * dt[z] -> P (bf16 in LDS)
#pragma unroll
            for (int mi = 0; mi < 4; ++mi) {
#pragma unroll
                for (int nj = 0; nj < 4; ++nj) {
                    int zl = nj * 16 + lr;
                    float az = s_acs[zt * 64 + zl];
                    float dz = s_dt[zt * 64 + zl];
#pragma unroll
                    for (int r = 0; r < 4; ++r) {
                        int sl = mi * 16 + lk * 4 + r;
                        float v = 0.f;
                        if (zt < w || zt * 64 + zl <= w * 64 + sl)
                            v = sfr[mi][nj][r] * expf(s_acs[w * 64 + sl] - az) * dz;
                        SP[w][sl * PXS + zl] = f2bf(v);
                    }
                }
            }
            // Y += P . X^T   (64x64, K=64)
#pragma unroll
            for (int kk = 0; kk < 2; ++kk) {
                bf16x8 av[4], bv[4];
#pragma unroll
                for (int mi = 0; mi < 4; ++mi)
                    av[mi] = *(const bf16x8*)&SP[w][(mi * 16 + lr) * PXS + kk * 32 + lk * 8];
#pragma unroll
                for (int nj = 0; nj < 4; ++nj)
                    bv[nj] = *(const bf16x8*)&SXT[(nj * 16 + lr) * PXS + kk * 32 + lk * 8];
#pragma unroll
                for (int mi = 0; mi < 4; ++mi)
#pragma unroll
                    for (int nj = 0; nj < 4; ++nj)
                        acc[mi][nj] = __builtin_amdgcn_mfma_f32_16x16x32_bf16(av[mi], bv[nj], acc[mi][nj], 0, 0, 0);
            }
        }
    }
    // off-chunk: Yoff = C . prev^T * exp(acs[s])
    __syncthreads();
    const float* pvbase = pv + (size_t)blk * (HDIM * DSTATE);
    for (int i = tid; i < 64 * 32; i += 256) {
        int r = i >> 5, c4 = (i & 31) * 4;
        float4 v = *(const float4*)&pvbase[r * DSTATE + c4];
        ushort4 o; o.x = f2bf(v.x); o.y = f2bf(v.y); o.z = f2bf(v.z); o.w = f2bf(v.w);
        *(ushort4*)&SBz[r * PCS + c4] = o;
    }
    __syncthreads();
    {
        f32x4 g[4][4] = {};
#pragma unroll
        for (int kk = 0; kk < 4; ++kk) {
            bf16x8 av[4], bv[4];
#pragma unroll
            for (int mi = 0; mi < 4; ++mi)
                av[mi] = *(const bf16x8*)&SC[(w * 64 + mi * 16 + lr) * PCS + kk * 32 + lk * 8];
#pragma unroll
            for (int nj = 0; nj < 4; ++nj)
                bv[nj] = *(const bf16x8*)&SBz[(nj * 16 + lr) * PCS + kk * 32 + lk * 8];
#pragma unroll
            for (int mi = 0; mi < 4; ++mi)
#pragma unroll
                for (int nj = 0; nj < 4; ++nj)
                    g[mi][nj] = __builtin_amdgcn_mfma_f32_16x16x32_bf16(av[mi], bv[nj], g[mi][nj], 0, 0, 0);
        }
#pragma unroll
        for (int mi = 0; mi < 4; ++mi) {
#pragma unroll
            for (int r = 0; r < 4; ++r) {
                float e = expf(s_acs[w * 64 + mi * 16 + lk * 4 + r]);
#pragma unroll
                for (int nj = 0; nj < 4; ++nj)
                    acc[mi][nj][r] = fmaf(e, g[mi][nj][r], acc[mi][nj][r]);
            }
        }
    }
    // store + D*x
    float dph = Dp[h];
#pragma unroll
    for (int mi = 0; mi < 4; ++mi) {
#pragma unroll
        for (int r = 0; r < 4; ++r) {
            int s = w * 64 + mi * 16 + lk * 4 + r;
#pragma unroll
            for (int nj = 0; nj < 4; ++nj) {
                int p = nj * 16 + lr;
                float xv = xc[(rowbase + s) * CDIM + h * HDIM + p];
                Y[(rowbase + s) * DSSM + h * HDIM + p] = acc[mi][nj][r] + dph * xv;
            }
        }
    }
}

// ---------------- gated RMS norm in place
__global__ __launch_bounds__(256) void rmsnorm_k(float* __restrict__ Y,
    const float* __restrict__ zbuf, const float* __restrict__ nw)
{
    __shared__ float red[8];
    int row = blockIdx.x;
    float* y = Y + (size_t)row * DSSM;
    const float* z = zbuf + (size_t)row * DSSM;
    float v[6];
    float ss = 0.f;
#pragma unroll
    for (int k = 0; k < 6; ++k) {
        int i = threadIdx.x + k * 256;
        float g = y[i] * siluf(z[i]);
        v[k] = g;
        ss = fmaf(g, g, ss);
    }
#pragma unroll
    for (int o = 32; o > 0; o >>= 1) ss += __shfl_down(ss, o, 64);
    int wv = threadIdx.x >> 6, ln = threadIdx.x & 63;
    if (ln == 0) red[wv] = ss;
    __syncthreads();
    float tot = red[0] + red[1] + red[2] + red[3];
    float sc = rsqrtf(tot / (float)DSSM + 1e-12f);
#pragma unroll
    for (int k = 0; k < 6; ++k) {
        int i = threadIdx.x + k * 256;
        y[i] = v[k] * sc * nw[i];
    }
}

// ---------------- time_out: gate + mix + LayerNorm over SEQ
__global__ __launch_bounds__(256) void timeout_k(const float* __restrict__ td,
    const float* __restrict__ tdt, const float* __restrict__ gw, const float* __restrict__ gb,
    const float* __restrict__ lnw, const float* __restrict__ lnb, float* __restrict__ out2)
{
    __shared__ float tm[SEQ];
    __shared__ float red[8];
    int row = blockIdx.x;
    const float* tdr = td + (size_t)row * SEQ;
    const float* tdtr = tdt + (size_t)row * SEQ;
    int wv = threadIdx.x >> 6, ln = threadIdx.x & 63;
    float part = 0.f;
    for (int i = threadIdx.x; i < SEQ; i += 256) part = fmaf(tdr[i], gw[i], part);
#pragma unroll
    for (int o = 32; o > 0; o >>= 1) part += __shfl_down(part, o, 64);
    if (ln == 0) red[wv] = part;
    __syncthreads();
    float dot = red[0] + red[1] + red[2] + red[3];
    float tg = 1.f / (1.f + expf(-(dot + gb[0])));
    __syncthreads();
    float sum = 0.f;
    for (int i = threadIdx.x; i < SEQ; i += 256) {
        float x = tg * tdr[i] + (1.f - tg) * tdtr[i];
        tm[i] = x;
        sum += x;
    }
#pragma unroll
    for (int o = 32; o > 0; o >>= 1) sum += __shfl_down(sum, o, 64);
    if (ln == 0) red[wv] = sum;
    __syncthreads();
    float mu = (red[0] + red[1] + red[2] + red[3]) / (float)SEQ;
    __syncthreads();
    float s2 = 0.f;
    for (int i = threadIdx.x; i < SEQ; i += 256) { float d = tm[i] - mu; s2 = fmaf(d, d, s2); }
#pragma unroll
    for (int o = 32; o > 0; o >>= 1) s2 += __shfl_down(s2, o, 64);
    if (ln == 0) red[wv] = s2;
    __syncthreads();
    float var = (red[0] + red[1] + red[2] + red[3]) / (float)SEQ;
    float inv = rsqrtf(var + 1e-12f);
    for (int i = threadIdx.x; i < SEQ; i += 256)
        out2[(size_t)row * SEQ + i] = (tm[i] - mu) * inv * lnw[i] + lnb[i];
}

extern "C" void kernel_launch(void* const* d_in, const int* in_sizes, int n_in,
                              void* d_out, int out_size, void* d_ws, size_t ws_size,
                              hipStream_t stream)
{
    const float* u      = (const float*)d_in[0];
    const float* td     = (const float*)d_in[1];
    const float* W_in   = (const float*)d_in[2];
    const float* b_in   = (const float*)d_in[3];
    const float* conv_w = (const float*)d_in[4];
    const float* conv_b = (const float*)d_in[5];
    const float* t1w    = (const float*)d_in[6];
    const float* t1b    = (const float*)d_in[7];
    const float* t2w    = (const float*)d_in[8];
    const float* t2b    = (const float*)d_in[9];
    const float* m1w    = (const float*)d_in[10];
    const float* m1b    = (const float*)d_in[11];
    const float* m2w    = (const float*)d_in[12];
    const float* m2b    = (const float*)d_in[13];
    const float* gw     = (const float*)d_in[14];
    const float* gb     = (const float*)d_in[15];
    const float* lnw    = (const float*)d_in[16];
    const float* lnb    = (const float*)d_in[17];
    const float* A_log  = (const float*)d_in[18];
    const float* dt_bias= (const float*)d_in[19];
    const float* Dpv    = (const float*)d_in[20];
    const float* nw     = (const float*)d_in[21];
    const float* W_out  = (const float*)d_in[22];
    const float* b_out  = (const float*)d_in[23];
    float* out  = (float*)d_out;
    float* out2 = out + (size_t)MR * DMODEL;

    float* ws = (float*)d_ws;
    size_t o = 0;
    float* zbuf  = ws + o; o += (size_t)MR * DSSM;
    float* r1    = ws + o; o += (size_t)MR * CDIM;
    float* xcv   = ws + o; o += (size_t)MR * CDIM;
    float* dtraw = ws + o; o += (size_t)MR * NHH;
    float* hid   = ws + o; o += (size_t)BB * NHH * SEQ;
    float* tss   = ws + o; o += (size_t)BB * NHH * SEQ;
    float* tdt   = ws + o; o += (size_t)BB * NHH * SEQ;
    float* dtp   = ws + o; o += (size_t)MR * NHH;
    float* pvb   = ws + o; o += (size_t)BB * NC * NHH * HDIM * DSTATE;
    float* alb   = ws + o; o += (size_t)BB * NC * NHH;
    float* stb = r1;
    float* Yb  = r1;
    unsigned short* u_bf  = (unsigned short*)pvb;
    unsigned short* Wi_bf = (unsigned short*)(pvb + 3145728);
    unsigned short* Y_bf  = (unsigned short*)zbuf;
    unsigned short* Wo_bf = (unsigned short*)(zbuf + 6291456);

    dim3 blk(256);
    cvt_bf16_k<<<dim3((MR * DMODEL / 4 + 255) / 256), blk, 0, stream>>>(u, u_bf, MR * DMODEL);
    cvt_bf16_k<<<dim3((3328 * DMODEL / 4 + 255) / 256), blk, 0, stream>>>(W_in, Wi_bf, 3328 * DMODEL);
    gemm_mfma_nt<<<dim3(CDIM / 128, MR / 128), blk, 0, stream>>>(
        u_bf, Wi_bf + (size_t)DSSM * DMODEL, b_in + DSSM, r1, CDIM, DMODEL, DMODEL / 32);
    conv_xbc_k<<<dim3((MR * CDIM + 255) / 256), blk, 0, stream>>>(r1, conv_w, conv_b, xcv);
    gemm_mfma_nt<<<dim3(DSSM / 128, MR / 128), blk, 0, stream>>>(
        u_bf, Wi_bf, b_in, zbuf, DSSM, DMODEL, DMODEL / 32);
    gemm_nt<<<dim3(1, MR / 64), blk, 0, stream>>>(
        u, W_in + (size_t)(DSSM + CDIM) * DMODEL, b_in + DSSM + CDIM, dtraw, MR, NHH, DMODEL, 0);
    gemm_nt<<<dim3(SEQ / 64, 1), blk, 0, stream>>>(td, m1w, m1b, hid, BB * NHH, SEQ, SEQ, 1);
    gemm_nt<<<dim3(SEQ / 64, 1), blk, 0, stream>>>(hid, m2w, m2b, tss, BB * NHH, SEQ, SEQ, 0);
    time_conv_k<<<dim3(BB * NHH), blk, 0, stream>>>(tss, td, t1w, t1b, t2w, t2b, tdt);
    dtsp_k<<<dim3((MR * NHH + 255) / 256), blk, 0, stream>>>(dtraw, tdt, dt_bias, dtp);
    ssd_states_k<<<dim3(BB * NC * NHH), blk, 0, stream>>>(xcv, dtp, A_log, stb, alb);
    ssd_scan_k<<<dim3(BB * NHH), blk, 0, stream>>>(stb, alb, pvb);
    ssd_y_mfma_k<<<dim3(BB * NC * NHH), blk, 0, stream>>>(xcv, dtp, A_log, pvb, Dpv, Yb);
    rmsnorm_k<<<dim3(MR), blk, 0, stream>>>(Yb, zbuf, nw);
    cvt_bf16_k<<<dim3((MR * DSSM / 4 + 255) / 256), blk, 0, stream>>>(Yb, Y_bf, MR * DSSM);
    cvt_bf16_k<<<dim3((DMODEL * DSSM / 4 + 255) / 256), blk, 0, stream>>>(W_out, Wo_bf, DMODEL * DSSM);
    gemm_mfma_nt<<<dim3(DMODEL / 128, MR / 128), blk, 0, stream>>>(
        Y_bf, Wo_bf, b_out, out, DMODEL, DSSM, DSSM / 32);
    timeout_k<<<dim3(BB * NHH), blk, 0, stream>>>(td, tdt, gw, gb, lnw, lnb, out2);
}

// Round 5
// 820.579 us; speedup vs baseline: 4.2539x; 2.1967x over previous
//
#include <hip/hip_runtime.h>
#include <math.h>

#define BB 2
#define SEQ 4096
#define DMODEL 768
#define DSTATE 128
#define NHH 24
#define HDIM 64
#define DSSM 1536
#define CDIM 1792
#define CHK 256
#define NC 16
#define DPROJ 3352
#define MR (BB*SEQ)
#define KSPLIT 16

typedef __attribute__((ext_vector_type(8))) short bf16x8;
typedef __attribute__((ext_vector_type(4))) float f32x4;

__device__ __forceinline__ float siluf(float x) { return x / (1.0f + expf(-x)); }

__device__ __forceinline__ unsigned short f2bf(float f) {
    unsigned u = __float_as_uint(f);
    unsigned r = (u + 0x7fffu + ((u >> 16) & 1u)) >> 16;
    return (unsigned short)r;
}

__device__ __forceinline__ void gload_lds16(const void* g, void* l) {
    __builtin_amdgcn_global_load_lds((const __attribute__((address_space(1))) unsigned int*)g,
                                     (__attribute__((address_space(3))) unsigned int*)l, 16, 0, 0);
}

// ---------------- f32 -> bf16 conversion (vectorized)
__global__ __launch_bounds__(256) void cvt_bf16_k(const float* __restrict__ in,
    unsigned short* __restrict__ out, int n)
{
    int i = (blockIdx.x * 256 + threadIdx.x) * 4;
    if (i >= n) return;
    float4 v = *(const float4*)&in[i];
    ushort4 o;
    o.x = f2bf(v.x); o.y = f2bf(v.y); o.z = f2bf(v.z); o.w = f2bf(v.w);
    *(ushort4*)&out[i] = o;
}

// ---------------- bf16 MFMA GEMM: C(MxN) = A(MxK) @ B(NxK)^T + bias(N)
__global__ __launch_bounds__(256) void gemm_mfma_nt(
    const unsigned short* __restrict__ A, const unsigned short* __restrict__ B,
    const float* __restrict__ bias, float* __restrict__ C, int N, int K, int KT)
{
    __shared__ unsigned short SA[2][128 * 32];
    __shared__ unsigned short SB[2][128 * 32];
    const int tid = threadIdx.x;
    const int w = tid >> 6, l = tid & 63;
    const int wr = w >> 1, wc = w & 1;
    const int lr = l & 15, lk = l >> 4;
    const int m0 = blockIdx.y * 128, n0 = blockIdx.x * 128;
    f32x4 acc[4][4] = {};
    const int i16 = w * 64 + l;
    const int row0 = i16 >> 2, sl = i16 & 3;
    const size_t ga0 = (size_t)(m0 + row0) * K + sl * 8;
    const size_t ga1 = (size_t)(m0 + row0 + 64) * K + sl * 8;
    const size_t gb0 = (size_t)(n0 + row0) * K + sl * 8;
    const size_t gb1 = (size_t)(n0 + row0 + 64) * K + sl * 8;
    const int lo0 = (w * 64) * 8;
    const int lo1 = (256 + w * 64) * 8;

#define STAGE(bb, kt) { int ko = (kt) * 32;                      \
      gload_lds16(A + ga0 + ko, &SA[bb][lo0]);                   \
      gload_lds16(A + ga1 + ko, &SA[bb][lo1]);                   \
      gload_lds16(B + gb0 + ko, &SB[bb][lo0]);                   \
      gload_lds16(B + gb1 + ko, &SB[bb][lo1]); }

    STAGE(0, 0);
    for (int kt = 0; kt < KT; ++kt) {
        int cur = kt & 1;
        asm volatile("s_waitcnt vmcnt(0)" ::: "memory");
        __syncthreads();
        if (kt + 1 < KT) STAGE(cur ^ 1, kt + 1);
        bf16x8 af[4], bg[4];
#pragma unroll
        for (int mi = 0; mi < 4; ++mi)
            af[mi] = *(const bf16x8*)&SA[cur][(wr * 64 + mi * 16 + lr) * 32 + lk * 8];
#pragma unroll
        for (int nj = 0; nj < 4; ++nj)
            bg[nj] = *(const bf16x8*)&SB[cur][(wc * 64 + nj * 16 + lr) * 32 + lk * 8];
#pragma unroll
        for (int mi = 0; mi < 4; ++mi)
#pragma unroll
            for (int nj = 0; nj < 4; ++nj)
                acc[mi][nj] = __builtin_amdgcn_mfma_f32_16x16x32_bf16(af[mi], bg[nj], acc[mi][nj], 0, 0, 0);
    }
#undef STAGE
#pragma unroll
    for (int nj = 0; nj < 4; ++nj) {
        int col = n0 + wc * 64 + nj * 16 + lr;
        float bz = bias[col];
#pragma unroll
        for (int mi = 0; mi < 4; ++mi) {
#pragma unroll
            for (int r = 0; r < 4; ++r) {
                int m = m0 + wr * 64 + mi * 16 + lk * 4 + r;
                C[(size_t)m * N + col] = acc[mi][nj][r] + bz;
            }
        }
    }
}

// ---------------- generic f32 GEMM (small shapes)
__global__ __launch_bounds__(256) void gemm_nt(const float* __restrict__ A,
    const float* __restrict__ Bw, const float* __restrict__ bias,
    float* __restrict__ C, int M, int N, int K, int act)
{
    __shared__ float As[16][68];
    __shared__ float Bs[16][68];
    const int tx = threadIdx.x & 15, ty = threadIdx.x >> 4;
    const int m0 = blockIdx.y * 64, n0 = blockIdx.x * 64;
    float acc[4][4] = {{0.f}};
    for (int k0 = 0; k0 < K; k0 += 16) {
        for (int idx = threadIdx.x; idx < 1024; idx += 256) {
            int r = idx >> 4, kk = idx & 15;
            int m = m0 + r, n = n0 + r;
            As[kk][r] = (m < M) ? A[(size_t)m * K + k0 + kk] : 0.0f;
            Bs[kk][r] = (n < N) ? Bw[(size_t)n * K + k0 + kk] : 0.0f;
        }
        __syncthreads();
#pragma unroll
        for (int kk = 0; kk < 16; ++kk) {
            float4 a4 = *(const float4*)&As[kk][ty * 4];
            float4 b4 = *(const float4*)&Bs[kk][tx * 4];
            float av[4] = {a4.x, a4.y, a4.z, a4.w};
            float bv[4] = {b4.x, b4.y, b4.z, b4.w};
#pragma unroll
            for (int i = 0; i < 4; ++i)
#pragma unroll
                for (int j = 0; j < 4; ++j)
                    acc[i][j] = fmaf(av[i], bv[j], acc[i][j]);
        }
        __syncthreads();
    }
#pragma unroll
    for (int i = 0; i < 4; ++i) {
        int m = m0 + ty * 4 + i;
        if (m >= M) continue;
#pragma unroll
        for (int j = 0; j < 4; ++j) {
            int n = n0 + tx * 4 + j;
            if (n >= N) continue;
            float v = acc[i][j] + bias[n];
            if (act == 1) v = siluf(v);
            C[(size_t)m * N + n] = v;
        }
    }
}

// ---------------- split-K skinny GEMM: part[kb] = A(48xKS) @ B(128xKS)^T per block
// M fixed = 48. Grid: (N/128, KSPLIT). KS = K/KSPLIT.
__global__ __launch_bounds__(256) void gemm_skinny_nt(const float* __restrict__ A,
    const float* __restrict__ Bw, float* __restrict__ part, int N, int K)
{
    __shared__ float sA[32][49];
    __shared__ float sB[32][133];
    const int nb = blockIdx.x, kb = blockIdx.y;
    const int n0 = nb * 128;
    const int KS = K / KSPLIT;
    const int k0 = kb * KS;
    const int tid = threadIdx.x;
    const int tx = tid & 31, ty = tid >> 5;
    float acc[6][4] = {{0.f}};
    for (int kc = 0; kc < KS; kc += 32) {
        for (int i = tid; i < 48 * 32; i += 256) {
            int m = i >> 5, kk = i & 31;
            sA[kk][m] = A[(size_t)m * K + k0 + kc + kk];
        }
        for (int i = tid; i < 128 * 32; i += 256) {
            int n = i >> 5, kk = i & 31;
            sB[kk][n] = Bw[(size_t)(n0 + n) * K + k0 + kc + kk];
        }
        __syncthreads();
#pragma unroll 4
        for (int kk = 0; kk < 32; ++kk) {
            float a[6], b[4];
#pragma unroll
            for (int r = 0; r < 6; ++r) a[r] = sA[kk][ty * 6 + r];
#pragma unroll
            for (int j = 0; j < 4; ++j) b[j] = sB[kk][tx * 4 + j];
#pragma unroll
            for (int r = 0; r < 6; ++r)
#pragma unroll
                for (int j = 0; j < 4; ++j)
                    acc[r][j] = fmaf(a[r], b[j], acc[r][j]);
        }
        __syncthreads();
    }
    float* pb = part + (size_t)kb * 48 * N;
#pragma unroll
    for (int r = 0; r < 6; ++r)
#pragma unroll
        for (int j = 0; j < 4; ++j)
            pb[(size_t)(ty * 6 + r) * N + n0 + tx * 4 + j] = acc[r][j];
}

// ---------------- reduce split-K partials + bias (+ optional silu)
__global__ __launch_bounds__(256) void reduce_part_k(const float* __restrict__ part,
    const float* __restrict__ bias, float* __restrict__ out, int N, int act)
{
    int idx = blockIdx.x * 256 + threadIdx.x;
    if (idx >= 48 * N) return;
    int n = idx % N;
    float s = bias[n];
#pragma unroll
    for (int kb = 0; kb < KSPLIT; ++kb) s += part[(size_t)kb * 48 * N + idx];
    if (act) s = siluf(s);
    out[idx] = s;
}

// ---------------- depthwise causal conv (window 4) + silu
__global__ __launch_bounds__(256) void conv_xbc_k(const float* __restrict__ xbc,
    const float* __restrict__ cw, const float* __restrict__ cb, float* __restrict__ out)
{
    int idx = blockIdx.x * 256 + threadIdx.x;
    if (idx >= MR * CDIM) return;
    int c = idx % CDIM;
    int row = idx / CDIM;
    int t = row % SEQ;
    float acc = cb[c];
#pragma unroll
    for (int k = 0; k < 4; ++k) {
        int tt = t + k - 3;
        if (tt >= 0) acc = fmaf(xbc[(size_t)(row + k - 3) * CDIM + c], cw[c * 4 + k], acc);
    }
    out[idx] = siluf(acc);
}

// ---------------- per-(b,h) row: tdt0 = ts*td; conv1+silu; conv2+silu
__global__ __launch_bounds__(256) void time_conv_k(const float* __restrict__ ts,
    const float* __restrict__ td, const float* __restrict__ w1, const float* __restrict__ b1,
    const float* __restrict__ w2, const float* __restrict__ b2, float* __restrict__ tdt)
{
    __shared__ float u0[SEQ];
    __shared__ float u1[SEQ];
    int row = blockIdx.x, h = row % NHH;
    const float* tsr = ts + (size_t)row * SEQ;
    const float* tdr = td + (size_t)row * SEQ;
    for (int i = threadIdx.x; i < SEQ; i += 256) u0[i] = tsr[i] * tdr[i];
    __syncthreads();
    float wa[4], wb[4];
#pragma unroll
    for (int k = 0; k < 4; ++k) { wa[k] = w1[h * 4 + k]; wb[k] = w2[h * 4 + k]; }
    float ba = b1[h], bbv = b2[h];
    for (int i = threadIdx.x; i < SEQ; i += 256) {
        float acc = ba;
#pragma unroll
        for (int k = 0; k < 4; ++k) { int tt = i + k - 3; if (tt >= 0) acc = fmaf(u0[tt], wa[k], acc); }
        u1[i] = siluf(acc);
    }
    __syncthreads();
    for (int i = threadIdx.x; i < SEQ; i += 256) {
        float acc = bbv;
#pragma unroll
        for (int k = 0; k < 4; ++k) { int tt = i + k - 3; if (tt >= 0) acc = fmaf(u1[tt], wb[k], acc); }
        tdt[(size_t)row * SEQ + i] = siluf(acc);
    }
}

// ---------------- dt_sp = softplus(dt * tdt^T + dt_bias)
__global__ __launch_bounds__(256) void dtsp_k(const float* __restrict__ dtraw,
    const float* __restrict__ tdt, const float* __restrict__ dt_bias, float* __restrict__ dtp)
{
    int idx = blockIdx.x * 256 + threadIdx.x;
    if (idx >= MR * NHH) return;
    int h = idx % NHH;
    int row = idx / NHH;
    int b = row / SEQ, s = row % SEQ;
    float x = dtraw[(size_t)row * NHH + h] * tdt[((size_t)(b * NHH + h)) * SEQ + s] + dt_bias[h];
    dtp[idx] = (x > 20.0f) ? x : log1pf(expf(x));
}

// ---------------- SSD: per-(b,c,h) chunk states (64 x 128) + alast
__global__ __launch_bounds__(256) void ssd_states_k(const float* __restrict__ xc,
    const float* __restrict__ dtp, const float* __restrict__ A_log,
    float* __restrict__ st, float* __restrict__ al)
{
    __shared__ float s_acs[256];
    __shared__ float s_coef[256];
    __shared__ float xs[64][64];
    __shared__ float bs[64][128];
    int blk = blockIdx.x;
    int h = blk % NHH, c = (blk / NHH) % NC, b = blk / (NHH * NC);
    int tid = threadIdx.x;
    size_t rowbase = (size_t)b * SEQ + c * CHK;
    float Ah = -expf(A_log[h]);
    float dtv = dtp[(rowbase + tid) * NHH + h];
    s_acs[tid] = Ah * dtv;
    __syncthreads();
    for (int off = 1; off < 256; off <<= 1) {
        float pv_ = (tid >= off) ? s_acs[tid - off] : 0.f;
        __syncthreads();
        s_acs[tid] += pv_;
        __syncthreads();
    }
    float alv = s_acs[255];
    s_coef[tid] = expf(alv - s_acs[tid]) * dtv;
    if (tid == 255) al[blk] = alv;
    __syncthreads();
    int p = tid >> 2, t4 = tid & 3;
    float acc[32];
#pragma unroll
    for (int j = 0; j < 32; ++j) acc[j] = 0.f;
    for (int z0 = 0; z0 < CHK; z0 += 64) {
        for (int idx = tid; idx < 64 * 64; idx += 256) {
            int zz = idx >> 6, pp = idx & 63;
            xs[zz][pp] = xc[(rowbase + z0 + zz) * CDIM + h * HDIM + pp];
        }
        for (int idx = tid; idx < 64 * 128; idx += 256) {
            int zz = idx >> 7, nn = idx & 127;
            bs[zz][nn] = xc[(rowbase + z0 + zz) * CDIM + DSSM + nn] * s_coef[z0 + zz];
        }
        __syncthreads();
        for (int zz = 0; zz < 64; ++zz) {
            float xv = xs[zz][p];
#pragma unroll
            for (int j = 0; j < 32; ++j)
                acc[j] = fmaf(xv, bs[zz][t4 + j * 4], acc[j]);
        }
        __syncthreads();
    }
    size_t base = (size_t)blk * (HDIM * DSTATE);
#pragma unroll
    for (int j = 0; j < 32; ++j)
        st[base + p * DSTATE + t4 + j * 4] = acc[j];
}

// ---------------- inter-chunk scan
__global__ __launch_bounds__(256) void ssd_scan_k(const float* __restrict__ st,
    const float* __restrict__ al, float* __restrict__ pv)
{
    int b = blockIdx.x / NHH, h = blockIdx.x % NHH;
    int tid = threadIdx.x;
    float carry[32];
#pragma unroll
    for (int j = 0; j < 32; ++j) carry[j] = 0.f;
    for (int c = 0; c < NC; ++c) {
        int bch = (b * NC + c) * NHH + h;
        size_t base = (size_t)bch * (HDIM * DSTATE);
        float dcy = expf(al[bch]);
#pragma unroll
        for (int j = 0; j < 32; ++j) {
            pv[base + tid + j * 256] = carry[j];
            carry[j] = fmaf(dcy, carry[j], st[base + tid + j * 256]);
        }
    }
}

// ---------------- MFMA SSD-Y
#define PCS 136
#define PXS 72
__global__ __launch_bounds__(256) void ssd_y_mfma_k(const float* __restrict__ xc,
    const float* __restrict__ dtp, const float* __restrict__ A_log,
    const float* __restrict__ pv, const float* __restrict__ Dp,
    float* __restrict__ Y)
{
    __shared__ float s_acs[256];
    __shared__ float s_dt[256];
    __shared__ unsigned short SC[256 * PCS];
    __shared__ unsigned short SBz[64 * PCS];
    __shared__ unsigned short SXT[64 * PXS];
    __shared__ unsigned short SP[4][64 * PXS];
    int blk = blockIdx.x;
    int h = blk % NHH;
    int tid = threadIdx.x;
    int w = tid >> 6, l = tid & 63;
    int lr = l & 15, lk = l >> 4;
    int b = blk / (NHH * NC);
    int c = (blk / NHH) % NC;
    size_t rowbase = (size_t)b * SEQ + c * CHK;
    float Ah = -expf(A_log[h]);
    float dtv = dtp[(rowbase + tid) * NHH + h];
    s_dt[tid] = dtv;
    s_acs[tid] = Ah * dtv;
    __syncthreads();
    for (int off = 1; off < 256; off <<= 1) {
        float t = (tid >= off) ? s_acs[tid - off] : 0.f;
        __syncthreads();
        s_acs[tid] += t;
        __syncthreads();
    }
    for (int i = tid; i < 256 * 32; i += 256) {
        int r = i >> 5, c4 = (i & 31) * 4;
        float4 v = *(const float4*)&xc[(rowbase + r) * CDIM + DSSM + DSTATE + c4];
        ushort4 o; o.x = f2bf(v.x); o.y = f2bf(v.y); o.z = f2bf(v.z); o.w = f2bf(v.w);
        *(ushort4*)&SC[r * PCS + c4] = o;
    }

    f32x4 acc[4][4] = {};
    for (int zt = 0; zt < 4; ++zt) {
        __syncthreads();
        for (int i = tid; i < 64 * 32; i += 256) {
            int r = i >> 5, c4 = (i & 31) * 4;
            float4 v = *(const float4*)&xc[(rowbase + zt * 64 + r) * CDIM + DSSM + c4];
            ushort4 o; o.x = f2bf(v.x); o.y = f2bf(v.y); o.z = f2bf(v.z); o.w = f2bf(v.w);
            *(ushort4*)&SBz[r * PCS + c4] = o;
        }
        for (int i = tid; i < 64 * 16; i += 256) {
            int z = i >> 4, p4 = (i & 15) * 4;
            float4 v = *(const float4*)&xc[(rowbase + zt * 64 + z) * CDIM + h * HDIM + p4];
            SXT[(p4 + 0) * PXS + z] = f2bf(v.x);
            SXT[(p4 + 1) * PXS + z] = f2bf(v.y);
            SXT[(p4 + 2) * PXS + z] = f2bf(v.z);
            SXT[(p4 + 3) * PXS + z] = f2bf(v.w);
        }
        __syncthreads();
        if (w >= zt) {
            f32x4 sfr[4][4] = {};
#pragma unroll
            for (int kk = 0; kk < 4; ++kk) {
                bf16x8 av[4], bv[4];
#pragma unroll
                for (int mi = 0; mi < 4; ++mi)
                    av[mi] = *(const bf16x8*)&SC[(w * 64 + mi * 16 + lr) * PCS + kk * 32 + lk * 8];
#pragma unroll
                for (int nj = 0; nj < 4; ++nj)
                    bv[nj] = *(const bf16x8*)&SBz[(nj * 16 + lr) * PCS + kk * 32 + lk * 8];
#pragma unroll
                for (int mi = 0; mi < 4; ++mi)
#pragma unroll
                    for (int nj = 0; nj < 4; ++nj)
                        sfr[mi][nj] = __builtin_amdgcn_mfma_f32_16x16x32_bf16(av[mi], bv[nj], sfr[mi][nj], 0, 0, 0);
            }
#pragma unroll
            for (int mi = 0; mi < 4; ++mi) {
#pragma unroll
                for (int nj = 0; nj < 4; ++nj) {
                    int zl = nj * 16 + lr;
                    float az = s_acs[zt * 64 + zl];
                    float dz = s_dt[zt * 64 + zl];
#pragma unroll
                    for (int r = 0; r < 4; ++r) {
                        int sl = mi * 16 + lk * 4 + r;
                        float v = 0.f;
                        if (zt < w || zt * 64 + zl <= w * 64 + sl)
                            v = sfr[mi][nj][r] * expf(s_acs[w * 64 + sl] - az) * dz;
                        SP[w][sl * PXS + zl] = f2bf(v);
                    }
                }
            }
#pragma unroll
            for (int kk = 0; kk < 2; ++kk) {
                bf16x8 av[4], bv[4];
#pragma unroll
                for (int mi = 0; mi < 4; ++mi)
                    av[mi] = *(const bf16x8*)&SP[w][(mi * 16 + lr) * PXS + kk * 32 + lk * 8];
#pragma unroll
                for (int nj = 0; nj < 4; ++nj)
                    bv[nj] = *(const bf16x8*)&SXT[(nj * 16 + lr) * PXS + kk * 32 + lk * 8];
#pragma unroll
                for (int mi = 0; mi < 4; ++mi)
#pragma unroll
                    for (int nj = 0; nj < 4; ++nj)
                        acc[mi][nj] = __builtin_amdgcn_mfma_f32_16x16x32_bf16(av[mi], bv[nj], acc[mi][nj], 0, 0, 0);
            }
        }
    }
    __syncthreads();
    const float* pvbase = pv + (size_t)blk * (HDIM * DSTATE);
    for (int i = tid; i < 64 * 32; i += 256) {
        int r = i >> 5, c4 = (i & 31) * 4;
        float4 v = *(const float4*)&pvbase[r * DSTATE + c4];
        ushort4 o; o.x = f2bf(v.x); o.y = f2bf(v.y); o.z = f2bf(v.z); o.w = f2bf(v.w);
        *(ushort4*)&SBz[r * PCS + c4] = o;
    }
    __syncthreads();
    {
        f32x4 g[4][4] = {};
#pragma unroll
        for (int kk = 0; kk < 4; ++kk) {
            bf16x8 av[4], bv[4];
#pragma unroll
            for (int mi = 0; mi < 4; ++mi)
                av[mi] = *(const bf16x8*)&SC[(w * 64 + mi * 16 + lr) * PCS + kk * 32 + lk * 8];
#pragma unroll
            for (int nj = 0; nj < 4; ++nj)
                bv[nj] = *(const bf16x8*)&SBz[(nj * 16 + lr) * PCS + kk * 32 + lk * 8];
#pragma unroll
            for (int mi = 0; mi < 4; ++mi)
#pragma unroll
                for (int nj = 0; nj < 4; ++nj)
                    g[mi][nj] = __builtin_amdgcn_mfma_f32_16x16x32_bf16(av[mi], bv[nj], g[mi][nj], 0, 0, 0);
        }
#pragma unroll
        for (int mi = 0; mi < 4; ++mi) {
#pragma unroll
            for (int r = 0; r < 4; ++r) {
                float e = expf(s_acs[w * 64 + mi * 16 + lk * 4 + r]);
#pragma unroll
                for (int nj = 0; nj < 4; ++nj)
                    acc[mi][nj][r] = fmaf(e, g[mi][nj][r], acc[mi][nj][r]);
            }
        }
    }
    float dph = Dp[h];
#pragma unroll
    for (int mi = 0; mi < 4; ++mi) {
#pragma unroll
        for (int r = 0; r < 4; ++r) {
            int s = w * 64 + mi * 16 + lk * 4 + r;
#pragma unroll
            for (int nj = 0; nj < 4; ++nj) {
                int p = nj * 16 + lr;
                float xv = xc[(rowbase + s) * CDIM + h * HDIM + p];
                Y[(rowbase + s) * DSSM + h * HDIM + p] = acc[mi][nj][r] + dph * xv;
            }
        }
    }
}

// ---------------- gated RMS norm in place
__global__ __launch_bounds__(256) void rmsnorm_k(float* __restrict__ Y,
    const float* __restrict__ zbuf, const float* __restrict__ nw)
{
    __shared__ float red[8];
    int row = blockIdx.x;
    float* y = Y + (size_t)row * DSSM;
    const float* z = zbuf + (size_t)row * DSSM;
    float v[6];
    float ss = 0.f;
#pragma unroll
    for (int k = 0; k < 6; ++k) {
        int i = threadIdx.x + k * 256;
        float g = y[i] * siluf(z[i]);
        v[k] = g;
        ss = fmaf(g, g, ss);
    }
#pragma unroll
    for (int o = 32; o > 0; o >>= 1) ss += __shfl_down(ss, o, 64);
    int wv = threadIdx.x >> 6, ln = threadIdx.x & 63;
    if (ln == 0) red[wv] = ss;
    __syncthreads();
    float tot = red[0] + red[1] + red[2] + red[3];
    float sc = rsqrtf(tot / (float)DSSM + 1e-12f);
#pragma unroll
    for (int k = 0; k < 6; ++k) {
        int i = threadIdx.x + k * 256;
        y[i] = v[k] * sc * nw[i];
    }
}

// ---------------- time_out: gate + mix + LayerNorm over SEQ
__global__ __launch_bounds__(256) void timeout_k(const float* __restrict__ td,
    const float* __restrict__ tdt, const float* __restrict__ gw, const float* __restrict__ gb,
    const float* __restrict__ lnw, const float* __restrict__ lnb, float* __restrict__ out2)
{
    __shared__ float tm[SEQ];
    __shared__ float red[8];
    int row = blockIdx.x;
    const float* tdr = td + (size_t)row * SEQ;
    const float* tdtr = tdt + (size_t)row * SEQ;
    int wv = threadIdx.x >> 6, ln = threadIdx.x & 63;
    float part = 0.f;
    for (int i = threadIdx.x; i < SEQ; i += 256) part = fmaf(tdr[i], gw[i], part);
#pragma unroll
    for (int o = 32; o > 0; o >>= 1) part += __shfl_down(part, o, 64);
    if (ln == 0) red[wv] = part;
    __syncthreads();
    float dot = red[0] + red[1] + red[2] + red[3];
    float tg = 1.f / (1.f + expf(-(dot + gb[0])));
    __syncthreads();
    float sum = 0.f;
    for (int i = threadIdx.x; i < SEQ; i += 256) {
        float x = tg * tdr[i] + (1.f - tg) * tdtr[i];
        tm[i] = x;
        sum += x;
    }
#pragma unroll
    for (int o = 32; o > 0; o >>= 1) sum += __shfl_down(sum, o, 64);
    if (ln == 0) red[wv] = sum;
    __syncthreads();
    float mu = (red[0] + red[1] + red[2] + red[3]) / (float)SEQ;
    __syncthreads();
    float s2 = 0.f;
    for (int i = threadIdx.x; i < SEQ; i += 256) { float d = tm[i] - mu; s2 = fmaf(d, d, s2); }
#pragma unroll
    for (int o = 32; o > 0; o >>= 1) s2 += __shfl_down(s2, o, 64);
    if (ln == 0) red[wv] = s2;
    __syncthreads();
    float var = (red[0] + red[1] + red[2] + red[3]) / (float)SEQ;
    float inv = rsqrtf(var + 1e-12f);
    for (int i = threadIdx.x; i < SEQ; i += 256)
        out2[(size_t)row * SEQ + i] = (tm[i] - mu) * inv * lnw[i] + lnb[i];
}

extern "C" void kernel_launch(void* const* d_in, const int* in_sizes, int n_in,
                              void* d_out, int out_size, void* d_ws, size_t ws_size,
                              hipStream_t stream)
{
    const float* u      = (const float*)d_in[0];
    const float* td     = (const float*)d_in[1];
    const float* W_in   = (const float*)d_in[2];
    const float* b_in   = (const float*)d_in[3];
    const float* conv_w = (const float*)d_in[4];
    const float* conv_b = (const float*)d_in[5];
    const float* t1w    = (const float*)d_in[6];
    const float* t1b    = (const float*)d_in[7];
    const float* t2w    = (const float*)d_in[8];
    const float* t2b    = (const float*)d_in[9];
    const float* m1w    = (const float*)d_in[10];
    const float* m1b    = (const float*)d_in[11];
    const float* m2w    = (const float*)d_in[12];
    const float* m2b    = (const float*)d_in[13];
    const float* gw     = (const float*)d_in[14];
    const float* gb     = (const float*)d_in[15];
    const float* lnw    = (const float*)d_in[16];
    const float* lnb    = (const float*)d_in[17];
    const float* A_log  = (const float*)d_in[18];
    const float* dt_bias= (const float*)d_in[19];
    const float* Dpv    = (const float*)d_in[20];
    const float* nw     = (const float*)d_in[21];
    const float* W_out  = (const float*)d_in[22];
    const float* b_out  = (const float*)d_in[23];
    float* out  = (float*)d_out;
    float* out2 = out + (size_t)MR * DMODEL;

    float* ws = (float*)d_ws;
    size_t o = 0;
    float* zbuf  = ws + o; o += (size_t)MR * DSSM;
    float* r1    = ws + o; o += (size_t)MR * CDIM;
    float* xcv   = ws + o; o += (size_t)MR * CDIM;   // also split-K partials early
    float* dtraw = ws + o; o += (size_t)MR * NHH;
    float* hid   = ws + o; o += (size_t)BB * NHH * SEQ;
    float* tss   = ws + o; o += (size_t)BB * NHH * SEQ;
    float* tdt   = ws + o; o += (size_t)BB * NHH * SEQ;
    float* dtp   = ws + o; o += (size_t)MR * NHH;
    float* pvb   = ws + o; o += (size_t)BB * NC * NHH * HDIM * DSTATE;
    float* alb   = ws + o; o += (size_t)BB * NC * NHH;
    float* stb = r1;
    float* Yb  = r1;
    float* partb = xcv;                              // 3,145,728 floats (xcv dead until conv)
    unsigned short* u_bf  = (unsigned short*)pvb;
    unsigned short* Wi_bf = (unsigned short*)(pvb + 3145728);
    unsigned short* Y_bf  = (unsigned short*)zbuf;
    unsigned short* Wo_bf = (unsigned short*)(zbuf + 6291456);

    dim3 blk(256);
    // --- time MLP first (partials use xcv region, dead until conv) ---
    gemm_skinny_nt<<<dim3(SEQ / 128, KSPLIT), blk, 0, stream>>>(td, m1w, partb, SEQ, SEQ);
    reduce_part_k<<<dim3((48 * SEQ + 255) / 256), blk, 0, stream>>>(partb, m1b, hid, SEQ, 1);
    gemm_skinny_nt<<<dim3(SEQ / 128, KSPLIT), blk, 0, stream>>>(hid, m2w, partb, SEQ, SEQ);
    reduce_part_k<<<dim3((48 * SEQ + 255) / 256), blk, 0, stream>>>(partb, m2b, tss, SEQ, 0);
    time_conv_k<<<dim3(BB * NHH), blk, 0, stream>>>(tss, td, t1w, t1b, t2w, t2b, tdt);
    // --- in-proj ---
    cvt_bf16_k<<<dim3((MR * DMODEL / 4 + 255) / 256), blk, 0, stream>>>(u, u_bf, MR * DMODEL);
    cvt_bf16_k<<<dim3((3328 * DMODEL / 4 + 255) / 256), blk, 0, stream>>>(W_in, Wi_bf, 3328 * DMODEL);
    gemm_mfma_nt<<<dim3(CDIM / 128, MR / 128), blk, 0, stream>>>(
        u_bf, Wi_bf + (size_t)DSSM * DMODEL, b_in + DSSM, r1, CDIM, DMODEL, DMODEL / 32);
    conv_xbc_k<<<dim3((MR * CDIM + 255) / 256), blk, 0, stream>>>(r1, conv_w, conv_b, xcv);
    gemm_mfma_nt<<<dim3(DSSM / 128, MR / 128), blk, 0, stream>>>(
        u_bf, Wi_bf, b_in, zbuf, DSSM, DMODEL, DMODEL / 32);
    gemm_nt<<<dim3(1, MR / 64), blk, 0, stream>>>(
        u, W_in + (size_t)(DSSM + CDIM) * DMODEL, b_in + DSSM + CDIM, dtraw, MR, NHH, DMODEL, 0);
    dtsp_k<<<dim3((MR * NHH + 255) / 256), blk, 0, stream>>>(dtraw, tdt, dt_bias, dtp);
    // --- SSD ---
    ssd_states_k<<<dim3(BB * NC * NHH), blk, 0, stream>>>(xcv, dtp, A_log, stb, alb);
    ssd_scan_k<<<dim3(BB * NHH), blk, 0, stream>>>(stb, alb, pvb);
    ssd_y_mfma_k<<<dim3(BB * NC * NHH), blk, 0, stream>>>(xcv, dtp, A_log, pvb, Dpv, Yb);
    // --- epilogue ---
    rmsnorm_k<<<dim3(MR), blk, 0, stream>>>(Yb, zbuf, nw);
    cvt_bf16_k<<<dim3((MR * DSSM / 4 + 255) / 256), blk, 0, stream>>>(Yb, Y_bf, MR * DSSM);
    cvt_bf16_k<<<dim3((DMODEL * DSSM / 4 + 255) / 256), blk, 0, stream>>>(W_out, Wo_bf, DMODEL * DSSM);
    gemm_mfma_nt<<<dim3(DMODEL / 128, MR / 128), blk, 0, stream>>>(
        Y_bf, Wo_bf, b_out, out, DMODEL, DSSM, DSSM / 32);
    timeout_k<<<dim3(BB * NHH), blk, 0, stream>>>(td, tdt, gw, gb, lnw, lnb, out2);
}

// Round 6
// 760.885 us; speedup vs baseline: 4.5876x; 1.0785x over previous
//
#include <hip/hip_runtime.h>
#include <math.h>

#define BB 2
#define SEQ 4096
#define DMODEL 768
#define DSTATE 128
#define NHH 24
#define HDIM 64
#define DSSM 1536
#define CDIM 1792
#define CHK 256
#define NC 16
#define DPROJ 3352
#define MR (BB*SEQ)
#define KSPLIT 16

typedef __attribute__((ext_vector_type(8))) short bf16x8;
typedef __attribute__((ext_vector_type(4))) float f32x4;

__device__ __forceinline__ float siluf(float x) { return x / (1.0f + expf(-x)); }

__device__ __forceinline__ unsigned short f2bf(float f) {
    unsigned u = __float_as_uint(f);
    unsigned r = (u + 0x7fffu + ((u >> 16) & 1u)) >> 16;
    return (unsigned short)r;
}

__device__ __forceinline__ void gload_lds16(const void* g, void* l) {
    __builtin_amdgcn_global_load_lds((const __attribute__((address_space(1))) unsigned int*)g,
                                     (__attribute__((address_space(3))) unsigned int*)l, 16, 0, 0);
}

// ---------------- f32 -> bf16 conversion (vectorized)
__global__ __launch_bounds__(256) void cvt_bf16_k(const float* __restrict__ in,
    unsigned short* __restrict__ out, int n)
{
    int i = (blockIdx.x * 256 + threadIdx.x) * 4;
    if (i >= n) return;
    float4 v = *(const float4*)&in[i];
    ushort4 o;
    o.x = f2bf(v.x); o.y = f2bf(v.y); o.z = f2bf(v.z); o.w = f2bf(v.w);
    *(ushort4*)&out[i] = o;
}

// ---------------- bf16 MFMA GEMM: C(MxN) = A(MxK) @ B(NxK)^T + bias(N)
__global__ __launch_bounds__(256) void gemm_mfma_nt(
    const unsigned short* __restrict__ A, const unsigned short* __restrict__ B,
    const float* __restrict__ bias, float* __restrict__ C, int N, int K, int KT)
{
    __shared__ unsigned short SA[2][128 * 32];
    __shared__ unsigned short SB[2][128 * 32];
    const int tid = threadIdx.x;
    const int w = tid >> 6, l = tid & 63;
    const int wr = w >> 1, wc = w & 1;
    const int lr = l & 15, lk = l >> 4;
    const int m0 = blockIdx.y * 128, n0 = blockIdx.x * 128;
    f32x4 acc[4][4] = {};
    const int i16 = w * 64 + l;
    const int row0 = i16 >> 2, sl = i16 & 3;
    const size_t ga0 = (size_t)(m0 + row0) * K + sl * 8;
    const size_t ga1 = (size_t)(m0 + row0 + 64) * K + sl * 8;
    const size_t gb0 = (size_t)(n0 + row0) * K + sl * 8;
    const size_t gb1 = (size_t)(n0 + row0 + 64) * K + sl * 8;
    const int lo0 = (w * 64) * 8;
    const int lo1 = (256 + w * 64) * 8;

#define STAGE(bb, kt) { int ko = (kt) * 32;                      \
      gload_lds16(A + ga0 + ko, &SA[bb][lo0]);                   \
      gload_lds16(A + ga1 + ko, &SA[bb][lo1]);                   \
      gload_lds16(B + gb0 + ko, &SB[bb][lo0]);                   \
      gload_lds16(B + gb1 + ko, &SB[bb][lo1]); }

    STAGE(0, 0);
    for (int kt = 0; kt < KT; ++kt) {
        int cur = kt & 1;
        asm volatile("s_waitcnt vmcnt(0)" ::: "memory");
        __syncthreads();
        if (kt + 1 < KT) STAGE(cur ^ 1, kt + 1);
        bf16x8 af[4], bg[4];
#pragma unroll
        for (int mi = 0; mi < 4; ++mi)
            af[mi] = *(const bf16x8*)&SA[cur][(wr * 64 + mi * 16 + lr) * 32 + lk * 8];
#pragma unroll
        for (int nj = 0; nj < 4; ++nj)
            bg[nj] = *(const bf16x8*)&SB[cur][(wc * 64 + nj * 16 + lr) * 32 + lk * 8];
#pragma unroll
        for (int mi = 0; mi < 4; ++mi)
#pragma unroll
            for (int nj = 0; nj < 4; ++nj)
                acc[mi][nj] = __builtin_amdgcn_mfma_f32_16x16x32_bf16(af[mi], bg[nj], acc[mi][nj], 0, 0, 0);
    }
#undef STAGE
#pragma unroll
    for (int nj = 0; nj < 4; ++nj) {
        int col = n0 + wc * 64 + nj * 16 + lr;
        float bz = bias[col];
#pragma unroll
        for (int mi = 0; mi < 4; ++mi) {
#pragma unroll
            for (int r = 0; r < 4; ++r) {
                int m = m0 + wr * 64 + mi * 16 + lk * 4 + r;
                C[(size_t)m * N + col] = acc[mi][nj][r] + bz;
            }
        }
    }
}

// ---------------- generic f32 GEMM (small shapes)
__global__ __launch_bounds__(256) void gemm_nt(const float* __restrict__ A,
    const float* __restrict__ Bw, const float* __restrict__ bias,
    float* __restrict__ C, int M, int N, int K, int act)
{
    __shared__ float As[16][68];
    __shared__ float Bs[16][68];
    const int tx = threadIdx.x & 15, ty = threadIdx.x >> 4;
    const int m0 = blockIdx.y * 64, n0 = blockIdx.x * 64;
    float acc[4][4] = {{0.f}};
    for (int k0 = 0; k0 < K; k0 += 16) {
        for (int idx = threadIdx.x; idx < 1024; idx += 256) {
            int r = idx >> 4, kk = idx & 15;
            int m = m0 + r, n = n0 + r;
            As[kk][r] = (m < M) ? A[(size_t)m * K + k0 + kk] : 0.0f;
            Bs[kk][r] = (n < N) ? Bw[(size_t)n * K + k0 + kk] : 0.0f;
        }
        __syncthreads();
#pragma unroll
        for (int kk = 0; kk < 16; ++kk) {
            float4 a4 = *(const float4*)&As[kk][ty * 4];
            float4 b4 = *(const float4*)&Bs[kk][tx * 4];
            float av[4] = {a4.x, a4.y, a4.z, a4.w};
            float bv[4] = {b4.x, b4.y, b4.z, b4.w};
#pragma unroll
            for (int i = 0; i < 4; ++i)
#pragma unroll
                for (int j = 0; j < 4; ++j)
                    acc[i][j] = fmaf(av[i], bv[j], acc[i][j]);
        }
        __syncthreads();
    }
#pragma unroll
    for (int i = 0; i < 4; ++i) {
        int m = m0 + ty * 4 + i;
        if (m >= M) continue;
#pragma unroll
        for (int j = 0; j < 4; ++j) {
            int n = n0 + tx * 4 + j;
            if (n >= N) continue;
            float v = acc[i][j] + bias[n];
            if (act == 1) v = siluf(v);
            C[(size_t)m * N + n] = v;
        }
    }
}

// ---------------- split-K skinny GEMM (M=48)
__global__ __launch_bounds__(256) void gemm_skinny_nt(const float* __restrict__ A,
    const float* __restrict__ Bw, float* __restrict__ part, int N, int K)
{
    __shared__ float sA[32][49];
    __shared__ float sB[32][133];
    const int nb = blockIdx.x, kb = blockIdx.y;
    const int n0 = nb * 128;
    const int KS = K / KSPLIT;
    const int k0 = kb * KS;
    const int tid = threadIdx.x;
    const int tx = tid & 31, ty = tid >> 5;
    float acc[6][4] = {{0.f}};
    for (int kc = 0; kc < KS; kc += 32) {
        for (int i = tid; i < 48 * 32; i += 256) {
            int m = i >> 5, kk = i & 31;
            sA[kk][m] = A[(size_t)m * K + k0 + kc + kk];
        }
        for (int i = tid; i < 128 * 32; i += 256) {
            int n = i >> 5, kk = i & 31;
            sB[kk][n] = Bw[(size_t)(n0 + n) * K + k0 + kc + kk];
        }
        __syncthreads();
#pragma unroll 4
        for (int kk = 0; kk < 32; ++kk) {
            float a[6], b[4];
#pragma unroll
            for (int r = 0; r < 6; ++r) a[r] = sA[kk][ty * 6 + r];
#pragma unroll
            for (int j = 0; j < 4; ++j) b[j] = sB[kk][tx * 4 + j];
#pragma unroll
            for (int r = 0; r < 6; ++r)
#pragma unroll
                for (int j = 0; j < 4; ++j)
                    acc[r][j] = fmaf(a[r], b[j], acc[r][j]);
        }
        __syncthreads();
    }
    float* pb = part + (size_t)kb * 48 * N;
#pragma unroll
    for (int r = 0; r < 6; ++r)
#pragma unroll
        for (int j = 0; j < 4; ++j)
            pb[(size_t)(ty * 6 + r) * N + n0 + tx * 4 + j] = acc[r][j];
}

// ---------------- reduce split-K partials + bias (+ optional silu)
__global__ __launch_bounds__(256) void reduce_part_k(const float* __restrict__ part,
    const float* __restrict__ bias, float* __restrict__ out, int N, int act)
{
    int idx = blockIdx.x * 256 + threadIdx.x;
    if (idx >= 48 * N) return;
    int n = idx % N;
    float s = bias[n];
#pragma unroll
    for (int kb = 0; kb < KSPLIT; ++kb) s += part[(size_t)kb * 48 * N + idx];
    if (act) s = siluf(s);
    out[idx] = s;
}

// ---------------- depthwise causal conv (window 4) + silu
__global__ __launch_bounds__(256) void conv_xbc_k(const float* __restrict__ xbc,
    const float* __restrict__ cw, const float* __restrict__ cb, float* __restrict__ out)
{
    int idx = blockIdx.x * 256 + threadIdx.x;
    if (idx >= MR * CDIM) return;
    int c = idx % CDIM;
    int row = idx / CDIM;
    int t = row % SEQ;
    float acc = cb[c];
#pragma unroll
    for (int k = 0; k < 4; ++k) {
        int tt = t + k - 3;
        if (tt >= 0) acc = fmaf(xbc[(size_t)(row + k - 3) * CDIM + c], cw[c * 4 + k], acc);
    }
    out[idx] = siluf(acc);
}

// ---------------- per-(b,h) row: tdt0 = ts*td; conv1+silu; conv2+silu
__global__ __launch_bounds__(256) void time_conv_k(const float* __restrict__ ts,
    const float* __restrict__ td, const float* __restrict__ w1, const float* __restrict__ b1,
    const float* __restrict__ w2, const float* __restrict__ b2, float* __restrict__ tdt)
{
    __shared__ float u0[SEQ];
    __shared__ float u1[SEQ];
    int row = blockIdx.x, h = row % NHH;
    const float* tsr = ts + (size_t)row * SEQ;
    const float* tdr = td + (size_t)row * SEQ;
    for (int i = threadIdx.x; i < SEQ; i += 256) u0[i] = tsr[i] * tdr[i];
    __syncthreads();
    float wa[4], wb[4];
#pragma unroll
    for (int k = 0; k < 4; ++k) { wa[k] = w1[h * 4 + k]; wb[k] = w2[h * 4 + k]; }
    float ba = b1[h], bbv = b2[h];
    for (int i = threadIdx.x; i < SEQ; i += 256) {
        float acc = ba;
#pragma unroll
        for (int k = 0; k < 4; ++k) { int tt = i + k - 3; if (tt >= 0) acc = fmaf(u0[tt], wa[k], acc); }
        u1[i] = siluf(acc);
    }
    __syncthreads();
    for (int i = threadIdx.x; i < SEQ; i += 256) {
        float acc = bbv;
#pragma unroll
        for (int k = 0; k < 4; ++k) { int tt = i + k - 3; if (tt >= 0) acc = fmaf(u1[tt], wb[k], acc); }
        tdt[(size_t)row * SEQ + i] = siluf(acc);
    }
}

// ---------------- dt_sp = softplus(dt * tdt^T + dt_bias)
__global__ __launch_bounds__(256) void dtsp_k(const float* __restrict__ dtraw,
    const float* __restrict__ tdt, const float* __restrict__ dt_bias, float* __restrict__ dtp)
{
    int idx = blockIdx.x * 256 + threadIdx.x;
    if (idx >= MR * NHH) return;
    int h = idx % NHH;
    int row = idx / NHH;
    int b = row / SEQ, s = row % SEQ;
    float x = dtraw[(size_t)row * NHH + h] * tdt[((size_t)(b * NHH + h)) * SEQ + s] + dt_bias[h];
    dtp[idx] = (x > 20.0f) ? x : log1pf(expf(x));
}

// ---------------- SSD: per-(b,c,h) chunk states (64 x 128) + alast
__global__ __launch_bounds__(256) void ssd_states_k(const float* __restrict__ xc,
    const float* __restrict__ dtp, const float* __restrict__ A_log,
    float* __restrict__ st, float* __restrict__ al)
{
    __shared__ float s_acs[256];
    __shared__ float s_coef[256];
    __shared__ float xs[64][64];
    __shared__ float bs[64][128];
    int blk = blockIdx.x;
    int h = blk % NHH, c = (blk / NHH) % NC, b = blk / (NHH * NC);
    int tid = threadIdx.x;
    size_t rowbase = (size_t)b * SEQ + c * CHK;
    float Ah = -expf(A_log[h]);
    float dtv = dtp[(rowbase + tid) * NHH + h];
    s_acs[tid] = Ah * dtv;
    __syncthreads();
    for (int off = 1; off < 256; off <<= 1) {
        float pv_ = (tid >= off) ? s_acs[tid - off] : 0.f;
        __syncthreads();
        s_acs[tid] += pv_;
        __syncthreads();
    }
    float alv = s_acs[255];
    s_coef[tid] = expf(alv - s_acs[tid]) * dtv;
    if (tid == 255) al[blk] = alv;
    __syncthreads();
    int p = tid >> 2, t4 = tid & 3;
    float acc[32];
#pragma unroll
    for (int j = 0; j < 32; ++j) acc[j] = 0.f;
    for (int z0 = 0; z0 < CHK; z0 += 64) {
        for (int idx = tid; idx < 64 * 64; idx += 256) {
            int zz = idx >> 6, pp = idx & 63;
            xs[zz][pp] = xc[(rowbase + z0 + zz) * CDIM + h * HDIM + pp];
        }
        for (int idx = tid; idx < 64 * 128; idx += 256) {
            int zz = idx >> 7, nn = idx & 127;
            bs[zz][nn] = xc[(rowbase + z0 + zz) * CDIM + DSSM + nn] * s_coef[z0 + zz];
        }
        __syncthreads();
        for (int zz = 0; zz < 64; ++zz) {
            float xv = xs[zz][p];
#pragma unroll
            for (int j = 0; j < 32; ++j)
                acc[j] = fmaf(xv, bs[zz][t4 + j * 4], acc[j]);
        }
        __syncthreads();
    }
    size_t base = (size_t)blk * (HDIM * DSTATE);
#pragma unroll
    for (int j = 0; j < 32; ++j)
        st[base + p * DSTATE + t4 + j * 4] = acc[j];
}

// ---------------- inter-chunk scan
__global__ __launch_bounds__(256) void ssd_scan_k(const float* __restrict__ st,
    const float* __restrict__ al, float* __restrict__ pv)
{
    int b = blockIdx.x / NHH, h = blockIdx.x % NHH;
    int tid = threadIdx.x;
    float carry[32];
#pragma unroll
    for (int j = 0; j < 32; ++j) carry[j] = 0.f;
    for (int c = 0; c < NC; ++c) {
        int bch = (b * NC + c) * NHH + h;
        size_t base = (size_t)bch * (HDIM * DSTATE);
        float dcy = expf(al[bch]);
#pragma unroll
        for (int j = 0; j < 32; ++j) {
            pv[base + tid + j * 256] = carry[j];
            carry[j] = fmaf(dcy, carry[j], st[base + tid + j * 256]);
        }
    }
}

// ---------------- S_raw = C.B^T per (b,c), lower-triangular 64x64 tiles, bf16
// grid 32 blocks x 512 thr (8 waves). Tile (st,zt), zt<=st: 10 tasks round-robin.
__global__ __launch_bounds__(512) void ssd_sraw_k(const float* __restrict__ xc,
    unsigned short* __restrict__ sraw)
{
    __shared__ unsigned short SC[256 * 136];
    __shared__ unsigned short SB[256 * 136];
    int bc = blockIdx.x;
    int b = bc / NC, c = bc % NC;
    size_t rowbase = (size_t)b * SEQ + c * CHK;
    int tid = threadIdx.x;
    int w = tid >> 6, l = tid & 63;
    int lr = l & 15, lk = l >> 4;
    for (int i = tid; i < 256 * 32; i += 512) {
        int r = i >> 5, c4 = (i & 31) * 4;
        float4 vc = *(const float4*)&xc[(rowbase + r) * CDIM + DSSM + DSTATE + c4];
        float4 vb = *(const float4*)&xc[(rowbase + r) * CDIM + DSSM + c4];
        ushort4 oc, ob;
        oc.x = f2bf(vc.x); oc.y = f2bf(vc.y); oc.z = f2bf(vc.z); oc.w = f2bf(vc.w);
        ob.x = f2bf(vb.x); ob.y = f2bf(vb.y); ob.z = f2bf(vb.z); ob.w = f2bf(vb.w);
        *(ushort4*)&SC[r * 136 + c4] = oc;
        *(ushort4*)&SB[r * 136 + c4] = ob;
    }
    __syncthreads();
    unsigned short* tb = sraw + (size_t)bc * 16 * 4096;
    int t = 0;
#pragma unroll
    for (int st = 0; st < 4; ++st) {
#pragma unroll
        for (int zt = 0; zt <= st; ++zt, ++t) {
            if ((t & 7) != w) continue;
            f32x4 d[4][4] = {};
#pragma unroll
            for (int kt = 0; kt < 4; ++kt) {
                bf16x8 av[4], bv[4];
#pragma unroll
                for (int mi = 0; mi < 4; ++mi)
                    av[mi] = *(const bf16x8*)&SC[(st * 64 + mi * 16 + lr) * 136 + kt * 32 + lk * 8];
#pragma unroll
                for (int nj = 0; nj < 4; ++nj)
                    bv[nj] = *(const bf16x8*)&SB[(zt * 64 + nj * 16 + lr) * 136 + kt * 32 + lk * 8];
#pragma unroll
                for (int mi = 0; mi < 4; ++mi)
#pragma unroll
                    for (int nj = 0; nj < 4; ++nj)
                        d[mi][nj] = __builtin_amdgcn_mfma_f32_16x16x32_bf16(av[mi], bv[nj], d[mi][nj], 0, 0, 0);
            }
            unsigned short* tp = tb + (size_t)(st * 4 + zt) * 4096;
#pragma unroll
            for (int mi = 0; mi < 4; ++mi)
#pragma unroll
                for (int nj = 0; nj < 4; ++nj)
#pragma unroll
                    for (int r = 0; r < 4; ++r)
                        tp[(mi * 16 + lk * 4 + r) * 64 + nj * 16 + lr] = f2bf(d[mi][nj][r]);
        }
    }
}

// ---------------- Y from precomputed S_raw: per (b,c,h), 4 waves = 4 s-tiles.
// Scaled-X trick: SXT[p][z] = X^T * exp(clamp(az0[zt]-acs[z],60)) * dt[z] (bf16);
// per z-tile: tmp = S_frag . SXT; acc += exp(acs[s]-az0[zt]) * tmp.
// Diagonal tile: zero-mask z>s on the S A-frag. Off-chunk: C.prev^T * exp(acs[s]).
__global__ __launch_bounds__(256) void ssd_y2_k(const float* __restrict__ xc,
    const float* __restrict__ dtp, const float* __restrict__ A_log,
    const unsigned short* __restrict__ sraw, const float* __restrict__ pv,
    const float* __restrict__ Dp, float* __restrict__ Y)
{
    __shared__ float s_acs[256];
    __shared__ float s_dt[256];
    __shared__ float s_edt[256];
    __shared__ float s_az0[4];
    __shared__ unsigned short SXT[64 * 264];   // [p][z]  z contiguous
    __shared__ unsigned short SPV[64 * 136];   // [p][n]
    int blk = blockIdx.x;
    int h = blk % NHH;
    int c = (blk / NHH) % NC;
    int b = blk / (NHH * NC);
    int tid = threadIdx.x;
    int w = tid >> 6, l = tid & 63;
    int lr = l & 15, lk = l >> 4;
    size_t rowbase = (size_t)b * SEQ + c * CHK;
    float Ah = -expf(A_log[h]);
    float dtv = dtp[(rowbase + tid) * NHH + h];
    s_dt[tid] = dtv;
    s_acs[tid] = Ah * dtv;
    __syncthreads();
    for (int off = 1; off < 256; off <<= 1) {
        float t = (tid >= off) ? s_acs[tid - off] : 0.f;
        __syncthreads();
        s_acs[tid] += t;
        __syncthreads();
    }
    if (tid < 4) s_az0[tid] = s_acs[tid * 64];
    __syncthreads();
    {
        float e = s_az0[tid >> 6] - s_acs[tid];
        if (e > 60.f) e = 60.f;
        s_edt[tid] = expf(e) * s_dt[tid];
    }
    __syncthreads();
    // stage scaled X^T (all 256 z) and prev
    for (int i = tid; i < 256 * 16; i += 256) {
        int z = i >> 4, p4 = (i & 15) * 4;
        float sc = s_edt[z];
        float4 v = *(const float4*)&xc[(rowbase + z) * CDIM + h * HDIM + p4];
        SXT[(p4 + 0) * 264 + z] = f2bf(v.x * sc);
        SXT[(p4 + 1) * 264 + z] = f2bf(v.y * sc);
        SXT[(p4 + 2) * 264 + z] = f2bf(v.z * sc);
        SXT[(p4 + 3) * 264 + z] = f2bf(v.w * sc);
    }
    const float* pvbase = pv + (size_t)blk * (HDIM * DSTATE);
    for (int i = tid; i < 64 * 32; i += 256) {
        int p = i >> 5, n4 = (i & 31) * 4;
        float4 v = *(const float4*)&pvbase[p * DSTATE + n4];
        ushort4 o; o.x = f2bf(v.x); o.y = f2bf(v.y); o.z = f2bf(v.z); o.w = f2bf(v.w);
        *(ushort4*)&SPV[p * 136 + n4] = o;
    }
    __syncthreads();

    const unsigned short* tbase = sraw + (size_t)(b * NC + c) * 16 * 4096;
    f32x4 acc[4][4] = {};
    for (int zt = 0; zt <= w; ++zt) {
        const unsigned short* tp = tbase + (size_t)(w * 4 + zt) * 4096;
        f32x4 tmp[4][4] = {};
#pragma unroll
        for (int kt = 0; kt < 2; ++kt) {
            bf16x8 av[4], bv[4];
#pragma unroll
            for (int mi = 0; mi < 4; ++mi) {
                av[mi] = *(const bf16x8*)&tp[(mi * 16 + lr) * 64 + kt * 32 + lk * 8];
                if (zt == w) {
                    int zb = kt * 32 + lk * 8;
                    int sl = mi * 16 + lr;
#pragma unroll
                    for (int e = 0; e < 8; ++e)
                        if (zb + e > sl) av[mi][e] = 0;
                }
            }
#pragma unroll
            for (int nj = 0; nj < 4; ++nj)
                bv[nj] = *(const bf16x8*)&SXT[(nj * 16 + lr) * 264 + zt * 64 + kt * 32 + lk * 8];
#pragma unroll
            for (int mi = 0; mi < 4; ++mi)
#pragma unroll
                for (int nj = 0; nj < 4; ++nj)
                    tmp[mi][nj] = __builtin_amdgcn_mfma_f32_16x16x32_bf16(av[mi], bv[nj], tmp[mi][nj], 0, 0, 0);
        }
        float az = s_az0[zt];
#pragma unroll
        for (int mi = 0; mi < 4; ++mi) {
#pragma unroll
            for (int r = 0; r < 4; ++r) {
                float es = expf(s_acs[w * 64 + mi * 16 + lk * 4 + r] - az);
#pragma unroll
                for (int nj = 0; nj < 4; ++nj)
                    acc[mi][nj][r] += es * tmp[mi][nj][r];
            }
        }
    }
    // off-chunk: C.prev^T * exp(acs[s])
    {
        f32x4 tmp[4][4] = {};
#pragma unroll
        for (int kt = 0; kt < 4; ++kt) {
            bf16x8 av[4], bv[4];
#pragma unroll
            for (int mi = 0; mi < 4; ++mi) {
                const float* cp = &xc[(rowbase + w * 64 + mi * 16 + lr) * CDIM + DSSM + DSTATE + kt * 32 + lk * 8];
                float4 c0 = *(const float4*)cp;
                float4 c1 = *(const float4*)(cp + 4);
                av[mi][0] = (short)f2bf(c0.x); av[mi][1] = (short)f2bf(c0.y);
                av[mi][2] = (short)f2bf(c0.z); av[mi][3] = (short)f2bf(c0.w);
                av[mi][4] = (short)f2bf(c1.x); av[mi][5] = (short)f2bf(c1.y);
                av[mi][6] = (short)f2bf(c1.z); av[mi][7] = (short)f2bf(c1.w);
            }
#pragma unroll
            for (int nj = 0; nj < 4; ++nj)
                bv[nj] = *(const bf16x8*)&SPV[(nj * 16 + lr) * 136 + kt * 32 + lk * 8];
#pragma unroll
            for (int mi = 0; mi < 4; ++mi)
#pragma unroll
                for (int nj = 0; nj < 4; ++nj)
                    tmp[mi][nj] = __builtin_amdgcn_mfma_f32_16x16x32_bf16(av[mi], bv[nj], tmp[mi][nj], 0, 0, 0);
        }
#pragma unroll
        for (int mi = 0; mi < 4; ++mi) {
#pragma unroll
            for (int r = 0; r < 4; ++r) {
                float es = expf(s_acs[w * 64 + mi * 16 + lk * 4 + r]);
#pragma unroll
                for (int nj = 0; nj < 4; ++nj)
                    acc[mi][nj][r] += es * tmp[mi][nj][r];
            }
        }
    }
    // store + D*x
    float dph = Dp[h];
#pragma unroll
    for (int mi = 0; mi < 4; ++mi) {
#pragma unroll
        for (int r = 0; r < 4; ++r) {
            int s = w * 64 + mi * 16 + lk * 4 + r;
#pragma unroll
            for (int nj = 0; nj < 4; ++nj) {
                int p = nj * 16 + lr;
                float xv = xc[(rowbase + s) * CDIM + h * HDIM + p];
                Y[(rowbase + s) * DSSM + h * HDIM + p] = acc[mi][nj][r] + dph * xv;
            }
        }
    }
}

// ---------------- gated RMS norm in place
__global__ __launch_bounds__(256) void rmsnorm_k(float* __restrict__ Y,
    const float* __restrict__ zbuf, const float* __restrict__ nw)
{
    __shared__ float red[8];
    int row = blockIdx.x;
    float* y = Y + (size_t)row * DSSM;
    const float* z = zbuf + (size_t)row * DSSM;
    float v[6];
    float ss = 0.f;
#pragma unroll
    for (int k = 0; k < 6; ++k) {
        int i = threadIdx.x + k * 256;
        float g = y[i] * siluf(z[i]);
        v[k] = g;
        ss = fmaf(g, g, ss);
    }
#pragma unroll
    for (int o = 32; o > 0; o >>= 1) ss += __shfl_down(ss, o, 64);
    int wv = threadIdx.x >> 6, ln = threadIdx.x & 63;
    if (ln == 0) red[wv] = ss;
    __syncthreads();
    float tot = red[0] + red[1] + red[2] + red[3];
    float sc = rsqrtf(tot / (float)DSSM + 1e-12f);
#pragma unroll
    for (int k = 0; k < 6; ++k) {
        int i = threadIdx.x + k * 256;
        y[i] = v[k] * sc * nw[i];
    }
}

// ---------------- time_out: gate + mix + LayerNorm over SEQ
__global__ __launch_bounds__(256) void timeout_k(const float* __restrict__ td,
    const float* __restrict__ tdt, const float* __restrict__ gw, const float* __restrict__ gb,
    const float* __restrict__ lnw, const float* __restrict__ lnb, float* __restrict__ out2)
{
    __shared__ float tm[SEQ];
    __shared__ float red[8];
    int row = blockIdx.x;
    const float* tdr = td + (size_t)row * SEQ;
    const float* tdtr = tdt + (size_t)row * SEQ;
    int wv = threadIdx.x >> 6, ln = threadIdx.x & 63;
    float part = 0.f;
    for (int i = threadIdx.x; i < SEQ; i += 256) part = fmaf(tdr[i], gw[i], part);
#pragma unroll
    for (int o = 32; o > 0; o >>= 1) part += __shfl_down(part, o, 64);
    if (ln == 0) red[wv] = part;
    __syncthreads();
    float dot = red[0] + red[1] + red[2] + red[3];
    float tg = 1.f / (1.f + expf(-(dot + gb[0])));
    __syncthreads();
    float sum = 0.f;
    for (int i = threadIdx.x; i < SEQ; i += 256) {
        float x = tg * tdr[i] + (1.f - tg) * tdtr[i];
        tm[i] = x;
        sum += x;
    }
#pragma unroll
    for (int o = 32; o > 0; o >>= 1) sum += __shfl_down(sum, o, 64);
    if (ln == 0) red[wv] = sum;
    __syncthreads();
    float mu = (red[0] + red[1] + red[2] + red[3]) / (float)SEQ;
    __syncthreads();
    float s2 = 0.f;
    for (int i = threadIdx.x; i < SEQ; i += 256) { float d = tm[i] - mu; s2 = fmaf(d, d, s2); }
#pragma unroll
    for (int o = 32; o > 0; o >>= 1) s2 += __shfl_down(s2, o, 64);
    if (ln == 0) red[wv] = s2;
    __syncthreads();
    float var = (red[0] + red[1] + red[2] + red[3]) / (float)SEQ;
    float inv = rsqrtf(var + 1e-12f);
    for (int i = threadIdx.x; i < SEQ; i += 256)
        out2[(size_t)row * SEQ + i] = (tm[i] - mu) * inv * lnw[i] + lnb[i];
}

extern "C" void kernel_launch(void* const* d_in, const int* in_sizes, int n_in,
                              void* d_out, int out_size, void* d_ws, size_t ws_size,
                              hipStream_t stream)
{
    const float* u      = (const float*)d_in[0];
    const float* td     = (const float*)d_in[1];
    const float* W_in   = (const float*)d_in[2];
    const float* b_in   = (const float*)d_in[3];
    const float* conv_w = (const float*)d_in[4];
    const float* conv_b = (const float*)d_in[5];
    const float* t1w    = (const float*)d_in[6];
    const float* t1b    = (const float*)d_in[7];
    const float* t2w    = (const float*)d_in[8];
    const float* t2b    = (const float*)d_in[9];
    const float* m1w    = (const float*)d_in[10];
    const float* m1b    = (const float*)d_in[11];
    const float* m2w    = (const float*)d_in[12];
    const float* m2b    = (const float*)d_in[13];
    const float* gw     = (const float*)d_in[14];
    const float* gb     = (const float*)d_in[15];
    const float* lnw    = (const float*)d_in[16];
    const float* lnb    = (const float*)d_in[17];
    const float* A_log  = (const float*)d_in[18];
    const float* dt_bias= (const float*)d_in[19];
    const float* Dpv    = (const float*)d_in[20];
    const float* nw     = (const float*)d_in[21];
    const float* W_out  = (const float*)d_in[22];
    const float* b_out  = (const float*)d_in[23];
    float* out  = (float*)d_out;
    float* out2 = out + (size_t)MR * DMODEL;

    float* ws = (float*)d_ws;
    size_t o = 0;
    float* zbuf  = ws + o; o += (size_t)MR * DSSM;
    float* r1    = ws + o; o += (size_t)MR * CDIM;
    float* xcv   = ws + o; o += (size_t)MR * CDIM;   // also split-K partials early
    float* dtraw = ws + o; o += (size_t)MR * NHH;
    float* hid   = ws + o; o += (size_t)BB * NHH * SEQ;
    float* tss   = ws + o; o += (size_t)BB * NHH * SEQ;
    float* tdt   = ws + o; o += (size_t)BB * NHH * SEQ;
    float* dtp   = ws + o; o += (size_t)MR * NHH;
    float* pvb   = ws + o; o += (size_t)BB * NC * NHH * HDIM * DSTATE;
    float* alb   = ws + o; o += (size_t)BB * NC * NHH;
    unsigned short* sraw = (unsigned short*)(ws + o); o += (size_t)BB * NC * 16 * 4096 / 2;  // 4 MiB bf16
    float* stb = r1;
    float* Yb  = r1;
    float* partb = xcv;
    unsigned short* u_bf  = (unsigned short*)pvb;
    unsigned short* Wi_bf = (unsigned short*)(pvb + 3145728);
    unsigned short* Y_bf  = (unsigned short*)zbuf;
    unsigned short* Wo_bf = (unsigned short*)(zbuf + 6291456);

    dim3 blk(256);
    // --- time MLP first (partials use xcv region, dead until conv) ---
    gemm_skinny_nt<<<dim3(SEQ / 128, KSPLIT), blk, 0, stream>>>(td, m1w, partb, SEQ, SEQ);
    reduce_part_k<<<dim3((48 * SEQ + 255) / 256), blk, 0, stream>>>(partb, m1b, hid, SEQ, 1);
    gemm_skinny_nt<<<dim3(SEQ / 128, KSPLIT), blk, 0, stream>>>(hid, m2w, partb, SEQ, SEQ);
    reduce_part_k<<<dim3((48 * SEQ + 255) / 256), blk, 0, stream>>>(partb, m2b, tss, SEQ, 0);
    time_conv_k<<<dim3(BB * NHH), blk, 0, stream>>>(tss, td, t1w, t1b, t2w, t2b, tdt);
    // --- in-proj ---
    cvt_bf16_k<<<dim3((MR * DMODEL / 4 + 255) / 256), blk, 0, stream>>>(u, u_bf, MR * DMODEL);
    cvt_bf16_k<<<dim3((3328 * DMODEL / 4 + 255) / 256), blk, 0, stream>>>(W_in, Wi_bf, 3328 * DMODEL);
    gemm_mfma_nt<<<dim3(CDIM / 128, MR / 128), blk, 0, stream>>>(
        u_bf, Wi_bf + (size_t)DSSM * DMODEL, b_in + DSSM, r1, CDIM, DMODEL, DMODEL / 32);
    conv_xbc_k<<<dim3((MR * CDIM + 255) / 256), blk, 0, stream>>>(r1, conv_w, conv_b, xcv);
    gemm_mfma_nt<<<dim3(DSSM / 128, MR / 128), blk, 0, stream>>>(
        u_bf, Wi_bf, b_in, zbuf, DSSM, DMODEL, DMODEL / 32);
    gemm_nt<<<dim3(1, MR / 64), blk, 0, stream>>>(
        u, W_in + (size_t)(DSSM + CDIM) * DMODEL, b_in + DSSM + CDIM, dtraw, MR, NHH, DMODEL, 0);
    dtsp_k<<<dim3((MR * NHH + 255) / 256), blk, 0, stream>>>(dtraw, tdt, dt_bias, dtp);
    // --- SSD ---
    ssd_sraw_k<<<dim3(BB * NC), dim3(512), 0, stream>>>(xcv, sraw);
    ssd_states_k<<<dim3(BB * NC * NHH), blk, 0, stream>>>(xcv, dtp, A_log, stb, alb);
    ssd_scan_k<<<dim3(BB * NHH), blk, 0, stream>>>(stb, alb, pvb);
    ssd_y2_k<<<dim3(BB * NC * NHH), blk, 0, stream>>>(xcv, dtp, A_log, sraw, pvb, Dpv, Yb);
    // --- epilogue ---
    rmsnorm_k<<<dim3(MR), blk, 0, stream>>>(Yb, zbuf, nw);
    cvt_bf16_k<<<dim3((MR * DSSM / 4 + 255) / 256), blk, 0, stream>>>(Yb, Y_bf, MR * DSSM);
    cvt_bf16_k<<<dim3((DMODEL * DSSM / 4 + 255) / 256), blk, 0, stream>>>(W_out, Wo_bf, DMODEL * DSSM);
    gemm_mfma_nt<<<dim3(DMODEL / 128, MR / 128), blk, 0, stream>>>(
        Y_bf, Wo_bf, b_out, out, DMODEL, DSSM, DSSM / 32);
    timeout_k<<<dim3(BB * NHH), blk, 0, stream>>>(td, tdt, gw, gb, lnw, lnb, out2);
}

// Round 7
// 658.330 us; speedup vs baseline: 5.3023x; 1.1558x over previous
//
#include <hip/hip_runtime.h>
#include <math.h>

#define BB 2
#define SEQ 4096
#define DMODEL 768
#define DSTATE 128
#define NHH 24
#define HDIM 64
#define DSSM 1536
#define CDIM 1792
#define CHK 256
#define NC 16
#define DPROJ 3352
#define MR (BB*SEQ)
#define KSPLIT 16

typedef __attribute__((ext_vector_type(8))) short bf16x8;
typedef __attribute__((ext_vector_type(8))) unsigned short u16x8;
typedef __attribute__((ext_vector_type(4))) float f32x4;

__device__ __forceinline__ float siluf(float x) { return x / (1.0f + expf(-x)); }

__device__ __forceinline__ unsigned short f2bf(float f) {
    unsigned u = __float_as_uint(f);
    unsigned r = (u + 0x7fffu + ((u >> 16) & 1u)) >> 16;
    return (unsigned short)r;
}

__device__ __forceinline__ float bf2f(unsigned short u) {
    return __uint_as_float(((unsigned)u) << 16);
}

__device__ __forceinline__ void gload_lds16(const void* g, void* l) {
    __builtin_amdgcn_global_load_lds((const __attribute__((address_space(1))) unsigned int*)g,
                                     (__attribute__((address_space(3))) unsigned int*)l, 16, 0, 0);
}

// ---------------- f32 -> bf16 conversion (vectorized)
__global__ __launch_bounds__(256) void cvt_bf16_k(const float* __restrict__ in,
    unsigned short* __restrict__ out, int n)
{
    int i = (blockIdx.x * 256 + threadIdx.x) * 4;
    if (i >= n) return;
    float4 v = *(const float4*)&in[i];
    ushort4 o;
    o.x = f2bf(v.x); o.y = f2bf(v.y); o.z = f2bf(v.z); o.w = f2bf(v.w);
    *(ushort4*)&out[i] = o;
}

// ---------------- bf16 MFMA GEMM: C(MxN) = A(MxK) @ B(NxK)^T + bias(N)
__global__ __launch_bounds__(256) void gemm_mfma_nt(
    const unsigned short* __restrict__ A, const unsigned short* __restrict__ B,
    const float* __restrict__ bias, float* __restrict__ C, int N, int K, int KT)
{
    __shared__ unsigned short SA[2][128 * 32];
    __shared__ unsigned short SB[2][128 * 32];
    const int tid = threadIdx.x;
    const int w = tid >> 6, l = tid & 63;
    const int wr = w >> 1, wc = w & 1;
    const int lr = l & 15, lk = l >> 4;
    const int m0 = blockIdx.y * 128, n0 = blockIdx.x * 128;
    f32x4 acc[4][4] = {};
    const int i16 = w * 64 + l;
    const int row0 = i16 >> 2, sl = i16 & 3;
    const size_t ga0 = (size_t)(m0 + row0) * K + sl * 8;
    const size_t ga1 = (size_t)(m0 + row0 + 64) * K + sl * 8;
    const size_t gb0 = (size_t)(n0 + row0) * K + sl * 8;
    const size_t gb1 = (size_t)(n0 + row0 + 64) * K + sl * 8;
    const int lo0 = (w * 64) * 8;
    const int lo1 = (256 + w * 64) * 8;

#define STAGE(bb, kt) { int ko = (kt) * 32;                      \
      gload_lds16(A + ga0 + ko, &SA[bb][lo0]);                   \
      gload_lds16(A + ga1 + ko, &SA[bb][lo1]);                   \
      gload_lds16(B + gb0 + ko, &SB[bb][lo0]);                   \
      gload_lds16(B + gb1 + ko, &SB[bb][lo1]); }

    STAGE(0, 0);
    for (int kt = 0; kt < KT; ++kt) {
        int cur = kt & 1;
        asm volatile("s_waitcnt vmcnt(0)" ::: "memory");
        __syncthreads();
        if (kt + 1 < KT) STAGE(cur ^ 1, kt + 1);
        bf16x8 af[4], bg[4];
#pragma unroll
        for (int mi = 0; mi < 4; ++mi)
            af[mi] = *(const bf16x8*)&SA[cur][(wr * 64 + mi * 16 + lr) * 32 + lk * 8];
#pragma unroll
        for (int nj = 0; nj < 4; ++nj)
            bg[nj] = *(const bf16x8*)&SB[cur][(wc * 64 + nj * 16 + lr) * 32 + lk * 8];
#pragma unroll
        for (int mi = 0; mi < 4; ++mi)
#pragma unroll
            for (int nj = 0; nj < 4; ++nj)
                acc[mi][nj] = __builtin_amdgcn_mfma_f32_16x16x32_bf16(af[mi], bg[nj], acc[mi][nj], 0, 0, 0);
    }
#undef STAGE
#pragma unroll
    for (int nj = 0; nj < 4; ++nj) {
        int col = n0 + wc * 64 + nj * 16 + lr;
        float bz = bias[col];
#pragma unroll
        for (int mi = 0; mi < 4; ++mi) {
#pragma unroll
            for (int r = 0; r < 4; ++r) {
                int m = m0 + wr * 64 + mi * 16 + lk * 4 + r;
                C[(size_t)m * N + col] = acc[mi][nj][r] + bz;
            }
        }
    }
}

// ---------------- generic f32 GEMM (small shapes)
__global__ __launch_bounds__(256) void gemm_nt(const float* __restrict__ A,
    const float* __restrict__ Bw, const float* __restrict__ bias,
    float* __restrict__ C, int M, int N, int K, int act)
{
    __shared__ float As[16][68];
    __shared__ float Bs[16][68];
    const int tx = threadIdx.x & 15, ty = threadIdx.x >> 4;
    const int m0 = blockIdx.y * 64, n0 = blockIdx.x * 64;
    float acc[4][4] = {{0.f}};
    for (int k0 = 0; k0 < K; k0 += 16) {
        for (int idx = threadIdx.x; idx < 1024; idx += 256) {
            int r = idx >> 4, kk = idx & 15;
            int m = m0 + r, n = n0 + r;
            As[kk][r] = (m < M) ? A[(size_t)m * K + k0 + kk] : 0.0f;
            Bs[kk][r] = (n < N) ? Bw[(size_t)n * K + k0 + kk] : 0.0f;
        }
        __syncthreads();
#pragma unroll
        for (int kk = 0; kk < 16; ++kk) {
            float4 a4 = *(const float4*)&As[kk][ty * 4];
            float4 b4 = *(const float4*)&Bs[kk][tx * 4];
            float av[4] = {a4.x, a4.y, a4.z, a4.w};
            float bv[4] = {b4.x, b4.y, b4.z, b4.w};
#pragma unroll
            for (int i = 0; i < 4; ++i)
#pragma unroll
                for (int j = 0; j < 4; ++j)
                    acc[i][j] = fmaf(av[i], bv[j], acc[i][j]);
        }
        __syncthreads();
    }
#pragma unroll
    for (int i = 0; i < 4; ++i) {
        int m = m0 + ty * 4 + i;
        if (m >= M) continue;
#pragma unroll
        for (int j = 0; j < 4; ++j) {
            int n = n0 + tx * 4 + j;
            if (n >= N) continue;
            float v = acc[i][j] + bias[n];
            if (act == 1) v = siluf(v);
            C[(size_t)m * N + n] = v;
        }
    }
}

// ---------------- split-K skinny GEMM (M=48)
__global__ __launch_bounds__(256) void gemm_skinny_nt(const float* __restrict__ A,
    const float* __restrict__ Bw, float* __restrict__ part, int N, int K)
{
    __shared__ float sA[32][49];
    __shared__ float sB[32][133];
    const int nb = blockIdx.x, kb = blockIdx.y;
    const int n0 = nb * 128;
    const int KS = K / KSPLIT;
    const int k0 = kb * KS;
    const int tid = threadIdx.x;
    const int tx = tid & 31, ty = tid >> 5;
    float acc[6][4] = {{0.f}};
    for (int kc = 0; kc < KS; kc += 32) {
        for (int i = tid; i < 48 * 32; i += 256) {
            int m = i >> 5, kk = i & 31;
            sA[kk][m] = A[(size_t)m * K + k0 + kc + kk];
        }
        for (int i = tid; i < 128 * 32; i += 256) {
            int n = i >> 5, kk = i & 31;
            sB[kk][n] = Bw[(size_t)(n0 + n) * K + k0 + kc + kk];
        }
        __syncthreads();
#pragma unroll 4
        for (int kk = 0; kk < 32; ++kk) {
            float a[6], b[4];
#pragma unroll
            for (int r = 0; r < 6; ++r) a[r] = sA[kk][ty * 6 + r];
#pragma unroll
            for (int j = 0; j < 4; ++j) b[j] = sB[kk][tx * 4 + j];
#pragma unroll
            for (int r = 0; r < 6; ++r)
#pragma unroll
                for (int j = 0; j < 4; ++j)
                    acc[r][j] = fmaf(a[r], b[j], acc[r][j]);
        }
        __syncthreads();
    }
    float* pb = part + (size_t)kb * 48 * N;
#pragma unroll
    for (int r = 0; r < 6; ++r)
#pragma unroll
        for (int j = 0; j < 4; ++j)
            pb[(size_t)(ty * 6 + r) * N + n0 + tx * 4 + j] = acc[r][j];
}

// ---------------- reduce split-K partials + bias (+ optional silu)
__global__ __launch_bounds__(256) void reduce_part_k(const float* __restrict__ part,
    const float* __restrict__ bias, float* __restrict__ out, int N, int act)
{
    int idx = blockIdx.x * 256 + threadIdx.x;
    if (idx >= 48 * N) return;
    int n = idx % N;
    float s = bias[n];
#pragma unroll
    for (int kb = 0; kb < KSPLIT; ++kb) s += part[(size_t)kb * 48 * N + idx];
    if (act) s = siluf(s);
    out[idx] = s;
}

// ---------------- depthwise causal conv (window 4) + silu -> bf16 output
__global__ __launch_bounds__(256) void conv_xbc_k(const float* __restrict__ xbc,
    const float* __restrict__ cw, const float* __restrict__ cb,
    unsigned short* __restrict__ out)
{
    int idx = blockIdx.x * 256 + threadIdx.x;
    if (idx >= MR * CDIM) return;
    int c = idx % CDIM;
    int row = idx / CDIM;
    int t = row % SEQ;
    float acc = cb[c];
#pragma unroll
    for (int k = 0; k < 4; ++k) {
        int tt = t + k - 3;
        if (tt >= 0) acc = fmaf(xbc[(size_t)(row + k - 3) * CDIM + c], cw[c * 4 + k], acc);
    }
    out[idx] = f2bf(siluf(acc));
}

// ---------------- per-(b,h) row: tdt0 = ts*td; conv1+silu; conv2+silu
__global__ __launch_bounds__(256) void time_conv_k(const float* __restrict__ ts,
    const float* __restrict__ td, const float* __restrict__ w1, const float* __restrict__ b1,
    const float* __restrict__ w2, const float* __restrict__ b2, float* __restrict__ tdt)
{
    __shared__ float u0[SEQ];
    __shared__ float u1[SEQ];
    int row = blockIdx.x, h = row % NHH;
    const float* tsr = ts + (size_t)row * SEQ;
    const float* tdr = td + (size_t)row * SEQ;
    for (int i = threadIdx.x; i < SEQ; i += 256) u0[i] = tsr[i] * tdr[i];
    __syncthreads();
    float wa[4], wb[4];
#pragma unroll
    for (int k = 0; k < 4; ++k) { wa[k] = w1[h * 4 + k]; wb[k] = w2[h * 4 + k]; }
    float ba = b1[h], bbv = b2[h];
    for (int i = threadIdx.x; i < SEQ; i += 256) {
        float acc = ba;
#pragma unroll
        for (int k = 0; k < 4; ++k) { int tt = i + k - 3; if (tt >= 0) acc = fmaf(u0[tt], wa[k], acc); }
        u1[i] = siluf(acc);
    }
    __syncthreads();
    for (int i = threadIdx.x; i < SEQ; i += 256) {
        float acc = bbv;
#pragma unroll
        for (int k = 0; k < 4; ++k) { int tt = i + k - 3; if (tt >= 0) acc = fmaf(u1[tt], wb[k], acc); }
        tdt[(size_t)row * SEQ + i] = siluf(acc);
    }
}

// ---------------- dt_sp = softplus(dt * tdt^T + dt_bias)
__global__ __launch_bounds__(256) void dtsp_k(const float* __restrict__ dtraw,
    const float* __restrict__ tdt, const float* __restrict__ dt_bias, float* __restrict__ dtp)
{
    int idx = blockIdx.x * 256 + threadIdx.x;
    if (idx >= MR * NHH) return;
    int h = idx % NHH;
    int row = idx / NHH;
    int b = row / SEQ, s = row % SEQ;
    float x = dtraw[(size_t)row * NHH + h] * tdt[((size_t)(b * NHH + h)) * SEQ + s] + dt_bias[h];
    dtp[idx] = (x > 20.0f) ? x : log1pf(expf(x));
}

// ---------------- SSD chunk states via MFMA: st[p][n] = sum_z X[z][p]*coef[z]*B[z][n]
// per (b,c,h); K processed in 2 halves of 128; 4 waves each own 32 n-cols.
__global__ __launch_bounds__(256) void ssd_states_mfma_k(const unsigned short* __restrict__ xc,
    const float* __restrict__ dtp, const float* __restrict__ A_log,
    float* __restrict__ st, float* __restrict__ al)
{
    __shared__ float s_acs[256];
    __shared__ float s_coef[256];
    __shared__ unsigned short SXT[64 * 136];    // scaled X^T [p][z-half]
    __shared__ unsigned short SBT[128 * 136];   // B^T [n][z-half]
    int blk = blockIdx.x;
    int h = blk % NHH, c = (blk / NHH) % NC, b = blk / (NHH * NC);
    int tid = threadIdx.x;
    int w = tid >> 6, l = tid & 63;
    int lr = l & 15, lk = l >> 4;
    size_t rowbase = (size_t)b * SEQ + c * CHK;
    float Ah = -expf(A_log[h]);
    float dtv = dtp[(rowbase + tid) * NHH + h];
    s_acs[tid] = Ah * dtv;
    __syncthreads();
    for (int off = 1; off < 256; off <<= 1) {
        float t = (tid >= off) ? s_acs[tid - off] : 0.f;
        __syncthreads();
        s_acs[tid] += t;
        __syncthreads();
    }
    float alv = s_acs[255];
    s_coef[tid] = expf(alv - s_acs[tid]) * dtv;   // <= dt, no overflow
    if (tid == 255) al[blk] = alv;
    __syncthreads();
    f32x4 acc[4][2] = {};
    for (int z0 = 0; z0 < CHK; z0 += 128) {
        if (z0) __syncthreads();
        for (int i = tid; i < 128 * 8; i += 256) {
            int zz = i >> 3, p8 = (i & 7) * 8;
            float sc = s_coef[z0 + zz];
            u16x8 v = *(const u16x8*)&xc[(rowbase + z0 + zz) * CDIM + h * HDIM + p8];
#pragma unroll
            for (int e = 0; e < 8; ++e)
                SXT[(p8 + e) * 136 + zz] = f2bf(bf2f(v[e]) * sc);
        }
        for (int i = tid; i < 128 * 16; i += 256) {
            int zz = i >> 4, n8 = (i & 15) * 8;
            u16x8 v = *(const u16x8*)&xc[(rowbase + z0 + zz) * CDIM + DSSM + n8];
#pragma unroll
            for (int e = 0; e < 8; ++e)
                SBT[(n8 + e) * 136 + zz] = v[e];
        }
        __syncthreads();
#pragma unroll
        for (int kt = 0; kt < 4; ++kt) {
            bf16x8 av[4], bv[2];
#pragma unroll
            for (int mi = 0; mi < 4; ++mi)
                av[mi] = *(const bf16x8*)&SXT[(mi * 16 + lr) * 136 + kt * 32 + lk * 8];
#pragma unroll
            for (int nj = 0; nj < 2; ++nj)
                bv[nj] = *(const bf16x8*)&SBT[(w * 32 + nj * 16 + lr) * 136 + kt * 32 + lk * 8];
#pragma unroll
            for (int mi = 0; mi < 4; ++mi)
#pragma unroll
                for (int nj = 0; nj < 2; ++nj)
                    acc[mi][nj] = __builtin_amdgcn_mfma_f32_16x16x32_bf16(av[mi], bv[nj], acc[mi][nj], 0, 0, 0);
        }
    }
    size_t base = (size_t)blk * (HDIM * DSTATE);
#pragma unroll
    for (int mi = 0; mi < 4; ++mi)
#pragma unroll
        for (int r = 0; r < 4; ++r) {
            int p = mi * 16 + lk * 4 + r;
#pragma unroll
            for (int nj = 0; nj < 2; ++nj)
                st[base + p * DSTATE + w * 32 + nj * 16 + lr] = acc[mi][nj][r];
        }
}

// ---------------- inter-chunk scan
__global__ __launch_bounds__(256) void ssd_scan_k(const float* __restrict__ st,
    const float* __restrict__ al, float* __restrict__ pv)
{
    int b = blockIdx.x / NHH, h = blockIdx.x % NHH;
    int tid = threadIdx.x;
    float carry[32];
#pragma unroll
    for (int j = 0; j < 32; ++j) carry[j] = 0.f;
    for (int c = 0; c < NC; ++c) {
        int bch = (b * NC + c) * NHH + h;
        size_t base = (size_t)bch * (HDIM * DSTATE);
        float dcy = expf(al[bch]);
#pragma unroll
        for (int j = 0; j < 32; ++j) {
            pv[base + tid + j * 256] = carry[j];
            carry[j] = fmaf(dcy, carry[j], st[base + tid + j * 256]);
        }
    }
}

// ---------------- S_raw = C.B^T per (b,c), lower-triangular 64x64 tiles, bf16
__global__ __launch_bounds__(512) void ssd_sraw_k(const unsigned short* __restrict__ xc,
    unsigned short* __restrict__ sraw)
{
    __shared__ unsigned short SC[256 * 136];
    __shared__ unsigned short SB[256 * 136];
    int bc = blockIdx.x;
    int b = bc / NC, c = bc % NC;
    size_t rowbase = (size_t)b * SEQ + c * CHK;
    int tid = threadIdx.x;
    int w = tid >> 6, l = tid & 63;
    int lr = l & 15, lk = l >> 4;
    for (int i = tid; i < 256 * 32; i += 512) {
        int r = i >> 5, c4 = (i & 31) * 4;
        *(ushort4*)&SC[r * 136 + c4] = *(const ushort4*)&xc[(rowbase + r) * CDIM + DSSM + DSTATE + c4];
        *(ushort4*)&SB[r * 136 + c4] = *(const ushort4*)&xc[(rowbase + r) * CDIM + DSSM + c4];
    }
    __syncthreads();
    unsigned short* tb = sraw + (size_t)bc * 16 * 4096;
    int t = 0;
#pragma unroll
    for (int st = 0; st < 4; ++st) {
#pragma unroll
        for (int zt = 0; zt <= st; ++zt, ++t) {
            if ((t & 7) != w) continue;
            f32x4 d[4][4] = {};
#pragma unroll
            for (int kt = 0; kt < 4; ++kt) {
                bf16x8 av[4], bv[4];
#pragma unroll
                for (int mi = 0; mi < 4; ++mi)
                    av[mi] = *(const bf16x8*)&SC[(st * 64 + mi * 16 + lr) * 136 + kt * 32 + lk * 8];
#pragma unroll
                for (int nj = 0; nj < 4; ++nj)
                    bv[nj] = *(const bf16x8*)&SB[(zt * 64 + nj * 16 + lr) * 136 + kt * 32 + lk * 8];
#pragma unroll
                for (int mi = 0; mi < 4; ++mi)
#pragma unroll
                    for (int nj = 0; nj < 4; ++nj)
                        d[mi][nj] = __builtin_amdgcn_mfma_f32_16x16x32_bf16(av[mi], bv[nj], d[mi][nj], 0, 0, 0);
            }
            unsigned short* tp = tb + (size_t)(st * 4 + zt) * 4096;
#pragma unroll
            for (int mi = 0; mi < 4; ++mi)
#pragma unroll
                for (int nj = 0; nj < 4; ++nj)
#pragma unroll
                    for (int r = 0; r < 4; ++r)
                        tp[(mi * 16 + lk * 4 + r) * 64 + nj * 16 + lr] = f2bf(d[mi][nj][r]);
        }
    }
}

// ---------------- Y from precomputed S_raw: per (b,c,h), 4 waves = 4 s-tiles.
__global__ __launch_bounds__(256) void ssd_y2_k(const unsigned short* __restrict__ xc,
    const float* __restrict__ dtp, const float* __restrict__ A_log,
    const unsigned short* __restrict__ sraw, const float* __restrict__ pv,
    const float* __restrict__ Dp, float* __restrict__ Y)
{
    __shared__ float s_acs[256];
    __shared__ float s_dt[256];
    __shared__ float s_edt[256];
    __shared__ float s_az0[4];
    __shared__ unsigned short SXT[64 * 264];   // [p][z]
    __shared__ unsigned short SPV[64 * 136];   // [p][n]
    int blk = blockIdx.x;
    int h = blk % NHH;
    int c = (blk / NHH) % NC;
    int b = blk / (NHH * NC);
    int tid = threadIdx.x;
    int w = tid >> 6, l = tid & 63;
    int lr = l & 15, lk = l >> 4;
    size_t rowbase = (size_t)b * SEQ + c * CHK;
    float Ah = -expf(A_log[h]);
    float dtv = dtp[(rowbase + tid) * NHH + h];
    s_dt[tid] = dtv;
    s_acs[tid] = Ah * dtv;
    __syncthreads();
    for (int off = 1; off < 256; off <<= 1) {
        float t = (tid >= off) ? s_acs[tid - off] : 0.f;
        __syncthreads();
        s_acs[tid] += t;
        __syncthreads();
    }
    if (tid < 4) s_az0[tid] = s_acs[tid * 64];
    __syncthreads();
    {
        float e = s_az0[tid >> 6] - s_acs[tid];
        if (e > 60.f) e = 60.f;
        s_edt[tid] = expf(e) * s_dt[tid];
    }
    __syncthreads();
    for (int i = tid; i < 256 * 8; i += 256) {
        int z = i >> 3, p8 = (i & 7) * 8;
        float sc = s_edt[z];
        u16x8 v = *(const u16x8*)&xc[(rowbase + z) * CDIM + h * HDIM + p8];
#pragma unroll
        for (int e = 0; e < 8; ++e)
            SXT[(p8 + e) * 264 + z] = f2bf(bf2f(v[e]) * sc);
    }
    const float* pvbase = pv + (size_t)blk * (HDIM * DSTATE);
    for (int i = tid; i < 64 * 32; i += 256) {
        int p = i >> 5, n4 = (i & 31) * 4;
        float4 v = *(const float4*)&pvbase[p * DSTATE + n4];
        ushort4 o; o.x = f2bf(v.x); o.y = f2bf(v.y); o.z = f2bf(v.z); o.w = f2bf(v.w);
        *(ushort4*)&SPV[p * 136 + n4] = o;
    }
    __syncthreads();

    const unsigned short* tbase = sraw + (size_t)(b * NC + c) * 16 * 4096;
    f32x4 acc[4][4] = {};
    for (int zt = 0; zt <= w; ++zt) {
        const unsigned short* tp = tbase + (size_t)(w * 4 + zt) * 4096;
        f32x4 tmp[4][4] = {};
#pragma unroll
        for (int kt = 0; kt < 2; ++kt) {
            bf16x8 av[4], bv[4];
#pragma unroll
            for (int mi = 0; mi < 4; ++mi) {
                av[mi] = *(const bf16x8*)&tp[(mi * 16 + lr) * 64 + kt * 32 + lk * 8];
                if (zt == w) {
                    int zb = kt * 32 + lk * 8;
                    int sl = mi * 16 + lr;
#pragma unroll
                    for (int e = 0; e < 8; ++e)
                        if (zb + e > sl) av[mi][e] = 0;
                }
            }
#pragma unroll
            for (int nj = 0; nj < 4; ++nj)
                bv[nj] = *(const bf16x8*)&SXT[(nj * 16 + lr) * 264 + zt * 64 + kt * 32 + lk * 8];
#pragma unroll
            for (int mi = 0; mi < 4; ++mi)
#pragma unroll
                for (int nj = 0; nj < 4; ++nj)
                    tmp[mi][nj] = __builtin_amdgcn_mfma_f32_16x16x32_bf16(av[mi], bv[nj], tmp[mi][nj], 0, 0, 0);
        }
        float az = s_az0[zt];
#pragma unroll
        for (int mi = 0; mi < 4; ++mi) {
#pragma unroll
            for (int r = 0; r < 4; ++r) {
                float es = expf(s_acs[w * 64 + mi * 16 + lk * 4 + r] - az);
#pragma unroll
                for (int nj = 0; nj < 4; ++nj)
                    acc[mi][nj][r] += es * tmp[mi][nj][r];
            }
        }
    }
    // off-chunk: C.prev^T * exp(acs[s]) — C read directly as bf16
    {
        f32x4 tmp[4][4] = {};
#pragma unroll
        for (int kt = 0; kt < 4; ++kt) {
            bf16x8 av[4], bv[4];
#pragma unroll
            for (int mi = 0; mi < 4; ++mi)
                av[mi] = *(const bf16x8*)&xc[(rowbase + w * 64 + mi * 16 + lr) * CDIM + DSSM + DSTATE + kt * 32 + lk * 8];
#pragma unroll
            for (int nj = 0; nj < 4; ++nj)
                bv[nj] = *(const bf16x8*)&SPV[(nj * 16 + lr) * 136 + kt * 32 + lk * 8];
#pragma unroll
            for (int mi = 0; mi < 4; ++mi)
#pragma unroll
                for (int nj = 0; nj < 4; ++nj)
                    tmp[mi][nj] = __builtin_amdgcn_mfma_f32_16x16x32_bf16(av[mi], bv[nj], tmp[mi][nj], 0, 0, 0);
        }
#pragma unroll
        for (int mi = 0; mi < 4; ++mi) {
#pragma unroll
            for (int r = 0; r < 4; ++r) {
                float es = expf(s_acs[w * 64 + mi * 16 + lk * 4 + r]);
#pragma unroll
                for (int nj = 0; nj < 4; ++nj)
                    acc[mi][nj][r] += es * tmp[mi][nj][r];
            }
        }
    }
    float dph = Dp[h];
#pragma unroll
    for (int mi = 0; mi < 4; ++mi) {
#pragma unroll
        for (int r = 0; r < 4; ++r) {
            int s = w * 64 + mi * 16 + lk * 4 + r;
#pragma unroll
            for (int nj = 0; nj < 4; ++nj) {
                int p = nj * 16 + lr;
                float xv = bf2f(xc[(rowbase + s) * CDIM + h * HDIM + p]);
                Y[(rowbase + s) * DSSM + h * HDIM + p] = acc[mi][nj][r] + dph * xv;
            }
        }
    }
}

// ---------------- gated RMS norm in place
__global__ __launch_bounds__(256) void rmsnorm_k(float* __restrict__ Y,
    const float* __restrict__ zbuf, const float* __restrict__ nw)
{
    __shared__ float red[8];
    int row = blockIdx.x;
    float* y = Y + (size_t)row * DSSM;
    const float* z = zbuf + (size_t)row * DSSM;
    float v[6];
    float ss = 0.f;
#pragma unroll
    for (int k = 0; k < 6; ++k) {
        int i = threadIdx.x + k * 256;
        float g = y[i] * siluf(z[i]);
        v[k] = g;
        ss = fmaf(g, g, ss);
    }
#pragma unroll
    for (int o = 32; o > 0; o >>= 1) ss += __shfl_down(ss, o, 64);
    int wv = threadIdx.x >> 6, ln = threadIdx.x & 63;
    if (ln == 0) red[wv] = ss;
    __syncthreads();
    float tot = red[0] + red[1] + red[2] + red[3];
    float sc = rsqrtf(tot / (float)DSSM + 1e-12f);
#pragma unroll
    for (int k = 0; k < 6; ++k) {
        int i = threadIdx.x + k * 256;
        y[i] = v[k] * sc * nw[i];
    }
}

// ---------------- time_out: gate + mix + LayerNorm over SEQ
__global__ __launch_bounds__(256) void timeout_k(const float* __restrict__ td,
    const float* __restrict__ tdt, const float* __restrict__ gw, const float* __restrict__ gb,
    const float* __restrict__ lnw, const float* __restrict__ lnb, float* __restrict__ out2)
{
    __shared__ float tm[SEQ];
    __shared__ float red[8];
    int row = blockIdx.x;
    const float* tdr = td + (size_t)row * SEQ;
    const float* tdtr = tdt + (size_t)row * SEQ;
    int wv = threadIdx.x >> 6, ln = threadIdx.x & 63;
    float part = 0.f;
    for (int i = threadIdx.x; i < SEQ; i += 256) part = fmaf(tdr[i], gw[i], part);
#pragma unroll
    for (int o = 32; o > 0; o >>= 1) part += __shfl_down(part, o, 64);
    if (ln == 0) red[wv] = part;
    __syncthreads();
    float dot = red[0] + red[1] + red[2] + red[3];
    float tg = 1.f / (1.f + expf(-(dot + gb[0])));
    __syncthreads();
    float sum = 0.f;
    for (int i = threadIdx.x; i < SEQ; i += 256) {
        float x = tg * tdr[i] + (1.f - tg) * tdtr[i];
        tm[i] = x;
        sum += x;
    }
#pragma unroll
    for (int o = 32; o > 0; o >>= 1) sum += __shfl_down(sum, o, 64);
    if (ln == 0) red[wv] = sum;
    __syncthreads();
    float mu = (red[0] + red[1] + red[2] + red[3]) / (float)SEQ;
    __syncthreads();
    float s2 = 0.f;
    for (int i = threadIdx.x; i < SEQ; i += 256) { float d = tm[i] - mu; s2 = fmaf(d, d, s2); }
#pragma unroll
    for (int o = 32; o > 0; o >>= 1) s2 += __shfl_down(s2, o, 64);
    if (ln == 0) red[wv] = s2;
    __syncthreads();
    float var = (red[0] + red[1] + red[2] + red[3]) / (float)SEQ;
    float inv = rsqrtf(var + 1e-12f);
    for (int i = threadIdx.x; i < SEQ; i += 256)
        out2[(size_t)row * SEQ + i] = (tm[i] - mu) * inv * lnw[i] + lnb[i];
}

extern "C" void kernel_launch(void* const* d_in, const int* in_sizes, int n_in,
                              void* d_out, int out_size, void* d_ws, size_t ws_size,
                              hipStream_t stream)
{
    const float* u      = (const float*)d_in[0];
    const float* td     = (const float*)d_in[1];
    const float* W_in   = (const float*)d_in[2];
    const float* b_in   = (const float*)d_in[3];
    const float* conv_w = (const float*)d_in[4];
    const float* conv_b = (const float*)d_in[5];
    const float* t1w    = (const float*)d_in[6];
    const float* t1b    = (const float*)d_in[7];
    const float* t2w    = (const float*)d_in[8];
    const float* t2b    = (const float*)d_in[9];
    const float* m1w    = (const float*)d_in[10];
    const float* m1b    = (const float*)d_in[11];
    const float* m2w    = (const float*)d_in[12];
    const float* m2b    = (const float*)d_in[13];
    const float* gw     = (const float*)d_in[14];
    const float* gb     = (const float*)d_in[15];
    const float* lnw    = (const float*)d_in[16];
    const float* lnb    = (const float*)d_in[17];
    const float* A_log  = (const float*)d_in[18];
    const float* dt_bias= (const float*)d_in[19];
    const float* Dpv    = (const float*)d_in[20];
    const float* nw     = (const float*)d_in[21];
    const float* W_out  = (const float*)d_in[22];
    const float* b_out  = (const float*)d_in[23];
    float* out  = (float*)d_out;
    float* out2 = out + (size_t)MR * DMODEL;

    float* ws = (float*)d_ws;
    size_t o = 0;
    float* zbuf  = ws + o; o += (size_t)MR * DSSM;
    float* r1    = ws + o; o += (size_t)MR * CDIM;
    float* xcv   = ws + o; o += (size_t)MR * CDIM;   // bf16 activations; also split-K partials early
    float* dtraw = ws + o; o += (size_t)MR * NHH;
    float* hid   = ws + o; o += (size_t)BB * NHH * SEQ;
    float* tss   = ws + o; o += (size_t)BB * NHH * SEQ;
    float* tdt   = ws + o; o += (size_t)BB * NHH * SEQ;
    float* dtp   = ws + o; o += (size_t)MR * NHH;
    float* pvb   = ws + o; o += (size_t)BB * NC * NHH * HDIM * DSTATE;
    float* alb   = ws + o; o += (size_t)BB * NC * NHH;
    unsigned short* sraw = (unsigned short*)(ws + o); o += (size_t)BB * NC * 16 * 4096 / 2;
    float* stb = r1;
    float* Yb  = r1;
    float* partb = xcv;
    unsigned short* xcv_bf = (unsigned short*)xcv;
    unsigned short* u_bf  = (unsigned short*)pvb;
    unsigned short* Wi_bf = (unsigned short*)(pvb + 3145728);
    unsigned short* Y_bf  = (unsigned short*)zbuf;
    unsigned short* Wo_bf = (unsigned short*)(zbuf + 6291456);

    dim3 blk(256);
    // --- time MLP first (partials use xcv region, dead until conv) ---
    gemm_skinny_nt<<<dim3(SEQ / 128, KSPLIT), blk, 0, stream>>>(td, m1w, partb, SEQ, SEQ);
    reduce_part_k<<<dim3((48 * SEQ + 255) / 256), blk, 0, stream>>>(partb, m1b, hid, SEQ, 1);
    gemm_skinny_nt<<<dim3(SEQ / 128, KSPLIT), blk, 0, stream>>>(hid, m2w, partb, SEQ, SEQ);
    reduce_part_k<<<dim3((48 * SEQ + 255) / 256), blk, 0, stream>>>(partb, m2b, tss, SEQ, 0);
    time_conv_k<<<dim3(BB * NHH), blk, 0, stream>>>(tss, td, t1w, t1b, t2w, t2b, tdt);
    // --- in-proj ---
    cvt_bf16_k<<<dim3((MR * DMODEL / 4 + 255) / 256), blk, 0, stream>>>(u, u_bf, MR * DMODEL);
    cvt_bf16_k<<<dim3((3328 * DMODEL / 4 + 255) / 256), blk, 0, stream>>>(W_in, Wi_bf, 3328 * DMODEL);
    gemm_mfma_nt<<<dim3(CDIM / 128, MR / 128), blk, 0, stream>>>(
        u_bf, Wi_bf + (size_t)DSSM * DMODEL, b_in + DSSM, r1, CDIM, DMODEL, DMODEL / 32);
    conv_xbc_k<<<dim3((MR * CDIM + 255) / 256), blk, 0, stream>>>(r1, conv_w, conv_b, xcv_bf);
    gemm_mfma_nt<<<dim3(DSSM / 128, MR / 128), blk, 0, stream>>>(
        u_bf, Wi_bf, b_in, zbuf, DSSM, DMODEL, DMODEL / 32);
    gemm_nt<<<dim3(1, MR / 64), blk, 0, stream>>>(
        u, W_in + (size_t)(DSSM + CDIM) * DMODEL, b_in + DSSM + CDIM, dtraw, MR, NHH, DMODEL, 0);
    dtsp_k<<<dim3((MR * NHH + 255) / 256), blk, 0, stream>>>(dtraw, tdt, dt_bias, dtp);
    // --- SSD ---
    ssd_sraw_k<<<dim3(BB * NC), dim3(512), 0, stream>>>(xcv_bf, sraw);
    ssd_states_mfma_k<<<dim3(BB * NC * NHH), blk, 0, stream>>>(xcv_bf, dtp, A_log, stb, alb);
    ssd_scan_k<<<dim3(BB * NHH), blk, 0, stream>>>(stb, alb, pvb);
    ssd_y2_k<<<dim3(BB * NC * NHH), blk, 0, stream>>>(xcv_bf, dtp, A_log, sraw, pvb, Dpv, Yb);
    // --- epilogue ---
    rmsnorm_k<<<dim3(MR), blk, 0, stream>>>(Yb, zbuf, nw);
    cvt_bf16_k<<<dim3((MR * DSSM / 4 + 255) / 256), blk, 0, stream>>>(Yb, Y_bf, MR * DSSM);
    cvt_bf16_k<<<dim3((DMODEL * DSSM / 4 + 255) / 256), blk, 0, stream>>>(W_out, Wo_bf, DMODEL * DSSM);
    gemm_mfma_nt<<<dim3(DMODEL / 128, MR / 128), blk, 0, stream>>>(
        Y_bf, Wo_bf, b_out, out, DMODEL, DSSM, DSSM / 32);
    timeout_k<<<dim3(BB * NHH), blk, 0, stream>>>(td, tdt, gw, gb, lnw, lnb, out2);
}

// Round 8
// 541.499 us; speedup vs baseline: 6.4463x; 1.2158x over previous
//
#include <hip/hip_runtime.h>
#include <math.h>

#define BB 2
#define SEQ 4096
#define DMODEL 768
#define DSTATE 128
#define NHH 24
#define HDIM 64
#define DSSM 1536
#define CDIM 1792
#define CHK 256
#define NC 16
#define DPROJ 3352
#define MR (BB*SEQ)
#define KSPLIT 16
#define XSTR 1920   // r1 row stride: xBC(1792) + dt(24) + pad(104)

typedef __attribute__((ext_vector_type(8))) short bf16x8;
typedef __attribute__((ext_vector_type(8))) unsigned short u16x8;
typedef __attribute__((ext_vector_type(4))) float f32x4;

__device__ __forceinline__ float siluf(float x) { return x / (1.0f + expf(-x)); }

__device__ __forceinline__ unsigned short f2bf(float f) {
    unsigned u = __float_as_uint(f);
    unsigned r = (u + 0x7fffu + ((u >> 16) & 1u)) >> 16;
    return (unsigned short)r;
}

__device__ __forceinline__ float bf2f(unsigned short u) {
    return __uint_as_float(((unsigned)u) << 16);
}

__device__ __forceinline__ void gload_lds16(const void* g, void* l) {
    __builtin_amdgcn_global_load_lds((const __attribute__((address_space(1))) unsigned int*)g,
                                     (__attribute__((address_space(3))) unsigned int*)l, 16, 0, 0);
}

// ---------------- f32 -> bf16 conversion (vectorized), zero-pad beyond n_valid
__global__ __launch_bounds__(256) void cvt_bf16_k(const float* __restrict__ in,
    unsigned short* __restrict__ out, int n_valid, int n_total)
{
    int i = (blockIdx.x * 256 + threadIdx.x) * 4;
    if (i >= n_total) return;
    ushort4 o;
    if (i + 3 < n_valid) {
        float4 v = *(const float4*)&in[i];
        o.x = f2bf(v.x); o.y = f2bf(v.y); o.z = f2bf(v.z); o.w = f2bf(v.w);
    } else {
        o.x = (i + 0 < n_valid) ? f2bf(in[i + 0]) : 0;
        o.y = (i + 1 < n_valid) ? f2bf(in[i + 1]) : 0;
        o.z = (i + 2 < n_valid) ? f2bf(in[i + 2]) : 0;
        o.w = (i + 3 < n_valid) ? f2bf(in[i + 3]) : 0;
    }
    *(ushort4*)&out[i] = o;
}

// ---------------- bf16 MFMA GEMM: C(MxN) = A(MxK) @ B(NxK)^T + bias(N, guarded at nbias)
__global__ __launch_bounds__(256) void gemm_mfma_nt(
    const unsigned short* __restrict__ A, const unsigned short* __restrict__ B,
    const float* __restrict__ bias, float* __restrict__ C, int N, int K, int KT, int nbias)
{
    __shared__ unsigned short SA[2][128 * 32];
    __shared__ unsigned short SB[2][128 * 32];
    const int tid = threadIdx.x;
    const int w = tid >> 6, l = tid & 63;
    const int wr = w >> 1, wc = w & 1;
    const int lr = l & 15, lk = l >> 4;
    const int m0 = blockIdx.y * 128, n0 = blockIdx.x * 128;
    f32x4 acc[4][4] = {};
    const int i16 = w * 64 + l;
    const int row0 = i16 >> 2, sl = i16 & 3;
    const size_t ga0 = (size_t)(m0 + row0) * K + sl * 8;
    const size_t ga1 = (size_t)(m0 + row0 + 64) * K + sl * 8;
    const size_t gb0 = (size_t)(n0 + row0) * K + sl * 8;
    const size_t gb1 = (size_t)(n0 + row0 + 64) * K + sl * 8;
    const int lo0 = (w * 64) * 8;
    const int lo1 = (256 + w * 64) * 8;

#define STAGE(bb, kt) { int ko = (kt) * 32;                      \
      gload_lds16(A + ga0 + ko, &SA[bb][lo0]);                   \
      gload_lds16(A + ga1 + ko, &SA[bb][lo1]);                   \
      gload_lds16(B + gb0 + ko, &SB[bb][lo0]);                   \
      gload_lds16(B + gb1 + ko, &SB[bb][lo1]); }

    STAGE(0, 0);
    for (int kt = 0; kt < KT; ++kt) {
        int cur = kt & 1;
        asm volatile("s_waitcnt vmcnt(0)" ::: "memory");
        __syncthreads();
        if (kt + 1 < KT) STAGE(cur ^ 1, kt + 1);
        bf16x8 af[4], bg[4];
#pragma unroll
        for (int mi = 0; mi < 4; ++mi)
            af[mi] = *(const bf16x8*)&SA[cur][(wr * 64 + mi * 16 + lr) * 32 + lk * 8];
#pragma unroll
        for (int nj = 0; nj < 4; ++nj)
            bg[nj] = *(const bf16x8*)&SB[cur][(wc * 64 + nj * 16 + lr) * 32 + lk * 8];
#pragma unroll
        for (int mi = 0; mi < 4; ++mi)
#pragma unroll
            for (int nj = 0; nj < 4; ++nj)
                acc[mi][nj] = __builtin_amdgcn_mfma_f32_16x16x32_bf16(af[mi], bg[nj], acc[mi][nj], 0, 0, 0);
    }
#undef STAGE
#pragma unroll
    for (int nj = 0; nj < 4; ++nj) {
        int col = n0 + wc * 64 + nj * 16 + lr;
        float bz = (col < nbias) ? bias[col] : 0.f;
#pragma unroll
        for (int mi = 0; mi < 4; ++mi) {
#pragma unroll
            for (int r = 0; r < 4; ++r) {
                int m = m0 + wr * 64 + mi * 16 + lk * 4 + r;
                C[(size_t)m * N + col] = acc[mi][nj][r] + bz;
            }
        }
    }
}

// ---------------- split-K skinny GEMM (M=48)
__global__ __launch_bounds__(256) void gemm_skinny_nt(const float* __restrict__ A,
    const float* __restrict__ Bw, float* __restrict__ part, int N, int K)
{
    __shared__ float sA[32][49];
    __shared__ float sB[32][133];
    const int nb = blockIdx.x, kb = blockIdx.y;
    const int n0 = nb * 128;
    const int KS = K / KSPLIT;
    const int k0 = kb * KS;
    const int tid = threadIdx.x;
    const int tx = tid & 31, ty = tid >> 5;
    float acc[6][4] = {{0.f}};
    for (int kc = 0; kc < KS; kc += 32) {
        for (int i = tid; i < 48 * 32; i += 256) {
            int m = i >> 5, kk = i & 31;
            sA[kk][m] = A[(size_t)m * K + k0 + kc + kk];
        }
        for (int i = tid; i < 128 * 32; i += 256) {
            int n = i >> 5, kk = i & 31;
            sB[kk][n] = Bw[(size_t)(n0 + n) * K + k0 + kc + kk];
        }
        __syncthreads();
#pragma unroll 4
        for (int kk = 0; kk < 32; ++kk) {
            float a[6], b[4];
#pragma unroll
            for (int r = 0; r < 6; ++r) a[r] = sA[kk][ty * 6 + r];
#pragma unroll
            for (int j = 0; j < 4; ++j) b[j] = sB[kk][tx * 4 + j];
#pragma unroll
            for (int r = 0; r < 6; ++r)
#pragma unroll
                for (int j = 0; j < 4; ++j)
                    acc[r][j] = fmaf(a[r], b[j], acc[r][j]);
        }
        __syncthreads();
    }
    float* pb = part + (size_t)kb * 48 * N;
#pragma unroll
    for (int r = 0; r < 6; ++r)
#pragma unroll
        for (int j = 0; j < 4; ++j)
            pb[(size_t)(ty * 6 + r) * N + n0 + tx * 4 + j] = acc[r][j];
}

// ---------------- reduce split-K partials + bias (+ optional silu)
__global__ __launch_bounds__(256) void reduce_part_k(const float* __restrict__ part,
    const float* __restrict__ bias, float* __restrict__ out, int N, int act)
{
    int idx = blockIdx.x * 256 + threadIdx.x;
    if (idx >= 48 * N) return;
    int n = idx % N;
    float s = bias[n];
#pragma unroll
    for (int kb = 0; kb < KSPLIT; ++kb) s += part[(size_t)kb * 48 * N + idx];
    if (act) s = siluf(s);
    out[idx] = s;
}

// ---------------- depthwise causal conv (window 4) + silu -> bf16 output
// input stride XSTR (combined xBC+dt buffer), only cols < CDIM convolved
__global__ __launch_bounds__(256) void conv_xbc_k(const float* __restrict__ xbc,
    const float* __restrict__ cw, const float* __restrict__ cb,
    unsigned short* __restrict__ out)
{
    int idx = blockIdx.x * 256 + threadIdx.x;
    if (idx >= MR * CDIM) return;
    int c = idx % CDIM;
    int row = idx / CDIM;
    int t = row % SEQ;
    float acc = cb[c];
#pragma unroll
    for (int k = 0; k < 4; ++k) {
        int tt = t + k - 3;
        if (tt >= 0) acc = fmaf(xbc[(size_t)(row + k - 3) * XSTR + c], cw[c * 4 + k], acc);
    }
    out[idx] = f2bf(siluf(acc));
}

// ---------------- per-(b,h) row: tdt0 = ts*td; conv1+silu; conv2+silu
__global__ __launch_bounds__(256) void time_conv_k(const float* __restrict__ ts,
    const float* __restrict__ td, const float* __restrict__ w1, const float* __restrict__ b1,
    const float* __restrict__ w2, const float* __restrict__ b2, float* __restrict__ tdt)
{
    __shared__ float u0[SEQ];
    __shared__ float u1[SEQ];
    int row = blockIdx.x, h = row % NHH;
    const float* tsr = ts + (size_t)row * SEQ;
    const float* tdr = td + (size_t)row * SEQ;
    for (int i = threadIdx.x; i < SEQ; i += 256) u0[i] = tsr[i] * tdr[i];
    __syncthreads();
    float wa[4], wb[4];
#pragma unroll
    for (int k = 0; k < 4; ++k) { wa[k] = w1[h * 4 + k]; wb[k] = w2[h * 4 + k]; }
    float ba = b1[h], bbv = b2[h];
    for (int i = threadIdx.x; i < SEQ; i += 256) {
        float acc = ba;
#pragma unroll
        for (int k = 0; k < 4; ++k) { int tt = i + k - 3; if (tt >= 0) acc = fmaf(u0[tt], wa[k], acc); }
        u1[i] = siluf(acc);
    }
    __syncthreads();
    for (int i = threadIdx.x; i < SEQ; i += 256) {
        float acc = bbv;
#pragma unroll
        for (int k = 0; k < 4; ++k) { int tt = i + k - 3; if (tt >= 0) acc = fmaf(u1[tt], wb[k], acc); }
        tdt[(size_t)row * SEQ + i] = siluf(acc);
    }
}

// ---------------- dt_sp = softplus(dt * tdt^T + dt_bias); dt read from r1 col 1792+h
__global__ __launch_bounds__(256) void dtsp_k(const float* __restrict__ r1,
    const float* __restrict__ tdt, const float* __restrict__ dt_bias, float* __restrict__ dtp)
{
    int idx = blockIdx.x * 256 + threadIdx.x;
    if (idx >= MR * NHH) return;
    int h = idx % NHH;
    int row = idx / NHH;
    int b = row / SEQ, s = row % SEQ;
    float x = r1[(size_t)row * XSTR + CDIM + h] * tdt[((size_t)(b * NHH + h)) * SEQ + s] + dt_bias[h];
    dtp[idx] = (x > 20.0f) ? x : log1pf(expf(x));
}

// ---------------- SSD chunk states via MFMA
__global__ __launch_bounds__(256) void ssd_states_mfma_k(const unsigned short* __restrict__ xc,
    const float* __restrict__ dtp, const float* __restrict__ A_log,
    float* __restrict__ st, float* __restrict__ al)
{
    __shared__ float s_acs[256];
    __shared__ float s_coef[256];
    __shared__ unsigned short SXT[64 * 136];
    __shared__ unsigned short SBT[128 * 136];
    int blk = blockIdx.x;
    int h = blk % NHH, c = (blk / NHH) % NC, b = blk / (NHH * NC);
    int tid = threadIdx.x;
    int w = tid >> 6, l = tid & 63;
    int lr = l & 15, lk = l >> 4;
    size_t rowbase = (size_t)b * SEQ + c * CHK;
    float Ah = -expf(A_log[h]);
    float dtv = dtp[(rowbase + tid) * NHH + h];
    s_acs[tid] = Ah * dtv;
    __syncthreads();
    for (int off = 1; off < 256; off <<= 1) {
        float t = (tid >= off) ? s_acs[tid - off] : 0.f;
        __syncthreads();
        s_acs[tid] += t;
        __syncthreads();
    }
    float alv = s_acs[255];
    s_coef[tid] = expf(alv - s_acs[tid]) * dtv;
    if (tid == 255) al[blk] = alv;
    __syncthreads();
    f32x4 acc[4][2] = {};
    for (int z0 = 0; z0 < CHK; z0 += 128) {
        if (z0) __syncthreads();
        for (int i = tid; i < 128 * 8; i += 256) {
            int zz = i >> 3, p8 = (i & 7) * 8;
            float sc = s_coef[z0 + zz];
            u16x8 v = *(const u16x8*)&xc[(rowbase + z0 + zz) * CDIM + h * HDIM + p8];
#pragma unroll
            for (int e = 0; e < 8; ++e)
                SXT[(p8 + e) * 136 + zz] = f2bf(bf2f(v[e]) * sc);
        }
        for (int i = tid; i < 128 * 16; i += 256) {
            int zz = i >> 4, n8 = (i & 15) * 8;
            u16x8 v = *(const u16x8*)&xc[(rowbase + z0 + zz) * CDIM + DSSM + n8];
#pragma unroll
            for (int e = 0; e < 8; ++e)
                SBT[(n8 + e) * 136 + zz] = v[e];
        }
        __syncthreads();
#pragma unroll
        for (int kt = 0; kt < 4; ++kt) {
            bf16x8 av[4], bv[2];
#pragma unroll
            for (int mi = 0; mi < 4; ++mi)
                av[mi] = *(const bf16x8*)&SXT[(mi * 16 + lr) * 136 + kt * 32 + lk * 8];
#pragma unroll
            for (int nj = 0; nj < 2; ++nj)
                bv[nj] = *(const bf16x8*)&SBT[(w * 32 + nj * 16 + lr) * 136 + kt * 32 + lk * 8];
#pragma unroll
            for (int mi = 0; mi < 4; ++mi)
#pragma unroll
                for (int nj = 0; nj < 2; ++nj)
                    acc[mi][nj] = __builtin_amdgcn_mfma_f32_16x16x32_bf16(av[mi], bv[nj], acc[mi][nj], 0, 0, 0);
        }
    }
    size_t base = (size_t)blk * (HDIM * DSTATE);
#pragma unroll
    for (int mi = 0; mi < 4; ++mi)
#pragma unroll
        for (int r = 0; r < 4; ++r) {
            int p = mi * 16 + lk * 4 + r;
#pragma unroll
            for (int nj = 0; nj < 2; ++nj)
                st[base + p * DSTATE + w * 32 + nj * 16 + lr] = acc[mi][nj][r];
        }
}

// ---------------- inter-chunk scan
__global__ __launch_bounds__(256) void ssd_scan_k(const float* __restrict__ st,
    const float* __restrict__ al, float* __restrict__ pv)
{
    int b = blockIdx.x / NHH, h = blockIdx.x % NHH;
    int tid = threadIdx.x;
    float carry[32];
#pragma unroll
    for (int j = 0; j < 32; ++j) carry[j] = 0.f;
    for (int c = 0; c < NC; ++c) {
        int bch = (b * NC + c) * NHH + h;
        size_t base = (size_t)bch * (HDIM * DSTATE);
        float dcy = expf(al[bch]);
#pragma unroll
        for (int j = 0; j < 32; ++j) {
            pv[base + tid + j * 256] = carry[j];
            carry[j] = fmaf(dcy, carry[j], st[base + tid + j * 256]);
        }
    }
}

// ---------------- S_raw = C.B^T per (b,c), lower-triangular 64x64 tiles, bf16
__global__ __launch_bounds__(512) void ssd_sraw_k(const unsigned short* __restrict__ xc,
    unsigned short* __restrict__ sraw)
{
    __shared__ unsigned short SC[256 * 136];
    __shared__ unsigned short SB[256 * 136];
    int bc = blockIdx.x;
    int b = bc / NC, c = bc % NC;
    size_t rowbase = (size_t)b * SEQ + c * CHK;
    int tid = threadIdx.x;
    int w = tid >> 6, l = tid & 63;
    int lr = l & 15, lk = l >> 4;
    for (int i = tid; i < 256 * 32; i += 512) {
        int r = i >> 5, c4 = (i & 31) * 4;
        *(ushort4*)&SC[r * 136 + c4] = *(const ushort4*)&xc[(rowbase + r) * CDIM + DSSM + DSTATE + c4];
        *(ushort4*)&SB[r * 136 + c4] = *(const ushort4*)&xc[(rowbase + r) * CDIM + DSSM + c4];
    }
    __syncthreads();
    unsigned short* tb = sraw + (size_t)bc * 16 * 4096;
    int t = 0;
#pragma unroll
    for (int st = 0; st < 4; ++st) {
#pragma unroll
        for (int zt = 0; zt <= st; ++zt, ++t) {
            if ((t & 7) != w) continue;
            f32x4 d[4][4] = {};
#pragma unroll
            for (int kt = 0; kt < 4; ++kt) {
                bf16x8 av[4], bv[4];
#pragma unroll
                for (int mi = 0; mi < 4; ++mi)
                    av[mi] = *(const bf16x8*)&SC[(st * 64 + mi * 16 + lr) * 136 + kt * 32 + lk * 8];
#pragma unroll
                for (int nj = 0; nj < 4; ++nj)
                    bv[nj] = *(const bf16x8*)&SB[(zt * 64 + nj * 16 + lr) * 136 + kt * 32 + lk * 8];
#pragma unroll
                for (int mi = 0; mi < 4; ++mi)
#pragma unroll
                    for (int nj = 0; nj < 4; ++nj)
                        d[mi][nj] = __builtin_amdgcn_mfma_f32_16x16x32_bf16(av[mi], bv[nj], d[mi][nj], 0, 0, 0);
            }
            unsigned short* tp = tb + (size_t)(st * 4 + zt) * 4096;
#pragma unroll
            for (int mi = 0; mi < 4; ++mi)
#pragma unroll
                for (int nj = 0; nj < 4; ++nj)
#pragma unroll
                    for (int r = 0; r < 4; ++r)
                        tp[(mi * 16 + lk * 4 + r) * 64 + nj * 16 + lr] = f2bf(d[mi][nj][r]);
        }
    }
}

// ---------------- Y from precomputed S_raw: per (b,c,h), 4 waves = 4 s-tiles.
__global__ __launch_bounds__(256) void ssd_y2_k(const unsigned short* __restrict__ xc,
    const float* __restrict__ dtp, const float* __restrict__ A_log,
    const unsigned short* __restrict__ sraw, const float* __restrict__ pv,
    const float* __restrict__ Dp, float* __restrict__ Y)
{
    __shared__ float s_acs[256];
    __shared__ float s_dt[256];
    __shared__ float s_edt[256];
    __shared__ float s_az0[4];
    __shared__ unsigned short SXT[64 * 264];
    __shared__ unsigned short SPV[64 * 136];
    int blk = blockIdx.x;
    int h = blk % NHH;
    int c = (blk / NHH) % NC;
    int b = blk / (NHH * NC);
    int tid = threadIdx.x;
    int w = tid >> 6, l = tid & 63;
    int lr = l & 15, lk = l >> 4;
    size_t rowbase = (size_t)b * SEQ + c * CHK;
    float Ah = -expf(A_log[h]);
    float dtv = dtp[(rowbase + tid) * NHH + h];
    s_dt[tid] = dtv;
    s_acs[tid] = Ah * dtv;
    __syncthreads();
    for (int off = 1; off < 256; off <<= 1) {
        float t = (tid >= off) ? s_acs[tid - off] : 0.f;
        __syncthreads();
        s_acs[tid] += t;
        __syncthreads();
    }
    if (tid < 4) s_az0[tid] = s_acs[tid * 64];
    __syncthreads();
    {
        float e = s_az0[tid >> 6] - s_acs[tid];
        if (e > 60.f) e = 60.f;
        s_edt[tid] = expf(e) * s_dt[tid];
    }
    __syncthreads();
    for (int i = tid; i < 256 * 8; i += 256) {
        int z = i >> 3, p8 = (i & 7) * 8;
        float sc = s_edt[z];
        u16x8 v = *(const u16x8*)&xc[(rowbase + z) * CDIM + h * HDIM + p8];
#pragma unroll
        for (int e = 0; e < 8; ++e)
            SXT[(p8 + e) * 264 + z] = f2bf(bf2f(v[e]) * sc);
    }
    const float* pvbase = pv + (size_t)blk * (HDIM * DSTATE);
    for (int i = tid; i < 64 * 32; i += 256) {
        int p = i >> 5, n4 = (i & 31) * 4;
        float4 v = *(const float4*)&pvbase[p * DSTATE + n4];
        ushort4 o; o.x = f2bf(v.x); o.y = f2bf(v.y); o.z = f2bf(v.z); o.w = f2bf(v.w);
        *(ushort4*)&SPV[p * 136 + n4] = o;
    }
    __syncthreads();

    const unsigned short* tbase = sraw + (size_t)(b * NC + c) * 16 * 4096;
    f32x4 acc[4][4] = {};
    for (int zt = 0; zt <= w; ++zt) {
        const unsigned short* tp = tbase + (size_t)(w * 4 + zt) * 4096;
        f32x4 tmp[4][4] = {};
#pragma unroll
        for (int kt = 0; kt < 2; ++kt) {
            bf16x8 av[4], bv[4];
#pragma unroll
            for (int mi = 0; mi < 4; ++mi) {
                av[mi] = *(const bf16x8*)&tp[(mi * 16 + lr) * 64 + kt * 32 + lk * 8];
                if (zt == w) {
                    int zb = kt * 32 + lk * 8;
                    int sl = mi * 16 + lr;
#pragma unroll
                    for (int e = 0; e < 8; ++e)
                        if (zb + e > sl) av[mi][e] = 0;
                }
            }
#pragma unroll
            for (int nj = 0; nj < 4; ++nj)
                bv[nj] = *(const bf16x8*)&SXT[(nj * 16 + lr) * 264 + zt * 64 + kt * 32 + lk * 8];
#pragma unroll
            for (int mi = 0; mi < 4; ++mi)
#pragma unroll
                for (int nj = 0; nj < 4; ++nj)
                    tmp[mi][nj] = __builtin_amdgcn_mfma_f32_16x16x32_bf16(av[mi], bv[nj], tmp[mi][nj], 0, 0, 0);
        }
        float az = s_az0[zt];
#pragma unroll
        for (int mi = 0; mi < 4; ++mi) {
#pragma unroll
            for (int r = 0; r < 4; ++r) {
                float es = expf(s_acs[w * 64 + mi * 16 + lk * 4 + r] - az);
#pragma unroll
                for (int nj = 0; nj < 4; ++nj)
                    acc[mi][nj][r] += es * tmp[mi][nj][r];
            }
        }
    }
    {
        f32x4 tmp[4][4] = {};
#pragma unroll
        for (int kt = 0; kt < 4; ++kt) {
            bf16x8 av[4], bv[4];
#pragma unroll
            for (int mi = 0; mi < 4; ++mi)
                av[mi] = *(const bf16x8*)&xc[(rowbase + w * 64 + mi * 16 + lr) * CDIM + DSSM + DSTATE + kt * 32 + lk * 8];
#pragma unroll
            for (int nj = 0; nj < 4; ++nj)
                bv[nj] = *(const bf16x8*)&SPV[(nj * 16 + lr) * 136 + kt * 32 + lk * 8];
#pragma unroll
            for (int mi = 0; mi < 4; ++mi)
#pragma unroll
                for (int nj = 0; nj < 4; ++nj)
                    tmp[mi][nj] = __builtin_amdgcn_mfma_f32_16x16x32_bf16(av[mi], bv[nj], tmp[mi][nj], 0, 0, 0);
        }
#pragma unroll
        for (int mi = 0; mi < 4; ++mi) {
#pragma unroll
            for (int r = 0; r < 4; ++r) {
                float es = expf(s_acs[w * 64 + mi * 16 + lk * 4 + r]);
#pragma unroll
                for (int nj = 0; nj < 4; ++nj)
                    acc[mi][nj][r] += es * tmp[mi][nj][r];
            }
        }
    }
    float dph = Dp[h];
#pragma unroll
    for (int mi = 0; mi < 4; ++mi) {
#pragma unroll
        for (int r = 0; r < 4; ++r) {
            int s = w * 64 + mi * 16 + lk * 4 + r;
#pragma unroll
            for (int nj = 0; nj < 4; ++nj) {
                int p = nj * 16 + lr;
                float xv = bf2f(xc[(rowbase + s) * CDIM + h * HDIM + p]);
                Y[(rowbase + s) * DSSM + h * HDIM + p] = acc[mi][nj][r] + dph * xv;
            }
        }
    }
}

// ---------------- gated RMS norm -> bf16 output (separate buffer)
__global__ __launch_bounds__(256) void rmsnorm_k(const float* __restrict__ Y,
    const float* __restrict__ zbuf, const float* __restrict__ nw,
    unsigned short* __restrict__ Ybf)
{
    __shared__ float red[8];
    int row = blockIdx.x;
    const float* y = Y + (size_t)row * DSSM;
    const float* z = zbuf + (size_t)row * DSSM;
    float v[6];
    float ss = 0.f;
#pragma unroll
    for (int k = 0; k < 6; ++k) {
        int i = threadIdx.x + k * 256;
        float g = y[i] * siluf(z[i]);
        v[k] = g;
        ss = fmaf(g, g, ss);
    }
#pragma unroll
    for (int o = 32; o > 0; o >>= 1) ss += __shfl_down(ss, o, 64);
    int wv = threadIdx.x >> 6, ln = threadIdx.x & 63;
    if (ln == 0) red[wv] = ss;
    __syncthreads();
    float tot = red[0] + red[1] + red[2] + red[3];
    float sc = rsqrtf(tot / (float)DSSM + 1e-12f);
    unsigned short* yo = Ybf + (size_t)row * DSSM;
#pragma unroll
    for (int k = 0; k < 6; ++k) {
        int i = threadIdx.x + k * 256;
        yo[i] = f2bf(v[k] * sc * nw[i]);
    }
}

// ---------------- time_out: gate + mix + LayerNorm over SEQ
__global__ __launch_bounds__(256) void timeout_k(const float* __restrict__ td,
    const float* __restrict__ tdt, const float* __restrict__ gw, const float* __restrict__ gb,
    const float* __restrict__ lnw, const float* __restrict__ lnb, float* __restrict__ out2)
{
    __shared__ float tm[SEQ];
    __shared__ float red[8];
    int row = blockIdx.x;
    const float* tdr = td + (size_t)row * SEQ;
    const float* tdtr = tdt + (size_t)row * SEQ;
    int wv = threadIdx.x >> 6, ln = threadIdx.x & 63;
    float part = 0.f;
    for (int i = threadIdx.x; i < SEQ; i += 256) part = fmaf(tdr[i], gw[i], part);
#pragma unroll
    for (int o = 32; o > 0; o >>= 1) part += __shfl_down(part, o, 64);
    if (ln == 0) red[wv] = part;
    __syncthreads();
    float dot = red[0] + red[1] + red[2] + red[3];
    float tg = 1.f / (1.f + expf(-(dot + gb[0])));
    __syncthreads();
    float sum = 0.f;
    for (int i = threadIdx.x; i < SEQ; i += 256) {
        float x = tg * tdr[i] + (1.f - tg) * tdtr[i];
        tm[i] = x;
        sum += x;
    }
#pragma unroll
    for (int o = 32; o > 0; o >>= 1) sum += __shfl_down(sum, o, 64);
    if (ln == 0) red[wv] = sum;
    __syncthreads();
    float mu = (red[0] + red[1] + red[2] + red[3]) / (float)SEQ;
    __syncthreads();
    float s2 = 0.f;
    for (int i = threadIdx.x; i < SEQ; i += 256) { float d = tm[i] - mu; s2 = fmaf(d, d, s2); }
#pragma unroll
    for (int o = 32; o > 0; o >>= 1) s2 += __shfl_down(s2, o, 64);
    if (ln == 0) red[wv] = s2;
    __syncthreads();
    float var = (red[0] + red[1] + red[2] + red[3]) / (float)SEQ;
    float inv = rsqrtf(var + 1e-12f);
    for (int i = threadIdx.x; i < SEQ; i += 256)
        out2[(size_t)row * SEQ + i] = (tm[i] - mu) * inv * lnw[i] + lnb[i];
}

extern "C" void kernel_launch(void* const* d_in, const int* in_sizes, int n_in,
                              void* d_out, int out_size, void* d_ws, size_t ws_size,
                              hipStream_t stream)
{
    const float* u      = (const float*)d_in[0];
    const float* td     = (const float*)d_in[1];
    const float* W_in   = (const float*)d_in[2];
    const float* b_in   = (const float*)d_in[3];
    const float* conv_w = (const float*)d_in[4];
    const float* conv_b = (const float*)d_in[5];
    const float* t1w    = (const float*)d_in[6];
    const float* t1b    = (const float*)d_in[7];
    const float* t2w    = (const float*)d_in[8];
    const float* t2b    = (const float*)d_in[9];
    const float* m1w    = (const float*)d_in[10];
    const float* m1b    = (const float*)d_in[11];
    const float* m2w    = (const float*)d_in[12];
    const float* m2b    = (const float*)d_in[13];
    const float* gw     = (const float*)d_in[14];
    const float* gb     = (const float*)d_in[15];
    const float* lnw    = (const float*)d_in[16];
    const float* lnb    = (const float*)d_in[17];
    const float* A_log  = (const float*)d_in[18];
    const float* dt_bias= (const float*)d_in[19];
    const float* Dpv    = (const float*)d_in[20];
    const float* nw     = (const float*)d_in[21];
    const float* W_out  = (const float*)d_in[22];
    const float* b_out  = (const float*)d_in[23];
    float* out  = (float*)d_out;
    float* out2 = out + (size_t)MR * DMODEL;

    // ---- workspace layout (~43.8M floats = 167 MiB) ----
    float* ws = (float*)d_ws;
    size_t o = 0;
    float* zbuf  = ws + o; o += (size_t)MR * DSSM;          // z (f32); 2nd half also Wo_bf later
    float* r1    = ws + o; o += (size_t)MR * XSTR;          // xBC+dt (stride 1920) -> stb -> Yb
    float* xcv   = ws + o; o += (size_t)MR * CDIM / 2;      // bf16 activations; early: partb; late: Y_bf
    float* hid   = ws + o; o += (size_t)BB * NHH * SEQ;
    float* tss   = ws + o; o += (size_t)BB * NHH * SEQ;
    float* tdt   = ws + o; o += (size_t)BB * NHH * SEQ;
    float* dtp   = ws + o; o += (size_t)MR * NHH;
    float* pvb   = ws + o; o += (size_t)BB * NC * NHH * HDIM * DSTATE;  // early: u_bf/Wi_bf
    float* alb   = ws + o; o += (size_t)BB * NC * NHH;
    unsigned short* sraw = (unsigned short*)(ws + o); o += (size_t)BB * NC * 16 * 4096 / 2;
    float* stb = r1;
    float* Yb  = r1;
    float* partb = xcv;                                     // 3,145,728 floats fits in 7,340,032
    unsigned short* xcv_bf = (unsigned short*)xcv;
    unsigned short* u_bf  = (unsigned short*)pvb;           // 6,291,456 sh
    unsigned short* Wi_bf = (unsigned short*)(pvb + 3145728); // 3456*768 = 2,654,208 sh
    unsigned short* Y_bf  = (unsigned short*)xcv;           // after ssd_y2 (xcv dead)
    unsigned short* Wo_bf = (unsigned short*)(zbuf + 6291456);

    dim3 blk(256);
    // --- time MLP first (partials use xcv region, dead until conv) ---
    gemm_skinny_nt<<<dim3(SEQ / 128, KSPLIT), blk, 0, stream>>>(td, m1w, partb, SEQ, SEQ);
    reduce_part_k<<<dim3((48 * SEQ + 255) / 256), blk, 0, stream>>>(partb, m1b, hid, SEQ, 1);
    gemm_skinny_nt<<<dim3(SEQ / 128, KSPLIT), blk, 0, stream>>>(hid, m2w, partb, SEQ, SEQ);
    reduce_part_k<<<dim3((48 * SEQ + 255) / 256), blk, 0, stream>>>(partb, m2b, tss, SEQ, 0);
    time_conv_k<<<dim3(BB * NHH), blk, 0, stream>>>(tss, td, t1w, t1b, t2w, t2b, tdt);
    // --- in-proj: u,W -> bf16; combined xBC+dt GEMM (N=1920); z GEMM ---
    cvt_bf16_k<<<dim3((MR * DMODEL / 4 + 255) / 256), blk, 0, stream>>>(u, u_bf, MR * DMODEL, MR * DMODEL);
    cvt_bf16_k<<<dim3((3456 * DMODEL / 4 + 255) / 256), blk, 0, stream>>>(W_in, Wi_bf, DPROJ * DMODEL, 3456 * DMODEL);
    gemm_mfma_nt<<<dim3(XSTR / 128, MR / 128), blk, 0, stream>>>(
        u_bf, Wi_bf + (size_t)DSSM * DMODEL, b_in + DSSM, r1, XSTR, DMODEL, DMODEL / 32, DPROJ - DSSM);
    conv_xbc_k<<<dim3((MR * CDIM + 255) / 256), blk, 0, stream>>>(r1, conv_w, conv_b, xcv_bf);
    gemm_mfma_nt<<<dim3(DSSM / 128, MR / 128), blk, 0, stream>>>(
        u_bf, Wi_bf, b_in, zbuf, DSSM, DMODEL, DMODEL / 32, DSSM);
    dtsp_k<<<dim3((MR * NHH + 255) / 256), blk, 0, stream>>>(r1, tdt, dt_bias, dtp);
    // --- SSD ---
    ssd_sraw_k<<<dim3(BB * NC), dim3(512), 0, stream>>>(xcv_bf, sraw);
    ssd_states_mfma_k<<<dim3(BB * NC * NHH), blk, 0, stream>>>(xcv_bf, dtp, A_log, stb, alb);
    ssd_scan_k<<<dim3(BB * NHH), blk, 0, stream>>>(stb, alb, pvb);
    ssd_y2_k<<<dim3(BB * NC * NHH), blk, 0, stream>>>(xcv_bf, dtp, A_log, sraw, pvb, Dpv, Yb);
    // --- epilogue: rmsnorm fused with bf16 convert (Y_bf in dead xcv region) ---
    rmsnorm_k<<<dim3(MR), blk, 0, stream>>>(Yb, zbuf, nw, Y_bf);
    cvt_bf16_k<<<dim3((DMODEL * DSSM / 4 + 255) / 256), blk, 0, stream>>>(W_out, Wo_bf, DMODEL * DSSM, DMODEL * DSSM);
    gemm_mfma_nt<<<dim3(DMODEL / 128, MR / 128), blk, 0, stream>>>(
        Y_bf, Wo_bf, b_out, out, DMODEL, DSSM, DSSM / 32, DMODEL);
    timeout_k<<<dim3(BB * NHH), blk, 0, stream>>>(td, tdt, gw, gb, lnw, lnb, out2);
}

// Round 9
// 525.614 us; speedup vs baseline: 6.6411x; 1.0302x over previous
//
#include <hip/hip_runtime.h>
#include <math.h>

#define BB 2
#define SEQ 4096
#define DMODEL 768
#define DSTATE 128
#define NHH 24
#define HDIM 64
#define DSSM 1536
#define CDIM 1792
#define CHK 256
#define NC 16
#define DPROJ 3352
#define MR (BB*SEQ)
#define KSPLIT 32
#define XSTR 1920   // r1 row stride: xBC(1792) + dt(24) + pad(104)

typedef __attribute__((ext_vector_type(8))) short bf16x8;
typedef __attribute__((ext_vector_type(8))) unsigned short u16x8;
typedef __attribute__((ext_vector_type(4))) float f32x4;

__device__ __forceinline__ float siluf(float x) { return x / (1.0f + expf(-x)); }

__device__ __forceinline__ unsigned short f2bf(float f) {
    unsigned u = __float_as_uint(f);
    unsigned r = (u + 0x7fffu + ((u >> 16) & 1u)) >> 16;
    return (unsigned short)r;
}

__device__ __forceinline__ float bf2f(unsigned short u) {
    return __uint_as_float(((unsigned)u) << 16);
}

__device__ __forceinline__ void gload_lds16(const void* g, void* l) {
    __builtin_amdgcn_global_load_lds((const __attribute__((address_space(1))) unsigned int*)g,
                                     (__attribute__((address_space(3))) unsigned int*)l, 16, 0, 0);
}

// ---------------- f32 -> bf16 conversion (vectorized), zero-pad beyond n_valid
__global__ __launch_bounds__(256) void cvt_bf16_k(const float* __restrict__ in,
    unsigned short* __restrict__ out, int n_valid, int n_total)
{
    int i = (blockIdx.x * 256 + threadIdx.x) * 4;
    if (i >= n_total) return;
    ushort4 o;
    if (i + 3 < n_valid) {
        float4 v = *(const float4*)&in[i];
        o.x = f2bf(v.x); o.y = f2bf(v.y); o.z = f2bf(v.z); o.w = f2bf(v.w);
    } else {
        o.x = (i + 0 < n_valid) ? f2bf(in[i + 0]) : 0;
        o.y = (i + 1 < n_valid) ? f2bf(in[i + 1]) : 0;
        o.z = (i + 2 < n_valid) ? f2bf(in[i + 2]) : 0;
        o.w = (i + 3 < n_valid) ? f2bf(in[i + 3]) : 0;
    }
    *(ushort4*)&out[i] = o;
}

// ---------------- bf16 MFMA GEMM: C(MxN) = A(MxK) @ B(NxK)^T + bias(N, guarded at nbias)
__global__ __launch_bounds__(256) void gemm_mfma_nt(
    const unsigned short* __restrict__ A, const unsigned short* __restrict__ B,
    const float* __restrict__ bias, float* __restrict__ C, int N, int K, int KT, int nbias)
{
    __shared__ unsigned short SA[2][128 * 32];
    __shared__ unsigned short SB[2][128 * 32];
    const int tid = threadIdx.x;
    const int w = tid >> 6, l = tid & 63;
    const int wr = w >> 1, wc = w & 1;
    const int lr = l & 15, lk = l >> 4;
    const int m0 = blockIdx.y * 128, n0 = blockIdx.x * 128;
    f32x4 acc[4][4] = {};
    const int i16 = w * 64 + l;
    const int row0 = i16 >> 2, sl = i16 & 3;
    const size_t ga0 = (size_t)(m0 + row0) * K + sl * 8;
    const size_t ga1 = (size_t)(m0 + row0 + 64) * K + sl * 8;
    const size_t gb0 = (size_t)(n0 + row0) * K + sl * 8;
    const size_t gb1 = (size_t)(n0 + row0 + 64) * K + sl * 8;
    const int lo0 = (w * 64) * 8;
    const int lo1 = (256 + w * 64) * 8;

#define STAGE(bb, kt) { int ko = (kt) * 32;                      \
      gload_lds16(A + ga0 + ko, &SA[bb][lo0]);                   \
      gload_lds16(A + ga1 + ko, &SA[bb][lo1]);                   \
      gload_lds16(B + gb0 + ko, &SB[bb][lo0]);                   \
      gload_lds16(B + gb1 + ko, &SB[bb][lo1]); }

    STAGE(0, 0);
    for (int kt = 0; kt < KT; ++kt) {
        int cur = kt & 1;
        asm volatile("s_waitcnt vmcnt(0)" ::: "memory");
        __syncthreads();
        if (kt + 1 < KT) STAGE(cur ^ 1, kt + 1);
        bf16x8 af[4], bg[4];
#pragma unroll
        for (int mi = 0; mi < 4; ++mi)
            af[mi] = *(const bf16x8*)&SA[cur][(wr * 64 + mi * 16 + lr) * 32 + lk * 8];
#pragma unroll
        for (int nj = 0; nj < 4; ++nj)
            bg[nj] = *(const bf16x8*)&SB[cur][(wc * 64 + nj * 16 + lr) * 32 + lk * 8];
#pragma unroll
        for (int mi = 0; mi < 4; ++mi)
#pragma unroll
            for (int nj = 0; nj < 4; ++nj)
                acc[mi][nj] = __builtin_amdgcn_mfma_f32_16x16x32_bf16(af[mi], bg[nj], acc[mi][nj], 0, 0, 0);
    }
#undef STAGE
#pragma unroll
    for (int nj = 0; nj < 4; ++nj) {
        int col = n0 + wc * 64 + nj * 16 + lr;
        float bz = (col < nbias) ? bias[col] : 0.f;
#pragma unroll
        for (int mi = 0; mi < 4; ++mi) {
#pragma unroll
            for (int r = 0; r < 4; ++r) {
                int m = m0 + wr * 64 + mi * 16 + lk * 4 + r;
                C[(size_t)m * N + col] = acc[mi][nj][r] + bz;
            }
        }
    }
}

// ---------------- split-K skinny GEMM (M=48), conflict-free [row][k] LDS layout
// grid (N/128, KSPLIT); KS = K/KSPLIT; output cols mapped tx + j*32
__global__ __launch_bounds__(256) void gemm_skinny_nt(const float* __restrict__ A,
    const float* __restrict__ Bw, float* __restrict__ part, int N, int K)
{
    __shared__ float sA[48 * 33];
    __shared__ float sB[128 * 33];
    const int nb = blockIdx.x, kb = blockIdx.y;
    const int n0 = nb * 128;
    const int KS = K / KSPLIT;
    const int k0 = kb * KS;
    const int tid = threadIdx.x;
    const int tx = tid & 31, ty = tid >> 5;
    float acc[6][4] = {{0.f}};
    for (int kc = 0; kc < KS; kc += 32) {
        if (kc) __syncthreads();
        for (int i = tid; i < 384; i += 256) {
            int m = i >> 3, k4 = (i & 7) * 4;
            float4 v = *(const float4*)&A[(size_t)m * K + k0 + kc + k4];
            sA[m * 33 + k4 + 0] = v.x;
            sA[m * 33 + k4 + 1] = v.y;
            sA[m * 33 + k4 + 2] = v.z;
            sA[m * 33 + k4 + 3] = v.w;
        }
        for (int i = tid; i < 1024; i += 256) {
            int n = i >> 3, k4 = (i & 7) * 4;
            float4 v = *(const float4*)&Bw[(size_t)(n0 + n) * K + k0 + kc + k4];
            sB[n * 33 + k4 + 0] = v.x;
            sB[n * 33 + k4 + 1] = v.y;
            sB[n * 33 + k4 + 2] = v.z;
            sB[n * 33 + k4 + 3] = v.w;
        }
        __syncthreads();
#pragma unroll 8
        for (int kk = 0; kk < 32; ++kk) {
            float a[6], b[4];
#pragma unroll
            for (int r = 0; r < 6; ++r) a[r] = sA[(ty * 6 + r) * 33 + kk];
#pragma unroll
            for (int j = 0; j < 4; ++j) b[j] = sB[(tx + j * 32) * 33 + kk];
#pragma unroll
            for (int r = 0; r < 6; ++r)
#pragma unroll
                for (int j = 0; j < 4; ++j)
                    acc[r][j] = fmaf(a[r], b[j], acc[r][j]);
        }
    }
    float* pb = part + (size_t)kb * 48 * N;
#pragma unroll
    for (int r = 0; r < 6; ++r)
#pragma unroll
        for (int j = 0; j < 4; ++j)
            pb[(size_t)(ty * 6 + r) * N + n0 + tx + j * 32] = acc[r][j];
}

// ---------------- reduce split-K partials + bias (+ optional silu)
__global__ __launch_bounds__(256) void reduce_part_k(const float* __restrict__ part,
    const float* __restrict__ bias, float* __restrict__ out, int N, int act)
{
    int idx = blockIdx.x * 256 + threadIdx.x;
    if (idx >= 48 * N) return;
    int n = idx % N;
    float s = bias[n];
#pragma unroll
    for (int kb = 0; kb < KSPLIT; ++kb) s += part[(size_t)kb * 48 * N + idx];
    if (act) s = siluf(s);
    out[idx] = s;
}

// ---------------- depthwise causal conv (window 4) + silu -> bf16, 4 channels/thread
__global__ __launch_bounds__(256) void conv_xbc_k(const float* __restrict__ xbc,
    const float* __restrict__ cw, const float* __restrict__ cb,
    unsigned short* __restrict__ out)
{
    int idx = blockIdx.x * 256 + threadIdx.x;
    if (idx >= MR * (CDIM / 4)) return;
    int c4 = (idx % (CDIM / 4)) * 4;
    int row = idx / (CDIM / 4);
    int t = row % SEQ;
    float acc0 = cb[c4 + 0], acc1 = cb[c4 + 1], acc2 = cb[c4 + 2], acc3 = cb[c4 + 3];
#pragma unroll
    for (int k = 0; k < 4; ++k) {
        int tt = t + k - 3;
        if (tt >= 0) {
            float4 v = *(const float4*)&xbc[(size_t)(row + k - 3) * XSTR + c4];
            acc0 = fmaf(v.x, cw[(c4 + 0) * 4 + k], acc0);
            acc1 = fmaf(v.y, cw[(c4 + 1) * 4 + k], acc1);
            acc2 = fmaf(v.z, cw[(c4 + 2) * 4 + k], acc2);
            acc3 = fmaf(v.w, cw[(c4 + 3) * 4 + k], acc3);
        }
    }
    ushort4 o;
    o.x = f2bf(siluf(acc0)); o.y = f2bf(siluf(acc1));
    o.z = f2bf(siluf(acc2)); o.w = f2bf(siluf(acc3));
    *(ushort4*)&out[(size_t)row * CDIM + c4] = o;
}

// ---------------- per-(b,h) row: tdt0 = ts*td; conv1+silu; conv2+silu
__global__ __launch_bounds__(256) void time_conv_k(const float* __restrict__ ts,
    const float* __restrict__ td, const float* __restrict__ w1, const float* __restrict__ b1,
    const float* __restrict__ w2, const float* __restrict__ b2, float* __restrict__ tdt)
{
    __shared__ float u0[SEQ];
    __shared__ float u1[SEQ];
    int row = blockIdx.x, h = row % NHH;
    const float* tsr = ts + (size_t)row * SEQ;
    const float* tdr = td + (size_t)row * SEQ;
    for (int i = threadIdx.x; i < SEQ; i += 256) u0[i] = tsr[i] * tdr[i];
    __syncthreads();
    float wa[4], wb[4];
#pragma unroll
    for (int k = 0; k < 4; ++k) { wa[k] = w1[h * 4 + k]; wb[k] = w2[h * 4 + k]; }
    float ba = b1[h], bbv = b2[h];
    for (int i = threadIdx.x; i < SEQ; i += 256) {
        float acc = ba;
#pragma unroll
        for (int k = 0; k < 4; ++k) { int tt = i + k - 3; if (tt >= 0) acc = fmaf(u0[tt], wa[k], acc); }
        u1[i] = siluf(acc);
    }
    __syncthreads();
    for (int i = threadIdx.x; i < SEQ; i += 256) {
        float acc = bbv;
#pragma unroll
        for (int k = 0; k < 4; ++k) { int tt = i + k - 3; if (tt >= 0) acc = fmaf(u1[tt], wb[k], acc); }
        tdt[(size_t)row * SEQ + i] = siluf(acc);
    }
}

// ---------------- dt_sp = softplus(dt * tdt^T + dt_bias); dt read from r1 col 1792+h
__global__ __launch_bounds__(256) void dtsp_k(const float* __restrict__ r1,
    const float* __restrict__ tdt, const float* __restrict__ dt_bias, float* __restrict__ dtp)
{
    int idx = blockIdx.x * 256 + threadIdx.x;
    if (idx >= MR * NHH) return;
    int h = idx % NHH;
    int row = idx / NHH;
    int b = row / SEQ, s = row % SEQ;
    float x = r1[(size_t)row * XSTR + CDIM + h] * tdt[((size_t)(b * NHH + h)) * SEQ + s] + dt_bias[h];
    dtp[idx] = (x > 20.0f) ? x : log1pf(expf(x));
}

// ---------------- SSD chunk states via MFMA
__global__ __launch_bounds__(256) void ssd_states_mfma_k(const unsigned short* __restrict__ xc,
    const float* __restrict__ dtp, const float* __restrict__ A_log,
    float* __restrict__ st, float* __restrict__ al)
{
    __shared__ float s_acs[256];
    __shared__ float s_coef[256];
    __shared__ unsigned short SXT[64 * 136];
    __shared__ unsigned short SBT[128 * 136];
    int blk = blockIdx.x;
    int h = blk % NHH, c = (blk / NHH) % NC, b = blk / (NHH * NC);
    int tid = threadIdx.x;
    int w = tid >> 6, l = tid & 63;
    int lr = l & 15, lk = l >> 4;
    size_t rowbase = (size_t)b * SEQ + c * CHK;
    float Ah = -expf(A_log[h]);
    float dtv = dtp[(rowbase + tid) * NHH + h];
    s_acs[tid] = Ah * dtv;
    __syncthreads();
    for (int off = 1; off < 256; off <<= 1) {
        float t = (tid >= off) ? s_acs[tid - off] : 0.f;
        __syncthreads();
        s_acs[tid] += t;
        __syncthreads();
    }
    float alv = s_acs[255];
    s_coef[tid] = expf(alv - s_acs[tid]) * dtv;
    if (tid == 255) al[blk] = alv;
    __syncthreads();
    f32x4 acc[4][2] = {};
    for (int z0 = 0; z0 < CHK; z0 += 128) {
        if (z0) __syncthreads();
        for (int i = tid; i < 128 * 8; i += 256) {
            int zz = i >> 3, p8 = (i & 7) * 8;
            float sc = s_coef[z0 + zz];
            u16x8 v = *(const u16x8*)&xc[(rowbase + z0 + zz) * CDIM + h * HDIM + p8];
#pragma unroll
            for (int e = 0; e < 8; ++e)
                SXT[(p8 + e) * 136 + zz] = f2bf(bf2f(v[e]) * sc);
        }
        for (int i = tid; i < 128 * 16; i += 256) {
            int zz = i >> 4, n8 = (i & 15) * 8;
            u16x8 v = *(const u16x8*)&xc[(rowbase + z0 + zz) * CDIM + DSSM + n8];
#pragma unroll
            for (int e = 0; e < 8; ++e)
                SBT[(n8 + e) * 136 + zz] = v[e];
        }
        __syncthreads();
#pragma unroll
        for (int kt = 0; kt < 4; ++kt) {
            bf16x8 av[4], bv[2];
#pragma unroll
            for (int mi = 0; mi < 4; ++mi)
                av[mi] = *(const bf16x8*)&SXT[(mi * 16 + lr) * 136 + kt * 32 + lk * 8];
#pragma unroll
            for (int nj = 0; nj < 2; ++nj)
                bv[nj] = *(const bf16x8*)&SBT[(w * 32 + nj * 16 + lr) * 136 + kt * 32 + lk * 8];
#pragma unroll
            for (int mi = 0; mi < 4; ++mi)
#pragma unroll
                for (int nj = 0; nj < 2; ++nj)
                    acc[mi][nj] = __builtin_amdgcn_mfma_f32_16x16x32_bf16(av[mi], bv[nj], acc[mi][nj], 0, 0, 0);
        }
    }
    size_t base = (size_t)blk * (HDIM * DSTATE);
#pragma unroll
    for (int mi = 0; mi < 4; ++mi)
#pragma unroll
        for (int r = 0; r < 4; ++r) {
            int p = mi * 16 + lk * 4 + r;
#pragma unroll
            for (int nj = 0; nj < 2; ++nj)
                st[base + p * DSTATE + w * 32 + nj * 16 + lr] = acc[mi][nj][r];
        }
}

// ---------------- inter-chunk scan
__global__ __launch_bounds__(256) void ssd_scan_k(const float* __restrict__ st,
    const float* __restrict__ al, float* __restrict__ pv)
{
    int b = blockIdx.x / NHH, h = blockIdx.x % NHH;
    int tid = threadIdx.x;
    float carry[32];
#pragma unroll
    for (int j = 0; j < 32; ++j) carry[j] = 0.f;
    for (int c = 0; c < NC; ++c) {
        int bch = (b * NC + c) * NHH + h;
        size_t base = (size_t)bch * (HDIM * DSTATE);
        float dcy = expf(al[bch]);
#pragma unroll
        for (int j = 0; j < 32; ++j) {
            pv[base + tid + j * 256] = carry[j];
            carry[j] = fmaf(dcy, carry[j], st[base + tid + j * 256]);
        }
    }
}

// ---------------- S_raw = C.B^T per (b,c), lower-triangular 64x64 tiles, bf16
__global__ __launch_bounds__(512) void ssd_sraw_k(const unsigned short* __restrict__ xc,
    unsigned short* __restrict__ sraw)
{
    __shared__ unsigned short SC[256 * 136];
    __shared__ unsigned short SB[256 * 136];
    int bc = blockIdx.x;
    int b = bc / NC, c = bc % NC;
    size_t rowbase = (size_t)b * SEQ + c * CHK;
    int tid = threadIdx.x;
    int w = tid >> 6, l = tid & 63;
    int lr = l & 15, lk = l >> 4;
    for (int i = tid; i < 256 * 32; i += 512) {
        int r = i >> 5, c4 = (i & 31) * 4;
        *(ushort4*)&SC[r * 136 + c4] = *(const ushort4*)&xc[(rowbase + r) * CDIM + DSSM + DSTATE + c4];
        *(ushort4*)&SB[r * 136 + c4] = *(const ushort4*)&xc[(rowbase + r) * CDIM + DSSM + c4];
    }
    __syncthreads();
    unsigned short* tb = sraw + (size_t)bc * 16 * 4096;
    int t = 0;
#pragma unroll
    for (int st = 0; st < 4; ++st) {
#pragma unroll
        for (int zt = 0; zt <= st; ++zt, ++t) {
            if ((t & 7) != w) continue;
            f32x4 d[4][4] = {};
#pragma unroll
            for (int kt = 0; kt < 4; ++kt) {
                bf16x8 av[4], bv[4];
#pragma unroll
                for (int mi = 0; mi < 4; ++mi)
                    av[mi] = *(const bf16x8*)&SC[(st * 64 + mi * 16 + lr) * 136 + kt * 32 + lk * 8];
#pragma unroll
                for (int nj = 0; nj < 4; ++nj)
                    bv[nj] = *(const bf16x8*)&SB[(zt * 64 + nj * 16 + lr) * 136 + kt * 32 + lk * 8];
#pragma unroll
                for (int mi = 0; mi < 4; ++mi)
#pragma unroll
                    for (int nj = 0; nj < 4; ++nj)
                        d[mi][nj] = __builtin_amdgcn_mfma_f32_16x16x32_bf16(av[mi], bv[nj], d[mi][nj], 0, 0, 0);
            }
            unsigned short* tp = tb + (size_t)(st * 4 + zt) * 4096;
#pragma unroll
            for (int mi = 0; mi < 4; ++mi)
#pragma unroll
                for (int nj = 0; nj < 4; ++nj)
#pragma unroll
                    for (int r = 0; r < 4; ++r)
                        tp[(mi * 16 + lk * 4 + r) * 64 + nj * 16 + lr] = f2bf(d[mi][nj][r]);
        }
    }
}

// ---------------- Y from precomputed S_raw: per (b,c,h), 4 waves = 4 s-tiles.
__global__ __launch_bounds__(256) void ssd_y2_k(const unsigned short* __restrict__ xc,
    const float* __restrict__ dtp, const float* __restrict__ A_log,
    const unsigned short* __restrict__ sraw, const float* __restrict__ pv,
    const float* __restrict__ Dp, float* __restrict__ Y)
{
    __shared__ float s_acs[256];
    __shared__ float s_dt[256];
    __shared__ float s_edt[256];
    __shared__ float s_az0[4];
    __shared__ unsigned short SXT[64 * 264];
    __shared__ unsigned short SPV[64 * 136];
    int blk = blockIdx.x;
    int h = blk % NHH;
    int c = (blk / NHH) % NC;
    int b = blk / (NHH * NC);
    int tid = threadIdx.x;
    int w = tid >> 6, l = tid & 63;
    int lr = l & 15, lk = l >> 4;
    size_t rowbase = (size_t)b * SEQ + c * CHK;
    float Ah = -expf(A_log[h]);
    float dtv = dtp[(rowbase + tid) * NHH + h];
    s_dt[tid] = dtv;
    s_acs[tid] = Ah * dtv;
    __syncthreads();
    for (int off = 1; off < 256; off <<= 1) {
        float t = (tid >= off) ? s_acs[tid - off] : 0.f;
        __syncthreads();
        s_acs[tid] += t;
        __syncthreads();
    }
    if (tid < 4) s_az0[tid] = s_acs[tid * 64];
    __syncthreads();
    {
        float e = s_az0[tid >> 6] - s_acs[tid];
        if (e > 60.f) e = 60.f;
        s_edt[tid] = expf(e) * s_dt[tid];
    }
    __syncthreads();
    for (int i = tid; i < 256 * 8; i += 256) {
        int z = i >> 3, p8 = (i & 7) * 8;
        float sc = s_edt[z];
        u16x8 v = *(const u16x8*)&xc[(rowbase + z) * CDIM + h * HDIM + p8];
#pragma unroll
        for (int e = 0; e < 8; ++e)
            SXT[(p8 + e) * 264 + z] = f2bf(bf2f(v[e]) * sc);
    }
    const float* pvbase = pv + (size_t)blk * (HDIM * DSTATE);
    for (int i = tid; i < 64 * 32; i += 256) {
        int p = i >> 5, n4 = (i & 31) * 4;
        float4 v = *(const float4*)&pvbase[p * DSTATE + n4];
        ushort4 o; o.x = f2bf(v.x); o.y = f2bf(v.y); o.z = f2bf(v.z); o.w = f2bf(v.w);
        *(ushort4*)&SPV[p * 136 + n4] = o;
    }
    __syncthreads();

    const unsigned short* tbase = sraw + (size_t)(b * NC + c) * 16 * 4096;
    f32x4 acc[4][4] = {};
    for (int zt = 0; zt <= w; ++zt) {
        const unsigned short* tp = tbase + (size_t)(w * 4 + zt) * 4096;
        f32x4 tmp[4][4] = {};
#pragma unroll
        for (int kt = 0; kt < 2; ++kt) {
            bf16x8 av[4], bv[4];
#pragma unroll
            for (int mi = 0; mi < 4; ++mi) {
                av[mi] = *(const bf16x8*)&tp[(mi * 16 + lr) * 64 + kt * 32 + lk * 8];
                if (zt == w) {
                    int zb = kt * 32 + lk * 8;
                    int sl = mi * 16 + lr;
#pragma unroll
                    for (int e = 0; e < 8; ++e)
                        if (zb + e > sl) av[mi][e] = 0;
                }
            }
#pragma unroll
            for (int nj = 0; nj < 4; ++nj)
                bv[nj] = *(const bf16x8*)&SXT[(nj * 16 + lr) * 264 + zt * 64 + kt * 32 + lk * 8];
#pragma unroll
            for (int mi = 0; mi < 4; ++mi)
#pragma unroll
                for (int nj = 0; nj < 4; ++nj)
                    tmp[mi][nj] = __builtin_amdgcn_mfma_f32_16x16x32_bf16(av[mi], bv[nj], tmp[mi][nj], 0, 0, 0);
        }
        float az = s_az0[zt];
#pragma unroll
        for (int mi = 0; mi < 4; ++mi) {
#pragma unroll
            for (int r = 0; r < 4; ++r) {
                float es = expf(s_acs[w * 64 + mi * 16 + lk * 4 + r] - az);
#pragma unroll
                for (int nj = 0; nj < 4; ++nj)
                    acc[mi][nj][r] += es * tmp[mi][nj][r];
            }
        }
    }
    {
        f32x4 tmp[4][4] = {};
#pragma unroll
        for (int kt = 0; kt < 4; ++kt) {
            bf16x8 av[4], bv[4];
#pragma unroll
            for (int mi = 0; mi < 4; ++mi)
                av[mi] = *(const bf16x8*)&xc[(rowbase + w * 64 + mi * 16 + lr) * CDIM + DSSM + DSTATE + kt * 32 + lk * 8];
#pragma unroll
            for (int nj = 0; nj < 4; ++nj)
                bv[nj] = *(const bf16x8*)&SPV[(nj * 16 + lr) * 136 + kt * 32 + lk * 8];
#pragma unroll
            for (int mi = 0; mi < 4; ++mi)
#pragma unroll
                for (int nj = 0; nj < 4; ++nj)
                    tmp[mi][nj] = __builtin_amdgcn_mfma_f32_16x16x32_bf16(av[mi], bv[nj], tmp[mi][nj], 0, 0, 0);
        }
#pragma unroll
        for (int mi = 0; mi < 4; ++mi) {
#pragma unroll
            for (int r = 0; r < 4; ++r) {
                float es = expf(s_acs[w * 64 + mi * 16 + lk * 4 + r]);
#pragma unroll
                for (int nj = 0; nj < 4; ++nj)
                    acc[mi][nj][r] += es * tmp[mi][nj][r];
            }
        }
    }
    float dph = Dp[h];
#pragma unroll
    for (int mi = 0; mi < 4; ++mi) {
#pragma unroll
        for (int r = 0; r < 4; ++r) {
            int s = w * 64 + mi * 16 + lk * 4 + r;
#pragma unroll
            for (int nj = 0; nj < 4; ++nj) {
                int p = nj * 16 + lr;
                float xv = bf2f(xc[(rowbase + s) * CDIM + h * HDIM + p]);
                Y[(rowbase + s) * DSSM + h * HDIM + p] = acc[mi][nj][r] + dph * xv;
            }
        }
    }
}

// ---------------- gated RMS norm -> bf16 output (separate buffer)
__global__ __launch_bounds__(256) void rmsnorm_k(const float* __restrict__ Y,
    const float* __restrict__ zbuf, const float* __restrict__ nw,
    unsigned short* __restrict__ Ybf)
{
    __shared__ float red[8];
    int row = blockIdx.x;
    const float* y = Y + (size_t)row * DSSM;
    const float* z = zbuf + (size_t)row * DSSM;
    float v[6];
    float ss = 0.f;
#pragma unroll
    for (int k = 0; k < 6; ++k) {
        int i = threadIdx.x + k * 256;
        float g = y[i] * siluf(z[i]);
        v[k] = g;
        ss = fmaf(g, g, ss);
    }
#pragma unroll
    for (int o = 32; o > 0; o >>= 1) ss += __shfl_down(ss, o, 64);
    int wv = threadIdx.x >> 6, ln = threadIdx.x & 63;
    if (ln == 0) red[wv] = ss;
    __syncthreads();
    float tot = red[0] + red[1] + red[2] + red[3];
    float sc = rsqrtf(tot / (float)DSSM + 1e-12f);
    unsigned short* yo = Ybf + (size_t)row * DSSM;
#pragma unroll
    for (int k = 0; k < 6; ++k) {
        int i = threadIdx.x + k * 256;
        yo[i] = f2bf(v[k] * sc * nw[i]);
    }
}

// ---------------- time_out: gate + mix + LayerNorm over SEQ
__global__ __launch_bounds__(256) void timeout_k(const float* __restrict__ td,
    const float* __restrict__ tdt, const float* __restrict__ gw, const float* __restrict__ gb,
    const float* __restrict__ lnw, const float* __restrict__ lnb, float* __restrict__ out2)
{
    __shared__ float tm[SEQ];
    __shared__ float red[8];
    int row = blockIdx.x;
    const float* tdr = td + (size_t)row * SEQ;
    const float* tdtr = tdt + (size_t)row * SEQ;
    int wv = threadIdx.x >> 6, ln = threadIdx.x & 63;
    float part = 0.f;
    for (int i = threadIdx.x; i < SEQ; i += 256) part = fmaf(tdr[i], gw[i], part);
#pragma unroll
    for (int o = 32; o > 0; o >>= 1) part += __shfl_down(part, o, 64);
    if (ln == 0) red[wv] = part;
    __syncthreads();
    float dot = red[0] + red[1] + red[2] + red[3];
    float tg = 1.f / (1.f + expf(-(dot + gb[0])));
    __syncthreads();
    float sum = 0.f;
    for (int i = threadIdx.x; i < SEQ; i += 256) {
        float x = tg * tdr[i] + (1.f - tg) * tdtr[i];
        tm[i] = x;
        sum += x;
    }
#pragma unroll
    for (int o = 32; o > 0; o >>= 1) sum += __shfl_down(sum, o, 64);
    if (ln == 0) red[wv] = sum;
    __syncthreads();
    float mu = (red[0] + red[1] + red[2] + red[3]) / (float)SEQ;
    __syncthreads();
    float s2 = 0.f;
    for (int i = threadIdx.x; i < SEQ; i += 256) { float d = tm[i] - mu; s2 = fmaf(d, d, s2); }
#pragma unroll
    for (int o = 32; o > 0; o >>= 1) s2 += __shfl_down(s2, o, 64);
    if (ln == 0) red[wv] = s2;
    __syncthreads();
    float var = (red[0] + red[1] + red[2] + red[3]) / (float)SEQ;
    float inv = rsqrtf(var + 1e-12f);
    for (int i = threadIdx.x; i < SEQ; i += 256)
        out2[(size_t)row * SEQ + i] = (tm[i] - mu) * inv * lnw[i] + lnb[i];
}

extern "C" void kernel_launch(void* const* d_in, const int* in_sizes, int n_in,
                              void* d_out, int out_size, void* d_ws, size_t ws_size,
                              hipStream_t stream)
{
    const float* u      = (const float*)d_in[0];
    const float* td     = (const float*)d_in[1];
    const float* W_in   = (const float*)d_in[2];
    const float* b_in   = (const float*)d_in[3];
    const float* conv_w = (const float*)d_in[4];
    const float* conv_b = (const float*)d_in[5];
    const float* t1w    = (const float*)d_in[6];
    const float* t1b    = (const float*)d_in[7];
    const float* t2w    = (const float*)d_in[8];
    const float* t2b    = (const float*)d_in[9];
    const float* m1w    = (const float*)d_in[10];
    const float* m1b    = (const float*)d_in[11];
    const float* m2w    = (const float*)d_in[12];
    const float* m2b    = (const float*)d_in[13];
    const float* gw     = (const float*)d_in[14];
    const float* gb     = (const float*)d_in[15];
    const float* lnw    = (const float*)d_in[16];
    const float* lnb    = (const float*)d_in[17];
    const float* A_log  = (const float*)d_in[18];
    const float* dt_bias= (const float*)d_in[19];
    const float* Dpv    = (const float*)d_in[20];
    const float* nw     = (const float*)d_in[21];
    const float* W_out  = (const float*)d_in[22];
    const float* b_out  = (const float*)d_in[23];
    float* out  = (float*)d_out;
    float* out2 = out + (size_t)MR * DMODEL;

    float* ws = (float*)d_ws;
    size_t o = 0;
    float* zbuf  = ws + o; o += (size_t)MR * DSSM;
    float* r1    = ws + o; o += (size_t)MR * XSTR;
    float* xcv   = ws + o; o += (size_t)MR * CDIM / 2;
    float* hid   = ws + o; o += (size_t)BB * NHH * SEQ;
    float* tss   = ws + o; o += (size_t)BB * NHH * SEQ;
    float* tdt   = ws + o; o += (size_t)BB * NHH * SEQ;
    float* dtp   = ws + o; o += (size_t)MR * NHH;
    float* pvb   = ws + o; o += (size_t)BB * NC * NHH * HDIM * DSTATE;
    float* alb   = ws + o; o += (size_t)BB * NC * NHH;
    unsigned short* sraw = (unsigned short*)(ws + o); o += (size_t)BB * NC * 16 * 4096 / 2;
    float* stb = r1;
    float* Yb  = r1;
    float* partb = xcv;                                     // 32*48*4096 = 6,291,456 fits 7,340,032
    unsigned short* xcv_bf = (unsigned short*)xcv;
    unsigned short* u_bf  = (unsigned short*)pvb;
    unsigned short* Wi_bf = (unsigned short*)(pvb + 3145728);
    unsigned short* Y_bf  = (unsigned short*)xcv;
    unsigned short* Wo_bf = (unsigned short*)(zbuf + 6291456);

    dim3 blk(256);
    // --- time MLP first (partials use xcv region, dead until conv) ---
    gemm_skinny_nt<<<dim3(SEQ / 128, KSPLIT), blk, 0, stream>>>(td, m1w, partb, SEQ, SEQ);
    reduce_part_k<<<dim3((48 * SEQ + 255) / 256), blk, 0, stream>>>(partb, m1b, hid, SEQ, 1);
    gemm_skinny_nt<<<dim3(SEQ / 128, KSPLIT), blk, 0, stream>>>(hid, m2w, partb, SEQ, SEQ);
    reduce_part_k<<<dim3((48 * SEQ + 255) / 256), blk, 0, stream>>>(partb, m2b, tss, SEQ, 0);
    time_conv_k<<<dim3(BB * NHH), blk, 0, stream>>>(tss, td, t1w, t1b, t2w, t2b, tdt);
    // --- in-proj ---
    cvt_bf16_k<<<dim3((MR * DMODEL / 4 + 255) / 256), blk, 0, stream>>>(u, u_bf, MR * DMODEL, MR * DMODEL);
    cvt_bf16_k<<<dim3((3456 * DMODEL / 4 + 255) / 256), blk, 0, stream>>>(W_in, Wi_bf, DPROJ * DMODEL, 3456 * DMODEL);
    gemm_mfma_nt<<<dim3(XSTR / 128, MR / 128), blk, 0, stream>>>(
        u_bf, Wi_bf + (size_t)DSSM * DMODEL, b_in + DSSM, r1, XSTR, DMODEL, DMODEL / 32, DPROJ - DSSM);
    conv_xbc_k<<<dim3((MR * (CDIM / 4) + 255) / 256), blk, 0, stream>>>(r1, conv_w, conv_b, xcv_bf);
    gemm_mfma_nt<<<dim3(DSSM / 128, MR / 128), blk, 0, stream>>>(
        u_bf, Wi_bf, b_in, zbuf, DSSM, DMODEL, DMODEL / 32, DSSM);
    dtsp_k<<<dim3((MR * NHH + 255) / 256), blk, 0, stream>>>(r1, tdt, dt_bias, dtp);
    // --- SSD ---
    ssd_sraw_k<<<dim3(BB * NC), dim3(512), 0, stream>>>(xcv_bf, sraw);
    ssd_states_mfma_k<<<dim3(BB * NC * NHH), blk, 0, stream>>>(xcv_bf, dtp, A_log, stb, alb);
    ssd_scan_k<<<dim3(BB * NHH), blk, 0, stream>>>(stb, alb, pvb);
    ssd_y2_k<<<dim3(BB * NC * NHH), blk, 0, stream>>>(xcv_bf, dtp, A_log, sraw, pvb, Dpv, Yb);
    // --- epilogue ---
    rmsnorm_k<<<dim3(MR), blk, 0, stream>>>(Yb, zbuf, nw, Y_bf);
    cvt_bf16_k<<<dim3((DMODEL * DSSM / 4 + 255) / 256), blk, 0, stream>>>(W_out, Wo_bf, DMODEL * DSSM, DMODEL * DSSM);
    gemm_mfma_nt<<<dim3(DMODEL / 128, MR / 128), blk, 0, stream>>>(
        Y_bf, Wo_bf, b_out, out, DMODEL, DSSM, DSSM / 32, DMODEL);
    timeout_k<<<dim3(BB * NHH), blk, 0, stream>>>(td, tdt, gw, gb, lnw, lnb, out2);
}

// Round 10
// 468.883 us; speedup vs baseline: 7.4446x; 1.1210x over previous
//
#include <hip/hip_runtime.h>
#include <math.h>

#define BB 2
#define SEQ 4096
#define DMODEL 768
#define DSTATE 128
#define NHH 24
#define HDIM 64
#define DSSM 1536
#define CDIM 1792
#define CHK 256
#define NC 16
#define DPROJ 3352
#define MR (BB*SEQ)
#define KSPLIT 32
#define XSTR 1920   // r1 row stride: xBC(1792) + dt(24) + pad(104)
#define CT 16       // conv timesteps per thread

typedef __attribute__((ext_vector_type(8))) short bf16x8;
typedef __attribute__((ext_vector_type(8))) unsigned short u16x8;
typedef __attribute__((ext_vector_type(4))) float f32x4;

__device__ __forceinline__ float siluf(float x) { return x / (1.0f + expf(-x)); }

__device__ __forceinline__ unsigned short f2bf(float f) {
    unsigned u = __float_as_uint(f);
    unsigned r = (u + 0x7fffu + ((u >> 16) & 1u)) >> 16;
    return (unsigned short)r;
}

__device__ __forceinline__ float bf2f(unsigned short u) {
    return __uint_as_float(((unsigned)u) << 16);
}

__device__ __forceinline__ float4 bf2f4(ushort4 v) {
    float4 o;
    o.x = bf2f(v.x); o.y = bf2f(v.y); o.z = bf2f(v.z); o.w = bf2f(v.w);
    return o;
}

__device__ __forceinline__ void gload_lds16(const void* g, void* l) {
    __builtin_amdgcn_global_load_lds((const __attribute__((address_space(1))) unsigned int*)g,
                                     (__attribute__((address_space(3))) unsigned int*)l, 16, 0, 0);
}

// ---------------- f32 -> bf16 conversion (vectorized), zero-pad beyond n_valid
__global__ __launch_bounds__(256) void cvt_bf16_k(const float* __restrict__ in,
    unsigned short* __restrict__ out, int n_valid, int n_total)
{
    int i = (blockIdx.x * 256 + threadIdx.x) * 4;
    if (i >= n_total) return;
    ushort4 o;
    if (i + 3 < n_valid) {
        float4 v = *(const float4*)&in[i];
        o.x = f2bf(v.x); o.y = f2bf(v.y); o.z = f2bf(v.z); o.w = f2bf(v.w);
    } else {
        o.x = (i + 0 < n_valid) ? f2bf(in[i + 0]) : 0;
        o.y = (i + 1 < n_valid) ? f2bf(in[i + 1]) : 0;
        o.z = (i + 2 < n_valid) ? f2bf(in[i + 2]) : 0;
        o.w = (i + 3 < n_valid) ? f2bf(in[i + 3]) : 0;
    }
    *(ushort4*)&out[i] = o;
}

// ---------------- bf16 MFMA GEMM: C(MxN) = A(MxK) @ B(NxK)^T + bias; f32 or bf16 store
__global__ __launch_bounds__(256) void gemm_mfma_nt(
    const unsigned short* __restrict__ A, const unsigned short* __restrict__ B,
    const float* __restrict__ bias, void* __restrict__ C, int N, int K, int KT,
    int nbias, int store_bf16)
{
    __shared__ unsigned short SA[2][128 * 32];
    __shared__ unsigned short SB[2][128 * 32];
    const int tid = threadIdx.x;
    const int w = tid >> 6, l = tid & 63;
    const int wr = w >> 1, wc = w & 1;
    const int lr = l & 15, lk = l >> 4;
    const int m0 = blockIdx.y * 128, n0 = blockIdx.x * 128;
    f32x4 acc[4][4] = {};
    const int i16 = w * 64 + l;
    const int row0 = i16 >> 2, sl = i16 & 3;
    const size_t ga0 = (size_t)(m0 + row0) * K + sl * 8;
    const size_t ga1 = (size_t)(m0 + row0 + 64) * K + sl * 8;
    const size_t gb0 = (size_t)(n0 + row0) * K + sl * 8;
    const size_t gb1 = (size_t)(n0 + row0 + 64) * K + sl * 8;
    const int lo0 = (w * 64) * 8;
    const int lo1 = (256 + w * 64) * 8;

#define STAGE(bb, kt) { int ko = (kt) * 32;                      \
      gload_lds16(A + ga0 + ko, &SA[bb][lo0]);                   \
      gload_lds16(A + ga1 + ko, &SA[bb][lo1]);                   \
      gload_lds16(B + gb0 + ko, &SB[bb][lo0]);                   \
      gload_lds16(B + gb1 + ko, &SB[bb][lo1]); }

    STAGE(0, 0);
    for (int kt = 0; kt < KT; ++kt) {
        int cur = kt & 1;
        asm volatile("s_waitcnt vmcnt(0)" ::: "memory");
        __syncthreads();
        if (kt + 1 < KT) STAGE(cur ^ 1, kt + 1);
        bf16x8 af[4], bg[4];
#pragma unroll
        for (int mi = 0; mi < 4; ++mi)
            af[mi] = *(const bf16x8*)&SA[cur][(wr * 64 + mi * 16 + lr) * 32 + lk * 8];
#pragma unroll
        for (int nj = 0; nj < 4; ++nj)
            bg[nj] = *(const bf16x8*)&SB[cur][(wc * 64 + nj * 16 + lr) * 32 + lk * 8];
#pragma unroll
        for (int mi = 0; mi < 4; ++mi)
#pragma unroll
            for (int nj = 0; nj < 4; ++nj)
                acc[mi][nj] = __builtin_amdgcn_mfma_f32_16x16x32_bf16(af[mi], bg[nj], acc[mi][nj], 0, 0, 0);
    }
#undef STAGE
#pragma unroll
    for (int nj = 0; nj < 4; ++nj) {
        int col = n0 + wc * 64 + nj * 16 + lr;
        float bz = (col < nbias) ? bias[col] : 0.f;
#pragma unroll
        for (int mi = 0; mi < 4; ++mi) {
#pragma unroll
            for (int r = 0; r < 4; ++r) {
                int m = m0 + wr * 64 + mi * 16 + lk * 4 + r;
                float v = acc[mi][nj][r] + bz;
                if (store_bf16)
                    ((unsigned short*)C)[(size_t)m * N + col] = f2bf(v);
                else
                    ((float*)C)[(size_t)m * N + col] = v;
            }
        }
    }
}

// ---------------- split-K skinny GEMM (M=48), conflict-free [row][k] LDS layout
__global__ __launch_bounds__(256) void gemm_skinny_nt(const float* __restrict__ A,
    const float* __restrict__ Bw, float* __restrict__ part, int N, int K)
{
    __shared__ float sA[48 * 33];
    __shared__ float sB[128 * 33];
    const int nb = blockIdx.x, kb = blockIdx.y;
    const int n0 = nb * 128;
    const int KS = K / KSPLIT;
    const int k0 = kb * KS;
    const int tid = threadIdx.x;
    const int tx = tid & 31, ty = tid >> 5;
    float acc[6][4] = {{0.f}};
    for (int kc = 0; kc < KS; kc += 32) {
        if (kc) __syncthreads();
        for (int i = tid; i < 384; i += 256) {
            int m = i >> 3, k4 = (i & 7) * 4;
            float4 v = *(const float4*)&A[(size_t)m * K + k0 + kc + k4];
            sA[m * 33 + k4 + 0] = v.x;
            sA[m * 33 + k4 + 1] = v.y;
            sA[m * 33 + k4 + 2] = v.z;
            sA[m * 33 + k4 + 3] = v.w;
        }
        for (int i = tid; i < 1024; i += 256) {
            int n = i >> 3, k4 = (i & 7) * 4;
            float4 v = *(const float4*)&Bw[(size_t)(n0 + n) * K + k0 + kc + k4];
            sB[n * 33 + k4 + 0] = v.x;
            sB[n * 33 + k4 + 1] = v.y;
            sB[n * 33 + k4 + 2] = v.z;
            sB[n * 33 + k4 + 3] = v.w;
        }
        __syncthreads();
#pragma unroll 8
        for (int kk = 0; kk < 32; ++kk) {
            float a[6], b[4];
#pragma unroll
            for (int r = 0; r < 6; ++r) a[r] = sA[(ty * 6 + r) * 33 + kk];
#pragma unroll
            for (int j = 0; j < 4; ++j) b[j] = sB[(tx + j * 32) * 33 + kk];
#pragma unroll
            for (int r = 0; r < 6; ++r)
#pragma unroll
                for (int j = 0; j < 4; ++j)
                    acc[r][j] = fmaf(a[r], b[j], acc[r][j]);
        }
    }
    float* pb = part + (size_t)kb * 48 * N;
#pragma unroll
    for (int r = 0; r < 6; ++r)
#pragma unroll
        for (int j = 0; j < 4; ++j)
            pb[(size_t)(ty * 6 + r) * N + n0 + tx + j * 32] = acc[r][j];
}

// ---------------- reduce split-K partials + bias (+ optional silu)
__global__ __launch_bounds__(256) void reduce_part_k(const float* __restrict__ part,
    const float* __restrict__ bias, float* __restrict__ out, int N, int act)
{
    int idx = blockIdx.x * 256 + threadIdx.x;
    if (idx >= 48 * N) return;
    int n = idx % N;
    float s = bias[n];
#pragma unroll
    for (int kb = 0; kb < KSPLIT; ++kb) s += part[(size_t)kb * 48 * N + idx];
    if (act) s = siluf(s);
    out[idx] = s;
}

// ---------------- sliding-window depthwise causal conv + silu, bf16 in/out
// thread = 4 channels x CT timesteps; reads each row once (+3 halo)
__global__ __launch_bounds__(256) void conv_xbc_k(const unsigned short* __restrict__ xbc,
    const float* __restrict__ cw, const float* __restrict__ cb,
    unsigned short* __restrict__ out)
{
    int idx = blockIdx.x * 256 + threadIdx.x;
    if (idx >= 448 * (MR / CT)) return;
    int slot = idx % 448;
    int g = idx / 448;
    int c4 = slot * 4;
    int b = g / (SEQ / CT);
    int t0 = (g % (SEQ / CT)) * CT;
    size_t rb = (size_t)b * SEQ;
    float4 cw0 = *(const float4*)&cw[(c4 + 0) * 4];
    float4 cw1 = *(const float4*)&cw[(c4 + 1) * 4];
    float4 cw2 = *(const float4*)&cw[(c4 + 2) * 4];
    float4 cw3 = *(const float4*)&cw[(c4 + 3) * 4];
    float4 cbv = *(const float4*)&cb[c4];
    float4 zero = {0.f, 0.f, 0.f, 0.f};
    float4 w0, w1, w2;
    w0 = (t0 - 3 >= 0) ? bf2f4(*(const ushort4*)&xbc[(rb + t0 - 3) * XSTR + c4]) : zero;
    w1 = (t0 - 2 >= 0) ? bf2f4(*(const ushort4*)&xbc[(rb + t0 - 2) * XSTR + c4]) : zero;
    w2 = (t0 - 1 >= 0) ? bf2f4(*(const ushort4*)&xbc[(rb + t0 - 1) * XSTR + c4]) : zero;
#pragma unroll
    for (int i = 0; i < CT; ++i) {
        int t = t0 + i;
        float4 w3 = bf2f4(*(const ushort4*)&xbc[(rb + t) * XSTR + c4]);
        float a0 = cbv.x + w0.x * cw0.x + w1.x * cw0.y + w2.x * cw0.z + w3.x * cw0.w;
        float a1 = cbv.y + w0.y * cw1.x + w1.y * cw1.y + w2.y * cw1.z + w3.y * cw1.w;
        float a2 = cbv.z + w0.z * cw2.x + w1.z * cw2.y + w2.z * cw2.z + w3.z * cw2.w;
        float a3 = cbv.w + w0.w * cw3.x + w1.w * cw3.y + w2.w * cw3.z + w3.w * cw3.w;
        ushort4 o;
        o.x = f2bf(siluf(a0)); o.y = f2bf(siluf(a1));
        o.z = f2bf(siluf(a2)); o.w = f2bf(siluf(a3));
        *(ushort4*)&out[(rb + t) * CDIM + c4] = o;
        w0 = w1; w1 = w2; w2 = w3;
    }
}

// ---------------- per-(b,h) row: tdt0 = ts*td; conv1+silu; conv2+silu
__global__ __launch_bounds__(256) void time_conv_k(const float* __restrict__ ts,
    const float* __restrict__ td, const float* __restrict__ w1, const float* __restrict__ b1,
    const float* __restrict__ w2, const float* __restrict__ b2, float* __restrict__ tdt)
{
    __shared__ float u0[SEQ];
    __shared__ float u1[SEQ];
    int row = blockIdx.x, h = row % NHH;
    const float* tsr = ts + (size_t)row * SEQ;
    const float* tdr = td + (size_t)row * SEQ;
    for (int i = threadIdx.x; i < SEQ; i += 256) u0[i] = tsr[i] * tdr[i];
    __syncthreads();
    float wa[4], wb[4];
#pragma unroll
    for (int k = 0; k < 4; ++k) { wa[k] = w1[h * 4 + k]; wb[k] = w2[h * 4 + k]; }
    float ba = b1[h], bbv = b2[h];
    for (int i = threadIdx.x; i < SEQ; i += 256) {
        float acc = ba;
#pragma unroll
        for (int k = 0; k < 4; ++k) { int tt = i + k - 3; if (tt >= 0) acc = fmaf(u0[tt], wa[k], acc); }
        u1[i] = siluf(acc);
    }
    __syncthreads();
    for (int i = threadIdx.x; i < SEQ; i += 256) {
        float acc = bbv;
#pragma unroll
        for (int k = 0; k < 4; ++k) { int tt = i + k - 3; if (tt >= 0) acc = fmaf(u1[tt], wb[k], acc); }
        tdt[(size_t)row * SEQ + i] = siluf(acc);
    }
}

// ---------------- dt_sp = softplus(dt * tdt^T + dt_bias); dt from bf16 r1 col 1792+h
__global__ __launch_bounds__(256) void dtsp_k(const unsigned short* __restrict__ r1,
    const float* __restrict__ tdt, const float* __restrict__ dt_bias, float* __restrict__ dtp)
{
    int idx = blockIdx.x * 256 + threadIdx.x;
    if (idx >= MR * NHH) return;
    int h = idx % NHH;
    int row = idx / NHH;
    int b = row / SEQ, s = row % SEQ;
    float x = bf2f(r1[(size_t)row * XSTR + CDIM + h]) * tdt[((size_t)(b * NHH + h)) * SEQ + s] + dt_bias[h];
    dtp[idx] = (x > 20.0f) ? x : log1pf(expf(x));
}

// ---------------- SSD chunk states via MFMA
__global__ __launch_bounds__(256) void ssd_states_mfma_k(const unsigned short* __restrict__ xc,
    const float* __restrict__ dtp, const float* __restrict__ A_log,
    float* __restrict__ st, float* __restrict__ al)
{
    __shared__ float s_acs[256];
    __shared__ float s_coef[256];
    __shared__ unsigned short SXT[64 * 136];
    __shared__ unsigned short SBT[128 * 136];
    int blk = blockIdx.x;
    int h = blk % NHH, c = (blk / NHH) % NC, b = blk / (NHH * NC);
    int tid = threadIdx.x;
    int w = tid >> 6, l = tid & 63;
    int lr = l & 15, lk = l >> 4;
    size_t rowbase = (size_t)b * SEQ + c * CHK;
    float Ah = -expf(A_log[h]);
    float dtv = dtp[(rowbase + tid) * NHH + h];
    s_acs[tid] = Ah * dtv;
    __syncthreads();
    for (int off = 1; off < 256; off <<= 1) {
        float t = (tid >= off) ? s_acs[tid - off] : 0.f;
        __syncthreads();
        s_acs[tid] += t;
        __syncthreads();
    }
    float alv = s_acs[255];
    s_coef[tid] = expf(alv - s_acs[tid]) * dtv;
    if (tid == 255) al[blk] = alv;
    __syncthreads();
    f32x4 acc[4][2] = {};
    for (int z0 = 0; z0 < CHK; z0 += 128) {
        if (z0) __syncthreads();
        for (int i = tid; i < 128 * 8; i += 256) {
            int zz = i >> 3, p8 = (i & 7) * 8;
            float sc = s_coef[z0 + zz];
            u16x8 v = *(const u16x8*)&xc[(rowbase + z0 + zz) * CDIM + h * HDIM + p8];
#pragma unroll
            for (int e = 0; e < 8; ++e)
                SXT[(p8 + e) * 136 + zz] = f2bf(bf2f(v[e]) * sc);
        }
        for (int i = tid; i < 128 * 16; i += 256) {
            int zz = i >> 4, n8 = (i & 15) * 8;
            u16x8 v = *(const u16x8*)&xc[(rowbase + z0 + zz) * CDIM + DSSM + n8];
#pragma unroll
            for (int e = 0; e < 8; ++e)
                SBT[(n8 + e) * 136 + zz] = v[e];
        }
        __syncthreads();
#pragma unroll
        for (int kt = 0; kt < 4; ++kt) {
            bf16x8 av[4], bv[2];
#pragma unroll
            for (int mi = 0; mi < 4; ++mi)
                av[mi] = *(const bf16x8*)&SXT[(mi * 16 + lr) * 136 + kt * 32 + lk * 8];
#pragma unroll
            for (int nj = 0; nj < 2; ++nj)
                bv[nj] = *(const bf16x8*)&SBT[(w * 32 + nj * 16 + lr) * 136 + kt * 32 + lk * 8];
#pragma unroll
            for (int mi = 0; mi < 4; ++mi)
#pragma unroll
                for (int nj = 0; nj < 2; ++nj)
                    acc[mi][nj] = __builtin_amdgcn_mfma_f32_16x16x32_bf16(av[mi], bv[nj], acc[mi][nj], 0, 0, 0);
        }
    }
    size_t base = (size_t)blk * (HDIM * DSTATE);
#pragma unroll
    for (int mi = 0; mi < 4; ++mi)
#pragma unroll
        for (int r = 0; r < 4; ++r) {
            int p = mi * 16 + lk * 4 + r;
#pragma unroll
            for (int nj = 0; nj < 2; ++nj)
                st[base + p * DSTATE + w * 32 + nj * 16 + lr] = acc[mi][nj][r];
        }
}

// ---------------- inter-chunk scan
__global__ __launch_bounds__(256) void ssd_scan_k(const float* __restrict__ st,
    const float* __restrict__ al, float* __restrict__ pv)
{
    int b = blockIdx.x / NHH, h = blockIdx.x % NHH;
    int tid = threadIdx.x;
    float carry[32];
#pragma unroll
    for (int j = 0; j < 32; ++j) carry[j] = 0.f;
    for (int c = 0; c < NC; ++c) {
        int bch = (b * NC + c) * NHH + h;
        size_t base = (size_t)bch * (HDIM * DSTATE);
        float dcy = expf(al[bch]);
#pragma unroll
        for (int j = 0; j < 32; ++j) {
            pv[base + tid + j * 256] = carry[j];
            carry[j] = fmaf(dcy, carry[j], st[base + tid + j * 256]);
        }
    }
}

// ---------------- S_raw = C.B^T per (b,c), lower-triangular 64x64 tiles, bf16
__global__ __launch_bounds__(512) void ssd_sraw_k(const unsigned short* __restrict__ xc,
    unsigned short* __restrict__ sraw)
{
    __shared__ unsigned short SC[256 * 136];
    __shared__ unsigned short SB[256 * 136];
    int bc = blockIdx.x;
    int b = bc / NC, c = bc % NC;
    size_t rowbase = (size_t)b * SEQ + c * CHK;
    int tid = threadIdx.x;
    int w = tid >> 6, l = tid & 63;
    int lr = l & 15, lk = l >> 4;
    for (int i = tid; i < 256 * 32; i += 512) {
        int r = i >> 5, c4 = (i & 31) * 4;
        *(ushort4*)&SC[r * 136 + c4] = *(const ushort4*)&xc[(rowbase + r) * CDIM + DSSM + DSTATE + c4];
        *(ushort4*)&SB[r * 136 + c4] = *(const ushort4*)&xc[(rowbase + r) * CDIM + DSSM + c4];
    }
    __syncthreads();
    unsigned short* tb = sraw + (size_t)bc * 16 * 4096;
    int t = 0;
#pragma unroll
    for (int st = 0; st < 4; ++st) {
#pragma unroll
        for (int zt = 0; zt <= st; ++zt, ++t) {
            if ((t & 7) != w) continue;
            f32x4 d[4][4] = {};
#pragma unroll
            for (int kt = 0; kt < 4; ++kt) {
                bf16x8 av[4], bv[4];
#pragma unroll
                for (int mi = 0; mi < 4; ++mi)
                    av[mi] = *(const bf16x8*)&SC[(st * 64 + mi * 16 + lr) * 136 + kt * 32 + lk * 8];
#pragma unroll
                for (int nj = 0; nj < 4; ++nj)
                    bv[nj] = *(const bf16x8*)&SB[(zt * 64 + nj * 16 + lr) * 136 + kt * 32 + lk * 8];
#pragma unroll
                for (int mi = 0; mi < 4; ++mi)
#pragma unroll
                    for (int nj = 0; nj < 4; ++nj)
                        d[mi][nj] = __builtin_amdgcn_mfma_f32_16x16x32_bf16(av[mi], bv[nj], d[mi][nj], 0, 0, 0);
            }
            unsigned short* tp = tb + (size_t)(st * 4 + zt) * 4096;
#pragma unroll
            for (int mi = 0; mi < 4; ++mi)
#pragma unroll
                for (int nj = 0; nj < 4; ++nj)
#pragma unroll
                    for (int r = 0; r < 4; ++r)
                        tp[(mi * 16 + lk * 4 + r) * 64 + nj * 16 + lr] = f2bf(d[mi][nj][r]);
        }
    }
}

// ---------------- Y from precomputed S_raw: per (b,c,h), 4 waves = 4 s-tiles.
__global__ __launch_bounds__(256) void ssd_y2_k(const unsigned short* __restrict__ xc,
    const float* __restrict__ dtp, const float* __restrict__ A_log,
    const unsigned short* __restrict__ sraw, const float* __restrict__ pv,
    const float* __restrict__ Dp, float* __restrict__ Y)
{
    __shared__ float s_acs[256];
    __shared__ float s_dt[256];
    __shared__ float s_edt[256];
    __shared__ float s_az0[4];
    __shared__ unsigned short SXT[64 * 264];
    __shared__ unsigned short SPV[64 * 136];
    int blk = blockIdx.x;
    int h = blk % NHH;
    int c = (blk / NHH) % NC;
    int b = blk / (NHH * NC);
    int tid = threadIdx.x;
    int w = tid >> 6, l = tid & 63;
    int lr = l & 15, lk = l >> 4;
    size_t rowbase = (size_t)b * SEQ + c * CHK;
    float Ah = -expf(A_log[h]);
    float dtv = dtp[(rowbase + tid) * NHH + h];
    s_dt[tid] = dtv;
    s_acs[tid] = Ah * dtv;
    __syncthreads();
    for (int off = 1; off < 256; off <<= 1) {
        float t = (tid >= off) ? s_acs[tid - off] : 0.f;
        __syncthreads();
        s_acs[tid] += t;
        __syncthreads();
    }
    if (tid < 4) s_az0[tid] = s_acs[tid * 64];
    __syncthreads();
    {
        float e = s_az0[tid >> 6] - s_acs[tid];
        if (e > 60.f) e = 60.f;
        s_edt[tid] = expf(e) * s_dt[tid];
    }
    __syncthreads();
    for (int i = tid; i < 256 * 8; i += 256) {
        int z = i >> 3, p8 = (i & 7) * 8;
        float sc = s_edt[z];
        u16x8 v = *(const u16x8*)&xc[(rowbase + z) * CDIM + h * HDIM + p8];
#pragma unroll
        for (int e = 0; e < 8; ++e)
            SXT[(p8 + e) * 264 + z] = f2bf(bf2f(v[e]) * sc);
    }
    const float* pvbase = pv + (size_t)blk * (HDIM * DSTATE);
    for (int i = tid; i < 64 * 32; i += 256) {
        int p = i >> 5, n4 = (i & 31) * 4;
        float4 v = *(const float4*)&pvbase[p * DSTATE + n4];
        ushort4 o; o.x = f2bf(v.x); o.y = f2bf(v.y); o.z = f2bf(v.z); o.w = f2bf(v.w);
        *(ushort4*)&SPV[p * 136 + n4] = o;
    }
    __syncthreads();

    const unsigned short* tbase = sraw + (size_t)(b * NC + c) * 16 * 4096;
    f32x4 acc[4][4] = {};
    for (int zt = 0; zt <= w; ++zt) {
        const unsigned short* tp = tbase + (size_t)(w * 4 + zt) * 4096;
        f32x4 tmp[4][4] = {};
#pragma unroll
        for (int kt = 0; kt < 2; ++kt) {
            bf16x8 av[4], bv[4];
#pragma unroll
            for (int mi = 0; mi < 4; ++mi) {
                av[mi] = *(const bf16x8*)&tp[(mi * 16 + lr) * 64 + kt * 32 + lk * 8];
                if (zt == w) {
                    int zb = kt * 32 + lk * 8;
                    int sl = mi * 16 + lr;
#pragma unroll
                    for (int e = 0; e < 8; ++e)
                        if (zb + e > sl) av[mi][e] = 0;
                }
            }
#pragma unroll
            for (int nj = 0; nj < 4; ++nj)
                bv[nj] = *(const bf16x8*)&SXT[(nj * 16 + lr) * 264 + zt * 64 + kt * 32 + lk * 8];
#pragma unroll
            for (int mi = 0; mi < 4; ++mi)
#pragma unroll
                for (int nj = 0; nj < 4; ++nj)
                    tmp[mi][nj] = __builtin_amdgcn_mfma_f32_16x16x32_bf16(av[mi], bv[nj], tmp[mi][nj], 0, 0, 0);
        }
        float az = s_az0[zt];
#pragma unroll
        for (int mi = 0; mi < 4; ++mi) {
#pragma unroll
            for (int r = 0; r < 4; ++r) {
                float es = expf(s_acs[w * 64 + mi * 16 + lk * 4 + r] - az);
#pragma unroll
                for (int nj = 0; nj < 4; ++nj)
                    acc[mi][nj][r] += es * tmp[mi][nj][r];
            }
        }
    }
    {
        f32x4 tmp[4][4] = {};
#pragma unroll
        for (int kt = 0; kt < 4; ++kt) {
            bf16x8 av[4], bv[4];
#pragma unroll
            for (int mi = 0; mi < 4; ++mi)
                av[mi] = *(const bf16x8*)&xc[(rowbase + w * 64 + mi * 16 + lr) * CDIM + DSSM + DSTATE + kt * 32 + lk * 8];
#pragma unroll
            for (int nj = 0; nj < 4; ++nj)
                bv[nj] = *(const bf16x8*)&SPV[(nj * 16 + lr) * 136 + kt * 32 + lk * 8];
#pragma unroll
            for (int mi = 0; mi < 4; ++mi)
#pragma unroll
                for (int nj = 0; nj < 4; ++nj)
                    tmp[mi][nj] = __builtin_amdgcn_mfma_f32_16x16x32_bf16(av[mi], bv[nj], tmp[mi][nj], 0, 0, 0);
        }
#pragma unroll
        for (int mi = 0; mi < 4; ++mi) {
#pragma unroll
            for (int r = 0; r < 4; ++r) {
                float es = expf(s_acs[w * 64 + mi * 16 + lk * 4 + r]);
#pragma unroll
                for (int nj = 0; nj < 4; ++nj)
                    acc[mi][nj][r] += es * tmp[mi][nj][r];
            }
        }
    }
    float dph = Dp[h];
#pragma unroll
    for (int mi = 0; mi < 4; ++mi) {
#pragma unroll
        for (int r = 0; r < 4; ++r) {
            int s = w * 64 + mi * 16 + lk * 4 + r;
#pragma unroll
            for (int nj = 0; nj < 4; ++nj) {
                int p = nj * 16 + lr;
                float xv = bf2f(xc[(rowbase + s) * CDIM + h * HDIM + p]);
                Y[(rowbase + s) * DSSM + h * HDIM + p] = acc[mi][nj][r] + dph * xv;
            }
        }
    }
}

// ---------------- gated RMS norm -> bf16 output
__global__ __launch_bounds__(256) void rmsnorm_k(const float* __restrict__ Y,
    const float* __restrict__ zbuf, const float* __restrict__ nw,
    unsigned short* __restrict__ Ybf)
{
    __shared__ float red[8];
    int row = blockIdx.x;
    const float* y = Y + (size_t)row * DSSM;
    const float* z = zbuf + (size_t)row * DSSM;
    float v[6];
    float ss = 0.f;
#pragma unroll
    for (int k = 0; k < 6; ++k) {
        int i = threadIdx.x + k * 256;
        float g = y[i] * siluf(z[i]);
        v[k] = g;
        ss = fmaf(g, g, ss);
    }
#pragma unroll
    for (int o = 32; o > 0; o >>= 1) ss += __shfl_down(ss, o, 64);
    int wv = threadIdx.x >> 6, ln = threadIdx.x & 63;
    if (ln == 0) red[wv] = ss;
    __syncthreads();
    float tot = red[0] + red[1] + red[2] + red[3];
    float sc = rsqrtf(tot / (float)DSSM + 1e-12f);
    unsigned short* yo = Ybf + (size_t)row * DSSM;
#pragma unroll
    for (int k = 0; k < 6; ++k) {
        int i = threadIdx.x + k * 256;
        yo[i] = f2bf(v[k] * sc * nw[i]);
    }
}

// ---------------- time_out: gate + mix + LayerNorm over SEQ
__global__ __launch_bounds__(256) void timeout_k(const float* __restrict__ td,
    const float* __restrict__ tdt, const float* __restrict__ gw, const float* __restrict__ gb,
    const float* __restrict__ lnw, const float* __restrict__ lnb, float* __restrict__ out2)
{
    __shared__ float tm[SEQ];
    __shared__ float red[8];
    int row = blockIdx.x;
    const float* tdr = td + (size_t)row * SEQ;
    const float* tdtr = tdt + (size_t)row * SEQ;
    int wv = threadIdx.x >> 6, ln = threadIdx.x & 63;
    float part = 0.f;
    for (int i = threadIdx.x; i < SEQ; i += 256) part = fmaf(tdr[i], gw[i], part);
#pragma unroll
    for (int o = 32; o > 0; o >>= 1) part += __shfl_down(part, o, 64);
    if (ln == 0) red[wv] = part;
    __syncthreads();
    float dot = red[0] + red[1] + red[2] + red[3];
    float tg = 1.f / (1.f + expf(-(dot + gb[0])));
    __syncthreads();
    float sum = 0.f;
    for (int i = threadIdx.x; i < SEQ; i += 256) {
        float x = tg * tdr[i] + (1.f - tg) * tdtr[i];
        tm[i] = x;
        sum += x;
    }
#pragma unroll
    for (int o = 32; o > 0; o >>= 1) sum += __shfl_down(sum, o, 64);
    if (ln == 0) red[wv] = sum;
    __syncthreads();
    float mu = (red[0] + red[1] + red[2] + red[3]) / (float)SEQ;
    __syncthreads();
    float s2 = 0.f;
    for (int i = threadIdx.x; i < SEQ; i += 256) { float d = tm[i] - mu; s2 = fmaf(d, d, s2); }
#pragma unroll
    for (int o = 32; o > 0; o >>= 1) s2 += __shfl_down(s2, o, 64);
    if (ln == 0) red[wv] = s2;
    __syncthreads();
    float var = (red[0] + red[1] + red[2] + red[3]) / (float)SEQ;
    float inv = rsqrtf(var + 1e-12f);
    for (int i = threadIdx.x; i < SEQ; i += 256)
        out2[(size_t)row * SEQ + i] = (tm[i] - mu) * inv * lnw[i] + lnb[i];
}

extern "C" void kernel_launch(void* const* d_in, const int* in_sizes, int n_in,
                              void* d_out, int out_size, void* d_ws, size_t ws_size,
                              hipStream_t stream)
{
    const float* u      = (const float*)d_in[0];
    const float* td     = (const float*)d_in[1];
    const float* W_in   = (const float*)d_in[2];
    const float* b_in   = (const float*)d_in[3];
    const float* conv_w = (const float*)d_in[4];
    const float* conv_b = (const float*)d_in[5];
    const float* t1w    = (const float*)d_in[6];
    const float* t1b    = (const float*)d_in[7];
    const float* t2w    = (const float*)d_in[8];
    const float* t2b    = (const float*)d_in[9];
    const float* m1w    = (const float*)d_in[10];
    const float* m1b    = (const float*)d_in[11];
    const float* m2w    = (const float*)d_in[12];
    const float* m2b    = (const float*)d_in[13];
    const float* gw     = (const float*)d_in[14];
    const float* gb     = (const float*)d_in[15];
    const float* lnw    = (const float*)d_in[16];
    const float* lnb    = (const float*)d_in[17];
    const float* A_log  = (const float*)d_in[18];
    const float* dt_bias= (const float*)d_in[19];
    const float* Dpv    = (const float*)d_in[20];
    const float* nw     = (const float*)d_in[21];
    const float* W_out  = (const float*)d_in[22];
    const float* b_out  = (const float*)d_in[23];
    float* out  = (float*)d_out;
    float* out2 = out + (size_t)MR * DMODEL;

    float* ws = (float*)d_ws;
    size_t o = 0;
    float* zbuf  = ws + o; o += (size_t)MR * DSSM;
    float* r1    = ws + o; o += (size_t)MR * DSSM;    // region: bf16 r1 (XSTR sh) / stb / Yb
    float* xcv   = ws + o; o += (size_t)MR * CDIM / 2;
    float* hid   = ws + o; o += (size_t)BB * NHH * SEQ;
    float* tss   = ws + o; o += (size_t)BB * NHH * SEQ;
    float* tdt   = ws + o; o += (size_t)BB * NHH * SEQ;
    float* dtp   = ws + o; o += (size_t)MR * NHH;
    float* pvb   = ws + o; o += (size_t)BB * NC * NHH * HDIM * DSTATE;
    float* alb   = ws + o; o += (size_t)BB * NC * NHH;
    unsigned short* sraw = (unsigned short*)(ws + o); o += (size_t)BB * NC * 16 * 4096 / 2;
    unsigned short* r1b = (unsigned short*)r1;        // MR*XSTR sh = 7.86M floats < 12.58M
    float* stb = r1;
    float* Yb  = r1;
    float* partb = xcv;
    unsigned short* xcv_bf = (unsigned short*)xcv;
    unsigned short* u_bf  = (unsigned short*)pvb;
    unsigned short* Wi_bf = (unsigned short*)(pvb + 3145728);
    unsigned short* Y_bf  = (unsigned short*)xcv;
    unsigned short* Wo_bf = (unsigned short*)(zbuf + 6291456);

    dim3 blk(256);
    // --- time MLP first (partials use xcv region, dead until conv) ---
    gemm_skinny_nt<<<dim3(SEQ / 128, KSPLIT), blk, 0, stream>>>(td, m1w, partb, SEQ, SEQ);
    reduce_part_k<<<dim3((48 * SEQ + 255) / 256), blk, 0, stream>>>(partb, m1b, hid, SEQ, 1);
    gemm_skinny_nt<<<dim3(SEQ / 128, KSPLIT), blk, 0, stream>>>(hid, m2w, partb, SEQ, SEQ);
    reduce_part_k<<<dim3((48 * SEQ + 255) / 256), blk, 0, stream>>>(partb, m2b, tss, SEQ, 0);
    time_conv_k<<<dim3(BB * NHH), blk, 0, stream>>>(tss, td, t1w, t1b, t2w, t2b, tdt);
    // --- in-proj: combined xBC+dt GEMM stores bf16; z GEMM stores f32 ---
    cvt_bf16_k<<<dim3((MR * DMODEL / 4 + 255) / 256), blk, 0, stream>>>(u, u_bf, MR * DMODEL, MR * DMODEL);
    cvt_bf16_k<<<dim3((3456 * DMODEL / 4 + 255) / 256), blk, 0, stream>>>(W_in, Wi_bf, DPROJ * DMODEL, 3456 * DMODEL);
    gemm_mfma_nt<<<dim3(XSTR / 128, MR / 128), blk, 0, stream>>>(
        u_bf, Wi_bf + (size_t)DSSM * DMODEL, b_in + DSSM, r1b, XSTR, DMODEL, DMODEL / 32, DPROJ - DSSM, 1);
    conv_xbc_k<<<dim3((448 * (MR / CT) + 255) / 256), blk, 0, stream>>>(r1b, conv_w, conv_b, xcv_bf);
    gemm_mfma_nt<<<dim3(DSSM / 128, MR / 128), blk, 0, stream>>>(
        u_bf, Wi_bf, b_in, zbuf, DSSM, DMODEL, DMODEL / 32, DSSM, 0);
    dtsp_k<<<dim3((MR * NHH + 255) / 256), blk, 0, stream>>>(r1b, tdt, dt_bias, dtp);
    // --- SSD ---
    ssd_sraw_k<<<dim3(BB * NC), dim3(512), 0, stream>>>(xcv_bf, sraw);
    ssd_states_mfma_k<<<dim3(BB * NC * NHH), blk, 0, stream>>>(xcv_bf, dtp, A_log, stb, alb);
    ssd_scan_k<<<dim3(BB * NHH), blk, 0, stream>>>(stb, alb, pvb);
    ssd_y2_k<<<dim3(BB * NC * NHH), blk, 0, stream>>>(xcv_bf, dtp, A_log, sraw, pvb, Dpv, Yb);
    // --- epilogue ---
    rmsnorm_k<<<dim3(MR), blk, 0, stream>>>(Yb, zbuf, nw, Y_bf);
    cvt_bf16_k<<<dim3((DMODEL * DSSM / 4 + 255) / 256), blk, 0, stream>>>(W_out, Wo_bf, DMODEL * DSSM, DMODEL * DSSM);
    gemm_mfma_nt<<<dim3(DMODEL / 128, MR / 128), blk, 0, stream>>>(
        Y_bf, Wo_bf, b_out, out, DMODEL, DSSM, DSSM / 32, DMODEL, 0);
    timeout_k<<<dim3(BB * NHH), blk, 0, stream>>>(td, tdt, gw, gb, lnw, lnb, out2);
}

// Round 11
// 449.263 us; speedup vs baseline: 7.7697x; 1.0437x over previous
//
#include <hip/hip_runtime.h>
#include <math.h>

#define BB 2
#define SEQ 4096
#define DMODEL 768
#define DSTATE 128
#define NHH 24
#define HDIM 64
#define DSSM 1536
#define CDIM 1792
#define CHK 256
#define NC 16
#define DPROJ 3352
#define MR (BB*SEQ)
#define KSPLIT 32
#define XSTR 1920   // r1 row stride: xBC(1792) + dt(24) + pad(104)
#define CT 16       // conv timesteps per thread

typedef __attribute__((ext_vector_type(8))) short bf16x8;
typedef __attribute__((ext_vector_type(8))) unsigned short u16x8;
typedef __attribute__((ext_vector_type(4))) float f32x4;

__device__ __forceinline__ float siluf(float x) { return x / (1.0f + expf(-x)); }

__device__ __forceinline__ unsigned short f2bf(float f) {
    unsigned u = __float_as_uint(f);
    unsigned r = (u + 0x7fffu + ((u >> 16) & 1u)) >> 16;
    return (unsigned short)r;
}

__device__ __forceinline__ float bf2f(unsigned short u) {
    return __uint_as_float(((unsigned)u) << 16);
}

__device__ __forceinline__ float4 bf2f4(ushort4 v) {
    float4 o;
    o.x = bf2f(v.x); o.y = bf2f(v.y); o.z = bf2f(v.z); o.w = bf2f(v.w);
    return o;
}

__device__ __forceinline__ void gload_lds16(const void* g, void* l) {
    __builtin_amdgcn_global_load_lds((const __attribute__((address_space(1))) unsigned int*)g,
                                     (__attribute__((address_space(3))) unsigned int*)l, 16, 0, 0);
}

// ---------------- f32 -> bf16 conversion (vectorized), zero-pad beyond n_valid
__global__ __launch_bounds__(256) void cvt_bf16_k(const float* __restrict__ in,
    unsigned short* __restrict__ out, int n_valid, int n_total)
{
    int i = (blockIdx.x * 256 + threadIdx.x) * 4;
    if (i >= n_total) return;
    ushort4 o;
    if (i + 3 < n_valid) {
        float4 v = *(const float4*)&in[i];
        o.x = f2bf(v.x); o.y = f2bf(v.y); o.z = f2bf(v.z); o.w = f2bf(v.w);
    } else {
        o.x = (i + 0 < n_valid) ? f2bf(in[i + 0]) : 0;
        o.y = (i + 1 < n_valid) ? f2bf(in[i + 1]) : 0;
        o.z = (i + 2 < n_valid) ? f2bf(in[i + 2]) : 0;
        o.w = (i + 3 < n_valid) ? f2bf(in[i + 3]) : 0;
    }
    *(ushort4*)&out[i] = o;
}

// ---------------- bf16 MFMA GEMM: C(MxN) = A(MxK) @ B(NxK)^T + bias; f32 or bf16 store
__global__ __launch_bounds__(256) void gemm_mfma_nt(
    const unsigned short* __restrict__ A, const unsigned short* __restrict__ B,
    const float* __restrict__ bias, void* __restrict__ C, int N, int K, int KT,
    int nbias, int store_bf16)
{
    __shared__ unsigned short SA[2][128 * 32];
    __shared__ unsigned short SB[2][128 * 32];
    const int tid = threadIdx.x;
    const int w = tid >> 6, l = tid & 63;
    const int wr = w >> 1, wc = w & 1;
    const int lr = l & 15, lk = l >> 4;
    const int m0 = blockIdx.y * 128, n0 = blockIdx.x * 128;
    f32x4 acc[4][4] = {};
    const int i16 = w * 64 + l;
    const int row0 = i16 >> 2, sl = i16 & 3;
    const size_t ga0 = (size_t)(m0 + row0) * K + sl * 8;
    const size_t ga1 = (size_t)(m0 + row0 + 64) * K + sl * 8;
    const size_t gb0 = (size_t)(n0 + row0) * K + sl * 8;
    const size_t gb1 = (size_t)(n0 + row0 + 64) * K + sl * 8;
    const int lo0 = (w * 64) * 8;
    const int lo1 = (256 + w * 64) * 8;

#define STAGE(bb, kt) { int ko = (kt) * 32;                      \
      gload_lds16(A + ga0 + ko, &SA[bb][lo0]);                   \
      gload_lds16(A + ga1 + ko, &SA[bb][lo1]);                   \
      gload_lds16(B + gb0 + ko, &SB[bb][lo0]);                   \
      gload_lds16(B + gb1 + ko, &SB[bb][lo1]); }

    STAGE(0, 0);
    for (int kt = 0; kt < KT; ++kt) {
        int cur = kt & 1;
        asm volatile("s_waitcnt vmcnt(0)" ::: "memory");
        __syncthreads();
        if (kt + 1 < KT) STAGE(cur ^ 1, kt + 1);
        bf16x8 af[4], bg[4];
#pragma unroll
        for (int mi = 0; mi < 4; ++mi)
            af[mi] = *(const bf16x8*)&SA[cur][(wr * 64 + mi * 16 + lr) * 32 + lk * 8];
#pragma unroll
        for (int nj = 0; nj < 4; ++nj)
            bg[nj] = *(const bf16x8*)&SB[cur][(wc * 64 + nj * 16 + lr) * 32 + lk * 8];
#pragma unroll
        for (int mi = 0; mi < 4; ++mi)
#pragma unroll
            for (int nj = 0; nj < 4; ++nj)
                acc[mi][nj] = __builtin_amdgcn_mfma_f32_16x16x32_bf16(af[mi], bg[nj], acc[mi][nj], 0, 0, 0);
    }
#undef STAGE
#pragma unroll
    for (int nj = 0; nj < 4; ++nj) {
        int col = n0 + wc * 64 + nj * 16 + lr;
        float bz = (col < nbias) ? bias[col] : 0.f;
#pragma unroll
        for (int mi = 0; mi < 4; ++mi) {
#pragma unroll
            for (int r = 0; r < 4; ++r) {
                int m = m0 + wr * 64 + mi * 16 + lk * 4 + r;
                float v = acc[mi][nj][r] + bz;
                if (store_bf16)
                    ((unsigned short*)C)[(size_t)m * N + col] = f2bf(v);
                else
                    ((float*)C)[(size_t)m * N + col] = v;
            }
        }
    }
}

// ---------------- split-K skinny GEMM (M=48), conflict-free [row][k] LDS layout
__global__ __launch_bounds__(256) void gemm_skinny_nt(const float* __restrict__ A,
    const float* __restrict__ Bw, float* __restrict__ part, int N, int K)
{
    __shared__ float sA[48 * 33];
    __shared__ float sB[128 * 33];
    const int nb = blockIdx.x, kb = blockIdx.y;
    const int n0 = nb * 128;
    const int KS = K / KSPLIT;
    const int k0 = kb * KS;
    const int tid = threadIdx.x;
    const int tx = tid & 31, ty = tid >> 5;
    float acc[6][4] = {{0.f}};
    for (int kc = 0; kc < KS; kc += 32) {
        if (kc) __syncthreads();
        for (int i = tid; i < 384; i += 256) {
            int m = i >> 3, k4 = (i & 7) * 4;
            float4 v = *(const float4*)&A[(size_t)m * K + k0 + kc + k4];
            sA[m * 33 + k4 + 0] = v.x;
            sA[m * 33 + k4 + 1] = v.y;
            sA[m * 33 + k4 + 2] = v.z;
            sA[m * 33 + k4 + 3] = v.w;
        }
        for (int i = tid; i < 1024; i += 256) {
            int n = i >> 3, k4 = (i & 7) * 4;
            float4 v = *(const float4*)&Bw[(size_t)(n0 + n) * K + k0 + kc + k4];
            sB[n * 33 + k4 + 0] = v.x;
            sB[n * 33 + k4 + 1] = v.y;
            sB[n * 33 + k4 + 2] = v.z;
            sB[n * 33 + k4 + 3] = v.w;
        }
        __syncthreads();
#pragma unroll 8
        for (int kk = 0; kk < 32; ++kk) {
            float a[6], b[4];
#pragma unroll
            for (int r = 0; r < 6; ++r) a[r] = sA[(ty * 6 + r) * 33 + kk];
#pragma unroll
            for (int j = 0; j < 4; ++j) b[j] = sB[(tx + j * 32) * 33 + kk];
#pragma unroll
            for (int r = 0; r < 6; ++r)
#pragma unroll
                for (int j = 0; j < 4; ++j)
                    acc[r][j] = fmaf(a[r], b[j], acc[r][j]);
        }
    }
    float* pb = part + (size_t)kb * 48 * N;
#pragma unroll
    for (int r = 0; r < 6; ++r)
#pragma unroll
        for (int j = 0; j < 4; ++j)
            pb[(size_t)(ty * 6 + r) * N + n0 + tx + j * 32] = acc[r][j];
}

// ---------------- reduce split-K partials + bias (+ optional silu)
__global__ __launch_bounds__(256) void reduce_part_k(const float* __restrict__ part,
    const float* __restrict__ bias, float* __restrict__ out, int N, int act)
{
    int idx = blockIdx.x * 256 + threadIdx.x;
    if (idx >= 48 * N) return;
    int n = idx % N;
    float s = bias[n];
#pragma unroll
    for (int kb = 0; kb < KSPLIT; ++kb) s += part[(size_t)kb * 48 * N + idx];
    if (act) s = siluf(s);
    out[idx] = s;
}

// ---------------- sliding-window depthwise causal conv + silu, bf16 in/out
__global__ __launch_bounds__(256) void conv_xbc_k(const unsigned short* __restrict__ xbc,
    const float* __restrict__ cw, const float* __restrict__ cb,
    unsigned short* __restrict__ out)
{
    int idx = blockIdx.x * 256 + threadIdx.x;
    if (idx >= 448 * (MR / CT)) return;
    int slot = idx % 448;
    int g = idx / 448;
    int c4 = slot * 4;
    int b = g / (SEQ / CT);
    int t0 = (g % (SEQ / CT)) * CT;
    size_t rb = (size_t)b * SEQ;
    float4 cw0 = *(const float4*)&cw[(c4 + 0) * 4];
    float4 cw1 = *(const float4*)&cw[(c4 + 1) * 4];
    float4 cw2 = *(const float4*)&cw[(c4 + 2) * 4];
    float4 cw3 = *(const float4*)&cw[(c4 + 3) * 4];
    float4 cbv = *(const float4*)&cb[c4];
    float4 zero = {0.f, 0.f, 0.f, 0.f};
    float4 w0, w1, w2;
    w0 = (t0 - 3 >= 0) ? bf2f4(*(const ushort4*)&xbc[(rb + t0 - 3) * XSTR + c4]) : zero;
    w1 = (t0 - 2 >= 0) ? bf2f4(*(const ushort4*)&xbc[(rb + t0 - 2) * XSTR + c4]) : zero;
    w2 = (t0 - 1 >= 0) ? bf2f4(*(const ushort4*)&xbc[(rb + t0 - 1) * XSTR + c4]) : zero;
#pragma unroll
    for (int i = 0; i < CT; ++i) {
        int t = t0 + i;
        float4 w3 = bf2f4(*(const ushort4*)&xbc[(rb + t) * XSTR + c4]);
        float a0 = cbv.x + w0.x * cw0.x + w1.x * cw0.y + w2.x * cw0.z + w3.x * cw0.w;
        float a1 = cbv.y + w0.y * cw1.x + w1.y * cw1.y + w2.y * cw1.z + w3.y * cw1.w;
        float a2 = cbv.z + w0.z * cw2.x + w1.z * cw2.y + w2.z * cw2.z + w3.z * cw2.w;
        float a3 = cbv.w + w0.w * cw3.x + w1.w * cw3.y + w2.w * cw3.z + w3.w * cw3.w;
        ushort4 o;
        o.x = f2bf(siluf(a0)); o.y = f2bf(siluf(a1));
        o.z = f2bf(siluf(a2)); o.w = f2bf(siluf(a3));
        *(ushort4*)&out[(rb + t) * CDIM + c4] = o;
        w0 = w1; w1 = w2; w2 = w3;
    }
}

// ---------------- per-(b,h) row: tdt0 = ts*td; conv1+silu; conv2+silu
__global__ __launch_bounds__(256) void time_conv_k(const float* __restrict__ ts,
    const float* __restrict__ td, const float* __restrict__ w1, const float* __restrict__ b1,
    const float* __restrict__ w2, const float* __restrict__ b2, float* __restrict__ tdt)
{
    __shared__ float u0[SEQ];
    __shared__ float u1[SEQ];
    int row = blockIdx.x, h = row % NHH;
    const float* tsr = ts + (size_t)row * SEQ;
    const float* tdr = td + (size_t)row * SEQ;
    for (int i = threadIdx.x; i < SEQ; i += 256) u0[i] = tsr[i] * tdr[i];
    __syncthreads();
    float wa[4], wb[4];
#pragma unroll
    for (int k = 0; k < 4; ++k) { wa[k] = w1[h * 4 + k]; wb[k] = w2[h * 4 + k]; }
    float ba = b1[h], bbv = b2[h];
    for (int i = threadIdx.x; i < SEQ; i += 256) {
        float acc = ba;
#pragma unroll
        for (int k = 0; k < 4; ++k) { int tt = i + k - 3; if (tt >= 0) acc = fmaf(u0[tt], wa[k], acc); }
        u1[i] = siluf(acc);
    }
    __syncthreads();
    for (int i = threadIdx.x; i < SEQ; i += 256) {
        float acc = bbv;
#pragma unroll
        for (int k = 0; k < 4; ++k) { int tt = i + k - 3; if (tt >= 0) acc = fmaf(u1[tt], wb[k], acc); }
        tdt[(size_t)row * SEQ + i] = siluf(acc);
    }
}

// ---------------- dt_sp = softplus(dt * tdt^T + dt_bias); dt from bf16 r1 col 1792+h
__global__ __launch_bounds__(256) void dtsp_k(const unsigned short* __restrict__ r1,
    const float* __restrict__ tdt, const float* __restrict__ dt_bias, float* __restrict__ dtp)
{
    int idx = blockIdx.x * 256 + threadIdx.x;
    if (idx >= MR * NHH) return;
    int h = idx % NHH;
    int row = idx / NHH;
    int b = row / SEQ, s = row % SEQ;
    float x = bf2f(r1[(size_t)row * XSTR + CDIM + h]) * tdt[((size_t)(b * NHH + h)) * SEQ + s] + dt_bias[h];
    dtp[idx] = (x > 20.0f) ? x : log1pf(expf(x));
}

// ---------------- SSD chunk states via MFMA
__global__ __launch_bounds__(256) void ssd_states_mfma_k(const unsigned short* __restrict__ xc,
    const float* __restrict__ dtp, const float* __restrict__ A_log,
    float* __restrict__ st, float* __restrict__ al)
{
    __shared__ float s_acs[256];
    __shared__ float s_coef[256];
    __shared__ unsigned short SXT[64 * 136];
    __shared__ unsigned short SBT[128 * 136];
    int blk = blockIdx.x;
    int h = blk % NHH, c = (blk / NHH) % NC, b = blk / (NHH * NC);
    int tid = threadIdx.x;
    int w = tid >> 6, l = tid & 63;
    int lr = l & 15, lk = l >> 4;
    size_t rowbase = (size_t)b * SEQ + c * CHK;
    float Ah = -expf(A_log[h]);
    float dtv = dtp[(rowbase + tid) * NHH + h];
    s_acs[tid] = Ah * dtv;
    __syncthreads();
    for (int off = 1; off < 256; off <<= 1) {
        float t = (tid >= off) ? s_acs[tid - off] : 0.f;
        __syncthreads();
        s_acs[tid] += t;
        __syncthreads();
    }
    float alv = s_acs[255];
    s_coef[tid] = expf(alv - s_acs[tid]) * dtv;
    if (tid == 255) al[blk] = alv;
    __syncthreads();
    f32x4 acc[4][2] = {};
    for (int z0 = 0; z0 < CHK; z0 += 128) {
        if (z0) __syncthreads();
        for (int i = tid; i < 128 * 8; i += 256) {
            int zz = i >> 3, p8 = (i & 7) * 8;
            float sc = s_coef[z0 + zz];
            u16x8 v = *(const u16x8*)&xc[(rowbase + z0 + zz) * CDIM + h * HDIM + p8];
#pragma unroll
            for (int e = 0; e < 8; ++e)
                SXT[(p8 + e) * 136 + zz] = f2bf(bf2f(v[e]) * sc);
        }
        for (int i = tid; i < 128 * 16; i += 256) {
            int zz = i >> 4, n8 = (i & 15) * 8;
            u16x8 v = *(const u16x8*)&xc[(rowbase + z0 + zz) * CDIM + DSSM + n8];
#pragma unroll
            for (int e = 0; e < 8; ++e)
                SBT[(n8 + e) * 136 + zz] = v[e];
        }
        __syncthreads();
#pragma unroll
        for (int kt = 0; kt < 4; ++kt) {
            bf16x8 av[4], bv[2];
#pragma unroll
            for (int mi = 0; mi < 4; ++mi)
                av[mi] = *(const bf16x8*)&SXT[(mi * 16 + lr) * 136 + kt * 32 + lk * 8];
#pragma unroll
            for (int nj = 0; nj < 2; ++nj)
                bv[nj] = *(const bf16x8*)&SBT[(w * 32 + nj * 16 + lr) * 136 + kt * 32 + lk * 8];
#pragma unroll
            for (int mi = 0; mi < 4; ++mi)
#pragma unroll
                for (int nj = 0; nj < 2; ++nj)
                    acc[mi][nj] = __builtin_amdgcn_mfma_f32_16x16x32_bf16(av[mi], bv[nj], acc[mi][nj], 0, 0, 0);
        }
    }
    size_t base = (size_t)blk * (HDIM * DSTATE);
#pragma unroll
    for (int mi = 0; mi < 4; ++mi)
#pragma unroll
        for (int r = 0; r < 4; ++r) {
            int p = mi * 16 + lk * 4 + r;
#pragma unroll
            for (int nj = 0; nj < 2; ++nj)
                st[base + p * DSTATE + w * 32 + nj * 16 + lr] = acc[mi][nj][r];
        }
}

// ---------------- inter-chunk scan: carry in f32, emit prev-states as bf16
__global__ __launch_bounds__(256) void ssd_scan_k(const float* __restrict__ st,
    const float* __restrict__ al, unsigned short* __restrict__ pv16)
{
    int b = blockIdx.x / NHH, h = blockIdx.x % NHH;
    int tid = threadIdx.x;
    float carry[32];
#pragma unroll
    for (int j = 0; j < 32; ++j) carry[j] = 0.f;
    for (int c = 0; c < NC; ++c) {
        int bch = (b * NC + c) * NHH + h;
        size_t base = (size_t)bch * (HDIM * DSTATE);
        float dcy = expf(al[bch]);
#pragma unroll
        for (int j = 0; j < 32; ++j) {
            pv16[base + tid + j * 256] = f2bf(carry[j]);
            carry[j] = fmaf(dcy, carry[j], st[base + tid + j * 256]);
        }
    }
}

// ---------------- S_raw = C.B^T per (b,c), lower-triangular 64x64 tiles, bf16
__global__ __launch_bounds__(512) void ssd_sraw_k(const unsigned short* __restrict__ xc,
    unsigned short* __restrict__ sraw)
{
    __shared__ unsigned short SC[256 * 136];
    __shared__ unsigned short SB[256 * 136];
    int bc = blockIdx.x;
    int b = bc / NC, c = bc % NC;
    size_t rowbase = (size_t)b * SEQ + c * CHK;
    int tid = threadIdx.x;
    int w = tid >> 6, l = tid & 63;
    int lr = l & 15, lk = l >> 4;
    for (int i = tid; i < 256 * 32; i += 512) {
        int r = i >> 5, c4 = (i & 31) * 4;
        *(ushort4*)&SC[r * 136 + c4] = *(const ushort4*)&xc[(rowbase + r) * CDIM + DSSM + DSTATE + c4];
        *(ushort4*)&SB[r * 136 + c4] = *(const ushort4*)&xc[(rowbase + r) * CDIM + DSSM + c4];
    }
    __syncthreads();
    unsigned short* tb = sraw + (size_t)bc * 16 * 4096;
    int t = 0;
#pragma unroll
    for (int st = 0; st < 4; ++st) {
#pragma unroll
        for (int zt = 0; zt <= st; ++zt, ++t) {
            if ((t & 7) != w) continue;
            f32x4 d[4][4] = {};
#pragma unroll
            for (int kt = 0; kt < 4; ++kt) {
                bf16x8 av[4], bv[4];
#pragma unroll
                for (int mi = 0; mi < 4; ++mi)
                    av[mi] = *(const bf16x8*)&SC[(st * 64 + mi * 16 + lr) * 136 + kt * 32 + lk * 8];
#pragma unroll
                for (int nj = 0; nj < 4; ++nj)
                    bv[nj] = *(const bf16x8*)&SB[(zt * 64 + nj * 16 + lr) * 136 + kt * 32 + lk * 8];
#pragma unroll
                for (int mi = 0; mi < 4; ++mi)
#pragma unroll
                    for (int nj = 0; nj < 4; ++nj)
                        d[mi][nj] = __builtin_amdgcn_mfma_f32_16x16x32_bf16(av[mi], bv[nj], d[mi][nj], 0, 0, 0);
            }
            unsigned short* tp = tb + (size_t)(st * 4 + zt) * 4096;
#pragma unroll
            for (int mi = 0; mi < 4; ++mi)
#pragma unroll
                for (int nj = 0; nj < 4; ++nj)
#pragma unroll
                    for (int r = 0; r < 4; ++r)
                        tp[(mi * 16 + lk * 4 + r) * 64 + nj * 16 + lr] = f2bf(d[mi][nj][r]);
        }
    }
}

// ---------------- Y from precomputed S_raw: per (b,c,h), 4 waves = 4 s-tiles.
// prev read directly from global bf16 (no LDS tile) -> 37KB LDS, 4 blocks/CU
__global__ __launch_bounds__(256) void ssd_y2_k(const unsigned short* __restrict__ xc,
    const float* __restrict__ dtp, const float* __restrict__ A_log,
    const unsigned short* __restrict__ sraw, const unsigned short* __restrict__ pv16,
    const float* __restrict__ Dp, float* __restrict__ Y)
{
    __shared__ float s_acs[256];
    __shared__ float s_dt[256];
    __shared__ float s_edt[256];
    __shared__ float s_az0[4];
    __shared__ unsigned short SXT[64 * 264];
    int blk = blockIdx.x;
    int h = blk % NHH;
    int c = (blk / NHH) % NC;
    int b = blk / (NHH * NC);
    int tid = threadIdx.x;
    int w = tid >> 6, l = tid & 63;
    int lr = l & 15, lk = l >> 4;
    size_t rowbase = (size_t)b * SEQ + c * CHK;
    float Ah = -expf(A_log[h]);
    float dtv = dtp[(rowbase + tid) * NHH + h];
    s_dt[tid] = dtv;
    s_acs[tid] = Ah * dtv;
    __syncthreads();
    for (int off = 1; off < 256; off <<= 1) {
        float t = (tid >= off) ? s_acs[tid - off] : 0.f;
        __syncthreads();
        s_acs[tid] += t;
        __syncthreads();
    }
    if (tid < 4) s_az0[tid] = s_acs[tid * 64];
    __syncthreads();
    {
        float e = s_az0[tid >> 6] - s_acs[tid];
        if (e > 60.f) e = 60.f;
        s_edt[tid] = expf(e) * s_dt[tid];
    }
    __syncthreads();
    for (int i = tid; i < 256 * 8; i += 256) {
        int z = i >> 3, p8 = (i & 7) * 8;
        float sc = s_edt[z];
        u16x8 v = *(const u16x8*)&xc[(rowbase + z) * CDIM + h * HDIM + p8];
#pragma unroll
        for (int e = 0; e < 8; ++e)
            SXT[(p8 + e) * 264 + z] = f2bf(bf2f(v[e]) * sc);
    }
    __syncthreads();

    const unsigned short* tbase = sraw + (size_t)(b * NC + c) * 16 * 4096;
    const unsigned short* pvbase = pv16 + (size_t)blk * (HDIM * DSTATE);
    f32x4 acc[4][4] = {};
    for (int zt = 0; zt <= w; ++zt) {
        const unsigned short* tp = tbase + (size_t)(w * 4 + zt) * 4096;
        f32x4 tmp[4][4] = {};
#pragma unroll
        for (int kt = 0; kt < 2; ++kt) {
            bf16x8 av[4], bv[4];
#pragma unroll
            for (int mi = 0; mi < 4; ++mi) {
                av[mi] = *(const bf16x8*)&tp[(mi * 16 + lr) * 64 + kt * 32 + lk * 8];
                if (zt == w) {
                    int zb = kt * 32 + lk * 8;
                    int sl = mi * 16 + lr;
#pragma unroll
                    for (int e = 0; e < 8; ++e)
                        if (zb + e > sl) av[mi][e] = 0;
                }
            }
#pragma unroll
            for (int nj = 0; nj < 4; ++nj)
                bv[nj] = *(const bf16x8*)&SXT[(nj * 16 + lr) * 264 + zt * 64 + kt * 32 + lk * 8];
#pragma unroll
            for (int mi = 0; mi < 4; ++mi)
#pragma unroll
                for (int nj = 0; nj < 4; ++nj)
                    tmp[mi][nj] = __builtin_amdgcn_mfma_f32_16x16x32_bf16(av[mi], bv[nj], tmp[mi][nj], 0, 0, 0);
        }
        float az = s_az0[zt];
#pragma unroll
        for (int mi = 0; mi < 4; ++mi) {
#pragma unroll
            for (int r = 0; r < 4; ++r) {
                float es = expf(s_acs[w * 64 + mi * 16 + lk * 4 + r] - az);
#pragma unroll
                for (int nj = 0; nj < 4; ++nj)
                    acc[mi][nj][r] += es * tmp[mi][nj][r];
            }
        }
    }
    // off-chunk: C.prev^T * exp(acs[s]) — both operands direct bf16 global loads
    {
        f32x4 tmp[4][4] = {};
#pragma unroll
        for (int kt = 0; kt < 4; ++kt) {
            bf16x8 av[4], bv[4];
#pragma unroll
            for (int mi = 0; mi < 4; ++mi)
                av[mi] = *(const bf16x8*)&xc[(rowbase + w * 64 + mi * 16 + lr) * CDIM + DSSM + DSTATE + kt * 32 + lk * 8];
#pragma unroll
            for (int nj = 0; nj < 4; ++nj)
                bv[nj] = *(const bf16x8*)&pvbase[(nj * 16 + lr) * DSTATE + kt * 32 + lk * 8];
#pragma unroll
            for (int mi = 0; mi < 4; ++mi)
#pragma unroll
                for (int nj = 0; nj < 4; ++nj)
                    tmp[mi][nj] = __builtin_amdgcn_mfma_f32_16x16x32_bf16(av[mi], bv[nj], tmp[mi][nj], 0, 0, 0);
        }
#pragma unroll
        for (int mi = 0; mi < 4; ++mi) {
#pragma unroll
            for (int r = 0; r < 4; ++r) {
                float es = expf(s_acs[w * 64 + mi * 16 + lk * 4 + r]);
#pragma unroll
                for (int nj = 0; nj < 4; ++nj)
                    acc[mi][nj][r] += es * tmp[mi][nj][r];
            }
        }
    }
    float dph = Dp[h];
#pragma unroll
    for (int mi = 0; mi < 4; ++mi) {
#pragma unroll
        for (int r = 0; r < 4; ++r) {
            int s = w * 64 + mi * 16 + lk * 4 + r;
#pragma unroll
            for (int nj = 0; nj < 4; ++nj) {
                int p = nj * 16 + lr;
                float xv = bf2f(xc[(rowbase + s) * CDIM + h * HDIM + p]);
                Y[(rowbase + s) * DSSM + h * HDIM + p] = acc[mi][nj][r] + dph * xv;
            }
        }
    }
}

// ---------------- gated RMS norm (y f32, z bf16) -> bf16 output
__global__ __launch_bounds__(256) void rmsnorm_k(const float* __restrict__ Y,
    const unsigned short* __restrict__ zbf, const float* __restrict__ nw,
    unsigned short* __restrict__ Ybf)
{
    __shared__ float red[8];
    int row = blockIdx.x;
    const float* y = Y + (size_t)row * DSSM;
    const unsigned short* z = zbf + (size_t)row * DSSM;
    float v[6];
    float ss = 0.f;
#pragma unroll
    for (int k = 0; k < 6; ++k) {
        int i = threadIdx.x + k * 256;
        float g = y[i] * siluf(bf2f(z[i]));
        v[k] = g;
        ss = fmaf(g, g, ss);
    }
#pragma unroll
    for (int o = 32; o > 0; o >>= 1) ss += __shfl_down(ss, o, 64);
    int wv = threadIdx.x >> 6, ln = threadIdx.x & 63;
    if (ln == 0) red[wv] = ss;
    __syncthreads();
    float tot = red[0] + red[1] + red[2] + red[3];
    float sc = rsqrtf(tot / (float)DSSM + 1e-12f);
    unsigned short* yo = Ybf + (size_t)row * DSSM;
#pragma unroll
    for (int k = 0; k < 6; ++k) {
        int i = threadIdx.x + k * 256;
        yo[i] = f2bf(v[k] * sc * nw[i]);
    }
}

// ---------------- time_out: gate + mix + LayerNorm over SEQ
__global__ __launch_bounds__(256) void timeout_k(const float* __restrict__ td,
    const float* __restrict__ tdt, const float* __restrict__ gw, const float* __restrict__ gb,
    const float* __restrict__ lnw, const float* __restrict__ lnb, float* __restrict__ out2)
{
    __shared__ float tm[SEQ];
    __shared__ float red[8];
    int row = blockIdx.x;
    const float* tdr = td + (size_t)row * SEQ;
    const float* tdtr = tdt + (size_t)row * SEQ;
    int wv = threadIdx.x >> 6, ln = threadIdx.x & 63;
    float part = 0.f;
    for (int i = threadIdx.x; i < SEQ; i += 256) part = fmaf(tdr[i], gw[i], part);
#pragma unroll
    for (int o = 32; o > 0; o >>= 1) part += __shfl_down(part, o, 64);
    if (ln == 0) red[wv] = part;
    __syncthreads();
    float dot = red[0] + red[1] + red[2] + red[3];
    float tg = 1.f / (1.f + expf(-(dot + gb[0])));
    __syncthreads();
    float sum = 0.f;
    for (int i = threadIdx.x; i < SEQ; i += 256) {
        float x = tg * tdr[i] + (1.f - tg) * tdtr[i];
        tm[i] = x;
        sum += x;
    }
#pragma unroll
    for (int o = 32; o > 0; o >>= 1) sum += __shfl_down(sum, o, 64);
    if (ln == 0) red[wv] = sum;
    __syncthreads();
    float mu = (red[0] + red[1] + red[2] + red[3]) / (float)SEQ;
    __syncthreads();
    float s2 = 0.f;
    for (int i = threadIdx.x; i < SEQ; i += 256) { float d = tm[i] - mu; s2 = fmaf(d, d, s2); }
#pragma unroll
    for (int o = 32; o > 0; o >>= 1) s2 += __shfl_down(s2, o, 64);
    if (ln == 0) red[wv] = s2;
    __syncthreads();
    float var = (red[0] + red[1] + red[2] + red[3]) / (float)SEQ;
    float inv = rsqrtf(var + 1e-12f);
    for (int i = threadIdx.x; i < SEQ; i += 256)
        out2[(size_t)row * SEQ + i] = (tm[i] - mu) * inv * lnw[i] + lnb[i];
}

extern "C" void kernel_launch(void* const* d_in, const int* in_sizes, int n_in,
                              void* d_out, int out_size, void* d_ws, size_t ws_size,
                              hipStream_t stream)
{
    const float* u      = (const float*)d_in[0];
    const float* td     = (const float*)d_in[1];
    const float* W_in   = (const float*)d_in[2];
    const float* b_in   = (const float*)d_in[3];
    const float* conv_w = (const float*)d_in[4];
    const float* conv_b = (const float*)d_in[5];
    const float* t1w    = (const float*)d_in[6];
    const float* t1b    = (const float*)d_in[7];
    const float* t2w    = (const float*)d_in[8];
    const float* t2b    = (const float*)d_in[9];
    const float* m1w    = (const float*)d_in[10];
    const float* m1b    = (const float*)d_in[11];
    const float* m2w    = (const float*)d_in[12];
    const float* m2b    = (const float*)d_in[13];
    const float* gw     = (const float*)d_in[14];
    const float* gb     = (const float*)d_in[15];
    const float* lnw    = (const float*)d_in[16];
    const float* lnb    = (const float*)d_in[17];
    const float* A_log  = (const float*)d_in[18];
    const float* dt_bias= (const float*)d_in[19];
    const float* Dpv    = (const float*)d_in[20];
    const float* nw     = (const float*)d_in[21];
    const float* W_out  = (const float*)d_in[22];
    const float* b_out  = (const float*)d_in[23];
    float* out  = (float*)d_out;
    float* out2 = out + (size_t)MR * DMODEL;

    float* ws = (float*)d_ws;
    size_t o = 0;
    float* zbuf  = ws + o; o += (size_t)MR * DSSM;    // bf16 z (half) + Wo_bf at +6291456
    float* r1    = ws + o; o += (size_t)MR * DSSM;    // region: bf16 r1 (XSTR sh) / stb / Yb
    float* xcv   = ws + o; o += (size_t)MR * CDIM / 2;
    float* hid   = ws + o; o += (size_t)BB * NHH * SEQ;
    float* tss   = ws + o; o += (size_t)BB * NHH * SEQ;
    float* tdt   = ws + o; o += (size_t)BB * NHH * SEQ;
    float* dtp   = ws + o; o += (size_t)MR * NHH;
    float* pvb   = ws + o; o += (size_t)BB * NC * NHH * HDIM * DSTATE;  // early: u_bf/Wi_bf; late: pv16
    float* alb   = ws + o; o += (size_t)BB * NC * NHH;
    unsigned short* sraw = (unsigned short*)(ws + o); o += (size_t)BB * NC * 16 * 4096 / 2;
    unsigned short* r1b = (unsigned short*)r1;
    float* stb = r1;
    float* Yb  = r1;
    float* partb = xcv;
    unsigned short* xcv_bf = (unsigned short*)xcv;
    unsigned short* u_bf  = (unsigned short*)pvb;
    unsigned short* Wi_bf = (unsigned short*)(pvb + 3145728);
    unsigned short* pv16  = (unsigned short*)pvb;     // after u_bf/Wi_bf dead (post in-proj GEMMs)
    unsigned short* zbf   = (unsigned short*)zbuf;
    unsigned short* Y_bf  = (unsigned short*)xcv;
    unsigned short* Wo_bf = (unsigned short*)(zbuf + 6291456);

    dim3 blk(256);
    // --- time MLP first (partials use xcv region, dead until conv) ---
    gemm_skinny_nt<<<dim3(SEQ / 128, KSPLIT), blk, 0, stream>>>(td, m1w, partb, SEQ, SEQ);
    reduce_part_k<<<dim3((48 * SEQ + 255) / 256), blk, 0, stream>>>(partb, m1b, hid, SEQ, 1);
    gemm_skinny_nt<<<dim3(SEQ / 128, KSPLIT), blk, 0, stream>>>(hid, m2w, partb, SEQ, SEQ);
    reduce_part_k<<<dim3((48 * SEQ + 255) / 256), blk, 0, stream>>>(partb, m2b, tss, SEQ, 0);
    time_conv_k<<<dim3(BB * NHH), blk, 0, stream>>>(tss, td, t1w, t1b, t2w, t2b, tdt);
    // --- in-proj: combined xBC+dt GEMM stores bf16; z GEMM stores bf16 ---
    cvt_bf16_k<<<dim3((MR * DMODEL / 4 + 255) / 256), blk, 0, stream>>>(u, u_bf, MR * DMODEL, MR * DMODEL);
    cvt_bf16_k<<<dim3((3456 * DMODEL / 4 + 255) / 256), blk, 0, stream>>>(W_in, Wi_bf, DPROJ * DMODEL, 3456 * DMODEL);
    gemm_mfma_nt<<<dim3(XSTR / 128, MR / 128), blk, 0, stream>>>(
        u_bf, Wi_bf + (size_t)DSSM * DMODEL, b_in + DSSM, r1b, XSTR, DMODEL, DMODEL / 32, DPROJ - DSSM, 1);
    conv_xbc_k<<<dim3((448 * (MR / CT) + 255) / 256), blk, 0, stream>>>(r1b, conv_w, conv_b, xcv_bf);
    gemm_mfma_nt<<<dim3(DSSM / 128, MR / 128), blk, 0, stream>>>(
        u_bf, Wi_bf, b_in, zbf, DSSM, DMODEL, DMODEL / 32, DSSM, 1);
    dtsp_k<<<dim3((MR * NHH + 255) / 256), blk, 0, stream>>>(r1b, tdt, dt_bias, dtp);
    // --- SSD ---
    ssd_sraw_k<<<dim3(BB * NC), dim3(512), 0, stream>>>(xcv_bf, sraw);
    ssd_states_mfma_k<<<dim3(BB * NC * NHH), blk, 0, stream>>>(xcv_bf, dtp, A_log, stb, alb);
    ssd_scan_k<<<dim3(BB * NHH), blk, 0, stream>>>(stb, alb, pv16);
    ssd_y2_k<<<dim3(BB * NC * NHH), blk, 0, stream>>>(xcv_bf, dtp, A_log, sraw, pv16, Dpv, Yb);
    // --- epilogue ---
    rmsnorm_k<<<dim3(MR), blk, 0, stream>>>(Yb, zbf, nw, Y_bf);
    cvt_bf16_k<<<dim3((DMODEL * DSSM / 4 + 255) / 256), blk, 0, stream>>>(W_out, Wo_bf, DMODEL * DSSM, DMODEL * DSSM);
    gemm_mfma_nt<<<dim3(DMODEL / 128, MR / 128), blk, 0, stream>>>(
        Y_bf, Wo_bf, b_out, out, DMODEL, DSSM, DSSM / 32, DMODEL, 0);
    timeout_k<<<dim3(BB * NHH), blk, 0, stream>>>(td, tdt, gw, gb, lnw, lnb, out2);
}

// Round 12
// 447.204 us; speedup vs baseline: 7.8055x; 1.0046x over previous
//
#include <hip/hip_runtime.h>
#include <math.h>

#define BB 2
#define SEQ 4096
#define DMODEL 768
#define DSTATE 128
#define NHH 24
#define HDIM 64
#define DSSM 1536
#define CDIM 1792
#define CHK 256
#define NC 16
#define DPROJ 3352
#define MR (BB*SEQ)
#define KSPLIT 32
#define XSTR 1920   // r1 row stride: xBC(1792) + dt(24) + pad(104)
#define CT 16       // conv timesteps per thread

typedef __attribute__((ext_vector_type(8))) short bf16x8;
typedef __attribute__((ext_vector_type(8))) unsigned short u16x8;
typedef __attribute__((ext_vector_type(4))) float f32x4;

__device__ __forceinline__ float siluf(float x) { return x / (1.0f + expf(-x)); }

__device__ __forceinline__ unsigned short f2bf(float f) {
    unsigned u = __float_as_uint(f);
    unsigned r = (u + 0x7fffu + ((u >> 16) & 1u)) >> 16;
    return (unsigned short)r;
}

__device__ __forceinline__ float bf2f(unsigned short u) {
    return __uint_as_float(((unsigned)u) << 16);
}

__device__ __forceinline__ float4 bf2f4(ushort4 v) {
    float4 o;
    o.x = bf2f(v.x); o.y = bf2f(v.y); o.z = bf2f(v.z); o.w = bf2f(v.w);
    return o;
}

__device__ __forceinline__ void gload_lds16(const void* g, void* l) {
    __builtin_amdgcn_global_load_lds((const __attribute__((address_space(1))) unsigned int*)g,
                                     (__attribute__((address_space(3))) unsigned int*)l, 16, 0, 0);
}

// ---------------- f32 -> bf16 conversion (vectorized), zero-pad beyond n_valid
__global__ __launch_bounds__(256) void cvt_bf16_k(const float* __restrict__ in,
    unsigned short* __restrict__ out, int n_valid, int n_total)
{
    int i = (blockIdx.x * 256 + threadIdx.x) * 4;
    if (i >= n_total) return;
    ushort4 o;
    if (i + 3 < n_valid) {
        float4 v = *(const float4*)&in[i];
        o.x = f2bf(v.x); o.y = f2bf(v.y); o.z = f2bf(v.z); o.w = f2bf(v.w);
    } else {
        o.x = (i + 0 < n_valid) ? f2bf(in[i + 0]) : 0;
        o.y = (i + 1 < n_valid) ? f2bf(in[i + 1]) : 0;
        o.z = (i + 2 < n_valid) ? f2bf(in[i + 2]) : 0;
        o.w = (i + 3 < n_valid) ? f2bf(in[i + 3]) : 0;
    }
    *(ushort4*)&out[i] = o;
}

// ---------------- bf16 MFMA GEMM: C(MxN) = A(MxK) @ B(NxK)^T + bias; f32 or bf16 store
__global__ __launch_bounds__(256) void gemm_mfma_nt(
    const unsigned short* __restrict__ A, const unsigned short* __restrict__ B,
    const float* __restrict__ bias, void* __restrict__ C, int N, int K, int KT,
    int nbias, int store_bf16)
{
    __shared__ unsigned short SA[2][128 * 32];
    __shared__ unsigned short SB[2][128 * 32];
    const int tid = threadIdx.x;
    const int w = tid >> 6, l = tid & 63;
    const int wr = w >> 1, wc = w & 1;
    const int lr = l & 15, lk = l >> 4;
    const int m0 = blockIdx.y * 128, n0 = blockIdx.x * 128;
    f32x4 acc[4][4] = {};
    const int i16 = w * 64 + l;
    const int row0 = i16 >> 2, sl = i16 & 3;
    const size_t ga0 = (size_t)(m0 + row0) * K + sl * 8;
    const size_t ga1 = (size_t)(m0 + row0 + 64) * K + sl * 8;
    const size_t gb0 = (size_t)(n0 + row0) * K + sl * 8;
    const size_t gb1 = (size_t)(n0 + row0 + 64) * K + sl * 8;
    const int lo0 = (w * 64) * 8;
    const int lo1 = (256 + w * 64) * 8;

#define STAGE(bb, kt) { int ko = (kt) * 32;                      \
      gload_lds16(A + ga0 + ko, &SA[bb][lo0]);                   \
      gload_lds16(A + ga1 + ko, &SA[bb][lo1]);                   \
      gload_lds16(B + gb0 + ko, &SB[bb][lo0]);                   \
      gload_lds16(B + gb1 + ko, &SB[bb][lo1]); }

    STAGE(0, 0);
    for (int kt = 0; kt < KT; ++kt) {
        int cur = kt & 1;
        asm volatile("s_waitcnt vmcnt(0)" ::: "memory");
        __syncthreads();
        if (kt + 1 < KT) STAGE(cur ^ 1, kt + 1);
        bf16x8 af[4], bg[4];
#pragma unroll
        for (int mi = 0; mi < 4; ++mi)
            af[mi] = *(const bf16x8*)&SA[cur][(wr * 64 + mi * 16 + lr) * 32 + lk * 8];
#pragma unroll
        for (int nj = 0; nj < 4; ++nj)
            bg[nj] = *(const bf16x8*)&SB[cur][(wc * 64 + nj * 16 + lr) * 32 + lk * 8];
#pragma unroll
        for (int mi = 0; mi < 4; ++mi)
#pragma unroll
            for (int nj = 0; nj < 4; ++nj)
                acc[mi][nj] = __builtin_amdgcn_mfma_f32_16x16x32_bf16(af[mi], bg[nj], acc[mi][nj], 0, 0, 0);
    }
#undef STAGE
#pragma unroll
    for (int nj = 0; nj < 4; ++nj) {
        int col = n0 + wc * 64 + nj * 16 + lr;
        float bz = (col < nbias) ? bias[col] : 0.f;
#pragma unroll
        for (int mi = 0; mi < 4; ++mi) {
#pragma unroll
            for (int r = 0; r < 4; ++r) {
                int m = m0 + wr * 64 + mi * 16 + lk * 4 + r;
                float v = acc[mi][nj][r] + bz;
                if (store_bf16)
                    ((unsigned short*)C)[(size_t)m * N + col] = f2bf(v);
                else
                    ((float*)C)[(size_t)m * N + col] = v;
            }
        }
    }
}

// ---------------- split-K skinny GEMM (M=48), conflict-free [row][k] LDS layout
__global__ __launch_bounds__(256) void gemm_skinny_nt(const float* __restrict__ A,
    const float* __restrict__ Bw, float* __restrict__ part, int N, int K)
{
    __shared__ float sA[48 * 33];
    __shared__ float sB[128 * 33];
    const int nb = blockIdx.x, kb = blockIdx.y;
    const int n0 = nb * 128;
    const int KS = K / KSPLIT;
    const int k0 = kb * KS;
    const int tid = threadIdx.x;
    const int tx = tid & 31, ty = tid >> 5;
    float acc[6][4] = {{0.f}};
    for (int kc = 0; kc < KS; kc += 32) {
        if (kc) __syncthreads();
        for (int i = tid; i < 384; i += 256) {
            int m = i >> 3, k4 = (i & 7) * 4;
            float4 v = *(const float4*)&A[(size_t)m * K + k0 + kc + k4];
            sA[m * 33 + k4 + 0] = v.x;
            sA[m * 33 + k4 + 1] = v.y;
            sA[m * 33 + k4 + 2] = v.z;
            sA[m * 33 + k4 + 3] = v.w;
        }
        for (int i = tid; i < 1024; i += 256) {
            int n = i >> 3, k4 = (i & 7) * 4;
            float4 v = *(const float4*)&Bw[(size_t)(n0 + n) * K + k0 + kc + k4];
            sB[n * 33 + k4 + 0] = v.x;
            sB[n * 33 + k4 + 1] = v.y;
            sB[n * 33 + k4 + 2] = v.z;
            sB[n * 33 + k4 + 3] = v.w;
        }
        __syncthreads();
#pragma unroll 8
        for (int kk = 0; kk < 32; ++kk) {
            float a[6], b[4];
#pragma unroll
            for (int r = 0; r < 6; ++r) a[r] = sA[(ty * 6 + r) * 33 + kk];
#pragma unroll
            for (int j = 0; j < 4; ++j) b[j] = sB[(tx + j * 32) * 33 + kk];
#pragma unroll
            for (int r = 0; r < 6; ++r)
#pragma unroll
                for (int j = 0; j < 4; ++j)
                    acc[r][j] = fmaf(a[r], b[j], acc[r][j]);
        }
    }
    float* pb = part + (size_t)kb * 48 * N;
#pragma unroll
    for (int r = 0; r < 6; ++r)
#pragma unroll
        for (int j = 0; j < 4; ++j)
            pb[(size_t)(ty * 6 + r) * N + n0 + tx + j * 32] = acc[r][j];
}

// ---------------- reduce split-K partials + bias (+ optional silu)
__global__ __launch_bounds__(256) void reduce_part_k(const float* __restrict__ part,
    const float* __restrict__ bias, float* __restrict__ out, int N, int act)
{
    int idx = blockIdx.x * 256 + threadIdx.x;
    if (idx >= 48 * N) return;
    int n = idx % N;
    float s = bias[n];
#pragma unroll
    for (int kb = 0; kb < KSPLIT; ++kb) s += part[(size_t)kb * 48 * N + idx];
    if (act) s = siluf(s);
    out[idx] = s;
}

// ---------------- sliding-window depthwise causal conv + silu, bf16 in/out
__global__ __launch_bounds__(256) void conv_xbc_k(const unsigned short* __restrict__ xbc,
    const float* __restrict__ cw, const float* __restrict__ cb,
    unsigned short* __restrict__ out)
{
    int idx = blockIdx.x * 256 + threadIdx.x;
    if (idx >= 448 * (MR / CT)) return;
    int slot = idx % 448;
    int g = idx / 448;
    int c4 = slot * 4;
    int b = g / (SEQ / CT);
    int t0 = (g % (SEQ / CT)) * CT;
    size_t rb = (size_t)b * SEQ;
    float4 cw0 = *(const float4*)&cw[(c4 + 0) * 4];
    float4 cw1 = *(const float4*)&cw[(c4 + 1) * 4];
    float4 cw2 = *(const float4*)&cw[(c4 + 2) * 4];
    float4 cw3 = *(const float4*)&cw[(c4 + 3) * 4];
    float4 cbv = *(const float4*)&cb[c4];
    float4 zero = {0.f, 0.f, 0.f, 0.f};
    float4 w0, w1, w2;
    w0 = (t0 - 3 >= 0) ? bf2f4(*(const ushort4*)&xbc[(rb + t0 - 3) * XSTR + c4]) : zero;
    w1 = (t0 - 2 >= 0) ? bf2f4(*(const ushort4*)&xbc[(rb + t0 - 2) * XSTR + c4]) : zero;
    w2 = (t0 - 1 >= 0) ? bf2f4(*(const ushort4*)&xbc[(rb + t0 - 1) * XSTR + c4]) : zero;
#pragma unroll
    for (int i = 0; i < CT; ++i) {
        int t = t0 + i;
        float4 w3 = bf2f4(*(const ushort4*)&xbc[(rb + t) * XSTR + c4]);
        float a0 = cbv.x + w0.x * cw0.x + w1.x * cw0.y + w2.x * cw0.z + w3.x * cw0.w;
        float a1 = cbv.y + w0.y * cw1.x + w1.y * cw1.y + w2.y * cw1.z + w3.y * cw1.w;
        float a2 = cbv.z + w0.z * cw2.x + w1.z * cw2.y + w2.z * cw2.z + w3.z * cw2.w;
        float a3 = cbv.w + w0.w * cw3.x + w1.w * cw3.y + w2.w * cw3.z + w3.w * cw3.w;
        ushort4 o;
        o.x = f2bf(siluf(a0)); o.y = f2bf(siluf(a1));
        o.z = f2bf(siluf(a2)); o.w = f2bf(siluf(a3));
        *(ushort4*)&out[(rb + t) * CDIM + c4] = o;
        w0 = w1; w1 = w2; w2 = w3;
    }
}

// ---------------- per-(b,h) row: tdt0 = ts*td; conv1+silu; conv2+silu
__global__ __launch_bounds__(256) void time_conv_k(const float* __restrict__ ts,
    const float* __restrict__ td, const float* __restrict__ w1, const float* __restrict__ b1,
    const float* __restrict__ w2, const float* __restrict__ b2, float* __restrict__ tdt)
{
    __shared__ float u0[SEQ];
    __shared__ float u1[SEQ];
    int row = blockIdx.x, h = row % NHH;
    const float* tsr = ts + (size_t)row * SEQ;
    const float* tdr = td + (size_t)row * SEQ;
    for (int i = threadIdx.x; i < SEQ; i += 256) u0[i] = tsr[i] * tdr[i];
    __syncthreads();
    float wa[4], wb[4];
#pragma unroll
    for (int k = 0; k < 4; ++k) { wa[k] = w1[h * 4 + k]; wb[k] = w2[h * 4 + k]; }
    float ba = b1[h], bbv = b2[h];
    for (int i = threadIdx.x; i < SEQ; i += 256) {
        float acc = ba;
#pragma unroll
        for (int k = 0; k < 4; ++k) { int tt = i + k - 3; if (tt >= 0) acc = fmaf(u0[tt], wa[k], acc); }
        u1[i] = siluf(acc);
    }
    __syncthreads();
    for (int i = threadIdx.x; i < SEQ; i += 256) {
        float acc = bbv;
#pragma unroll
        for (int k = 0; k < 4; ++k) { int tt = i + k - 3; if (tt >= 0) acc = fmaf(u1[tt], wb[k], acc); }
        tdt[(size_t)row * SEQ + i] = siluf(acc);
    }
}

// ---------------- dt_sp = softplus(dt * tdt^T + dt_bias); dt from bf16 r1 col 1792+h
__global__ __launch_bounds__(256) void dtsp_k(const unsigned short* __restrict__ r1,
    const float* __restrict__ tdt, const float* __restrict__ dt_bias, float* __restrict__ dtp)
{
    int idx = blockIdx.x * 256 + threadIdx.x;
    if (idx >= MR * NHH) return;
    int h = idx % NHH;
    int row = idx / NHH;
    int b = row / SEQ, s = row % SEQ;
    float x = bf2f(r1[(size_t)row * XSTR + CDIM + h]) * tdt[((size_t)(b * NHH + h)) * SEQ + s] + dt_bias[h];
    dtp[idx] = (x > 20.0f) ? x : log1pf(expf(x));
}

// ---------------- SSD chunk states via MFMA
__global__ __launch_bounds__(256) void ssd_states_mfma_k(const unsigned short* __restrict__ xc,
    const float* __restrict__ dtp, const float* __restrict__ A_log,
    float* __restrict__ st, float* __restrict__ al)
{
    __shared__ float s_acs[256];
    __shared__ float s_coef[256];
    __shared__ unsigned short SXT[64 * 136];
    __shared__ unsigned short SBT[128 * 136];
    int blk = blockIdx.x;
    int h = blk % NHH, c = (blk / NHH) % NC, b = blk / (NHH * NC);
    int tid = threadIdx.x;
    int w = tid >> 6, l = tid & 63;
    int lr = l & 15, lk = l >> 4;
    size_t rowbase = (size_t)b * SEQ + c * CHK;
    float Ah = -expf(A_log[h]);
    float dtv = dtp[(rowbase + tid) * NHH + h];
    s_acs[tid] = Ah * dtv;
    __syncthreads();
    for (int off = 1; off < 256; off <<= 1) {
        float t = (tid >= off) ? s_acs[tid - off] : 0.f;
        __syncthreads();
        s_acs[tid] += t;
        __syncthreads();
    }
    float alv = s_acs[255];
    s_coef[tid] = expf(alv - s_acs[tid]) * dtv;
    if (tid == 255) al[blk] = alv;
    __syncthreads();
    f32x4 acc[4][2] = {};
    for (int z0 = 0; z0 < CHK; z0 += 128) {
        if (z0) __syncthreads();
        for (int i = tid; i < 128 * 8; i += 256) {
            int zz = i >> 3, p8 = (i & 7) * 8;
            float sc = s_coef[z0 + zz];
            u16x8 v = *(const u16x8*)&xc[(rowbase + z0 + zz) * CDIM + h * HDIM + p8];
#pragma unroll
            for (int e = 0; e < 8; ++e)
                SXT[(p8 + e) * 136 + zz] = f2bf(bf2f(v[e]) * sc);
        }
        for (int i = tid; i < 128 * 16; i += 256) {
            int zz = i >> 4, n8 = (i & 15) * 8;
            u16x8 v = *(const u16x8*)&xc[(rowbase + z0 + zz) * CDIM + DSSM + n8];
#pragma unroll
            for (int e = 0; e < 8; ++e)
                SBT[(n8 + e) * 136 + zz] = v[e];
        }
        __syncthreads();
#pragma unroll
        for (int kt = 0; kt < 4; ++kt) {
            bf16x8 av[4], bv[2];
#pragma unroll
            for (int mi = 0; mi < 4; ++mi)
                av[mi] = *(const bf16x8*)&SXT[(mi * 16 + lr) * 136 + kt * 32 + lk * 8];
#pragma unroll
            for (int nj = 0; nj < 2; ++nj)
                bv[nj] = *(const bf16x8*)&SBT[(w * 32 + nj * 16 + lr) * 136 + kt * 32 + lk * 8];
#pragma unroll
            for (int mi = 0; mi < 4; ++mi)
#pragma unroll
                for (int nj = 0; nj < 2; ++nj)
                    acc[mi][nj] = __builtin_amdgcn_mfma_f32_16x16x32_bf16(av[mi], bv[nj], acc[mi][nj], 0, 0, 0);
        }
    }
    size_t base = (size_t)blk * (HDIM * DSTATE);
#pragma unroll
    for (int mi = 0; mi < 4; ++mi)
#pragma unroll
        for (int r = 0; r < 4; ++r) {
            int p = mi * 16 + lk * 4 + r;
#pragma unroll
            for (int nj = 0; nj < 2; ++nj)
                st[base + p * DSTATE + w * 32 + nj * 16 + lr] = acc[mi][nj][r];
        }
}

// ---------------- inter-chunk scan: carry in f32, emit prev-states as bf16
__global__ __launch_bounds__(256) void ssd_scan_k(const float* __restrict__ st,
    const float* __restrict__ al, unsigned short* __restrict__ pv16)
{
    int b = blockIdx.x / NHH, h = blockIdx.x % NHH;
    int tid = threadIdx.x;
    float carry[32];
#pragma unroll
    for (int j = 0; j < 32; ++j) carry[j] = 0.f;
    for (int c = 0; c < NC; ++c) {
        int bch = (b * NC + c) * NHH + h;
        size_t base = (size_t)bch * (HDIM * DSTATE);
        float dcy = expf(al[bch]);
#pragma unroll
        for (int j = 0; j < 32; ++j) {
            pv16[base + tid + j * 256] = f2bf(carry[j]);
            carry[j] = fmaf(dcy, carry[j], st[base + tid + j * 256]);
        }
    }
}

// ---------------- S_raw = C.B^T per (b,c), lower-triangular 64x64 tiles, bf16
__global__ __launch_bounds__(512) void ssd_sraw_k(const unsigned short* __restrict__ xc,
    unsigned short* __restrict__ sraw)
{
    __shared__ unsigned short SC[256 * 136];
    __shared__ unsigned short SB[256 * 136];
    int bc = blockIdx.x;
    int b = bc / NC, c = bc % NC;
    size_t rowbase = (size_t)b * SEQ + c * CHK;
    int tid = threadIdx.x;
    int w = tid >> 6, l = tid & 63;
    int lr = l & 15, lk = l >> 4;
    for (int i = tid; i < 256 * 32; i += 512) {
        int r = i >> 5, c4 = (i & 31) * 4;
        *(ushort4*)&SC[r * 136 + c4] = *(const ushort4*)&xc[(rowbase + r) * CDIM + DSSM + DSTATE + c4];
        *(ushort4*)&SB[r * 136 + c4] = *(const ushort4*)&xc[(rowbase + r) * CDIM + DSSM + c4];
    }
    __syncthreads();
    unsigned short* tb = sraw + (size_t)bc * 16 * 4096;
    int t = 0;
#pragma unroll
    for (int st = 0; st < 4; ++st) {
#pragma unroll
        for (int zt = 0; zt <= st; ++zt, ++t) {
            if ((t & 7) != w) continue;
            f32x4 d[4][4] = {};
#pragma unroll
            for (int kt = 0; kt < 4; ++kt) {
                bf16x8 av[4], bv[4];
#pragma unroll
                for (int mi = 0; mi < 4; ++mi)
                    av[mi] = *(const bf16x8*)&SC[(st * 64 + mi * 16 + lr) * 136 + kt * 32 + lk * 8];
#pragma unroll
                for (int nj = 0; nj < 4; ++nj)
                    bv[nj] = *(const bf16x8*)&SB[(zt * 64 + nj * 16 + lr) * 136 + kt * 32 + lk * 8];
#pragma unroll
                for (int mi = 0; mi < 4; ++mi)
#pragma unroll
                    for (int nj = 0; nj < 4; ++nj)
                        d[mi][nj] = __builtin_amdgcn_mfma_f32_16x16x32_bf16(av[mi], bv[nj], d[mi][nj], 0, 0, 0);
            }
            unsigned short* tp = tb + (size_t)(st * 4 + zt) * 4096;
#pragma unroll
            for (int mi = 0; mi < 4; ++mi)
#pragma unroll
                for (int nj = 0; nj < 4; ++nj)
#pragma unroll
                    for (int r = 0; r < 4; ++r)
                        tp[(mi * 16 + lk * 4 + r) * 64 + nj * 16 + lr] = f2bf(d[mi][nj][r]);
        }
    }
}

// ---------------- Y from precomputed S_raw: per (b,c,h,half), 4 waves = 4 s-tiles, 32 p-cols.
// es factorization: exp(acs[s]-az0[zt]) = esw[s]*rho[zt], all factors <= 1. Y stored bf16.
__global__ __launch_bounds__(256) void ssd_y2_k(const unsigned short* __restrict__ xc,
    const float* __restrict__ dtp, const float* __restrict__ A_log,
    const unsigned short* __restrict__ sraw, const unsigned short* __restrict__ pv16,
    const float* __restrict__ Dp, unsigned short* __restrict__ Ybf)
{
    __shared__ float s_acs[256];
    __shared__ float s_dt[256];
    __shared__ float s_edt[256];
    __shared__ float s_az0[4];
    __shared__ unsigned short SXT[32 * 264];
    int blk2 = blockIdx.x;
    int half = blk2 & 1;
    int blk = blk2 >> 1;
    int h = blk % NHH;
    int c = (blk / NHH) % NC;
    int b = blk / (NHH * NC);
    int tid = threadIdx.x;
    int w = tid >> 6, l = tid & 63;
    int lr = l & 15, lk = l >> 4;
    int pbase = half * 32;
    size_t rowbase = (size_t)b * SEQ + c * CHK;
    float Ah = -expf(A_log[h]);
    float dtv = dtp[(rowbase + tid) * NHH + h];
    s_dt[tid] = dtv;
    s_acs[tid] = Ah * dtv;
    __syncthreads();
    for (int off = 1; off < 256; off <<= 1) {
        float t = (tid >= off) ? s_acs[tid - off] : 0.f;
        __syncthreads();
        s_acs[tid] += t;
        __syncthreads();
    }
    if (tid < 4) s_az0[tid] = s_acs[tid * 64];
    __syncthreads();
    {
        float e = s_az0[tid >> 6] - s_acs[tid];
        if (e > 60.f) e = 60.f;
        s_edt[tid] = expf(e) * s_dt[tid];
    }
    __syncthreads();
    // stage scaled X^T for this half: 256 z x 32 p
    for (int i = tid; i < 256 * 4; i += 256) {
        int z = i >> 2, p8 = (i & 3) * 8;
        float sc = s_edt[z];
        u16x8 v = *(const u16x8*)&xc[(rowbase + z) * CDIM + h * HDIM + pbase + p8];
#pragma unroll
        for (int e = 0; e < 8; ++e)
            SXT[(p8 + e) * 264 + z] = f2bf(bf2f(v[e]) * sc);
    }
    __syncthreads();

    // per-thread esw for its 16 s values
    float az0w = s_az0[w];
    float esw[4][4];
#pragma unroll
    for (int mi = 0; mi < 4; ++mi)
#pragma unroll
        for (int r = 0; r < 4; ++r)
            esw[mi][r] = expf(s_acs[w * 64 + mi * 16 + lk * 4 + r] - az0w);

    const unsigned short* tbase = sraw + (size_t)(b * NC + c) * 16 * 4096;
    const unsigned short* pvbase = pv16 + (size_t)blk * (HDIM * DSTATE);
    f32x4 acc[4][2] = {};
    for (int zt = 0; zt <= w; ++zt) {
        const unsigned short* tp = tbase + (size_t)(w * 4 + zt) * 4096;
        f32x4 tmp[4][2] = {};
#pragma unroll
        for (int kt = 0; kt < 2; ++kt) {
            bf16x8 av[4], bv[2];
#pragma unroll
            for (int mi = 0; mi < 4; ++mi) {
                av[mi] = *(const bf16x8*)&tp[(mi * 16 + lr) * 64 + kt * 32 + lk * 8];
                if (zt == w) {
                    int zb = kt * 32 + lk * 8;
                    int sl = mi * 16 + lr;
#pragma unroll
                    for (int e = 0; e < 8; ++e)
                        if (zb + e > sl) av[mi][e] = 0;
                }
            }
#pragma unroll
            for (int nj = 0; nj < 2; ++nj)
                bv[nj] = *(const bf16x8*)&SXT[(nj * 16 + lr) * 264 + zt * 64 + kt * 32 + lk * 8];
#pragma unroll
            for (int mi = 0; mi < 4; ++mi)
#pragma unroll
                for (int nj = 0; nj < 2; ++nj)
                    tmp[mi][nj] = __builtin_amdgcn_mfma_f32_16x16x32_bf16(av[mi], bv[nj], tmp[mi][nj], 0, 0, 0);
        }
        float rho = expf(az0w - s_az0[zt]);
#pragma unroll
        for (int mi = 0; mi < 4; ++mi)
#pragma unroll
            for (int r = 0; r < 4; ++r) {
                float es = esw[mi][r] * rho;
#pragma unroll
                for (int nj = 0; nj < 2; ++nj)
                    acc[mi][nj][r] += es * tmp[mi][nj][r];
            }
    }
    // off-chunk: C.prev^T * exp(acs[s]); exp(acs[s]) = esw * exp(az0w)
    {
        f32x4 tmp[4][2] = {};
#pragma unroll
        for (int kt = 0; kt < 4; ++kt) {
            bf16x8 av[4], bv[2];
#pragma unroll
            for (int mi = 0; mi < 4; ++mi)
                av[mi] = *(const bf16x8*)&xc[(rowbase + w * 64 + mi * 16 + lr) * CDIM + DSSM + DSTATE + kt * 32 + lk * 8];
#pragma unroll
            for (int nj = 0; nj < 2; ++nj)
                bv[nj] = *(const bf16x8*)&pvbase[(pbase + nj * 16 + lr) * DSTATE + kt * 32 + lk * 8];
#pragma unroll
            for (int mi = 0; mi < 4; ++mi)
#pragma unroll
                for (int nj = 0; nj < 2; ++nj)
                    tmp[mi][nj] = __builtin_amdgcn_mfma_f32_16x16x32_bf16(av[mi], bv[nj], tmp[mi][nj], 0, 0, 0);
        }
        float eoff = expf(az0w);
#pragma unroll
        for (int mi = 0; mi < 4; ++mi)
#pragma unroll
            for (int r = 0; r < 4; ++r) {
                float es = esw[mi][r] * eoff;
#pragma unroll
                for (int nj = 0; nj < 2; ++nj)
                    acc[mi][nj][r] += es * tmp[mi][nj][r];
            }
    }
    float dph = Dp[h];
#pragma unroll
    for (int mi = 0; mi < 4; ++mi) {
#pragma unroll
        for (int r = 0; r < 4; ++r) {
            int s = w * 64 + mi * 16 + lk * 4 + r;
#pragma unroll
            for (int nj = 0; nj < 2; ++nj) {
                int p = pbase + nj * 16 + lr;
                float xv = bf2f(xc[(rowbase + s) * CDIM + h * HDIM + p]);
                Ybf[(rowbase + s) * DSSM + h * HDIM + p] = f2bf(acc[mi][nj][r] + dph * xv);
            }
        }
    }
}

// ---------------- gated RMS norm (y bf16, z bf16) -> bf16 output
__global__ __launch_bounds__(256) void rmsnorm_k(const unsigned short* __restrict__ Ybf_in,
    const unsigned short* __restrict__ zbf, const float* __restrict__ nw,
    unsigned short* __restrict__ Ybf_out)
{
    __shared__ float red[8];
    int row = blockIdx.x;
    const unsigned short* y = Ybf_in + (size_t)row * DSSM;
    const unsigned short* z = zbf + (size_t)row * DSSM;
    float v[6];
    float ss = 0.f;
#pragma unroll
    for (int k = 0; k < 6; ++k) {
        int i = threadIdx.x + k * 256;
        float g = bf2f(y[i]) * siluf(bf2f(z[i]));
        v[k] = g;
        ss = fmaf(g, g, ss);
    }
#pragma unroll
    for (int o = 32; o > 0; o >>= 1) ss += __shfl_down(ss, o, 64);
    int wv = threadIdx.x >> 6, ln = threadIdx.x & 63;
    if (ln == 0) red[wv] = ss;
    __syncthreads();
    float tot = red[0] + red[1] + red[2] + red[3];
    float sc = rsqrtf(tot / (float)DSSM + 1e-12f);
    unsigned short* yo = Ybf_out + (size_t)row * DSSM;
#pragma unroll
    for (int k = 0; k < 6; ++k) {
        int i = threadIdx.x + k * 256;
        yo[i] = f2bf(v[k] * sc * nw[i]);
    }
}

// ---------------- time_out: gate + mix + LayerNorm over SEQ
__global__ __launch_bounds__(256) void timeout_k(const float* __restrict__ td,
    const float* __restrict__ tdt, const float* __restrict__ gw, const float* __restrict__ gb,
    const float* __restrict__ lnw, const float* __restrict__ lnb, float* __restrict__ out2)
{
    __shared__ float tm[SEQ];
    __shared__ float red[8];
    int row = blockIdx.x;
    const float* tdr = td + (size_t)row * SEQ;
    const float* tdtr = tdt + (size_t)row * SEQ;
    int wv = threadIdx.x >> 6, ln = threadIdx.x & 63;
    float part = 0.f;
    for (int i = threadIdx.x; i < SEQ; i += 256) part = fmaf(tdr[i], gw[i], part);
#pragma unroll
    for (int o = 32; o > 0; o >>= 1) part += __shfl_down(part, o, 64);
    if (ln == 0) red[wv] = part;
    __syncthreads();
    float dot = red[0] + red[1] + red[2] + red[3];
    float tg = 1.f / (1.f + expf(-(dot + gb[0])));
    __syncthreads();
    float sum = 0.f;
    for (int i = threadIdx.x; i < SEQ; i += 256) {
        float x = tg * tdr[i] + (1.f - tg) * tdtr[i];
        tm[i] = x;
        sum += x;
    }
#pragma unroll
    for (int o = 32; o > 0; o >>= 1) sum += __shfl_down(sum, o, 64);
    if (ln == 0) red[wv] = sum;
    __syncthreads();
    float mu = (red[0] + red[1] + red[2] + red[3]) / (float)SEQ;
    __syncthreads();
    float s2 = 0.f;
    for (int i = threadIdx.x; i < SEQ; i += 256) { float d = tm[i] - mu; s2 = fmaf(d, d, s2); }
#pragma unroll
    for (int o = 32; o > 0; o >>= 1) s2 += __shfl_down(s2, o, 64);
    if (ln == 0) red[wv] = s2;
    __syncthreads();
    float var = (red[0] + red[1] + red[2] + red[3]) / (float)SEQ;
    float inv = rsqrtf(var + 1e-12f);
    for (int i = threadIdx.x; i < SEQ; i += 256)
        out2[(size_t)row * SEQ + i] = (tm[i] - mu) * inv * lnw[i] + lnb[i];
}

extern "C" void kernel_launch(void* const* d_in, const int* in_sizes, int n_in,
                              void* d_out, int out_size, void* d_ws, size_t ws_size,
                              hipStream_t stream)
{
    const float* u      = (const float*)d_in[0];
    const float* td     = (const float*)d_in[1];
    const float* W_in   = (const float*)d_in[2];
    const float* b_in   = (const float*)d_in[3];
    const float* conv_w = (const float*)d_in[4];
    const float* conv_b = (const float*)d_in[5];
    const float* t1w    = (const float*)d_in[6];
    const float* t1b    = (const float*)d_in[7];
    const float* t2w    = (const float*)d_in[8];
    const float* t2b    = (const float*)d_in[9];
    const float* m1w    = (const float*)d_in[10];
    const float* m1b    = (const float*)d_in[11];
    const float* m2w    = (const float*)d_in[12];
    const float* m2b    = (const float*)d_in[13];
    const float* gw     = (const float*)d_in[14];
    const float* gb     = (const float*)d_in[15];
    const float* lnw    = (const float*)d_in[16];
    const float* lnb    = (const float*)d_in[17];
    const float* A_log  = (const float*)d_in[18];
    const float* dt_bias= (const float*)d_in[19];
    const float* Dpv    = (const float*)d_in[20];
    const float* nw     = (const float*)d_in[21];
    const float* W_out  = (const float*)d_in[22];
    const float* b_out  = (const float*)d_in[23];
    float* out  = (float*)d_out;
    float* out2 = out + (size_t)MR * DMODEL;

    float* ws = (float*)d_ws;
    size_t o = 0;
    float* zbuf  = ws + o; o += (size_t)MR * DSSM;    // bf16 z (half) + Wo_bf at +6291456
    float* r1    = ws + o; o += (size_t)MR * DSSM;    // region: bf16 r1 (XSTR sh) / stb / Y bf16
    float* xcv   = ws + o; o += (size_t)MR * CDIM / 2;
    float* hid   = ws + o; o += (size_t)BB * NHH * SEQ;
    float* tss   = ws + o; o += (size_t)BB * NHH * SEQ;
    float* tdt   = ws + o; o += (size_t)BB * NHH * SEQ;
    float* dtp   = ws + o; o += (size_t)MR * NHH;
    float* pvb   = ws + o; o += (size_t)BB * NC * NHH * HDIM * DSTATE;  // early: u_bf/Wi_bf; late: pv16
    float* alb   = ws + o; o += (size_t)BB * NC * NHH;
    unsigned short* sraw = (unsigned short*)(ws + o); o += (size_t)BB * NC * 16 * 4096 / 2;
    unsigned short* r1b = (unsigned short*)r1;
    float* stb = r1;
    unsigned short* ybf16 = (unsigned short*)r1;      // Y bf16 after stb dead
    float* partb = xcv;
    unsigned short* xcv_bf = (unsigned short*)xcv;
    unsigned short* u_bf  = (unsigned short*)pvb;
    unsigned short* Wi_bf = (unsigned short*)(pvb + 3145728);
    unsigned short* pv16  = (unsigned short*)pvb;     // after u_bf/Wi_bf dead (post in-proj GEMMs)
    unsigned short* zbf   = (unsigned short*)zbuf;
    unsigned short* Y_bf  = (unsigned short*)xcv;
    unsigned short* Wo_bf = (unsigned short*)(zbuf + 6291456);

    dim3 blk(256);
    // --- time MLP first (partials use xcv region, dead until conv) ---
    gemm_skinny_nt<<<dim3(SEQ / 128, KSPLIT), blk, 0, stream>>>(td, m1w, partb, SEQ, SEQ);
    reduce_part_k<<<dim3((48 * SEQ + 255) / 256), blk, 0, stream>>>(partb, m1b, hid, SEQ, 1);
    gemm_skinny_nt<<<dim3(SEQ / 128, KSPLIT), blk, 0, stream>>>(hid, m2w, partb, SEQ, SEQ);
    reduce_part_k<<<dim3((48 * SEQ + 255) / 256), blk, 0, stream>>>(partb, m2b, tss, SEQ, 0);
    time_conv_k<<<dim3(BB * NHH), blk, 0, stream>>>(tss, td, t1w, t1b, t2w, t2b, tdt);
    // --- in-proj: combined xBC+dt GEMM stores bf16; z GEMM stores bf16 ---
    cvt_bf16_k<<<dim3((MR * DMODEL / 4 + 255) / 256), blk, 0, stream>>>(u, u_bf, MR * DMODEL, MR * DMODEL);
    cvt_bf16_k<<<dim3((3456 * DMODEL / 4 + 255) / 256), blk, 0, stream>>>(W_in, Wi_bf, DPROJ * DMODEL, 3456 * DMODEL);
    gemm_mfma_nt<<<dim3(XSTR / 128, MR / 128), blk, 0, stream>>>(
        u_bf, Wi_bf + (size_t)DSSM * DMODEL, b_in + DSSM, r1b, XSTR, DMODEL, DMODEL / 32, DPROJ - DSSM, 1);
    conv_xbc_k<<<dim3((448 * (MR / CT) + 255) / 256), blk, 0, stream>>>(r1b, conv_w, conv_b, xcv_bf);
    gemm_mfma_nt<<<dim3(DSSM / 128, MR / 128), blk, 0, stream>>>(
        u_bf, Wi_bf, b_in, zbf, DSSM, DMODEL, DMODEL / 32, DSSM, 1);
    dtsp_k<<<dim3((MR * NHH + 255) / 256), blk, 0, stream>>>(r1b, tdt, dt_bias, dtp);
    // --- SSD ---
    ssd_sraw_k<<<dim3(BB * NC), dim3(512), 0, stream>>>(xcv_bf, sraw);
    ssd_states_mfma_k<<<dim3(BB * NC * NHH), blk, 0, stream>>>(xcv_bf, dtp, A_log, stb, alb);
    ssd_scan_k<<<dim3(BB * NHH), blk, 0, stream>>>(stb, alb, pv16);
    ssd_y2_k<<<dim3(BB * NC * NHH * 2), blk, 0, stream>>>(xcv_bf, dtp, A_log, sraw, pv16, Dpv, ybf16);
    // --- epilogue ---
    rmsnorm_k<<<dim3(MR), blk, 0, stream>>>(ybf16, zbf, nw, Y_bf);
    cvt_bf16_k<<<dim3((DMODEL * DSSM / 4 + 255) / 256), blk, 0, stream>>>(W_out, Wo_bf, DMODEL * DSSM, DMODEL * DSSM);
    gemm_mfma_nt<<<dim3(DMODEL / 128, MR / 128), blk, 0, stream>>>(
        Y_bf, Wo_bf, b_out, out, DMODEL, DSSM, DSSM / 32, DMODEL, 0);
    timeout_k<<<dim3(BB * NHH), blk, 0, stream>>>(td, tdt, gw, gb, lnw, lnb, out2);
}

// Round 13
// 432.247 us; speedup vs baseline: 8.0756x; 1.0346x over previous
//
#include <hip/hip_runtime.h>
#include <math.h>

#define BB 2
#define SEQ 4096
#define DMODEL 768
#define DSTATE 128
#define NHH 24
#define HDIM 64
#define DSSM 1536
#define CDIM 1792
#define CHK 256
#define NC 16
#define DPROJ 3352
#define MR (BB*SEQ)
#define KSPLIT 32
#define XSTR 1920   // r1 row stride: xBC(1792) + dt(24) + pad(104)
#define CT 16       // conv timesteps per thread

typedef __attribute__((ext_vector_type(8))) short bf16x8;
typedef __attribute__((ext_vector_type(8))) unsigned short u16x8;
typedef __attribute__((ext_vector_type(4))) float f32x4;

__device__ __forceinline__ float siluf(float x) { return x / (1.0f + expf(-x)); }

__device__ __forceinline__ unsigned short f2bf(float f) {
    unsigned u = __float_as_uint(f);
    unsigned r = (u + 0x7fffu + ((u >> 16) & 1u)) >> 16;
    return (unsigned short)r;
}

__device__ __forceinline__ float bf2f(unsigned short u) {
    return __uint_as_float(((unsigned)u) << 16);
}

__device__ __forceinline__ float4 bf2f4(ushort4 v) {
    float4 o;
    o.x = bf2f(v.x); o.y = bf2f(v.y); o.z = bf2f(v.z); o.w = bf2f(v.w);
    return o;
}

__device__ __forceinline__ void gload_lds16(const void* g, void* l) {
    __builtin_amdgcn_global_load_lds((const __attribute__((address_space(1))) unsigned int*)g,
                                     (__attribute__((address_space(3))) unsigned int*)l, 16, 0, 0);
}

// ---------------- f32 -> bf16 conversion (vectorized), zero-pad beyond n_valid
__global__ __launch_bounds__(256) void cvt_bf16_k(const float* __restrict__ in,
    unsigned short* __restrict__ out, int n_valid, int n_total)
{
    int i = (blockIdx.x * 256 + threadIdx.x) * 4;
    if (i >= n_total) return;
    ushort4 o;
    if (i + 3 < n_valid) {
        float4 v = *(const float4*)&in[i];
        o.x = f2bf(v.x); o.y = f2bf(v.y); o.z = f2bf(v.z); o.w = f2bf(v.w);
    } else {
        o.x = (i + 0 < n_valid) ? f2bf(in[i + 0]) : 0;
        o.y = (i + 1 < n_valid) ? f2bf(in[i + 1]) : 0;
        o.z = (i + 2 < n_valid) ? f2bf(in[i + 2]) : 0;
        o.w = (i + 3 < n_valid) ? f2bf(in[i + 3]) : 0;
    }
    *(ushort4*)&out[i] = o;
}

// ---------------- bf16 MFMA GEMM: C(MxN) = A(MxK) @ B(NxK)^T + bias; f32 or bf16 store
// 1-D grid = MT*NT with XCD-aware swizzle (requires nwg%8==0); bf16 path uses
// LDS-staged coalesced epilogue (stride-136 staging, ushort8 row stores).
__global__ __launch_bounds__(256) void gemm_mfma_nt(
    const unsigned short* __restrict__ A, const unsigned short* __restrict__ B,
    const float* __restrict__ bias, void* __restrict__ C, int N, int K, int KT,
    int nbias, int store_bf16, int NT)
{
    __shared__ unsigned short SMEM[16384];   // [0:8192) A dbuf, [8192:16384) B dbuf
    const int tid = threadIdx.x;
    const int w = tid >> 6, l = tid & 63;
    const int wr = w >> 1, wc = w & 1;
    const int lr = l & 15, lk = l >> 4;
    int nwg = gridDim.x, bid = blockIdx.x;
    int wg = (nwg & 7) ? bid : ((bid & 7) * (nwg >> 3) + (bid >> 3));
    const int m0 = (wg / NT) * 128, n0 = (wg % NT) * 128;
    f32x4 acc[4][4] = {};
    const int i16 = w * 64 + l;
    const int row0 = i16 >> 2, sl = i16 & 3;
    const size_t ga0 = (size_t)(m0 + row0) * K + sl * 8;
    const size_t ga1 = (size_t)(m0 + row0 + 64) * K + sl * 8;
    const size_t gb0 = (size_t)(n0 + row0) * K + sl * 8;
    const size_t gb1 = (size_t)(n0 + row0 + 64) * K + sl * 8;
    const int lo0 = (w * 64) * 8;
    const int lo1 = (256 + w * 64) * 8;

#define STAGE(bb, kt) { int ko = (kt) * 32;                                  \
      gload_lds16(A + ga0 + ko, &SMEM[(bb) * 4096 + lo0]);                   \
      gload_lds16(A + ga1 + ko, &SMEM[(bb) * 4096 + lo1]);                   \
      gload_lds16(B + gb0 + ko, &SMEM[8192 + (bb) * 4096 + lo0]);            \
      gload_lds16(B + gb1 + ko, &SMEM[8192 + (bb) * 4096 + lo1]); }

    STAGE(0, 0);
    for (int kt = 0; kt < KT; ++kt) {
        int cur = kt & 1;
        asm volatile("s_waitcnt vmcnt(0)" ::: "memory");
        __syncthreads();
        if (kt + 1 < KT) STAGE(cur ^ 1, kt + 1);
        bf16x8 af[4], bg[4];
#pragma unroll
        for (int mi = 0; mi < 4; ++mi)
            af[mi] = *(const bf16x8*)&SMEM[cur * 4096 + (wr * 64 + mi * 16 + lr) * 32 + lk * 8];
#pragma unroll
        for (int nj = 0; nj < 4; ++nj)
            bg[nj] = *(const bf16x8*)&SMEM[8192 + cur * 4096 + (wc * 64 + nj * 16 + lr) * 32 + lk * 8];
#pragma unroll
        for (int mi = 0; mi < 4; ++mi)
#pragma unroll
            for (int nj = 0; nj < 4; ++nj)
                acc[mi][nj] = __builtin_amdgcn_mfma_f32_16x16x32_bf16(af[mi], bg[nj], acc[mi][nj], 0, 0, 0);
    }
#undef STAGE
    if (store_bf16) {
        // LDS-staged coalesced epilogue: 64 rows (one wr half) at a time
        unsigned short* CL = SMEM;   // 64*136 = 8704 ushorts
#pragma unroll
        for (int half = 0; half < 2; ++half) {
            __syncthreads();
            if (wr == half) {
#pragma unroll
                for (int nj = 0; nj < 4; ++nj) {
                    int col = n0 + wc * 64 + nj * 16 + lr;
                    float bz = (col < nbias) ? bias[col] : 0.f;
                    int cl = wc * 64 + nj * 16 + lr;
#pragma unroll
                    for (int mi = 0; mi < 4; ++mi)
#pragma unroll
                        for (int r = 0; r < 4; ++r)
                            CL[(mi * 16 + lk * 4 + r) * 136 + cl] = f2bf(acc[mi][nj][r] + bz);
                }
            }
            __syncthreads();
            for (int i = tid; i < 1024; i += 256) {
                int rr = i >> 4, c8 = (i & 15) * 8;
                int m = m0 + half * 64 + rr;
                *(u16x8*)&((unsigned short*)C)[(size_t)m * N + n0 + c8] = *(const u16x8*)&CL[rr * 136 + c8];
            }
        }
    } else {
#pragma unroll
        for (int nj = 0; nj < 4; ++nj) {
            int col = n0 + wc * 64 + nj * 16 + lr;
            float bz = (col < nbias) ? bias[col] : 0.f;
#pragma unroll
            for (int mi = 0; mi < 4; ++mi) {
#pragma unroll
                for (int r = 0; r < 4; ++r) {
                    int m = m0 + wr * 64 + mi * 16 + lk * 4 + r;
                    ((float*)C)[(size_t)m * N + col] = acc[mi][nj][r] + bz;
                }
            }
        }
    }
}

// ---------------- split-K skinny GEMM (M=48), conflict-free [row][k] LDS layout
__global__ __launch_bounds__(256) void gemm_skinny_nt(const float* __restrict__ A,
    const float* __restrict__ Bw, float* __restrict__ part, int N, int K)
{
    __shared__ float sA[48 * 33];
    __shared__ float sB[128 * 33];
    const int nb = blockIdx.x, kb = blockIdx.y;
    const int n0 = nb * 128;
    const int KS = K / KSPLIT;
    const int k0 = kb * KS;
    const int tid = threadIdx.x;
    const int tx = tid & 31, ty = tid >> 5;
    float acc[6][4] = {{0.f}};
    for (int kc = 0; kc < KS; kc += 32) {
        if (kc) __syncthreads();
        for (int i = tid; i < 384; i += 256) {
            int m = i >> 3, k4 = (i & 7) * 4;
            float4 v = *(const float4*)&A[(size_t)m * K + k0 + kc + k4];
            sA[m * 33 + k4 + 0] = v.x;
            sA[m * 33 + k4 + 1] = v.y;
            sA[m * 33 + k4 + 2] = v.z;
            sA[m * 33 + k4 + 3] = v.w;
        }
        for (int i = tid; i < 1024; i += 256) {
            int n = i >> 3, k4 = (i & 7) * 4;
            float4 v = *(const float4*)&Bw[(size_t)(n0 + n) * K + k0 + kc + k4];
            sB[n * 33 + k4 + 0] = v.x;
            sB[n * 33 + k4 + 1] = v.y;
            sB[n * 33 + k4 + 2] = v.z;
            sB[n * 33 + k4 + 3] = v.w;
        }
        __syncthreads();
#pragma unroll 8
        for (int kk = 0; kk < 32; ++kk) {
            float a[6], b[4];
#pragma unroll
            for (int r = 0; r < 6; ++r) a[r] = sA[(ty * 6 + r) * 33 + kk];
#pragma unroll
            for (int j = 0; j < 4; ++j) b[j] = sB[(tx + j * 32) * 33 + kk];
#pragma unroll
            for (int r = 0; r < 6; ++r)
#pragma unroll
                for (int j = 0; j < 4; ++j)
                    acc[r][j] = fmaf(a[r], b[j], acc[r][j]);
        }
    }
    float* pb = part + (size_t)kb * 48 * N;
#pragma unroll
    for (int r = 0; r < 6; ++r)
#pragma unroll
        for (int j = 0; j < 4; ++j)
            pb[(size_t)(ty * 6 + r) * N + n0 + tx + j * 32] = acc[r][j];
}

// ---------------- reduce split-K partials + bias (+ optional silu)
__global__ __launch_bounds__(256) void reduce_part_k(const float* __restrict__ part,
    const float* __restrict__ bias, float* __restrict__ out, int N, int act)
{
    int idx = blockIdx.x * 256 + threadIdx.x;
    if (idx >= 48 * N) return;
    int n = idx % N;
    float s = bias[n];
#pragma unroll
    for (int kb = 0; kb < KSPLIT; ++kb) s += part[(size_t)kb * 48 * N + idx];
    if (act) s = siluf(s);
    out[idx] = s;
}

// ---------------- sliding-window depthwise causal conv + silu, bf16 in/out
__global__ __launch_bounds__(256) void conv_xbc_k(const unsigned short* __restrict__ xbc,
    const float* __restrict__ cw, const float* __restrict__ cb,
    unsigned short* __restrict__ out)
{
    int idx = blockIdx.x * 256 + threadIdx.x;
    if (idx >= 448 * (MR / CT)) return;
    int slot = idx % 448;
    int g = idx / 448;
    int c4 = slot * 4;
    int b = g / (SEQ / CT);
    int t0 = (g % (SEQ / CT)) * CT;
    size_t rb = (size_t)b * SEQ;
    float4 cw0 = *(const float4*)&cw[(c4 + 0) * 4];
    float4 cw1 = *(const float4*)&cw[(c4 + 1) * 4];
    float4 cw2 = *(const float4*)&cw[(c4 + 2) * 4];
    float4 cw3 = *(const float4*)&cw[(c4 + 3) * 4];
    float4 cbv = *(const float4*)&cb[c4];
    float4 zero = {0.f, 0.f, 0.f, 0.f};
    float4 w0, w1, w2;
    w0 = (t0 - 3 >= 0) ? bf2f4(*(const ushort4*)&xbc[(rb + t0 - 3) * XSTR + c4]) : zero;
    w1 = (t0 - 2 >= 0) ? bf2f4(*(const ushort4*)&xbc[(rb + t0 - 2) * XSTR + c4]) : zero;
    w2 = (t0 - 1 >= 0) ? bf2f4(*(const ushort4*)&xbc[(rb + t0 - 1) * XSTR + c4]) : zero;
#pragma unroll
    for (int i = 0; i < CT; ++i) {
        int t = t0 + i;
        float4 w3 = bf2f4(*(const ushort4*)&xbc[(rb + t) * XSTR + c4]);
        float a0 = cbv.x + w0.x * cw0.x + w1.x * cw0.y + w2.x * cw0.z + w3.x * cw0.w;
        float a1 = cbv.y + w0.y * cw1.x + w1.y * cw1.y + w2.y * cw1.z + w3.y * cw1.w;
        float a2 = cbv.z + w0.z * cw2.x + w1.z * cw2.y + w2.z * cw2.z + w3.z * cw2.w;
        float a3 = cbv.w + w0.w * cw3.x + w1.w * cw3.y + w2.w * cw3.z + w3.w * cw3.w;
        ushort4 o;
        o.x = f2bf(siluf(a0)); o.y = f2bf(siluf(a1));
        o.z = f2bf(siluf(a2)); o.w = f2bf(siluf(a3));
        *(ushort4*)&out[(rb + t) * CDIM + c4] = o;
        w0 = w1; w1 = w2; w2 = w3;
    }
}

// ---------------- per-(b,h) row: tdt0 = ts*td; conv1+silu; conv2+silu
__global__ __launch_bounds__(256) void time_conv_k(const float* __restrict__ ts,
    const float* __restrict__ td, const float* __restrict__ w1, const float* __restrict__ b1,
    const float* __restrict__ w2, const float* __restrict__ b2, float* __restrict__ tdt)
{
    __shared__ float u0[SEQ];
    __shared__ float u1[SEQ];
    int row = blockIdx.x, h = row % NHH;
    const float* tsr = ts + (size_t)row * SEQ;
    const float* tdr = td + (size_t)row * SEQ;
    for (int i = threadIdx.x; i < SEQ; i += 256) u0[i] = tsr[i] * tdr[i];
    __syncthreads();
    float wa[4], wb[4];
#pragma unroll
    for (int k = 0; k < 4; ++k) { wa[k] = w1[h * 4 + k]; wb[k] = w2[h * 4 + k]; }
    float ba = b1[h], bbv = b2[h];
    for (int i = threadIdx.x; i < SEQ; i += 256) {
        float acc = ba;
#pragma unroll
        for (int k = 0; k < 4; ++k) { int tt = i + k - 3; if (tt >= 0) acc = fmaf(u0[tt], wa[k], acc); }
        u1[i] = siluf(acc);
    }
    __syncthreads();
    for (int i = threadIdx.x; i < SEQ; i += 256) {
        float acc = bbv;
#pragma unroll
        for (int k = 0; k < 4; ++k) { int tt = i + k - 3; if (tt >= 0) acc = fmaf(u1[tt], wb[k], acc); }
        tdt[(size_t)row * SEQ + i] = siluf(acc);
    }
}

// ---------------- dt_sp = softplus(dt * tdt^T + dt_bias); dt from bf16 r1 col 1792+h
__global__ __launch_bounds__(256) void dtsp_k(const unsigned short* __restrict__ r1,
    const float* __restrict__ tdt, const float* __restrict__ dt_bias, float* __restrict__ dtp)
{
    int idx = blockIdx.x * 256 + threadIdx.x;
    if (idx >= MR * NHH) return;
    int h = idx % NHH;
    int row = idx / NHH;
    int b = row / SEQ, s = row % SEQ;
    float x = bf2f(r1[(size_t)row * XSTR + CDIM + h]) * tdt[((size_t)(b * NHH + h)) * SEQ + s] + dt_bias[h];
    dtp[idx] = (x > 20.0f) ? x : log1pf(expf(x));
}

// ---------------- SSD chunk states via MFMA
__global__ __launch_bounds__(256) void ssd_states_mfma_k(const unsigned short* __restrict__ xc,
    const float* __restrict__ dtp, const float* __restrict__ A_log,
    float* __restrict__ st, float* __restrict__ al)
{
    __shared__ float s_acs[256];
    __shared__ float s_coef[256];
    __shared__ unsigned short SXT[64 * 136];
    __shared__ unsigned short SBT[128 * 136];
    int blk = blockIdx.x;
    int h = blk % NHH, c = (blk / NHH) % NC, b = blk / (NHH * NC);
    int tid = threadIdx.x;
    int w = tid >> 6, l = tid & 63;
    int lr = l & 15, lk = l >> 4;
    size_t rowbase = (size_t)b * SEQ + c * CHK;
    float Ah = -expf(A_log[h]);
    float dtv = dtp[(rowbase + tid) * NHH + h];
    s_acs[tid] = Ah * dtv;
    __syncthreads();
    for (int off = 1; off < 256; off <<= 1) {
        float t = (tid >= off) ? s_acs[tid - off] : 0.f;
        __syncthreads();
        s_acs[tid] += t;
        __syncthreads();
    }
    float alv = s_acs[255];
    s_coef[tid] = expf(alv - s_acs[tid]) * dtv;
    if (tid == 255) al[blk] = alv;
    __syncthreads();
    f32x4 acc[4][2] = {};
    for (int z0 = 0; z0 < CHK; z0 += 128) {
        if (z0) __syncthreads();
        for (int i = tid; i < 128 * 8; i += 256) {
            int zz = i >> 3, p8 = (i & 7) * 8;
            float sc = s_coef[z0 + zz];
            u16x8 v = *(const u16x8*)&xc[(rowbase + z0 + zz) * CDIM + h * HDIM + p8];
#pragma unroll
            for (int e = 0; e < 8; ++e)
                SXT[(p8 + e) * 136 + zz] = f2bf(bf2f(v[e]) * sc);
        }
        for (int i = tid; i < 128 * 16; i += 256) {
            int zz = i >> 4, n8 = (i & 15) * 8;
            u16x8 v = *(const u16x8*)&xc[(rowbase + z0 + zz) * CDIM + DSSM + n8];
#pragma unroll
            for (int e = 0; e < 8; ++e)
                SBT[(n8 + e) * 136 + zz] = v[e];
        }
        __syncthreads();
#pragma unroll
        for (int kt = 0; kt < 4; ++kt) {
            bf16x8 av[4], bv[2];
#pragma unroll
            for (int mi = 0; mi < 4; ++mi)
                av[mi] = *(const bf16x8*)&SXT[(mi * 16 + lr) * 136 + kt * 32 + lk * 8];
#pragma unroll
            for (int nj = 0; nj < 2; ++nj)
                bv[nj] = *(const bf16x8*)&SBT[(w * 32 + nj * 16 + lr) * 136 + kt * 32 + lk * 8];
#pragma unroll
            for (int mi = 0; mi < 4; ++mi)
#pragma unroll
                for (int nj = 0; nj < 2; ++nj)
                    acc[mi][nj] = __builtin_amdgcn_mfma_f32_16x16x32_bf16(av[mi], bv[nj], acc[mi][nj], 0, 0, 0);
        }
    }
    size_t base = (size_t)blk * (HDIM * DSTATE);
#pragma unroll
    for (int mi = 0; mi < 4; ++mi)
#pragma unroll
        for (int r = 0; r < 4; ++r) {
            int p = mi * 16 + lk * 4 + r;
#pragma unroll
            for (int nj = 0; nj < 2; ++nj)
                st[base + p * DSTATE + w * 32 + nj * 16 + lr] = acc[mi][nj][r];
        }
}

// ---------------- inter-chunk scan: carry in f32, emit prev-states as bf16
__global__ __launch_bounds__(256) void ssd_scan_k(const float* __restrict__ st,
    const float* __restrict__ al, unsigned short* __restrict__ pv16)
{
    int b = blockIdx.x / NHH, h = blockIdx.x % NHH;
    int tid = threadIdx.x;
    float carry[32];
#pragma unroll
    for (int j = 0; j < 32; ++j) carry[j] = 0.f;
    for (int c = 0; c < NC; ++c) {
        int bch = (b * NC + c) * NHH + h;
        size_t base = (size_t)bch * (HDIM * DSTATE);
        float dcy = expf(al[bch]);
#pragma unroll
        for (int j = 0; j < 32; ++j) {
            pv16[base + tid + j * 256] = f2bf(carry[j]);
            carry[j] = fmaf(dcy, carry[j], st[base + tid + j * 256]);
        }
    }
}

// ---------------- S_raw = C.B^T per (b,c), lower-triangular 64x64 tiles, bf16
__global__ __launch_bounds__(512) void ssd_sraw_k(const unsigned short* __restrict__ xc,
    unsigned short* __restrict__ sraw)
{
    __shared__ unsigned short SC[256 * 136];
    __shared__ unsigned short SB[256 * 136];
    int bc = blockIdx.x;
    int b = bc / NC, c = bc % NC;
    size_t rowbase = (size_t)b * SEQ + c * CHK;
    int tid = threadIdx.x;
    int w = tid >> 6, l = tid & 63;
    int lr = l & 15, lk = l >> 4;
    for (int i = tid; i < 256 * 32; i += 512) {
        int r = i >> 5, c4 = (i & 31) * 4;
        *(ushort4*)&SC[r * 136 + c4] = *(const ushort4*)&xc[(rowbase + r) * CDIM + DSSM + DSTATE + c4];
        *(ushort4*)&SB[r * 136 + c4] = *(const ushort4*)&xc[(rowbase + r) * CDIM + DSSM + c4];
    }
    __syncthreads();
    unsigned short* tb = sraw + (size_t)bc * 16 * 4096;
    int t = 0;
#pragma unroll
    for (int st = 0; st < 4; ++st) {
#pragma unroll
        for (int zt = 0; zt <= st; ++zt, ++t) {
            if ((t & 7) != w) continue;
            f32x4 d[4][4] = {};
#pragma unroll
            for (int kt = 0; kt < 4; ++kt) {
                bf16x8 av[4], bv[4];
#pragma unroll
                for (int mi = 0; mi < 4; ++mi)
                    av[mi] = *(const bf16x8*)&SC[(st * 64 + mi * 16 + lr) * 136 + kt * 32 + lk * 8];
#pragma unroll
                for (int nj = 0; nj < 4; ++nj)
                    bv[nj] = *(const bf16x8*)&SB[(zt * 64 + nj * 16 + lr) * 136 + kt * 32 + lk * 8];
#pragma unroll
                for (int mi = 0; mi < 4; ++mi)
#pragma unroll
                    for (int nj = 0; nj < 4; ++nj)
                        d[mi][nj] = __builtin_amdgcn_mfma_f32_16x16x32_bf16(av[mi], bv[nj], d[mi][nj], 0, 0, 0);
            }
            unsigned short* tp = tb + (size_t)(st * 4 + zt) * 4096;
#pragma unroll
            for (int mi = 0; mi < 4; ++mi)
#pragma unroll
                for (int nj = 0; nj < 4; ++nj)
#pragma unroll
                    for (int r = 0; r < 4; ++r)
                        tp[(mi * 16 + lk * 4 + r) * 64 + nj * 16 + lr] = f2bf(d[mi][nj][r]);
        }
    }
}

// ---------------- Y from precomputed S_raw: per (b,c,h,half), 4 waves = 4 s-tiles, 32 p-cols.
__global__ __launch_bounds__(256) void ssd_y2_k(const unsigned short* __restrict__ xc,
    const float* __restrict__ dtp, const float* __restrict__ A_log,
    const unsigned short* __restrict__ sraw, const unsigned short* __restrict__ pv16,
    const float* __restrict__ Dp, unsigned short* __restrict__ Ybf)
{
    __shared__ float s_acs[256];
    __shared__ float s_dt[256];
    __shared__ float s_edt[256];
    __shared__ float s_az0[4];
    __shared__ unsigned short SXT[32 * 264];
    int blk2 = blockIdx.x;
    int half = blk2 & 1;
    int blk = blk2 >> 1;
    int h = blk % NHH;
    int c = (blk / NHH) % NC;
    int b = blk / (NHH * NC);
    int tid = threadIdx.x;
    int w = tid >> 6, l = tid & 63;
    int lr = l & 15, lk = l >> 4;
    int pbase = half * 32;
    size_t rowbase = (size_t)b * SEQ + c * CHK;
    float Ah = -expf(A_log[h]);
    float dtv = dtp[(rowbase + tid) * NHH + h];
    s_dt[tid] = dtv;
    s_acs[tid] = Ah * dtv;
    __syncthreads();
    for (int off = 1; off < 256; off <<= 1) {
        float t = (tid >= off) ? s_acs[tid - off] : 0.f;
        __syncthreads();
        s_acs[tid] += t;
        __syncthreads();
    }
    if (tid < 4) s_az0[tid] = s_acs[tid * 64];
    __syncthreads();
    {
        float e = s_az0[tid >> 6] - s_acs[tid];
        if (e > 60.f) e = 60.f;
        s_edt[tid] = expf(e) * s_dt[tid];
    }
    __syncthreads();
    for (int i = tid; i < 256 * 4; i += 256) {
        int z = i >> 2, p8 = (i & 3) * 8;
        float sc = s_edt[z];
        u16x8 v = *(const u16x8*)&xc[(rowbase + z) * CDIM + h * HDIM + pbase + p8];
#pragma unroll
        for (int e = 0; e < 8; ++e)
            SXT[(p8 + e) * 264 + z] = f2bf(bf2f(v[e]) * sc);
    }
    __syncthreads();

    float az0w = s_az0[w];
    float esw[4][4];
#pragma unroll
    for (int mi = 0; mi < 4; ++mi)
#pragma unroll
        for (int r = 0; r < 4; ++r)
            esw[mi][r] = expf(s_acs[w * 64 + mi * 16 + lk * 4 + r] - az0w);

    const unsigned short* tbase = sraw + (size_t)(b * NC + c) * 16 * 4096;
    const unsigned short* pvbase = pv16 + (size_t)blk * (HDIM * DSTATE);
    f32x4 acc[4][2] = {};
    for (int zt = 0; zt <= w; ++zt) {
        const unsigned short* tp = tbase + (size_t)(w * 4 + zt) * 4096;
        f32x4 tmp[4][2] = {};
#pragma unroll
        for (int kt = 0; kt < 2; ++kt) {
            bf16x8 av[4], bv[2];
#pragma unroll
            for (int mi = 0; mi < 4; ++mi) {
                av[mi] = *(const bf16x8*)&tp[(mi * 16 + lr) * 64 + kt * 32 + lk * 8];
                if (zt == w) {
                    int zb = kt * 32 + lk * 8;
                    int sl = mi * 16 + lr;
#pragma unroll
                    for (int e = 0; e < 8; ++e)
                        if (zb + e > sl) av[mi][e] = 0;
                }
            }
#pragma unroll
            for (int nj = 0; nj < 2; ++nj)
                bv[nj] = *(const bf16x8*)&SXT[(nj * 16 + lr) * 264 + zt * 64 + kt * 32 + lk * 8];
#pragma unroll
            for (int mi = 0; mi < 4; ++mi)
#pragma unroll
                for (int nj = 0; nj < 2; ++nj)
                    tmp[mi][nj] = __builtin_amdgcn_mfma_f32_16x16x32_bf16(av[mi], bv[nj], tmp[mi][nj], 0, 0, 0);
        }
        float rho = expf(az0w - s_az0[zt]);
#pragma unroll
        for (int mi = 0; mi < 4; ++mi)
#pragma unroll
            for (int r = 0; r < 4; ++r) {
                float es = esw[mi][r] * rho;
#pragma unroll
                for (int nj = 0; nj < 2; ++nj)
                    acc[mi][nj][r] += es * tmp[mi][nj][r];
            }
    }
    {
        f32x4 tmp[4][2] = {};
#pragma unroll
        for (int kt = 0; kt < 4; ++kt) {
            bf16x8 av[4], bv[2];
#pragma unroll
            for (int mi = 0; mi < 4; ++mi)
                av[mi] = *(const bf16x8*)&xc[(rowbase + w * 64 + mi * 16 + lr) * CDIM + DSSM + DSTATE + kt * 32 + lk * 8];
#pragma unroll
            for (int nj = 0; nj < 2; ++nj)
                bv[nj] = *(const bf16x8*)&pvbase[(pbase + nj * 16 + lr) * DSTATE + kt * 32 + lk * 8];
#pragma unroll
            for (int mi = 0; mi < 4; ++mi)
#pragma unroll
                for (int nj = 0; nj < 2; ++nj)
                    tmp[mi][nj] = __builtin_amdgcn_mfma_f32_16x16x32_bf16(av[mi], bv[nj], tmp[mi][nj], 0, 0, 0);
        }
        float eoff = expf(az0w);
#pragma unroll
        for (int mi = 0; mi < 4; ++mi)
#pragma unroll
            for (int r = 0; r < 4; ++r) {
                float es = esw[mi][r] * eoff;
#pragma unroll
                for (int nj = 0; nj < 2; ++nj)
                    acc[mi][nj][r] += es * tmp[mi][nj][r];
            }
    }
    float dph = Dp[h];
#pragma unroll
    for (int mi = 0; mi < 4; ++mi) {
#pragma unroll
        for (int r = 0; r < 4; ++r) {
            int s = w * 64 + mi * 16 + lk * 4 + r;
#pragma unroll
            for (int nj = 0; nj < 2; ++nj) {
                int p = pbase + nj * 16 + lr;
                float xv = bf2f(xc[(rowbase + s) * CDIM + h * HDIM + p]);
                Ybf[(rowbase + s) * DSSM + h * HDIM + p] = f2bf(acc[mi][nj][r] + dph * xv);
            }
        }
    }
}

// ---------------- gated RMS norm (y bf16, z bf16) -> bf16 output
__global__ __launch_bounds__(256) void rmsnorm_k(const unsigned short* __restrict__ Ybf_in,
    const unsigned short* __restrict__ zbf, const float* __restrict__ nw,
    unsigned short* __restrict__ Ybf_out)
{
    __shared__ float red[8];
    int row = blockIdx.x;
    const unsigned short* y = Ybf_in + (size_t)row * DSSM;
    const unsigned short* z = zbf + (size_t)row * DSSM;
    float v[6];
    float ss = 0.f;
#pragma unroll
    for (int k = 0; k < 6; ++k) {
        int i = threadIdx.x + k * 256;
        float g = bf2f(y[i]) * siluf(bf2f(z[i]));
        v[k] = g;
        ss = fmaf(g, g, ss);
    }
#pragma unroll
    for (int o = 32; o > 0; o >>= 1) ss += __shfl_down(ss, o, 64);
    int wv = threadIdx.x >> 6, ln = threadIdx.x & 63;
    if (ln == 0) red[wv] = ss;
    __syncthreads();
    float tot = red[0] + red[1] + red[2] + red[3];
    float sc = rsqrtf(tot / (float)DSSM + 1e-12f);
    unsigned short* yo = Ybf_out + (size_t)row * DSSM;
#pragma unroll
    for (int k = 0; k < 6; ++k) {
        int i = threadIdx.x + k * 256;
        yo[i] = f2bf(v[k] * sc * nw[i]);
    }
}

// ---------------- time_out: gate + mix + LayerNorm over SEQ
__global__ __launch_bounds__(256) void timeout_k(const float* __restrict__ td,
    const float* __restrict__ tdt, const float* __restrict__ gw, const float* __restrict__ gb,
    const float* __restrict__ lnw, const float* __restrict__ lnb, float* __restrict__ out2)
{
    __shared__ float tm[SEQ];
    __shared__ float red[8];
    int row = blockIdx.x;
    const float* tdr = td + (size_t)row * SEQ;
    const float* tdtr = tdt + (size_t)row * SEQ;
    int wv = threadIdx.x >> 6, ln = threadIdx.x & 63;
    float part = 0.f;
    for (int i = threadIdx.x; i < SEQ; i += 256) part = fmaf(tdr[i], gw[i], part);
#pragma unroll
    for (int o = 32; o > 0; o >>= 1) part += __shfl_down(part, o, 64);
    if (ln == 0) red[wv] = part;
    __syncthreads();
    float dot = red[0] + red[1] + red[2] + red[3];
    float tg = 1.f / (1.f + expf(-(dot + gb[0])));
    __syncthreads();
    float sum = 0.f;
    for (int i = threadIdx.x; i < SEQ; i += 256) {
        float x = tg * tdr[i] + (1.f - tg) * tdtr[i];
        tm[i] = x;
        sum += x;
    }
#pragma unroll
    for (int o = 32; o > 0; o >>= 1) sum += __shfl_down(sum, o, 64);
    if (ln == 0) red[wv] = sum;
    __syncthreads();
    float mu = (red[0] + red[1] + red[2] + red[3]) / (float)SEQ;
    __syncthreads();
    float s2 = 0.f;
    for (int i = threadIdx.x; i < SEQ; i += 256) { float d = tm[i] - mu; s2 = fmaf(d, d, s2); }
#pragma unroll
    for (int o = 32; o > 0; o >>= 1) s2 += __shfl_down(s2, o, 64);
    if (ln == 0) red[wv] = s2;
    __syncthreads();
    float var = (red[0] + red[1] + red[2] + red[3]) / (float)SEQ;
    float inv = rsqrtf(var + 1e-12f);
    for (int i = threadIdx.x; i < SEQ; i += 256)
        out2[(size_t)row * SEQ + i] = (tm[i] - mu) * inv * lnw[i] + lnb[i];
}

extern "C" void kernel_launch(void* const* d_in, const int* in_sizes, int n_in,
                              void* d_out, int out_size, void* d_ws, size_t ws_size,
                              hipStream_t stream)
{
    const float* u      = (const float*)d_in[0];
    const float* td     = (const float*)d_in[1];
    const float* W_in   = (const float*)d_in[2];
    const float* b_in   = (const float*)d_in[3];
    const float* conv_w = (const float*)d_in[4];
    const float* conv_b = (const float*)d_in[5];
    const float* t1w    = (const float*)d_in[6];
    const float* t1b    = (const float*)d_in[7];
    const float* t2w    = (const float*)d_in[8];
    const float* t2b    = (const float*)d_in[9];
    const float* m1w    = (const float*)d_in[10];
    const float* m1b    = (const float*)d_in[11];
    const float* m2w    = (const float*)d_in[12];
    const float* m2b    = (const float*)d_in[13];
    const float* gw     = (const float*)d_in[14];
    const float* gb     = (const float*)d_in[15];
    const float* lnw    = (const float*)d_in[16];
    const float* lnb    = (const float*)d_in[17];
    const float* A_log  = (const float*)d_in[18];
    const float* dt_bias= (const float*)d_in[19];
    const float* Dpv    = (const float*)d_in[20];
    const float* nw     = (const float*)d_in[21];
    const float* W_out  = (const float*)d_in[22];
    const float* b_out  = (const float*)d_in[23];
    float* out  = (float*)d_out;
    float* out2 = out + (size_t)MR * DMODEL;

    float* ws = (float*)d_ws;
    size_t o = 0;
    float* zbuf  = ws + o; o += (size_t)MR * DSSM;
    float* r1    = ws + o; o += (size_t)MR * DSSM;
    float* xcv   = ws + o; o += (size_t)MR * CDIM / 2;
    float* hid   = ws + o; o += (size_t)BB * NHH * SEQ;
    float* tss   = ws + o; o += (size_t)BB * NHH * SEQ;
    float* tdt   = ws + o; o += (size_t)BB * NHH * SEQ;
    float* dtp   = ws + o; o += (size_t)MR * NHH;
    float* pvb   = ws + o; o += (size_t)BB * NC * NHH * HDIM * DSTATE;
    float* alb   = ws + o; o += (size_t)BB * NC * NHH;
    unsigned short* sraw = (unsigned short*)(ws + o); o += (size_t)BB * NC * 16 * 4096 / 2;
    unsigned short* r1b = (unsigned short*)r1;
    float* stb = r1;
    unsigned short* ybf16 = (unsigned short*)r1;
    float* partb = xcv;
    unsigned short* xcv_bf = (unsigned short*)xcv;
    unsigned short* u_bf  = (unsigned short*)pvb;
    unsigned short* Wi_bf = (unsigned short*)(pvb + 3145728);
    unsigned short* pv16  = (unsigned short*)pvb;
    unsigned short* zbf   = (unsigned short*)zbuf;
    unsigned short* Y_bf  = (unsigned short*)xcv;
    unsigned short* Wo_bf = (unsigned short*)(zbuf + 6291456);

    dim3 blk(256);
    // --- time MLP first (partials use xcv region, dead until conv) ---
    gemm_skinny_nt<<<dim3(SEQ / 128, KSPLIT), blk, 0, stream>>>(td, m1w, partb, SEQ, SEQ);
    reduce_part_k<<<dim3((48 * SEQ + 255) / 256), blk, 0, stream>>>(partb, m1b, hid, SEQ, 1);
    gemm_skinny_nt<<<dim3(SEQ / 128, KSPLIT), blk, 0, stream>>>(hid, m2w, partb, SEQ, SEQ);
    reduce_part_k<<<dim3((48 * SEQ + 255) / 256), blk, 0, stream>>>(partb, m2b, tss, SEQ, 0);
    time_conv_k<<<dim3(BB * NHH), blk, 0, stream>>>(tss, td, t1w, t1b, t2w, t2b, tdt);
    // --- in-proj ---
    cvt_bf16_k<<<dim3((MR * DMODEL / 4 + 255) / 256), blk, 0, stream>>>(u, u_bf, MR * DMODEL, MR * DMODEL);
    cvt_bf16_k<<<dim3((3456 * DMODEL / 4 + 255) / 256), blk, 0, stream>>>(W_in, Wi_bf, DPROJ * DMODEL, 3456 * DMODEL);
    gemm_mfma_nt<<<dim3((XSTR / 128) * (MR / 128)), blk, 0, stream>>>(
        u_bf, Wi_bf + (size_t)DSSM * DMODEL, b_in + DSSM, r1b, XSTR, DMODEL, DMODEL / 32, DPROJ - DSSM, 1, XSTR / 128);
    conv_xbc_k<<<dim3((448 * (MR / CT) + 255) / 256), blk, 0, stream>>>(r1b, conv_w, conv_b, xcv_bf);
    gemm_mfma_nt<<<dim3((DSSM / 128) * (MR / 128)), blk, 0, stream>>>(
        u_bf, Wi_bf, b_in, zbf, DSSM, DMODEL, DMODEL / 32, DSSM, 1, DSSM / 128);
    dtsp_k<<<dim3((MR * NHH + 255) / 256), blk, 0, stream>>>(r1b, tdt, dt_bias, dtp);
    // --- SSD ---
    ssd_sraw_k<<<dim3(BB * NC), dim3(512), 0, stream>>>(xcv_bf, sraw);
    ssd_states_mfma_k<<<dim3(BB * NC * NHH), blk, 0, stream>>>(xcv_bf, dtp, A_log, stb, alb);
    ssd_scan_k<<<dim3(BB * NHH), blk, 0, stream>>>(stb, alb, pv16);
    ssd_y2_k<<<dim3(BB * NC * NHH * 2), blk, 0, stream>>>(xcv_bf, dtp, A_log, sraw, pv16, Dpv, ybf16);
    // --- epilogue ---
    rmsnorm_k<<<dim3(MR), blk, 0, stream>>>(ybf16, zbf, nw, Y_bf);
    cvt_bf16_k<<<dim3((DMODEL * DSSM / 4 + 255) / 256), blk, 0, stream>>>(W_out, Wo_bf, DMODEL * DSSM, DMODEL * DSSM);
    gemm_mfma_nt<<<dim3((DMODEL / 128) * (MR / 128)), blk, 0, stream>>>(
        Y_bf, Wo_bf, b_out, out, DMODEL, DSSM, DSSM / 32, DMODEL, 0, DMODEL / 128);
    timeout_k<<<dim3(BB * NHH), blk, 0, stream>>>(td, tdt, gw, gb, lnw, lnb, out2);
}

// Round 14
// 413.760 us; speedup vs baseline: 8.4364x; 1.0447x over previous
//
#include <hip/hip_runtime.h>
#include <math.h>

#define BB 2
#define SEQ 4096
#define DMODEL 768
#define DSTATE 128
#define NHH 24
#define HDIM 64
#define DSSM 1536
#define CDIM 1792
#define CHK 256
#define NC 16
#define DPROJ 3352
#define MR (BB*SEQ)
#define KSPLIT 32
#define XSTR 1920   // r1 row stride: xBC(1792) + dt(24) + pad(104)
#define CT 16       // conv timesteps per thread

typedef __attribute__((ext_vector_type(8))) short bf16x8;
typedef __attribute__((ext_vector_type(8))) unsigned short u16x8;
typedef __attribute__((ext_vector_type(4))) float f32x4;

__device__ __forceinline__ float siluf(float x) { return x / (1.0f + expf(-x)); }

__device__ __forceinline__ unsigned short f2bf(float f) {
    unsigned u = __float_as_uint(f);
    unsigned r = (u + 0x7fffu + ((u >> 16) & 1u)) >> 16;
    return (unsigned short)r;
}

__device__ __forceinline__ float bf2f(unsigned short u) {
    return __uint_as_float(((unsigned)u) << 16);
}

__device__ __forceinline__ float4 bf2f4(ushort4 v) {
    float4 o;
    o.x = bf2f(v.x); o.y = bf2f(v.y); o.z = bf2f(v.z); o.w = bf2f(v.w);
    return o;
}

__device__ __forceinline__ void gload_lds16(const void* g, void* l) {
    __builtin_amdgcn_global_load_lds((const __attribute__((address_space(1))) unsigned int*)g,
                                     (__attribute__((address_space(3))) unsigned int*)l, 16, 0, 0);
}

// ---------------- f32 -> bf16 conversion (vectorized), zero-pad beyond n_valid
__global__ __launch_bounds__(256) void cvt_bf16_k(const float* __restrict__ in,
    unsigned short* __restrict__ out, int n_valid, int n_total)
{
    int i = (blockIdx.x * 256 + threadIdx.x) * 4;
    if (i >= n_total) return;
    ushort4 o;
    if (i + 3 < n_valid) {
        float4 v = *(const float4*)&in[i];
        o.x = f2bf(v.x); o.y = f2bf(v.y); o.z = f2bf(v.z); o.w = f2bf(v.w);
    } else {
        o.x = (i + 0 < n_valid) ? f2bf(in[i + 0]) : 0;
        o.y = (i + 1 < n_valid) ? f2bf(in[i + 1]) : 0;
        o.z = (i + 2 < n_valid) ? f2bf(in[i + 2]) : 0;
        o.w = (i + 3 < n_valid) ? f2bf(in[i + 3]) : 0;
    }
    *(ushort4*)&out[i] = o;
}

// ---------------- bf16 MFMA GEMM: C(MxN) = A(MxK) @ B(NxK)^T + bias; f32 or bf16 store
__global__ __launch_bounds__(256) void gemm_mfma_nt(
    const unsigned short* __restrict__ A, const unsigned short* __restrict__ B,
    const float* __restrict__ bias, void* __restrict__ C, int N, int K, int KT,
    int nbias, int store_bf16, int NT)
{
    __shared__ unsigned short SMEM[16384];
    const int tid = threadIdx.x;
    const int w = tid >> 6, l = tid & 63;
    const int wr = w >> 1, wc = w & 1;
    const int lr = l & 15, lk = l >> 4;
    int nwg = gridDim.x, bid = blockIdx.x;
    int wg = (nwg & 7) ? bid : ((bid & 7) * (nwg >> 3) + (bid >> 3));
    const int m0 = (wg / NT) * 128, n0 = (wg % NT) * 128;
    f32x4 acc[4][4] = {};
    const int i16 = w * 64 + l;
    const int row0 = i16 >> 2, sl = i16 & 3;
    const size_t ga0 = (size_t)(m0 + row0) * K + sl * 8;
    const size_t ga1 = (size_t)(m0 + row0 + 64) * K + sl * 8;
    const size_t gb0 = (size_t)(n0 + row0) * K + sl * 8;
    const size_t gb1 = (size_t)(n0 + row0 + 64) * K + sl * 8;
    const int lo0 = (w * 64) * 8;
    const int lo1 = (256 + w * 64) * 8;

#define STAGE(bb, kt) { int ko = (kt) * 32;                                  \
      gload_lds16(A + ga0 + ko, &SMEM[(bb) * 4096 + lo0]);                   \
      gload_lds16(A + ga1 + ko, &SMEM[(bb) * 4096 + lo1]);                   \
      gload_lds16(B + gb0 + ko, &SMEM[8192 + (bb) * 4096 + lo0]);            \
      gload_lds16(B + gb1 + ko, &SMEM[8192 + (bb) * 4096 + lo1]); }

    STAGE(0, 0);
    for (int kt = 0; kt < KT; ++kt) {
        int cur = kt & 1;
        asm volatile("s_waitcnt vmcnt(0)" ::: "memory");
        __syncthreads();
        if (kt + 1 < KT) STAGE(cur ^ 1, kt + 1);
        bf16x8 af[4], bg[4];
#pragma unroll
        for (int mi = 0; mi < 4; ++mi)
            af[mi] = *(const bf16x8*)&SMEM[cur * 4096 + (wr * 64 + mi * 16 + lr) * 32 + lk * 8];
#pragma unroll
        for (int nj = 0; nj < 4; ++nj)
            bg[nj] = *(const bf16x8*)&SMEM[8192 + cur * 4096 + (wc * 64 + nj * 16 + lr) * 32 + lk * 8];
#pragma unroll
        for (int mi = 0; mi < 4; ++mi)
#pragma unroll
            for (int nj = 0; nj < 4; ++nj)
                acc[mi][nj] = __builtin_amdgcn_mfma_f32_16x16x32_bf16(af[mi], bg[nj], acc[mi][nj], 0, 0, 0);
    }
#undef STAGE
    if (store_bf16) {
        unsigned short* CL = SMEM;
#pragma unroll
        for (int half = 0; half < 2; ++half) {
            __syncthreads();
            if (wr == half) {
#pragma unroll
                for (int nj = 0; nj < 4; ++nj) {
                    int col = n0 + wc * 64 + nj * 16 + lr;
                    float bz = (col < nbias) ? bias[col] : 0.f;
                    int cl = wc * 64 + nj * 16 + lr;
#pragma unroll
                    for (int mi = 0; mi < 4; ++mi)
#pragma unroll
                        for (int r = 0; r < 4; ++r)
                            CL[(mi * 16 + lk * 4 + r) * 136 + cl] = f2bf(acc[mi][nj][r] + bz);
                }
            }
            __syncthreads();
            for (int i = tid; i < 1024; i += 256) {
                int rr = i >> 4, c8 = (i & 15) * 8;
                int m = m0 + half * 64 + rr;
                *(u16x8*)&((unsigned short*)C)[(size_t)m * N + n0 + c8] = *(const u16x8*)&CL[rr * 136 + c8];
            }
        }
    } else {
#pragma unroll
        for (int nj = 0; nj < 4; ++nj) {
            int col = n0 + wc * 64 + nj * 16 + lr;
            float bz = (col < nbias) ? bias[col] : 0.f;
#pragma unroll
            for (int mi = 0; mi < 4; ++mi) {
#pragma unroll
                for (int r = 0; r < 4; ++r) {
                    int m = m0 + wr * 64 + mi * 16 + lk * 4 + r;
                    ((float*)C)[(size_t)m * N + col] = acc[mi][nj][r] + bz;
                }
            }
        }
    }
}

// ---------------- split-K skinny GEMM (M=48), conflict-free [row][k] LDS layout
__global__ __launch_bounds__(256) void gemm_skinny_nt(const float* __restrict__ A,
    const float* __restrict__ Bw, float* __restrict__ part, int N, int K)
{
    __shared__ float sA[48 * 33];
    __shared__ float sB[128 * 33];
    const int nb = blockIdx.x, kb = blockIdx.y;
    const int n0 = nb * 128;
    const int KS = K / KSPLIT;
    const int k0 = kb * KS;
    const int tid = threadIdx.x;
    const int tx = tid & 31, ty = tid >> 5;
    float acc[6][4] = {{0.f}};
    for (int kc = 0; kc < KS; kc += 32) {
        if (kc) __syncthreads();
        for (int i = tid; i < 384; i += 256) {
            int m = i >> 3, k4 = (i & 7) * 4;
            float4 v = *(const float4*)&A[(size_t)m * K + k0 + kc + k4];
            sA[m * 33 + k4 + 0] = v.x;
            sA[m * 33 + k4 + 1] = v.y;
            sA[m * 33 + k4 + 2] = v.z;
            sA[m * 33 + k4 + 3] = v.w;
        }
        for (int i = tid; i < 1024; i += 256) {
            int n = i >> 3, k4 = (i & 7) * 4;
            float4 v = *(const float4*)&Bw[(size_t)(n0 + n) * K + k0 + kc + k4];
            sB[n * 33 + k4 + 0] = v.x;
            sB[n * 33 + k4 + 1] = v.y;
            sB[n * 33 + k4 + 2] = v.z;
            sB[n * 33 + k4 + 3] = v.w;
        }
        __syncthreads();
#pragma unroll 8
        for (int kk = 0; kk < 32; ++kk) {
            float a[6], b[4];
#pragma unroll
            for (int r = 0; r < 6; ++r) a[r] = sA[(ty * 6 + r) * 33 + kk];
#pragma unroll
            for (int j = 0; j < 4; ++j) b[j] = sB[(tx + j * 32) * 33 + kk];
#pragma unroll
            for (int r = 0; r < 6; ++r)
#pragma unroll
                for (int j = 0; j < 4; ++j)
                    acc[r][j] = fmaf(a[r], b[j], acc[r][j]);
        }
    }
    float* pb = part + (size_t)kb * 48 * N;
#pragma unroll
    for (int r = 0; r < 6; ++r)
#pragma unroll
        for (int j = 0; j < 4; ++j)
            pb[(size_t)(ty * 6 + r) * N + n0 + tx + j * 32] = acc[r][j];
}

// ---------------- reduce split-K partials + bias (+ optional silu)
__global__ __launch_bounds__(256) void reduce_part_k(const float* __restrict__ part,
    const float* __restrict__ bias, float* __restrict__ out, int N, int act)
{
    int idx = blockIdx.x * 256 + threadIdx.x;
    if (idx >= 48 * N) return;
    int n = idx % N;
    float s = bias[n];
#pragma unroll
    for (int kb = 0; kb < KSPLIT; ++kb) s += part[(size_t)kb * 48 * N + idx];
    if (act) s = siluf(s);
    out[idx] = s;
}

// ---------------- sliding-window depthwise causal conv + silu, bf16 in/out
__global__ __launch_bounds__(256) void conv_xbc_k(const unsigned short* __restrict__ xbc,
    const float* __restrict__ cw, const float* __restrict__ cb,
    unsigned short* __restrict__ out)
{
    int idx = blockIdx.x * 256 + threadIdx.x;
    if (idx >= 448 * (MR / CT)) return;
    int slot = idx % 448;
    int g = idx / 448;
    int c4 = slot * 4;
    int b = g / (SEQ / CT);
    int t0 = (g % (SEQ / CT)) * CT;
    size_t rb = (size_t)b * SEQ;
    float4 cw0 = *(const float4*)&cw[(c4 + 0) * 4];
    float4 cw1 = *(const float4*)&cw[(c4 + 1) * 4];
    float4 cw2 = *(const float4*)&cw[(c4 + 2) * 4];
    float4 cw3 = *(const float4*)&cw[(c4 + 3) * 4];
    float4 cbv = *(const float4*)&cb[c4];
    float4 zero = {0.f, 0.f, 0.f, 0.f};
    float4 w0, w1, w2;
    w0 = (t0 - 3 >= 0) ? bf2f4(*(const ushort4*)&xbc[(rb + t0 - 3) * XSTR + c4]) : zero;
    w1 = (t0 - 2 >= 0) ? bf2f4(*(const ushort4*)&xbc[(rb + t0 - 2) * XSTR + c4]) : zero;
    w2 = (t0 - 1 >= 0) ? bf2f4(*(const ushort4*)&xbc[(rb + t0 - 1) * XSTR + c4]) : zero;
#pragma unroll
    for (int i = 0; i < CT; ++i) {
        int t = t0 + i;
        float4 w3 = bf2f4(*(const ushort4*)&xbc[(rb + t) * XSTR + c4]);
        float a0 = cbv.x + w0.x * cw0.x + w1.x * cw0.y + w2.x * cw0.z + w3.x * cw0.w;
        float a1 = cbv.y + w0.y * cw1.x + w1.y * cw1.y + w2.y * cw1.z + w3.y * cw1.w;
        float a2 = cbv.z + w0.z * cw2.x + w1.z * cw2.y + w2.z * cw2.z + w3.z * cw2.w;
        float a3 = cbv.w + w0.w * cw3.x + w1.w * cw3.y + w2.w * cw3.z + w3.w * cw3.w;
        ushort4 o;
        o.x = f2bf(siluf(a0)); o.y = f2bf(siluf(a1));
        o.z = f2bf(siluf(a2)); o.w = f2bf(siluf(a3));
        *(ushort4*)&out[(rb + t) * CDIM + c4] = o;
        w0 = w1; w1 = w2; w2 = w3;
    }
}

// ---------------- per-(b,h) row: tdt0 = ts*td; conv1+silu; conv2+silu
__global__ __launch_bounds__(256) void time_conv_k(const float* __restrict__ ts,
    const float* __restrict__ td, const float* __restrict__ w1, const float* __restrict__ b1,
    const float* __restrict__ w2, const float* __restrict__ b2, float* __restrict__ tdt)
{
    __shared__ float u0[SEQ];
    __shared__ float u1[SEQ];
    int row = blockIdx.x, h = row % NHH;
    const float* tsr = ts + (size_t)row * SEQ;
    const float* tdr = td + (size_t)row * SEQ;
    for (int i = threadIdx.x; i < SEQ; i += 256) u0[i] = tsr[i] * tdr[i];
    __syncthreads();
    float wa[4], wb[4];
#pragma unroll
    for (int k = 0; k < 4; ++k) { wa[k] = w1[h * 4 + k]; wb[k] = w2[h * 4 + k]; }
    float ba = b1[h], bbv = b2[h];
    for (int i = threadIdx.x; i < SEQ; i += 256) {
        float acc = ba;
#pragma unroll
        for (int k = 0; k < 4; ++k) { int tt = i + k - 3; if (tt >= 0) acc = fmaf(u0[tt], wa[k], acc); }
        u1[i] = siluf(acc);
    }
    __syncthreads();
    for (int i = threadIdx.x; i < SEQ; i += 256) {
        float acc = bbv;
#pragma unroll
        for (int k = 0; k < 4; ++k) { int tt = i + k - 3; if (tt >= 0) acc = fmaf(u1[tt], wb[k], acc); }
        tdt[(size_t)row * SEQ + i] = siluf(acc);
    }
}

// ---------------- dt_sp = softplus(dt * tdt + dt_bias), TRANSPOSED output [b][h][s]
// idx = (b*NHH+h)*SEQ + s: tdt read + dtp write coalesced; r1 dt reads L2-absorbed
__global__ __launch_bounds__(256) void dtsp_k(const unsigned short* __restrict__ r1,
    const float* __restrict__ tdt, const float* __restrict__ dt_bias, float* __restrict__ dtp)
{
    int idx = blockIdx.x * 256 + threadIdx.x;
    if (idx >= MR * NHH) return;
    int s = idx % SEQ;
    int bh = idx / SEQ;
    int h = bh % NHH, b = bh / NHH;
    float x = bf2f(r1[((size_t)(b * SEQ + s)) * XSTR + CDIM + h]) * tdt[idx] + dt_bias[h];
    dtp[idx] = (x > 20.0f) ? x : log1pf(expf(x));
}

// ---------------- SSD chunk states via MFMA (dtp in [b][h][s] layout, XCD swizzle)
__global__ __launch_bounds__(256) void ssd_states_mfma_k(const unsigned short* __restrict__ xc,
    const float* __restrict__ dtp, const float* __restrict__ A_log,
    float* __restrict__ st, float* __restrict__ al)
{
    __shared__ float s_acs[256];
    __shared__ float s_coef[256];
    __shared__ unsigned short SXT[64 * 136];
    __shared__ unsigned short SBT[128 * 136];
    int bid = blockIdx.x;
    int blk = (gridDim.x & 7) ? bid : ((bid & 7) * (gridDim.x >> 3) + (bid >> 3));
    int h = blk % NHH, c = (blk / NHH) % NC, b = blk / (NHH * NC);
    int tid = threadIdx.x;
    int w = tid >> 6, l = tid & 63;
    int lr = l & 15, lk = l >> 4;
    size_t rowbase = (size_t)b * SEQ + c * CHK;
    float Ah = -expf(A_log[h]);
    float dtv = dtp[((size_t)(b * NHH + h)) * SEQ + c * CHK + tid];
    s_acs[tid] = Ah * dtv;
    __syncthreads();
    for (int off = 1; off < 256; off <<= 1) {
        float t = (tid >= off) ? s_acs[tid - off] : 0.f;
        __syncthreads();
        s_acs[tid] += t;
        __syncthreads();
    }
    float alv = s_acs[255];
    s_coef[tid] = expf(alv - s_acs[tid]) * dtv;
    if (tid == 255) al[blk] = alv;
    __syncthreads();
    f32x4 acc[4][2] = {};
    for (int z0 = 0; z0 < CHK; z0 += 128) {
        if (z0) __syncthreads();
        for (int i = tid; i < 128 * 8; i += 256) {
            int zz = i >> 3, p8 = (i & 7) * 8;
            float sc = s_coef[z0 + zz];
            u16x8 v = *(const u16x8*)&xc[(rowbase + z0 + zz) * CDIM + h * HDIM + p8];
#pragma unroll
            for (int e = 0; e < 8; ++e)
                SXT[(p8 + e) * 136 + zz] = f2bf(bf2f(v[e]) * sc);
        }
        for (int i = tid; i < 128 * 16; i += 256) {
            int zz = i >> 4, n8 = (i & 15) * 8;
            u16x8 v = *(const u16x8*)&xc[(rowbase + z0 + zz) * CDIM + DSSM + n8];
#pragma unroll
            for (int e = 0; e < 8; ++e)
                SBT[(n8 + e) * 136 + zz] = v[e];
        }
        __syncthreads();
#pragma unroll
        for (int kt = 0; kt < 4; ++kt) {
            bf16x8 av[4], bv[2];
#pragma unroll
            for (int mi = 0; mi < 4; ++mi)
                av[mi] = *(const bf16x8*)&SXT[(mi * 16 + lr) * 136 + kt * 32 + lk * 8];
#pragma unroll
            for (int nj = 0; nj < 2; ++nj)
                bv[nj] = *(const bf16x8*)&SBT[(w * 32 + nj * 16 + lr) * 136 + kt * 32 + lk * 8];
#pragma unroll
            for (int mi = 0; mi < 4; ++mi)
#pragma unroll
                for (int nj = 0; nj < 2; ++nj)
                    acc[mi][nj] = __builtin_amdgcn_mfma_f32_16x16x32_bf16(av[mi], bv[nj], acc[mi][nj], 0, 0, 0);
        }
    }
    size_t base = (size_t)blk * (HDIM * DSTATE);
#pragma unroll
    for (int mi = 0; mi < 4; ++mi)
#pragma unroll
        for (int r = 0; r < 4; ++r) {
            int p = mi * 16 + lk * 4 + r;
#pragma unroll
            for (int nj = 0; nj < 2; ++nj)
                st[base + p * DSTATE + w * 32 + nj * 16 + lr] = acc[mi][nj][r];
        }
}

// ---------------- inter-chunk scan: carry in f32, emit prev-states as bf16
__global__ __launch_bounds__(256) void ssd_scan_k(const float* __restrict__ st,
    const float* __restrict__ al, unsigned short* __restrict__ pv16)
{
    int b = blockIdx.x / NHH, h = blockIdx.x % NHH;
    int tid = threadIdx.x;
    float carry[32];
#pragma unroll
    for (int j = 0; j < 32; ++j) carry[j] = 0.f;
    for (int c = 0; c < NC; ++c) {
        int bch = (b * NC + c) * NHH + h;
        size_t base = (size_t)bch * (HDIM * DSTATE);
        float dcy = expf(al[bch]);
#pragma unroll
        for (int j = 0; j < 32; ++j) {
            pv16[base + tid + j * 256] = f2bf(carry[j]);
            carry[j] = fmaf(dcy, carry[j], st[base + tid + j * 256]);
        }
    }
}

// ---------------- S_raw = C.B^T per (b,c), lower-triangular 64x64 tiles, bf16
__global__ __launch_bounds__(512) void ssd_sraw_k(const unsigned short* __restrict__ xc,
    unsigned short* __restrict__ sraw)
{
    __shared__ unsigned short SC[256 * 136];
    __shared__ unsigned short SB[256 * 136];
    int bc = blockIdx.x;
    int b = bc / NC, c = bc % NC;
    size_t rowbase = (size_t)b * SEQ + c * CHK;
    int tid = threadIdx.x;
    int w = tid >> 6, l = tid & 63;
    int lr = l & 15, lk = l >> 4;
    for (int i = tid; i < 256 * 32; i += 512) {
        int r = i >> 5, c4 = (i & 31) * 4;
        *(ushort4*)&SC[r * 136 + c4] = *(const ushort4*)&xc[(rowbase + r) * CDIM + DSSM + DSTATE + c4];
        *(ushort4*)&SB[r * 136 + c4] = *(const ushort4*)&xc[(rowbase + r) * CDIM + DSSM + c4];
    }
    __syncthreads();
    unsigned short* tb = sraw + (size_t)bc * 16 * 4096;
    int t = 0;
#pragma unroll
    for (int st = 0; st < 4; ++st) {
#pragma unroll
        for (int zt = 0; zt <= st; ++zt, ++t) {
            if ((t & 7) != w) continue;
            f32x4 d[4][4] = {};
#pragma unroll
            for (int kt = 0; kt < 4; ++kt) {
                bf16x8 av[4], bv[4];
#pragma unroll
                for (int mi = 0; mi < 4; ++mi)
                    av[mi] = *(const bf16x8*)&SC[(st * 64 + mi * 16 + lr) * 136 + kt * 32 + lk * 8];
#pragma unroll
                for (int nj = 0; nj < 4; ++nj)
                    bv[nj] = *(const bf16x8*)&SB[(zt * 64 + nj * 16 + lr) * 136 + kt * 32 + lk * 8];
#pragma unroll
                for (int mi = 0; mi < 4; ++mi)
#pragma unroll
                    for (int nj = 0; nj < 4; ++nj)
                        d[mi][nj] = __builtin_amdgcn_mfma_f32_16x16x32_bf16(av[mi], bv[nj], d[mi][nj], 0, 0, 0);
            }
            unsigned short* tp = tb + (size_t)(st * 4 + zt) * 4096;
#pragma unroll
            for (int mi = 0; mi < 4; ++mi)
#pragma unroll
                for (int nj = 0; nj < 4; ++nj)
#pragma unroll
                    for (int r = 0; r < 4; ++r)
                        tp[(mi * 16 + lk * 4 + r) * 64 + nj * 16 + lr] = f2bf(d[mi][nj][r]);
        }
    }
}

// ---------------- Y from precomputed S_raw: per (b,c,h,half), XCD swizzle, dtp [b][h][s]
__global__ __launch_bounds__(256) void ssd_y2_k(const unsigned short* __restrict__ xc,
    const float* __restrict__ dtp, const float* __restrict__ A_log,
    const unsigned short* __restrict__ sraw, const unsigned short* __restrict__ pv16,
    const float* __restrict__ Dp, unsigned short* __restrict__ Ybf)
{
    __shared__ float s_acs[256];
    __shared__ float s_dt[256];
    __shared__ float s_edt[256];
    __shared__ float s_az0[4];
    __shared__ unsigned short SXT[32 * 264];
    int bid = blockIdx.x;
    int blk2 = (gridDim.x & 7) ? bid : ((bid & 7) * (gridDim.x >> 3) + (bid >> 3));
    int half = blk2 & 1;
    int blk = blk2 >> 1;
    int h = blk % NHH;
    int c = (blk / NHH) % NC;
    int b = blk / (NHH * NC);
    int tid = threadIdx.x;
    int w = tid >> 6, l = tid & 63;
    int lr = l & 15, lk = l >> 4;
    int pbase = half * 32;
    size_t rowbase = (size_t)b * SEQ + c * CHK;
    float Ah = -expf(A_log[h]);
    float dtv = dtp[((size_t)(b * NHH + h)) * SEQ + c * CHK + tid];
    s_dt[tid] = dtv;
    s_acs[tid] = Ah * dtv;
    __syncthreads();
    for (int off = 1; off < 256; off <<= 1) {
        float t = (tid >= off) ? s_acs[tid - off] : 0.f;
        __syncthreads();
        s_acs[tid] += t;
        __syncthreads();
    }
    if (tid < 4) s_az0[tid] = s_acs[tid * 64];
    __syncthreads();
    {
        float e = s_az0[tid >> 6] - s_acs[tid];
        if (e > 60.f) e = 60.f;
        s_edt[tid] = expf(e) * s_dt[tid];
    }
    __syncthreads();
    for (int i = tid; i < 256 * 4; i += 256) {
        int z = i >> 2, p8 = (i & 3) * 8;
        float sc = s_edt[z];
        u16x8 v = *(const u16x8*)&xc[(rowbase + z) * CDIM + h * HDIM + pbase + p8];
#pragma unroll
        for (int e = 0; e < 8; ++e)
            SXT[(p8 + e) * 264 + z] = f2bf(bf2f(v[e]) * sc);
    }
    __syncthreads();

    float az0w = s_az0[w];
    float esw[4][4];
#pragma unroll
    for (int mi = 0; mi < 4; ++mi)
#pragma unroll
        for (int r = 0; r < 4; ++r)
            esw[mi][r] = expf(s_acs[w * 64 + mi * 16 + lk * 4 + r] - az0w);

    const unsigned short* tbase = sraw + (size_t)(b * NC + c) * 16 * 4096;
    const unsigned short* pvbase = pv16 + (size_t)blk * (HDIM * DSTATE);
    f32x4 acc[4][2] = {};
    for (int zt = 0; zt <= w; ++zt) {
        const unsigned short* tp = tbase + (size_t)(w * 4 + zt) * 4096;
        f32x4 tmp[4][2] = {};
#pragma unroll
        for (int kt = 0; kt < 2; ++kt) {
            bf16x8 av[4], bv[2];
#pragma unroll
            for (int mi = 0; mi < 4; ++mi) {
                av[mi] = *(const bf16x8*)&tp[(mi * 16 + lr) * 64 + kt * 32 + lk * 8];
                if (zt == w) {
                    int zb = kt * 32 + lk * 8;
                    int sl = mi * 16 + lr;
#pragma unroll
                    for (int e = 0; e < 8; ++e)
                        if (zb + e > sl) av[mi][e] = 0;
                }
            }
#pragma unroll
            for (int nj = 0; nj < 2; ++nj)
                bv[nj] = *(const bf16x8*)&SXT[(nj * 16 + lr) * 264 + zt * 64 + kt * 32 + lk * 8];
#pragma unroll
            for (int mi = 0; mi < 4; ++mi)
#pragma unroll
                for (int nj = 0; nj < 2; ++nj)
                    tmp[mi][nj] = __builtin_amdgcn_mfma_f32_16x16x32_bf16(av[mi], bv[nj], tmp[mi][nj], 0, 0, 0);
        }
        float rho = expf(az0w - s_az0[zt]);
#pragma unroll
        for (int mi = 0; mi < 4; ++mi)
#pragma unroll
            for (int r = 0; r < 4; ++r) {
                float es = esw[mi][r] * rho;
#pragma unroll
                for (int nj = 0; nj < 2; ++nj)
                    acc[mi][nj][r] += es * tmp[mi][nj][r];
            }
    }
    {
        f32x4 tmp[4][2] = {};
#pragma unroll
        for (int kt = 0; kt < 4; ++kt) {
            bf16x8 av[4], bv[2];
#pragma unroll
            for (int mi = 0; mi < 4; ++mi)
                av[mi] = *(const bf16x8*)&xc[(rowbase + w * 64 + mi * 16 + lr) * CDIM + DSSM + DSTATE + kt * 32 + lk * 8];
#pragma unroll
            for (int nj = 0; nj < 2; ++nj)
                bv[nj] = *(const bf16x8*)&pvbase[(pbase + nj * 16 + lr) * DSTATE + kt * 32 + lk * 8];
#pragma unroll
            for (int mi = 0; mi < 4; ++mi)
#pragma unroll
                for (int nj = 0; nj < 2; ++nj)
                    tmp[mi][nj] = __builtin_amdgcn_mfma_f32_16x16x32_bf16(av[mi], bv[nj], tmp[mi][nj], 0, 0, 0);
        }
        float eoff = expf(az0w);
#pragma unroll
        for (int mi = 0; mi < 4; ++mi)
#pragma unroll
            for (int r = 0; r < 4; ++r) {
                float es = esw[mi][r] * eoff;
#pragma unroll
                for (int nj = 0; nj < 2; ++nj)
                    acc[mi][nj][r] += es * tmp[mi][nj][r];
            }
    }
    float dph = Dp[h];
#pragma unroll
    for (int mi = 0; mi < 4; ++mi) {
#pragma unroll
        for (int r = 0; r < 4; ++r) {
            int s = w * 64 + mi * 16 + lk * 4 + r;
#pragma unroll
            for (int nj = 0; nj < 2; ++nj) {
                int p = pbase + nj * 16 + lr;
                float xv = bf2f(xc[(rowbase + s) * CDIM + h * HDIM + p]);
                Ybf[(rowbase + s) * DSSM + h * HDIM + p] = f2bf(acc[mi][nj][r] + dph * xv);
            }
        }
    }
}

// ---------------- gated RMS norm (y bf16, z bf16) -> bf16 output
__global__ __launch_bounds__(256) void rmsnorm_k(const unsigned short* __restrict__ Ybf_in,
    const unsigned short* __restrict__ zbf, const float* __restrict__ nw,
    unsigned short* __restrict__ Ybf_out)
{
    __shared__ float red[8];
    int row = blockIdx.x;
    const unsigned short* y = Ybf_in + (size_t)row * DSSM;
    const unsigned short* z = zbf + (size_t)row * DSSM;
    float v[6];
    float ss = 0.f;
#pragma unroll
    for (int k = 0; k < 6; ++k) {
        int i = threadIdx.x + k * 256;
        float g = bf2f(y[i]) * siluf(bf2f(z[i]));
        v[k] = g;
        ss = fmaf(g, g, ss);
    }
#pragma unroll
    for (int o = 32; o > 0; o >>= 1) ss += __shfl_down(ss, o, 64);
    int wv = threadIdx.x >> 6, ln = threadIdx.x & 63;
    if (ln == 0) red[wv] = ss;
    __syncthreads();
    float tot = red[0] + red[1] + red[2] + red[3];
    float sc = rsqrtf(tot / (float)DSSM + 1e-12f);
    unsigned short* yo = Ybf_out + (size_t)row * DSSM;
#pragma unroll
    for (int k = 0; k < 6; ++k) {
        int i = threadIdx.x + k * 256;
        yo[i] = f2bf(v[k] * sc * nw[i]);
    }
}

// ---------------- time_out: gate + mix + LayerNorm over SEQ
__global__ __launch_bounds__(256) void timeout_k(const float* __restrict__ td,
    const float* __restrict__ tdt, const float* __restrict__ gw, const float* __restrict__ gb,
    const float* __restrict__ lnw, const float* __restrict__ lnb, float* __restrict__ out2)
{
    __shared__ float tm[SEQ];
    __shared__ float red[8];
    int row = blockIdx.x;
    const float* tdr = td + (size_t)row * SEQ;
    const float* tdtr = tdt + (size_t)row * SEQ;
    int wv = threadIdx.x >> 6, ln = threadIdx.x & 63;
    float part = 0.f;
    for (int i = threadIdx.x; i < SEQ; i += 256) part = fmaf(tdr[i], gw[i], part);
#pragma unroll
    for (int o = 32; o > 0; o >>= 1) part += __shfl_down(part, o, 64);
    if (ln == 0) red[wv] = part;
    __syncthreads();
    float dot = red[0] + red[1] + red[2] + red[3];
    float tg = 1.f / (1.f + expf(-(dot + gb[0])));
    __syncthreads();
    float sum = 0.f;
    for (int i = threadIdx.x; i < SEQ; i += 256) {
        float x = tg * tdr[i] + (1.f - tg) * tdtr[i];
        tm[i] = x;
        sum += x;
    }
#pragma unroll
    for (int o = 32; o > 0; o >>= 1) sum += __shfl_down(sum, o, 64);
    if (ln == 0) red[wv] = sum;
    __syncthreads();
    float mu = (red[0] + red[1] + red[2] + red[3]) / (float)SEQ;
    __syncthreads();
    float s2 = 0.f;
    for (int i = threadIdx.x; i < SEQ; i += 256) { float d = tm[i] - mu; s2 = fmaf(d, d, s2); }
#pragma unroll
    for (int o = 32; o > 0; o >>= 1) s2 += __shfl_down(s2, o, 64);
    if (ln == 0) red[wv] = s2;
    __syncthreads();
    float var = (red[0] + red[1] + red[2] + red[3]) / (float)SEQ;
    float inv = rsqrtf(var + 1e-12f);
    for (int i = threadIdx.x; i < SEQ; i += 256)
        out2[(size_t)row * SEQ + i] = (tm[i] - mu) * inv * lnw[i] + lnb[i];
}

extern "C" void kernel_launch(void* const* d_in, const int* in_sizes, int n_in,
                              void* d_out, int out_size, void* d_ws, size_t ws_size,
                              hipStream_t stream)
{
    const float* u      = (const float*)d_in[0];
    const float* td     = (const float*)d_in[1];
    const float* W_in   = (const float*)d_in[2];
    const float* b_in   = (const float*)d_in[3];
    const float* conv_w = (const float*)d_in[4];
    const float* conv_b = (const float*)d_in[5];
    const float* t1w    = (const float*)d_in[6];
    const float* t1b    = (const float*)d_in[7];
    const float* t2w    = (const float*)d_in[8];
    const float* t2b    = (const float*)d_in[9];
    const float* m1w    = (const float*)d_in[10];
    const float* m1b    = (const float*)d_in[11];
    const float* m2w    = (const float*)d_in[12];
    const float* m2b    = (const float*)d_in[13];
    const float* gw     = (const float*)d_in[14];
    const float* gb     = (const float*)d_in[15];
    const float* lnw    = (const float*)d_in[16];
    const float* lnb    = (const float*)d_in[17];
    const float* A_log  = (const float*)d_in[18];
    const float* dt_bias= (const float*)d_in[19];
    const float* Dpv    = (const float*)d_in[20];
    const float* nw     = (const float*)d_in[21];
    const float* W_out  = (const float*)d_in[22];
    const float* b_out  = (const float*)d_in[23];
    float* out  = (float*)d_out;
    float* out2 = out + (size_t)MR * DMODEL;

    float* ws = (float*)d_ws;
    size_t o = 0;
    float* zbuf  = ws + o; o += (size_t)MR * DSSM;
    float* r1    = ws + o; o += (size_t)MR * DSSM;
    float* xcv   = ws + o; o += (size_t)MR * CDIM / 2;
    float* hid   = ws + o; o += (size_t)BB * NHH * SEQ;
    float* tss   = ws + o; o += (size_t)BB * NHH * SEQ;
    float* tdt   = ws + o; o += (size_t)BB * NHH * SEQ;
    float* dtp   = ws + o; o += (size_t)MR * NHH;
    float* pvb   = ws + o; o += (size_t)BB * NC * NHH * HDIM * DSTATE;
    float* alb   = ws + o; o += (size_t)BB * NC * NHH;
    unsigned short* sraw = (unsigned short*)(ws + o); o += (size_t)BB * NC * 16 * 4096 / 2;
    unsigned short* r1b = (unsigned short*)r1;
    float* stb = r1;
    unsigned short* ybf16 = (unsigned short*)r1;
    float* partb = xcv;
    unsigned short* xcv_bf = (unsigned short*)xcv;
    unsigned short* u_bf  = (unsigned short*)pvb;
    unsigned short* Wi_bf = (unsigned short*)(pvb + 3145728);
    unsigned short* pv16  = (unsigned short*)pvb;
    unsigned short* zbf   = (unsigned short*)zbuf;
    unsigned short* Y_bf  = (unsigned short*)xcv;
    unsigned short* Wo_bf = (unsigned short*)(zbuf + 6291456);

    dim3 blk(256);
    // --- time MLP first (partials use xcv region, dead until conv) ---
    gemm_skinny_nt<<<dim3(SEQ / 128, KSPLIT), blk, 0, stream>>>(td, m1w, partb, SEQ, SEQ);
    reduce_part_k<<<dim3((48 * SEQ + 255) / 256), blk, 0, stream>>>(partb, m1b, hid, SEQ, 1);
    gemm_skinny_nt<<<dim3(SEQ / 128, KSPLIT), blk, 0, stream>>>(hid, m2w, partb, SEQ, SEQ);
    reduce_part_k<<<dim3((48 * SEQ + 255) / 256), blk, 0, stream>>>(partb, m2b, tss, SEQ, 0);
    time_conv_k<<<dim3(BB * NHH), blk, 0, stream>>>(tss, td, t1w, t1b, t2w, t2b, tdt);
    // --- in-proj ---
    cvt_bf16_k<<<dim3((MR * DMODEL / 4 + 255) / 256), blk, 0, stream>>>(u, u_bf, MR * DMODEL, MR * DMODEL);
    cvt_bf16_k<<<dim3((3456 * DMODEL / 4 + 255) / 256), blk, 0, stream>>>(W_in, Wi_bf, DPROJ * DMODEL, 3456 * DMODEL);
    gemm_mfma_nt<<<dim3((XSTR / 128) * (MR / 128)), blk, 0, stream>>>(
        u_bf, Wi_bf + (size_t)DSSM * DMODEL, b_in + DSSM, r1b, XSTR, DMODEL, DMODEL / 32, DPROJ - DSSM, 1, XSTR / 128);
    conv_xbc_k<<<dim3((448 * (MR / CT) + 255) / 256), blk, 0, stream>>>(r1b, conv_w, conv_b, xcv_bf);
    gemm_mfma_nt<<<dim3((DSSM / 128) * (MR / 128)), blk, 0, stream>>>(
        u_bf, Wi_bf, b_in, zbf, DSSM, DMODEL, DMODEL / 32, DSSM, 1, DSSM / 128);
    dtsp_k<<<dim3((MR * NHH + 255) / 256), blk, 0, stream>>>(r1b, tdt, dt_bias, dtp);
    // --- SSD ---
    ssd_sraw_k<<<dim3(BB * NC), dim3(512), 0, stream>>>(xcv_bf, sraw);
    ssd_states_mfma_k<<<dim3(BB * NC * NHH), blk, 0, stream>>>(xcv_bf, dtp, A_log, stb, alb);
    ssd_scan_k<<<dim3(BB * NHH), blk, 0, stream>>>(stb, alb, pv16);
    ssd_y2_k<<<dim3(BB * NC * NHH * 2), blk, 0, stream>>>(xcv_bf, dtp, A_log, sraw, pv16, Dpv, ybf16);
    // --- epilogue ---
    rmsnorm_k<<<dim3(MR), blk, 0, stream>>>(ybf16, zbf, nw, Y_bf);
    cvt_bf16_k<<<dim3((DMODEL * DSSM / 4 + 255) / 256), blk, 0, stream>>>(W_out, Wo_bf, DMODEL * DSSM, DMODEL * DSSM);
    gemm_mfma_nt<<<dim3((DMODEL / 128) * (MR / 128)), blk, 0, stream>>>(
        Y_bf, Wo_bf, b_out, out, DMODEL, DSSM, DSSM / 32, DMODEL, 0, DMODEL / 128);
    timeout_k<<<dim3(BB * NHH), blk, 0, stream>>>(td, tdt, gw, gb, lnw, lnb, out2);
}